// Round 6
// baseline (1062.050 us; speedup 1.0000x reference)
//
#include <hip/hip_runtime.h>
#include <hip/hip_fp16.h>

#define N_HITS 30000
#define N_EDGES 90000
#define N_SPS 30000
#define HD 128
#define NCLS 5

#define PADM 136  // 128 + 8 bf16 pad

typedef __attribute__((ext_vector_type(8))) __bf16 bf16x8;
typedef __attribute__((ext_vector_type(4))) float floatx4;

__device__ __forceinline__ void pk_add_f16(__half* addr, float a, float b) {
    unsafeAtomicAdd((__half2*)addr, __halves2half2(__float2half(a), __float2half(b)));
}

__device__ __forceinline__ uint4 cvt8_bf16(float4 a, float4 b) {
    union { __bf16 h[8]; uint4 u; } x;
    x.h[0] = (__bf16)a.x; x.h[1] = (__bf16)a.y; x.h[2] = (__bf16)a.z; x.h[3] = (__bf16)a.w;
    x.h[4] = (__bf16)b.x; x.h[5] = (__bf16)b.y; x.h[6] = (__bf16)b.z; x.h[7] = (__bf16)b.w;
    return x.u;
}

__device__ __forceinline__ uint4 cvt8_h2b(uint4 raw) {
    union { uint4 u; __half h[8]; } in; in.u = raw;
    union { __bf16 b[8]; uint4 u; } out;
#pragma unroll
    for (int k = 0; k < 8; ++k) out.b[k] = (__bf16)__half2float(in.h[k]);
    return out.u;
}

// ---------------- encoder: h = relu(x @ W_enc + b_enc) ----------------
__global__ void enc_kernel(const float* __restrict__ xu, const float* __restrict__ xv,
                           const float* __restrict__ xy, const float* __restrict__ W,
                           const float* __restrict__ b, float* __restrict__ h) {
    int gid = blockIdx.x * blockDim.x + threadIdx.x;
    if (gid >= 3 * N_HITS * HD) return;
    int j = gid & (HD - 1);
    int n = (gid >> 7) % N_HITS;
    int p = gid / (N_HITS * HD);
    const float* x = (p == 0) ? xu : (p == 1) ? xv : xy;
    float acc = b[j];
#pragma unroll
    for (int k = 0; k < 4; ++k) acc = fmaf(x[n * 4 + k], W[k * HD + j], acc);
    h[gid] = fmaxf(acc, 0.f);
}

// ---------------- merged histograms ----------------
__global__ void hist_all_kernel(const int* __restrict__ eu, const int* __restrict__ ev,
                                const int* __restrict__ ey, const int* __restrict__ nu,
                                const int* __restrict__ nv, const int* __restrict__ ny,
                                int* __restrict__ cnt) {
    int gid = blockIdx.x * blockDim.x + threadIdx.x;
    if (gid >= 450000) return;
    int p = gid / 150000;
    int r = gid - p * 150000;
    const int* e = (p == 0) ? eu : (p == 1) ? ev : ey;
    const int* nx = (p == 0) ? nu : (p == 1) ? nv : ny;
    if (r < N_EDGES) {
        atomicAdd(&cnt[p * N_HITS + e[N_EDGES + r]], 1);
    } else if (r < N_EDGES + N_SPS) {
        int i = r - N_EDGES;
        atomicAdd(&cnt[90000 + p * N_SPS + nx[N_SPS + i]], 1);
    } else {
        int i = r - N_EDGES - N_SPS;
        atomicAdd(&cnt[180000 + p * N_HITS + nx[i]], 1);
    }
}

__global__ void inv_kernel(const int* __restrict__ cnt, float* __restrict__ inv, int n) {
    int i = blockIdx.x * blockDim.x + threadIdx.x;
    if (i < n) inv[i] = 1.0f / (float)(cnt[i] > 1 ? cnt[i] : 1);
}

// ---------------- weight pre-pack ----------------
__device__ __forceinline__ void pack4(const float* __restrict__ W, __bf16* __restrict__ P,
                                      int idx, int koff) {
    int j = idx & 7, lane = (idx >> 3) & 63, ks = (idx >> 9) & 3, n = (idx >> 11) & 7;
    int k = ks * 32 + (lane >> 4) * 8 + j, col = n * 16 + (lane & 15);
    P[idx] = (__bf16)W[(k + koff) * 128 + col];
}
__device__ __forceinline__ void pack8(const float* __restrict__ W, __bf16* __restrict__ P, int idx) {
    int j = idx & 7, lane = (idx >> 3) & 63, ks = (idx >> 9) & 7, n = (idx >> 12) & 7;
    int k = ks * 32 + (lane >> 4) * 8 + j, col = n * 16 + (lane & 15);
    P[idx] = (__bf16)W[k * 128 + col];
}

__global__ void wprep_kernel(const float* __restrict__ W1, const float* __restrict__ W2,
                             const float* __restrict__ Wu, const float* __restrict__ Wn,
                             const float* __restrict__ Wsp, __bf16* __restrict__ packs) {
    int gid = blockIdx.x * blockDim.x + threadIdx.x;
    if (gid < 16384) { pack4(W1, packs, gid, 0); return; }            // W1d
    gid -= 16384;
    if (gid < 16384) { pack4(W1, packs + 16384, gid, 128); return; }  // W1s
    gid -= 16384;
    if (gid < 16384) { pack4(W2, packs + 32768, gid, 0); return; }    // W2
    gid -= 16384;
    if (gid < 32768) { pack8(Wu, packs + 49152, gid); return; }       // W_upd
    gid -= 32768;
    if (gid < 32768) { pack8(Wn, packs + 81920, gid); return; }       // W_nx
    gid -= 32768;
    if (gid < 16384) { pack4(Wsp, packs + 114688, gid, 0); }          // W_sp
}

// ---------------- y_init: y_d = h@W1d, y_s = h@W1s (bf16 A from fp32 h), f16 out ----------------
__launch_bounds__(256, 4)
__global__ void y_init_kernel(const float* __restrict__ h, const __bf16* __restrict__ W1dP,
                              const __bf16* __restrict__ W1sP, __half* __restrict__ y_d,
                              __half* __restrict__ y_s) {
    __shared__ __bf16 sA[128 * PADM];
    int t = threadIdx.x;
    int n0b = blockIdx.x * 128;
    const int M = 3 * N_HITS;
    for (int i = t; i < 2048; i += 256) {
        int row = i >> 4, c = i & 15;
        int n = n0b + row; if (n >= M) n = M - 1;
        const float4* src = (const float4*)(h + (size_t)n * HD + c * 8);
        *(uint4*)&sA[row * PADM + c * 8] = cvt8_bf16(src[0], src[1]);
    }
    __syncthreads();

    int lane = t & 63, wave = t >> 6;
    int lcol = lane & 15, quad = lane >> 4;
    int nt0 = wave * 2;
    bool odd = (lcol & 1) != 0;

    for (int half = 0; half < 2; ++half) {
        const bf16x8* wp = (const bf16x8*)(half == 0 ? W1dP : W1sP);
        __half* out = half == 0 ? y_d : y_s;
        bf16x8 B[2][4];
#pragma unroll
        for (int nt = 0; nt < 2; ++nt)
#pragma unroll
            for (int ks = 0; ks < 4; ++ks)
                B[nt][ks] = wp[((nt0 + nt) * 4 + ks) * 64 + lane];
        floatx4 acc[8][2];
#pragma unroll
        for (int mt = 0; mt < 8; ++mt) { acc[mt][0] = (floatx4){0,0,0,0}; acc[mt][1] = (floatx4){0,0,0,0}; }
#pragma unroll
        for (int mt = 0; mt < 8; ++mt)
#pragma unroll
            for (int ks = 0; ks < 4; ++ks) {
                bf16x8 a = *(const bf16x8*)&sA[(mt * 16 + lcol) * PADM + ks * 32 + quad * 8];
                acc[mt][0] = __builtin_amdgcn_mfma_f32_16x16x32_bf16(a, B[0][ks], acc[mt][0], 0, 0, 0);
                acc[mt][1] = __builtin_amdgcn_mfma_f32_16x16x32_bf16(a, B[1][ks], acc[mt][1], 0, 0, 0);
            }
#pragma unroll
        for (int mt = 0; mt < 8; ++mt)
#pragma unroll
            for (int r = 0; r < 4; ++r) {
                int m = n0b + mt * 16 + quad * 4 + r;
                float v0 = acc[mt][0][r], v1 = acc[mt][1][r];
                float p0 = __shfl_xor(v0, 1), p1 = __shfl_xor(v1, 1);
                float av = odd ? p1 : v0, bv = odd ? v1 : p0;
                int col = nt0 * 16 + (odd ? 15 + lcol : lcol);
                if (m < M)
                    *(__half2*)&out[(size_t)m * HD + col] =
                        __halves2half2(__float2half(av), __float2half(bv));
            }
    }
}

// ---------------- edge kernel: A = relu(y_d[dst]+y_s[src]+b1) -> @W2 -> atomic scatter ----------------
__launch_bounds__(256, 4)
__global__ void edge_mfma_kernel(const __half* __restrict__ y_d, const __half* __restrict__ y_s,
                                 const int* __restrict__ eu, const int* __restrict__ ev,
                                 const int* __restrict__ ey, const float* __restrict__ b1,
                                 const __bf16* __restrict__ W2P, const float* __restrict__ b2,
                                 const float* __restrict__ invd, __half* __restrict__ agg) {
    int p = blockIdx.y;
    const int* e = (p == 0) ? eu : (p == 1) ? ev : ey;
    const __half* ydp = y_d + (size_t)p * N_HITS * HD;
    const __half* ysp = y_s + (size_t)p * N_HITS * HD;
    __half* aggp = agg + (size_t)p * N_HITS * HD;
    const float* invp = invd + p * N_HITS;

    __shared__ __bf16 sA[128 * PADM];
    __shared__ int sDst[128];
    __shared__ float sInv[128];

    int t = threadIdx.x;
    int e0 = blockIdx.x * 128;
    if (t < 128) {
        int ei = e0 + t;
        int d = 0; float iv = 0.f;
        if (ei < N_EDGES) { d = e[N_EDGES + ei]; iv = invp[d]; }
        sDst[t] = d; sInv[t] = iv;
    }
    // stage A = relu(y_d[dst] + y_s[src] + b1), reading edge indices directly (L1-cached)
    for (int i = t; i < 2048; i += 256) {
        int row = i >> 4, c = i & 15;
        int ei = e0 + row; if (ei >= N_EDGES) ei = N_EDGES - 1;
        int src = e[ei], dst = e[N_EDGES + ei];
        union { uint4 u; __half hh[8]; } da, sa;
        da.u = ((const uint4*)(ydp + (size_t)dst * HD))[c];
        sa.u = ((const uint4*)(ysp + (size_t)src * HD))[c];
        float4 b1a = *(const float4*)(b1 + c * 8);
        float4 b1b = *(const float4*)(b1 + c * 8 + 4);
        float bb[8] = {b1a.x, b1a.y, b1a.z, b1a.w, b1b.x, b1b.y, b1b.z, b1b.w};
        union { __bf16 o[8]; uint4 u; } out;
#pragma unroll
        for (int j = 0; j < 8; ++j)
            out.o[j] = (__bf16)fmaxf(__half2float(da.hh[j]) + __half2float(sa.hh[j]) + bb[j], 0.f);
        *(uint4*)&sA[row * PADM + c * 8] = out.u;
    }
    __syncthreads();

    int lane = t & 63, wave = t >> 6;
    int lcol = lane & 15, quad = lane >> 4;
    int nt0 = wave * 2;

    const bf16x8* w2p = (const bf16x8*)W2P;
    bf16x8 B2[2][4];
#pragma unroll
    for (int nt = 0; nt < 2; ++nt)
#pragma unroll
        for (int ks = 0; ks < 4; ++ks)
            B2[nt][ks] = w2p[((nt0 + nt) * 4 + ks) * 64 + lane];

    floatx4 acc[8][2];
#pragma unroll
    for (int nt = 0; nt < 2; ++nt) {
        float bv = b2[(nt0 + nt) * 16 + lcol];
#pragma unroll
        for (int mt = 0; mt < 8; ++mt) acc[mt][nt] = (floatx4){bv, bv, bv, bv};
    }
#pragma unroll
    for (int mt = 0; mt < 8; ++mt)
#pragma unroll
        for (int ks = 0; ks < 4; ++ks) {
            bf16x8 a = *(const bf16x8*)&sA[(mt * 16 + lcol) * PADM + ks * 32 + quad * 8];
            acc[mt][0] = __builtin_amdgcn_mfma_f32_16x16x32_bf16(a, B2[0][ks], acc[mt][0], 0, 0, 0);
            acc[mt][1] = __builtin_amdgcn_mfma_f32_16x16x32_bf16(a, B2[1][ks], acc[mt][1], 0, 0, 0);
        }

    bool odd = (lcol & 1) != 0;
#pragma unroll
    for (int mt = 0; mt < 8; ++mt)
#pragma unroll
        for (int r = 0; r < 4; ++r) {
            int row = mt * 16 + quad * 4 + r;
            float s = sInv[row];
            float v0 = acc[mt][0][r] * s;
            float v1 = acc[mt][1][r] * s;
            float p0 = __shfl_xor(v0, 1), p1 = __shfl_xor(v1, 1);
            float av = odd ? p1 : v0, bv = odd ? v1 : p0;
            int col = nt0 * 16 + (odd ? 15 + lcol : lcol);
            pk_add_f16(&aggp[(size_t)sDst[row] * HD + col], av, bv);
        }
}

// ---------------- node update (planar): h += relu([h|aux]@W+b) ----------------
__launch_bounds__(256, 4)
__global__ void update_mfma_kernel(float* __restrict__ h, const __half* __restrict__ aux,
                                   const __bf16* __restrict__ WP, const float* __restrict__ b) {
    int p = blockIdx.y;
    float* hp = h + (size_t)p * N_HITS * HD;
    const __half* ap = aux + (size_t)p * N_HITS * HD;

    __shared__ __bf16 sA[128 * PADM];
    int t = threadIdx.x;
    int n0b = blockIdx.x * 128;

    int lane = t & 63, wave = t >> 6;
    int lcol = lane & 15, quad = lane >> 4;
    int nt0 = wave * 2;

    const bf16x8* wp = (const bf16x8*)WP;
    floatx4 acc[8][2];
#pragma unroll
    for (int nt = 0; nt < 2; ++nt) {
        float bv = b[(nt0 + nt) * 16 + lcol];
#pragma unroll
        for (int mt = 0; mt < 8; ++mt) acc[mt][nt] = (floatx4){bv, bv, bv, bv};
    }

    // phase 1: h half (fp32 -> bf16)
    for (int i = t; i < 2048; i += 256) {
        int row = i >> 4, c = i & 15;
        int n = n0b + row; if (n >= N_HITS) n = N_HITS - 1;
        const float4* src = (const float4*)(hp + (size_t)n * HD + c * 8);
        *(uint4*)&sA[row * PADM + c * 8] = cvt8_bf16(src[0], src[1]);
    }
    __syncthreads();
    {
        bf16x8 B[2][4];
#pragma unroll
        for (int nt = 0; nt < 2; ++nt)
#pragma unroll
            for (int ks = 0; ks < 4; ++ks)
                B[nt][ks] = wp[((nt0 + nt) * 8 + ks) * 64 + lane];
#pragma unroll
        for (int mt = 0; mt < 8; ++mt)
#pragma unroll
            for (int ks = 0; ks < 4; ++ks) {
                bf16x8 a = *(const bf16x8*)&sA[(mt * 16 + lcol) * PADM + ks * 32 + quad * 8];
                acc[mt][0] = __builtin_amdgcn_mfma_f32_16x16x32_bf16(a, B[0][ks], acc[mt][0], 0, 0, 0);
                acc[mt][1] = __builtin_amdgcn_mfma_f32_16x16x32_bf16(a, B[1][ks], acc[mt][1], 0, 0, 0);
            }
    }
    __syncthreads();
    // phase 2: aux half (f16 -> bf16)
    for (int i = t; i < 2048; i += 256) {
        int row = i >> 4, c = i & 15;
        int n = n0b + row; if (n >= N_HITS) n = N_HITS - 1;
        uint4 raw = ((const uint4*)(ap + (size_t)n * HD))[c];
        *(uint4*)&sA[row * PADM + c * 8] = cvt8_h2b(raw);
    }
    __syncthreads();
    {
        bf16x8 B[2][4];
#pragma unroll
        for (int nt = 0; nt < 2; ++nt)
#pragma unroll
            for (int ks = 0; ks < 4; ++ks)
                B[nt][ks] = wp[((nt0 + nt) * 8 + 4 + ks) * 64 + lane];
#pragma unroll
        for (int mt = 0; mt < 8; ++mt)
#pragma unroll
            for (int ks = 0; ks < 4; ++ks) {
                bf16x8 a = *(const bf16x8*)&sA[(mt * 16 + lcol) * PADM + ks * 32 + quad * 8];
                acc[mt][0] = __builtin_amdgcn_mfma_f32_16x16x32_bf16(a, B[0][ks], acc[mt][0], 0, 0, 0);
                acc[mt][1] = __builtin_amdgcn_mfma_f32_16x16x32_bf16(a, B[1][ks], acc[mt][1], 0, 0, 0);
            }
    }
#pragma unroll
    for (int mt = 0; mt < 8; ++mt)
#pragma unroll
        for (int nt = 0; nt < 2; ++nt)
#pragma unroll
            for (int r = 0; r < 4; ++r) {
                int m = n0b + mt * 16 + quad * 4 + r;
                if (m < N_HITS) {
                    size_t o = (size_t)m * HD + (nt0 + nt) * 16 + lcol;
                    hp[o] += fmaxf(acc[mt][nt][r], 0.f);
                }
            }
}

// ---------------- nexus update + fused y_d/y_s emission ----------------
__launch_bounds__(256, 4)
__global__ void update_y_kernel(float* __restrict__ h, const __half* __restrict__ aux,
                                const __bf16* __restrict__ WP, const float* __restrict__ b,
                                const __bf16* __restrict__ W1dP, const __bf16* __restrict__ W1sP,
                                __half* __restrict__ y_d, __half* __restrict__ y_s) {
    int p = blockIdx.y;
    float* hp = h + (size_t)p * N_HITS * HD;
    const __half* ap = aux + (size_t)p * N_HITS * HD;
    __half* ydp = y_d + (size_t)p * N_HITS * HD;
    __half* ysp = y_s + (size_t)p * N_HITS * HD;

    __shared__ __bf16 sA[128 * PADM];
    int t = threadIdx.x;
    int n0b = blockIdx.x * 128;

    int lane = t & 63, wave = t >> 6;
    int lcol = lane & 15, quad = lane >> 4;
    int nt0 = wave * 2;
    bool odd = (lcol & 1) != 0;

    const bf16x8* wp = (const bf16x8*)WP;
    floatx4 acc[8][2];
#pragma unroll
    for (int nt = 0; nt < 2; ++nt) {
        float bv = b[(nt0 + nt) * 16 + lcol];
#pragma unroll
        for (int mt = 0; mt < 8; ++mt) acc[mt][nt] = (floatx4){bv, bv, bv, bv};
    }

    for (int i = t; i < 2048; i += 256) {
        int row = i >> 4, c = i & 15;
        int n = n0b + row; if (n >= N_HITS) n = N_HITS - 1;
        const float4* src = (const float4*)(hp + (size_t)n * HD + c * 8);
        *(uint4*)&sA[row * PADM + c * 8] = cvt8_bf16(src[0], src[1]);
    }
    __syncthreads();
    {
        bf16x8 B[2][4];
#pragma unroll
        for (int nt = 0; nt < 2; ++nt)
#pragma unroll
            for (int ks = 0; ks < 4; ++ks)
                B[nt][ks] = wp[((nt0 + nt) * 8 + ks) * 64 + lane];
#pragma unroll
        for (int mt = 0; mt < 8; ++mt)
#pragma unroll
            for (int ks = 0; ks < 4; ++ks) {
                bf16x8 a = *(const bf16x8*)&sA[(mt * 16 + lcol) * PADM + ks * 32 + quad * 8];
                acc[mt][0] = __builtin_amdgcn_mfma_f32_16x16x32_bf16(a, B[0][ks], acc[mt][0], 0, 0, 0);
                acc[mt][1] = __builtin_amdgcn_mfma_f32_16x16x32_bf16(a, B[1][ks], acc[mt][1], 0, 0, 0);
            }
    }
    __syncthreads();
    for (int i = t; i < 2048; i += 256) {
        int row = i >> 4, c = i & 15;
        int n = n0b + row; if (n >= N_HITS) n = N_HITS - 1;
        uint4 raw = ((const uint4*)(ap + (size_t)n * HD))[c];
        *(uint4*)&sA[row * PADM + c * 8] = cvt8_h2b(raw);
    }
    __syncthreads();
    {
        bf16x8 B[2][4];
#pragma unroll
        for (int nt = 0; nt < 2; ++nt)
#pragma unroll
            for (int ks = 0; ks < 4; ++ks)
                B[nt][ks] = wp[((nt0 + nt) * 8 + 4 + ks) * 64 + lane];
#pragma unroll
        for (int mt = 0; mt < 8; ++mt)
#pragma unroll
            for (int ks = 0; ks < 4; ++ks) {
                bf16x8 a = *(const bf16x8*)&sA[(mt * 16 + lcol) * PADM + ks * 32 + quad * 8];
                acc[mt][0] = __builtin_amdgcn_mfma_f32_16x16x32_bf16(a, B[0][ks], acc[mt][0], 0, 0, 0);
                acc[mt][1] = __builtin_amdgcn_mfma_f32_16x16x32_bf16(a, B[1][ks], acc[mt][1], 0, 0, 0);
            }
    }
    __syncthreads();  // all reads of aux tile done; overwrite with h_new (bf16)

    // epilogue: h_new = h_old + relu(acc); write fp32 h + bf16 tile to LDS
#pragma unroll
    for (int mt = 0; mt < 8; ++mt)
#pragma unroll
        for (int nt = 0; nt < 2; ++nt)
#pragma unroll
            for (int r = 0; r < 4; ++r) {
                int row = mt * 16 + quad * 4 + r;
                int m = n0b + row;
                float nv;
                if (m < N_HITS) {
                    size_t o = (size_t)m * HD + (nt0 + nt) * 16 + lcol;
                    nv = hp[o] + fmaxf(acc[mt][nt][r], 0.f);
                    hp[o] = nv;
                } else nv = 0.f;
                sA[row * PADM + (nt0 + nt) * 16 + lcol] = (__bf16)nv;
            }
    __syncthreads();

    // y GEMMs: y_d = h_new @ W1d, y_s = h_new @ W1s (f16 out)
    for (int half = 0; half < 2; ++half) {
        const bf16x8* wyp = (const bf16x8*)(half == 0 ? W1dP : W1sP);
        __half* out = half == 0 ? ydp : ysp;
        bf16x8 B[2][4];
#pragma unroll
        for (int nt = 0; nt < 2; ++nt)
#pragma unroll
            for (int ks = 0; ks < 4; ++ks)
                B[nt][ks] = wyp[((nt0 + nt) * 4 + ks) * 64 + lane];
        floatx4 yacc[8][2];
#pragma unroll
        for (int mt = 0; mt < 8; ++mt) { yacc[mt][0] = (floatx4){0,0,0,0}; yacc[mt][1] = (floatx4){0,0,0,0}; }
#pragma unroll
        for (int mt = 0; mt < 8; ++mt)
#pragma unroll
            for (int ks = 0; ks < 4; ++ks) {
                bf16x8 a = *(const bf16x8*)&sA[(mt * 16 + lcol) * PADM + ks * 32 + quad * 8];
                yacc[mt][0] = __builtin_amdgcn_mfma_f32_16x16x32_bf16(a, B[0][ks], yacc[mt][0], 0, 0, 0);
                yacc[mt][1] = __builtin_amdgcn_mfma_f32_16x16x32_bf16(a, B[1][ks], yacc[mt][1], 0, 0, 0);
            }
#pragma unroll
        for (int mt = 0; mt < 8; ++mt)
#pragma unroll
            for (int r = 0; r < 4; ++r) {
                int m = n0b + mt * 16 + quad * 4 + r;
                float v0 = yacc[mt][0][r], v1 = yacc[mt][1][r];
                float p0 = __shfl_xor(v0, 1), p1 = __shfl_xor(v1, 1);
                float av = odd ? p1 : v0, bv = odd ? v1 : p0;
                int col = nt0 * 16 + (odd ? 15 + lcol : lcol);
                if (m < N_HITS)
                    *(__half2*)&out[(size_t)m * HD + col] =
                        __halves2half2(__float2half(av), __float2half(bv));
            }
    }
}

// ---------------- nexus scatter: sp[spid] += h[hit]*inv ----------------
__global__ void nx_scatter_kernel(const float* __restrict__ h, const int* __restrict__ nu,
                                  const int* __restrict__ nv, const int* __restrict__ ny,
                                  const float* __restrict__ invsp, __half* __restrict__ sp) {
    int gt = blockIdx.x * blockDim.x + threadIdx.x;
    int wid = gt >> 6;
    int lane = gt & 63;
    if (wid >= 3 * N_SPS) return;
    int p = wid / N_SPS;
    int i = wid - p * N_SPS;
    const int* nx = (p == 0) ? nu : (p == 1) ? nv : ny;
    int hit = nx[i];
    int spid = nx[N_SPS + i];
    float s = invsp[p * N_SPS + spid];
    const float* hrow = h + (size_t)(p * N_HITS + hit) * HD;
    __half* srow = sp + (size_t)spid * HD;
    float2 hv = *(const float2*)(hrow + 2 * lane);
    pk_add_f16(&srow[2 * lane], hv.x * s, hv.y * s);
}

// ---------------- sp = relu(sp @ W_sp + b_sp) (MFMA, f16 in/out) ----------------
__launch_bounds__(256, 4)
__global__ void sp_gemm_kernel(__half* __restrict__ spf, const __bf16* __restrict__ WspP,
                               const float* __restrict__ b) {
    __shared__ __bf16 sA[128 * PADM];
    int t = threadIdx.x;
    int n0b = blockIdx.x * 128;
    for (int i = t; i < 2048; i += 256) {
        int row = i >> 4, c = i & 15;
        int n = n0b + row; if (n >= N_SPS) n = N_SPS - 1;
        uint4 raw = ((const uint4*)(spf + (size_t)n * HD))[c];
        *(uint4*)&sA[row * PADM + c * 8] = cvt8_h2b(raw);
    }
    __syncthreads();

    int lane = t & 63, wave = t >> 6;
    int lcol = lane & 15, quad = lane >> 4;
    int nt0 = wave * 2;
    bool odd = (lcol & 1) != 0;

    const bf16x8* wp = (const bf16x8*)WspP;
    bf16x8 B[2][4];
#pragma unroll
    for (int nt = 0; nt < 2; ++nt)
#pragma unroll
        for (int ks = 0; ks < 4; ++ks)
            B[nt][ks] = wp[((nt0 + nt) * 4 + ks) * 64 + lane];

    floatx4 acc[8][2];
#pragma unroll
    for (int nt = 0; nt < 2; ++nt) {
        float bv = b[(nt0 + nt) * 16 + lcol];
#pragma unroll
        for (int mt = 0; mt < 8; ++mt) acc[mt][nt] = (floatx4){bv, bv, bv, bv};
    }
#pragma unroll
    for (int mt = 0; mt < 8; ++mt)
#pragma unroll
        for (int ks = 0; ks < 4; ++ks) {
            bf16x8 a = *(const bf16x8*)&sA[(mt * 16 + lcol) * PADM + ks * 32 + quad * 8];
            acc[mt][0] = __builtin_amdgcn_mfma_f32_16x16x32_bf16(a, B[0][ks], acc[mt][0], 0, 0, 0);
            acc[mt][1] = __builtin_amdgcn_mfma_f32_16x16x32_bf16(a, B[1][ks], acc[mt][1], 0, 0, 0);
        }
#pragma unroll
    for (int mt = 0; mt < 8; ++mt)
#pragma unroll
        for (int r = 0; r < 4; ++r) {
            int m = n0b + mt * 16 + quad * 4 + r;
            float v0 = fmaxf(acc[mt][0][r], 0.f), v1 = fmaxf(acc[mt][1][r], 0.f);
            float p0 = __shfl_xor(v0, 1), p1 = __shfl_xor(v1, 1);
            float av = odd ? p1 : v0, bv = odd ? v1 : p0;
            int col = nt0 * 16 + (odd ? 15 + lcol : lcol);
            if (m < N_SPS)
                *(__half2*)&spf[(size_t)m * HD + col] =
                    __halves2half2(__float2half(av), __float2half(bv));
        }
}

// ---------------- back scatter: back[hit] += sp[spid]*inv ----------------
__global__ void back_scatter_kernel(const __half* __restrict__ sp, const int* __restrict__ nu,
                                    const int* __restrict__ nv, const int* __restrict__ ny,
                                    const float* __restrict__ invhit, __half* __restrict__ back) {
    int gt = blockIdx.x * blockDim.x + threadIdx.x;
    int wid = gt >> 6;
    int lane = gt & 63;
    if (wid >= 3 * N_SPS) return;
    int p = wid / N_SPS;
    int i = wid - p * N_SPS;
    const int* nx = (p == 0) ? nu : (p == 1) ? nv : ny;
    int hit = nx[i];
    int spid = nx[N_SPS + i];
    float s = invhit[p * N_HITS + hit];
    const __half* srow = sp + (size_t)spid * HD;
    __half* brow = back + (size_t)(p * N_HITS + hit) * HD;
    float2 f = __half22float2(*(const __half2*)&srow[2 * lane]);
    pk_add_f16(&brow[2 * lane], f.x * s, f.y * s);
}

// ---------------- decoder: one thread per node, h row read once ----------------
__global__ void dec_kernel(const float* __restrict__ h, const float* __restrict__ W,
                           const float* __restrict__ b, float* __restrict__ out) {
    __shared__ float sW[640];
    __shared__ float sB[8];
    int t = threadIdx.x;
    for (int i = t; i < 640; i += 256) sW[i] = W[i];
    if (t < 5) sB[t] = b[t];
    __syncthreads();
    int n = blockIdx.x * 256 + t;
    if (n >= 3 * N_HITS) return;
    const float4* hr = (const float4*)(h + (size_t)n * HD);
    float a0 = sB[0], a1 = sB[1], a2 = sB[2], a3 = sB[3], a4 = sB[4];
#pragma unroll 8
    for (int q = 0; q < 32; ++q) {
        float4 v = hr[q];
        const float* w = &sW[q * 20];
        a0 = fmaf(v.x, w[0], a0); a1 = fmaf(v.x, w[1], a1); a2 = fmaf(v.x, w[2], a2);
        a3 = fmaf(v.x, w[3], a3); a4 = fmaf(v.x, w[4], a4);
        a0 = fmaf(v.y, w[5], a0); a1 = fmaf(v.y, w[6], a1); a2 = fmaf(v.y, w[7], a2);
        a3 = fmaf(v.y, w[8], a3); a4 = fmaf(v.y, w[9], a4);
        a0 = fmaf(v.z, w[10], a0); a1 = fmaf(v.z, w[11], a1); a2 = fmaf(v.z, w[12], a2);
        a3 = fmaf(v.z, w[13], a3); a4 = fmaf(v.z, w[14], a4);
        a0 = fmaf(v.w, w[15], a0); a1 = fmaf(v.w, w[16], a1); a2 = fmaf(v.w, w[17], a2);
        a3 = fmaf(v.w, w[18], a3); a4 = fmaf(v.w, w[19], a4);
    }
    float* o = out + (size_t)n * NCLS;
    o[0] = a0; o[1] = a1; o[2] = a2; o[3] = a3; o[4] = a4;
}

extern "C" void kernel_launch(void* const* d_in, const int* in_sizes, int n_in,
                              void* d_out, int out_size, void* d_ws, size_t ws_size,
                              hipStream_t stream) {
    const float* xu = (const float*)d_in[0];
    const int* eu = (const int*)d_in[1];
    const int* nu = (const int*)d_in[2];
    const float* xv = (const float*)d_in[3];
    const int* ev = (const int*)d_in[4];
    const int* nv = (const int*)d_in[5];
    const float* xy = (const float*)d_in[6];
    const int* ey = (const int*)d_in[7];
    const int* ny = (const int*)d_in[8];
    const float* W_enc = (const float*)d_in[9];
    const float* b_enc = (const float*)d_in[10];
    const float* W1 = (const float*)d_in[11];
    const float* b1 = (const float*)d_in[12];
    const float* W2 = (const float*)d_in[13];
    const float* b2 = (const float*)d_in[14];
    const float* W_upd = (const float*)d_in[15];
    const float* b_upd = (const float*)d_in[16];
    const float* W_sp = (const float*)d_in[17];
    const float* b_sp = (const float*)d_in[18];
    const float* W_nx = (const float*)d_in[19];
    const float* b_nx = (const float*)d_in[20];
    const float* W_sem = (const float*)d_in[21];
    const float* b_sem = (const float*)d_in[22];

    const size_t HN = (size_t)3 * N_HITS * HD;  // 11,520,000
    float* ws = (float*)d_ws;
    float* h = ws;                               // fp32 [3][N_HITS][HD]
    __half* agg = (__half*)(h + HN);             // f16 [3][N_HITS][HD]
    __half* sp = agg + HN;                       // f16 [N_SPS][HD]
    __half* y_d = sp + (size_t)N_SPS * HD;       // f16 [3][N_HITS][HD]
    __half* y_s = y_d + HN;                      // f16 [3][N_HITS][HD]
    float* inv = (float*)(y_s + HN);             // [270000]
    int* cnt = (int*)(inv + 270000);             // [270000]
    __bf16* packs = (__bf16*)(cnt + 270000);     // [131072]
    __bf16* W1dP = packs;
    __bf16* W1sP = packs + 16384;
    __bf16* W2P = packs + 32768;
    __bf16* WuP = packs + 49152;
    __bf16* WnP = packs + 81920;
    __bf16* WspP = packs + 114688;

    wprep_kernel<<<512, 256, 0, stream>>>(W1, W2, W_upd, W_nx, W_sp, packs);
    (void)hipMemsetAsync(cnt, 0, 270000 * sizeof(int), stream);
    hist_all_kernel<<<(450000 + 255) / 256, 256, 0, stream>>>(eu, ev, ey, nu, nv, ny, cnt);
    inv_kernel<<<(270000 + 255) / 256, 256, 0, stream>>>(cnt, inv, 270000);

    enc_kernel<<<(3 * N_HITS * HD + 255) / 256, 256, 0, stream>>>(xu, xv, xy, W_enc, b_enc, h);
    y_init_kernel<<<(3 * N_HITS + 127) / 128, 256, 0, stream>>>(h, W1dP, W1sP, y_d, y_s);

    for (int it = 0; it < 3; ++it) {
        (void)hipMemsetAsync(agg, 0, HN * sizeof(__half), stream);
        edge_mfma_kernel<<<dim3((N_EDGES + 127) / 128, 3), 256, 0, stream>>>(
            y_d, y_s, eu, ev, ey, b1, W2P, b2, inv, agg);
        update_mfma_kernel<<<dim3((N_HITS + 127) / 128, 3), 256, 0, stream>>>(h, agg, WuP, b_upd);
        (void)hipMemsetAsync(sp, 0, (size_t)N_SPS * HD * sizeof(__half), stream);
        nx_scatter_kernel<<<(3 * N_SPS * 64) / 256, 256, 0, stream>>>(h, nu, nv, ny, inv + 90000, sp);
        sp_gemm_kernel<<<(N_SPS + 127) / 128, 256, 0, stream>>>(sp, WspP, b_sp);
        (void)hipMemsetAsync(agg, 0, HN * sizeof(__half), stream);
        back_scatter_kernel<<<(3 * N_SPS * 64) / 256, 256, 0, stream>>>(sp, nu, nv, ny, inv + 180000, agg);
        update_y_kernel<<<dim3((N_HITS + 127) / 128, 3), 256, 0, stream>>>(
            h, agg, WnP, b_nx, W1dP, W1sP, y_d, y_s);
    }

    dec_kernel<<<(3 * N_HITS + 255) / 256, 256, 0, stream>>>(h, W_sem, b_sem, (float*)d_out);
}

// Round 7
// 940.295 us; speedup vs baseline: 1.1295x; 1.1295x over previous
//
#include <hip/hip_runtime.h>
#include <hip/hip_fp16.h>

#define N_HITS 30000
#define N_EDGES 90000
#define N_SPS 30000
#define HD 128
#define NCLS 5

#define PADM 136  // 128 + 8 bf16 pad

typedef __attribute__((ext_vector_type(8))) __bf16 bf16x8;
typedef __attribute__((ext_vector_type(4))) float floatx4;

__device__ __forceinline__ void pk_add_f16(__half* addr, float a, float b) {
    unsafeAtomicAdd((__half2*)addr, __halves2half2(__float2half(a), __float2half(b)));
}

__device__ __forceinline__ uint4 cvt8_h2b(uint4 raw) {
    union { uint4 u; __half h[8]; } in; in.u = raw;
    union { __bf16 b[8]; uint4 u; } out;
#pragma unroll
    for (int k = 0; k < 8; ++k) out.b[k] = (__bf16)__half2float(in.h[k]);
    return out.u;
}

// ---------------- encoder: h = relu(x @ W_enc + b_enc), f16 out ----------------
__global__ void enc_kernel(const float* __restrict__ xu, const float* __restrict__ xv,
                           const float* __restrict__ xy, const float* __restrict__ W,
                           const float* __restrict__ b, __half* __restrict__ h) {
    int gid = blockIdx.x * blockDim.x + threadIdx.x;
    if (gid >= 3 * N_HITS * HD) return;
    int j = gid & (HD - 1);
    int n = (gid >> 7) % N_HITS;
    int p = gid / (N_HITS * HD);
    const float* x = (p == 0) ? xu : (p == 1) ? xv : xy;
    float acc = b[j];
#pragma unroll
    for (int k = 0; k < 4; ++k) acc = fmaf(x[n * 4 + k], W[k * HD + j], acc);
    h[gid] = __float2half(fmaxf(acc, 0.f));
}

// ---------------- merged histograms ----------------
__global__ void hist_all_kernel(const int* __restrict__ eu, const int* __restrict__ ev,
                                const int* __restrict__ ey, const int* __restrict__ nu,
                                const int* __restrict__ nv, const int* __restrict__ ny,
                                int* __restrict__ cnt) {
    int gid = blockIdx.x * blockDim.x + threadIdx.x;
    if (gid >= 450000) return;
    int p = gid / 150000;
    int r = gid - p * 150000;
    const int* e = (p == 0) ? eu : (p == 1) ? ev : ey;
    const int* nx = (p == 0) ? nu : (p == 1) ? nv : ny;
    if (r < N_EDGES) {
        atomicAdd(&cnt[p * N_HITS + e[N_EDGES + r]], 1);
    } else if (r < N_EDGES + N_SPS) {
        int i = r - N_EDGES;
        atomicAdd(&cnt[90000 + p * N_SPS + nx[N_SPS + i]], 1);
    } else {
        int i = r - N_EDGES - N_SPS;
        atomicAdd(&cnt[180000 + p * N_HITS + nx[i]], 1);
    }
}

__global__ void inv_kernel(const int* __restrict__ cnt, float* __restrict__ inv, int n) {
    int i = blockIdx.x * blockDim.x + threadIdx.x;
    if (i < n) inv[i] = 1.0f / (float)(cnt[i] > 1 ? cnt[i] : 1);
}

// ---------------- weight pre-pack ----------------
__device__ __forceinline__ void pack4(const float* __restrict__ W, __bf16* __restrict__ P,
                                      int idx, int koff) {
    int j = idx & 7, lane = (idx >> 3) & 63, ks = (idx >> 9) & 3, n = (idx >> 11) & 7;
    int k = ks * 32 + (lane >> 4) * 8 + j, col = n * 16 + (lane & 15);
    P[idx] = (__bf16)W[(k + koff) * 128 + col];
}
__device__ __forceinline__ void pack8(const float* __restrict__ W, __bf16* __restrict__ P, int idx) {
    int j = idx & 7, lane = (idx >> 3) & 63, ks = (idx >> 9) & 7, n = (idx >> 12) & 7;
    int k = ks * 32 + (lane >> 4) * 8 + j, col = n * 16 + (lane & 15);
    P[idx] = (__bf16)W[k * 128 + col];
}

__global__ void wprep_kernel(const float* __restrict__ W1, const float* __restrict__ W2,
                             const float* __restrict__ Wu, const float* __restrict__ Wn,
                             const float* __restrict__ Wsp, __bf16* __restrict__ packs) {
    int gid = blockIdx.x * blockDim.x + threadIdx.x;
    if (gid < 16384) { pack4(W1, packs, gid, 0); return; }            // W1d
    gid -= 16384;
    if (gid < 16384) { pack4(W1, packs + 16384, gid, 128); return; }  // W1s
    gid -= 16384;
    if (gid < 16384) { pack4(W2, packs + 32768, gid, 0); return; }    // W2
    gid -= 16384;
    if (gid < 32768) { pack8(Wu, packs + 49152, gid); return; }       // W_upd
    gid -= 32768;
    if (gid < 32768) { pack8(Wn, packs + 81920, gid); return; }       // W_nx
    gid -= 32768;
    if (gid < 16384) { pack4(Wsp, packs + 114688, gid, 0); }          // W_sp
}

// ---------------- y_init: y_d = h@W1d, y_s = h@W1s ----------------
__launch_bounds__(256, 4)
__global__ void y_init_kernel(const __half* __restrict__ h, const __bf16* __restrict__ W1dP,
                              const __bf16* __restrict__ W1sP, __half* __restrict__ y_d,
                              __half* __restrict__ y_s) {
    __shared__ __bf16 sA[128 * PADM];
    int t = threadIdx.x;
    int n0b = blockIdx.x * 128;
    const int M = 3 * N_HITS;
    for (int i = t; i < 2048; i += 256) {
        int row = i >> 4, c = i & 15;
        int n = n0b + row; if (n >= M) n = M - 1;
        uint4 raw = ((const uint4*)(h + (size_t)n * HD))[c];
        *(uint4*)&sA[row * PADM + c * 8] = cvt8_h2b(raw);
    }
    __syncthreads();

    int lane = t & 63, wave = t >> 6;
    int lcol = lane & 15, quad = lane >> 4;
    int nt0 = wave * 2;
    bool odd = (lcol & 1) != 0;

    for (int half = 0; half < 2; ++half) {
        const bf16x8* wp = (const bf16x8*)(half == 0 ? W1dP : W1sP);
        __half* out = half == 0 ? y_d : y_s;
        bf16x8 B[2][4];
#pragma unroll
        for (int nt = 0; nt < 2; ++nt)
#pragma unroll
            for (int ks = 0; ks < 4; ++ks)
                B[nt][ks] = wp[((nt0 + nt) * 4 + ks) * 64 + lane];
        floatx4 acc[8][2];
#pragma unroll
        for (int mt = 0; mt < 8; ++mt) { acc[mt][0] = (floatx4){0,0,0,0}; acc[mt][1] = (floatx4){0,0,0,0}; }
#pragma unroll
        for (int mt = 0; mt < 8; ++mt)
#pragma unroll
            for (int ks = 0; ks < 4; ++ks) {
                bf16x8 a = *(const bf16x8*)&sA[(mt * 16 + lcol) * PADM + ks * 32 + quad * 8];
                acc[mt][0] = __builtin_amdgcn_mfma_f32_16x16x32_bf16(a, B[0][ks], acc[mt][0], 0, 0, 0);
                acc[mt][1] = __builtin_amdgcn_mfma_f32_16x16x32_bf16(a, B[1][ks], acc[mt][1], 0, 0, 0);
            }
#pragma unroll
        for (int mt = 0; mt < 8; ++mt)
#pragma unroll
            for (int r = 0; r < 4; ++r) {
                int m = n0b + mt * 16 + quad * 4 + r;
                float v0 = acc[mt][0][r], v1 = acc[mt][1][r];
                float p0 = __shfl_xor(v0, 1), p1 = __shfl_xor(v1, 1);
                float av = odd ? p1 : v0, bv = odd ? v1 : p0;
                int col = nt0 * 16 + (odd ? 15 + lcol : lcol);
                if (m < M)
                    *(__half2*)&out[(size_t)m * HD + col] =
                        __halves2half2(__float2half(av), __float2half(bv));
            }
    }
}

// ---------------- edge kernel: A = relu(y_d[dst]+y_s[src]+b1) -> @W2 -> atomic scatter ----------------
__launch_bounds__(256, 4)
__global__ void edge_mfma_kernel(const __half* __restrict__ y_d, const __half* __restrict__ y_s,
                                 const int* __restrict__ eu, const int* __restrict__ ev,
                                 const int* __restrict__ ey, const float* __restrict__ b1,
                                 const __bf16* __restrict__ W2P, const float* __restrict__ b2,
                                 const float* __restrict__ invd, __half* __restrict__ agg) {
    int p = blockIdx.y;
    const int* e = (p == 0) ? eu : (p == 1) ? ev : ey;
    const __half* ydp = y_d + (size_t)p * N_HITS * HD;
    const __half* ysp = y_s + (size_t)p * N_HITS * HD;
    __half* aggp = agg + (size_t)p * N_HITS * HD;
    const float* invp = invd + p * N_HITS;

    __shared__ __bf16 sA[128 * PADM];
    __shared__ int sDst[128];
    __shared__ float sInv[128];

    int t = threadIdx.x;
    int e0 = blockIdx.x * 128;
    if (t < 128) {
        int ei = e0 + t;
        int d = 0; float iv = 0.f;
        if (ei < N_EDGES) { d = e[N_EDGES + ei]; iv = invp[d]; }
        sDst[t] = d; sInv[t] = iv;
    }
    for (int i = t; i < 2048; i += 256) {
        int row = i >> 4, c = i & 15;
        int ei = e0 + row; if (ei >= N_EDGES) ei = N_EDGES - 1;
        int src = e[ei], dst = e[N_EDGES + ei];
        union { uint4 u; __half hh[8]; } da, sa;
        da.u = ((const uint4*)(ydp + (size_t)dst * HD))[c];
        sa.u = ((const uint4*)(ysp + (size_t)src * HD))[c];
        float4 b1a = *(const float4*)(b1 + c * 8);
        float4 b1b = *(const float4*)(b1 + c * 8 + 4);
        float bb[8] = {b1a.x, b1a.y, b1a.z, b1a.w, b1b.x, b1b.y, b1b.z, b1b.w};
        union { __bf16 o[8]; uint4 u; } out;
#pragma unroll
        for (int j = 0; j < 8; ++j)
            out.o[j] = (__bf16)fmaxf(__half2float(da.hh[j]) + __half2float(sa.hh[j]) + bb[j], 0.f);
        *(uint4*)&sA[row * PADM + c * 8] = out.u;
    }
    __syncthreads();

    int lane = t & 63, wave = t >> 6;
    int lcol = lane & 15, quad = lane >> 4;
    int nt0 = wave * 2;

    const bf16x8* w2p = (const bf16x8*)W2P;
    bf16x8 B2[2][4];
#pragma unroll
    for (int nt = 0; nt < 2; ++nt)
#pragma unroll
        for (int ks = 0; ks < 4; ++ks)
            B2[nt][ks] = w2p[((nt0 + nt) * 4 + ks) * 64 + lane];

    floatx4 acc[8][2];
#pragma unroll
    for (int nt = 0; nt < 2; ++nt) {
        float bv = b2[(nt0 + nt) * 16 + lcol];
#pragma unroll
        for (int mt = 0; mt < 8; ++mt) acc[mt][nt] = (floatx4){bv, bv, bv, bv};
    }
#pragma unroll
    for (int mt = 0; mt < 8; ++mt)
#pragma unroll
        for (int ks = 0; ks < 4; ++ks) {
            bf16x8 a = *(const bf16x8*)&sA[(mt * 16 + lcol) * PADM + ks * 32 + quad * 8];
            acc[mt][0] = __builtin_amdgcn_mfma_f32_16x16x32_bf16(a, B2[0][ks], acc[mt][0], 0, 0, 0);
            acc[mt][1] = __builtin_amdgcn_mfma_f32_16x16x32_bf16(a, B2[1][ks], acc[mt][1], 0, 0, 0);
        }

    bool odd = (lcol & 1) != 0;
#pragma unroll
    for (int mt = 0; mt < 8; ++mt)
#pragma unroll
        for (int r = 0; r < 4; ++r) {
            int row = mt * 16 + quad * 4 + r;
            float s = sInv[row];
            float v0 = acc[mt][0][r] * s;
            float v1 = acc[mt][1][r] * s;
            float p0 = __shfl_xor(v0, 1), p1 = __shfl_xor(v1, 1);
            float av = odd ? p1 : v0, bv = odd ? v1 : p0;
            int col = nt0 * 16 + (odd ? 15 + lcol : lcol);
            pk_add_f16(&aggp[(size_t)sDst[row] * HD + col], av, bv);
        }
}

// ---------------- node update (planar): h += relu([h|aux]@W+b), h is f16 ----------------
__launch_bounds__(256, 4)
__global__ void update_mfma_kernel(__half* __restrict__ h, const __half* __restrict__ aux,
                                   const __bf16* __restrict__ WP, const float* __restrict__ b) {
    int p = blockIdx.y;
    __half* hp = h + (size_t)p * N_HITS * HD;
    const __half* ap = aux + (size_t)p * N_HITS * HD;

    __shared__ __bf16 sA[128 * PADM];
    int t = threadIdx.x;
    int n0b = blockIdx.x * 128;

    int lane = t & 63, wave = t >> 6;
    int lcol = lane & 15, quad = lane >> 4;
    int nt0 = wave * 2;
    bool odd = (lcol & 1) != 0;

    const bf16x8* wp = (const bf16x8*)WP;
    floatx4 acc[8][2];
#pragma unroll
    for (int nt = 0; nt < 2; ++nt) {
        float bv = b[(nt0 + nt) * 16 + lcol];
#pragma unroll
        for (int mt = 0; mt < 8; ++mt) acc[mt][nt] = (floatx4){bv, bv, bv, bv};
    }

    // phase 1: h half (f16 -> bf16)
    for (int i = t; i < 2048; i += 256) {
        int row = i >> 4, c = i & 15;
        int n = n0b + row; if (n >= N_HITS) n = N_HITS - 1;
        uint4 raw = ((const uint4*)(hp + (size_t)n * HD))[c];
        *(uint4*)&sA[row * PADM + c * 8] = cvt8_h2b(raw);
    }
    __syncthreads();
    {
        bf16x8 B[2][4];
#pragma unroll
        for (int nt = 0; nt < 2; ++nt)
#pragma unroll
            for (int ks = 0; ks < 4; ++ks)
                B[nt][ks] = wp[((nt0 + nt) * 8 + ks) * 64 + lane];
#pragma unroll
        for (int mt = 0; mt < 8; ++mt)
#pragma unroll
            for (int ks = 0; ks < 4; ++ks) {
                bf16x8 a = *(const bf16x8*)&sA[(mt * 16 + lcol) * PADM + ks * 32 + quad * 8];
                acc[mt][0] = __builtin_amdgcn_mfma_f32_16x16x32_bf16(a, B[0][ks], acc[mt][0], 0, 0, 0);
                acc[mt][1] = __builtin_amdgcn_mfma_f32_16x16x32_bf16(a, B[1][ks], acc[mt][1], 0, 0, 0);
            }
    }
    __syncthreads();
    // phase 2: aux half (f16 -> bf16)
    for (int i = t; i < 2048; i += 256) {
        int row = i >> 4, c = i & 15;
        int n = n0b + row; if (n >= N_HITS) n = N_HITS - 1;
        uint4 raw = ((const uint4*)(ap + (size_t)n * HD))[c];
        *(uint4*)&sA[row * PADM + c * 8] = cvt8_h2b(raw);
    }
    __syncthreads();
    {
        bf16x8 B[2][4];
#pragma unroll
        for (int nt = 0; nt < 2; ++nt)
#pragma unroll
            for (int ks = 0; ks < 4; ++ks)
                B[nt][ks] = wp[((nt0 + nt) * 8 + 4 + ks) * 64 + lane];
#pragma unroll
        for (int mt = 0; mt < 8; ++mt)
#pragma unroll
            for (int ks = 0; ks < 4; ++ks) {
                bf16x8 a = *(const bf16x8*)&sA[(mt * 16 + lcol) * PADM + ks * 32 + quad * 8];
                acc[mt][0] = __builtin_amdgcn_mfma_f32_16x16x32_bf16(a, B[0][ks], acc[mt][0], 0, 0, 0);
                acc[mt][1] = __builtin_amdgcn_mfma_f32_16x16x32_bf16(a, B[1][ks], acc[mt][1], 0, 0, 0);
            }
    }
    // residual RMW on f16 h, paired columns (4B loads/stores)
#pragma unroll
    for (int mt = 0; mt < 8; ++mt)
#pragma unroll
        for (int r = 0; r < 4; ++r) {
            float v0 = fmaxf(acc[mt][0][r], 0.f), v1 = fmaxf(acc[mt][1][r], 0.f);
            float p0 = __shfl_xor(v0, 1), p1 = __shfl_xor(v1, 1);
            float av = odd ? p1 : v0, bv = odd ? v1 : p0;
            int col = nt0 * 16 + (odd ? 15 + lcol : lcol);
            int m = n0b + mt * 16 + quad * 4 + r;
            if (m < N_HITS) {
                __half2* hp2 = (__half2*)&hp[(size_t)m * HD + col];
                float2 ho = __half22float2(*hp2);
                *hp2 = __halves2half2(__float2half(ho.x + av), __float2half(ho.y + bv));
            }
        }
}

// ---------------- nexus update + fused y_d/y_s emission, h is f16 ----------------
__launch_bounds__(256, 4)
__global__ void update_y_kernel(__half* __restrict__ h, const __half* __restrict__ aux,
                                const __bf16* __restrict__ WP, const float* __restrict__ b,
                                const __bf16* __restrict__ W1dP, const __bf16* __restrict__ W1sP,
                                __half* __restrict__ y_d, __half* __restrict__ y_s) {
    int p = blockIdx.y;
    __half* hp = h + (size_t)p * N_HITS * HD;
    const __half* ap = aux + (size_t)p * N_HITS * HD;
    __half* ydp = y_d + (size_t)p * N_HITS * HD;
    __half* ysp = y_s + (size_t)p * N_HITS * HD;

    __shared__ __bf16 sA[128 * PADM];
    int t = threadIdx.x;
    int n0b = blockIdx.x * 128;

    int lane = t & 63, wave = t >> 6;
    int lcol = lane & 15, quad = lane >> 4;
    int nt0 = wave * 2;
    bool odd = (lcol & 1) != 0;

    const bf16x8* wp = (const bf16x8*)WP;
    floatx4 acc[8][2];
#pragma unroll
    for (int nt = 0; nt < 2; ++nt) {
        float bv = b[(nt0 + nt) * 16 + lcol];
#pragma unroll
        for (int mt = 0; mt < 8; ++mt) acc[mt][nt] = (floatx4){bv, bv, bv, bv};
    }

    for (int i = t; i < 2048; i += 256) {
        int row = i >> 4, c = i & 15;
        int n = n0b + row; if (n >= N_HITS) n = N_HITS - 1;
        uint4 raw = ((const uint4*)(hp + (size_t)n * HD))[c];
        *(uint4*)&sA[row * PADM + c * 8] = cvt8_h2b(raw);
    }
    __syncthreads();
    {
        bf16x8 B[2][4];
#pragma unroll
        for (int nt = 0; nt < 2; ++nt)
#pragma unroll
            for (int ks = 0; ks < 4; ++ks)
                B[nt][ks] = wp[((nt0 + nt) * 8 + ks) * 64 + lane];
#pragma unroll
        for (int mt = 0; mt < 8; ++mt)
#pragma unroll
            for (int ks = 0; ks < 4; ++ks) {
                bf16x8 a = *(const bf16x8*)&sA[(mt * 16 + lcol) * PADM + ks * 32 + quad * 8];
                acc[mt][0] = __builtin_amdgcn_mfma_f32_16x16x32_bf16(a, B[0][ks], acc[mt][0], 0, 0, 0);
                acc[mt][1] = __builtin_amdgcn_mfma_f32_16x16x32_bf16(a, B[1][ks], acc[mt][1], 0, 0, 0);
            }
    }
    __syncthreads();
    for (int i = t; i < 2048; i += 256) {
        int row = i >> 4, c = i & 15;
        int n = n0b + row; if (n >= N_HITS) n = N_HITS - 1;
        uint4 raw = ((const uint4*)(ap + (size_t)n * HD))[c];
        *(uint4*)&sA[row * PADM + c * 8] = cvt8_h2b(raw);
    }
    __syncthreads();
    {
        bf16x8 B[2][4];
#pragma unroll
        for (int nt = 0; nt < 2; ++nt)
#pragma unroll
            for (int ks = 0; ks < 4; ++ks)
                B[nt][ks] = wp[((nt0 + nt) * 8 + 4 + ks) * 64 + lane];
#pragma unroll
        for (int mt = 0; mt < 8; ++mt)
#pragma unroll
            for (int ks = 0; ks < 4; ++ks) {
                bf16x8 a = *(const bf16x8*)&sA[(mt * 16 + lcol) * PADM + ks * 32 + quad * 8];
                acc[mt][0] = __builtin_amdgcn_mfma_f32_16x16x32_bf16(a, B[0][ks], acc[mt][0], 0, 0, 0);
                acc[mt][1] = __builtin_amdgcn_mfma_f32_16x16x32_bf16(a, B[1][ks], acc[mt][1], 0, 0, 0);
            }
    }
    __syncthreads();  // aux tile reads done; overwrite with h_new bf16

    // epilogue: h_new = h_old + relu(acc); f16 RMW + bf16 tile to LDS (paired cols)
#pragma unroll
    for (int mt = 0; mt < 8; ++mt)
#pragma unroll
        for (int r = 0; r < 4; ++r) {
            float v0 = fmaxf(acc[mt][0][r], 0.f), v1 = fmaxf(acc[mt][1][r], 0.f);
            float p0 = __shfl_xor(v0, 1), p1 = __shfl_xor(v1, 1);
            float av = odd ? p1 : v0, bv = odd ? v1 : p0;
            int col = nt0 * 16 + (odd ? 15 + lcol : lcol);
            int row = mt * 16 + quad * 4 + r;
            int m = n0b + row;
            float n0v = 0.f, n1v = 0.f;
            if (m < N_HITS) {
                __half2* hp2 = (__half2*)&hp[(size_t)m * HD + col];
                float2 ho = __half22float2(*hp2);
                n0v = ho.x + av; n1v = ho.y + bv;
                *hp2 = __halves2half2(__float2half(n0v), __float2half(n1v));
            }
            union { __bf16 bb[2]; uint u; } w;
            w.bb[0] = (__bf16)n0v; w.bb[1] = (__bf16)n1v;
            *(uint*)&sA[row * PADM + col] = w.u;
        }
    __syncthreads();

    // y GEMMs: y_d = h_new @ W1d, y_s = h_new @ W1s
    for (int half = 0; half < 2; ++half) {
        const bf16x8* wyp = (const bf16x8*)(half == 0 ? W1dP : W1sP);
        __half* out = half == 0 ? ydp : ysp;
        bf16x8 B[2][4];
#pragma unroll
        for (int nt = 0; nt < 2; ++nt)
#pragma unroll
            for (int ks = 0; ks < 4; ++ks)
                B[nt][ks] = wyp[((nt0 + nt) * 4 + ks) * 64 + lane];
        floatx4 yacc[8][2];
#pragma unroll
        for (int mt = 0; mt < 8; ++mt) { yacc[mt][0] = (floatx4){0,0,0,0}; yacc[mt][1] = (floatx4){0,0,0,0}; }
#pragma unroll
        for (int mt = 0; mt < 8; ++mt)
#pragma unroll
            for (int ks = 0; ks < 4; ++ks) {
                bf16x8 a = *(const bf16x8*)&sA[(mt * 16 + lcol) * PADM + ks * 32 + quad * 8];
                yacc[mt][0] = __builtin_amdgcn_mfma_f32_16x16x32_bf16(a, B[0][ks], yacc[mt][0], 0, 0, 0);
                yacc[mt][1] = __builtin_amdgcn_mfma_f32_16x16x32_bf16(a, B[1][ks], yacc[mt][1], 0, 0, 0);
            }
#pragma unroll
        for (int mt = 0; mt < 8; ++mt)
#pragma unroll
            for (int r = 0; r < 4; ++r) {
                int m = n0b + mt * 16 + quad * 4 + r;
                float v0 = yacc[mt][0][r], v1 = yacc[mt][1][r];
                float p0 = __shfl_xor(v0, 1), p1 = __shfl_xor(v1, 1);
                float av = odd ? p1 : v0, bv = odd ? v1 : p0;
                int col = nt0 * 16 + (odd ? 15 + lcol : lcol);
                if (m < N_HITS)
                    *(__half2*)&out[(size_t)m * HD + col] =
                        __halves2half2(__float2half(av), __float2half(bv));
            }
    }
}

// ---------------- nexus scatter: sp[spid] += h[hit]*inv (h f16) ----------------
__global__ void nx_scatter_kernel(const __half* __restrict__ h, const int* __restrict__ nu,
                                  const int* __restrict__ nv, const int* __restrict__ ny,
                                  const float* __restrict__ invsp, __half* __restrict__ sp) {
    int gt = blockIdx.x * blockDim.x + threadIdx.x;
    int wid = gt >> 6;
    int lane = gt & 63;
    if (wid >= 3 * N_SPS) return;
    int p = wid / N_SPS;
    int i = wid - p * N_SPS;
    const int* nx = (p == 0) ? nu : (p == 1) ? nv : ny;
    int hit = nx[i];
    int spid = nx[N_SPS + i];
    float s = invsp[p * N_SPS + spid];
    const __half* hrow = h + (size_t)(p * N_HITS + hit) * HD;
    __half* srow = sp + (size_t)spid * HD;
    float2 hv = __half22float2(*(const __half2*)&hrow[2 * lane]);
    pk_add_f16(&srow[2 * lane], hv.x * s, hv.y * s);
}

// ---------------- sp = relu(sp @ W_sp + b_sp) (MFMA, f16 in/out) ----------------
__launch_bounds__(256, 4)
__global__ void sp_gemm_kernel(__half* __restrict__ spf, const __bf16* __restrict__ WspP,
                               const float* __restrict__ b) {
    __shared__ __bf16 sA[128 * PADM];
    int t = threadIdx.x;
    int n0b = blockIdx.x * 128;
    for (int i = t; i < 2048; i += 256) {
        int row = i >> 4, c = i & 15;
        int n = n0b + row; if (n >= N_SPS) n = N_SPS - 1;
        uint4 raw = ((const uint4*)(spf + (size_t)n * HD))[c];
        *(uint4*)&sA[row * PADM + c * 8] = cvt8_h2b(raw);
    }
    __syncthreads();

    int lane = t & 63, wave = t >> 6;
    int lcol = lane & 15, quad = lane >> 4;
    int nt0 = wave * 2;
    bool odd = (lcol & 1) != 0;

    const bf16x8* wp = (const bf16x8*)WspP;
    bf16x8 B[2][4];
#pragma unroll
    for (int nt = 0; nt < 2; ++nt)
#pragma unroll
        for (int ks = 0; ks < 4; ++ks)
            B[nt][ks] = wp[((nt0 + nt) * 4 + ks) * 64 + lane];

    floatx4 acc[8][2];
#pragma unroll
    for (int nt = 0; nt < 2; ++nt) {
        float bv = b[(nt0 + nt) * 16 + lcol];
#pragma unroll
        for (int mt = 0; mt < 8; ++mt) acc[mt][nt] = (floatx4){bv, bv, bv, bv};
    }
#pragma unroll
    for (int mt = 0; mt < 8; ++mt)
#pragma unroll
        for (int ks = 0; ks < 4; ++ks) {
            bf16x8 a = *(const bf16x8*)&sA[(mt * 16 + lcol) * PADM + ks * 32 + quad * 8];
            acc[mt][0] = __builtin_amdgcn_mfma_f32_16x16x32_bf16(a, B[0][ks], acc[mt][0], 0, 0, 0);
            acc[mt][1] = __builtin_amdgcn_mfma_f32_16x16x32_bf16(a, B[1][ks], acc[mt][1], 0, 0, 0);
        }
#pragma unroll
    for (int mt = 0; mt < 8; ++mt)
#pragma unroll
        for (int r = 0; r < 4; ++r) {
            int m = n0b + mt * 16 + quad * 4 + r;
            float v0 = fmaxf(acc[mt][0][r], 0.f), v1 = fmaxf(acc[mt][1][r], 0.f);
            float p0 = __shfl_xor(v0, 1), p1 = __shfl_xor(v1, 1);
            float av = odd ? p1 : v0, bv = odd ? v1 : p0;
            int col = nt0 * 16 + (odd ? 15 + lcol : lcol);
            if (m < N_SPS)
                *(__half2*)&spf[(size_t)m * HD + col] =
                    __halves2half2(__float2half(av), __float2half(bv));
        }
}

// ---------------- back scatter: back[hit] += sp[spid]*inv ----------------
__global__ void back_scatter_kernel(const __half* __restrict__ sp, const int* __restrict__ nu,
                                    const int* __restrict__ nv, const int* __restrict__ ny,
                                    const float* __restrict__ invhit, __half* __restrict__ back) {
    int gt = blockIdx.x * blockDim.x + threadIdx.x;
    int wid = gt >> 6;
    int lane = gt & 63;
    if (wid >= 3 * N_SPS) return;
    int p = wid / N_SPS;
    int i = wid - p * N_SPS;
    const int* nx = (p == 0) ? nu : (p == 1) ? nv : ny;
    int hit = nx[i];
    int spid = nx[N_SPS + i];
    float s = invhit[p * N_HITS + hit];
    const __half* srow = sp + (size_t)spid * HD;
    __half* brow = back + (size_t)(p * N_HITS + hit) * HD;
    float2 f = __half22float2(*(const __half2*)&srow[2 * lane]);
    pk_add_f16(&brow[2 * lane], f.x * s, f.y * s);
}

// ---------------- decoder: one thread per node, f16 h row read once ----------------
__global__ void dec_kernel(const __half* __restrict__ h, const float* __restrict__ W,
                           const float* __restrict__ b, float* __restrict__ out) {
    __shared__ float sW[640];
    __shared__ float sB[8];
    int t = threadIdx.x;
    for (int i = t; i < 640; i += 256) sW[i] = W[i];
    if (t < 5) sB[t] = b[t];
    __syncthreads();
    int n = blockIdx.x * 256 + t;
    if (n >= 3 * N_HITS) return;
    const uint4* hr = (const uint4*)(h + (size_t)n * HD);
    float a0 = sB[0], a1 = sB[1], a2 = sB[2], a3 = sB[3], a4 = sB[4];
#pragma unroll 4
    for (int q = 0; q < 16; ++q) {
        union { uint4 u; __half hh[8]; } v; v.u = hr[q];
        const float* w = &sW[q * 40];
#pragma unroll
        for (int j = 0; j < 8; ++j) {
            float x = __half2float(v.hh[j]);
            a0 = fmaf(x, w[j * 5 + 0], a0);
            a1 = fmaf(x, w[j * 5 + 1], a1);
            a2 = fmaf(x, w[j * 5 + 2], a2);
            a3 = fmaf(x, w[j * 5 + 3], a3);
            a4 = fmaf(x, w[j * 5 + 4], a4);
        }
    }
    float* o = out + (size_t)n * NCLS;
    o[0] = a0; o[1] = a1; o[2] = a2; o[3] = a3; o[4] = a4;
}

extern "C" void kernel_launch(void* const* d_in, const int* in_sizes, int n_in,
                              void* d_out, int out_size, void* d_ws, size_t ws_size,
                              hipStream_t stream) {
    const float* xu = (const float*)d_in[0];
    const int* eu = (const int*)d_in[1];
    const int* nu = (const int*)d_in[2];
    const float* xv = (const float*)d_in[3];
    const int* ev = (const int*)d_in[4];
    const int* nv = (const int*)d_in[5];
    const float* xy = (const float*)d_in[6];
    const int* ey = (const int*)d_in[7];
    const int* ny = (const int*)d_in[8];
    const float* W_enc = (const float*)d_in[9];
    const float* b_enc = (const float*)d_in[10];
    const float* W1 = (const float*)d_in[11];
    const float* b1 = (const float*)d_in[12];
    const float* W2 = (const float*)d_in[13];
    const float* b2 = (const float*)d_in[14];
    const float* W_upd = (const float*)d_in[15];
    const float* b_upd = (const float*)d_in[16];
    const float* W_sp = (const float*)d_in[17];
    const float* b_sp = (const float*)d_in[18];
    const float* W_nx = (const float*)d_in[19];
    const float* b_nx = (const float*)d_in[20];
    const float* W_sem = (const float*)d_in[21];
    const float* b_sem = (const float*)d_in[22];

    const size_t HN = (size_t)3 * N_HITS * HD;  // 11,520,000
    __half* h = (__half*)d_ws;                   // f16 [3][N_HITS][HD]
    __half* agg = h + HN;                        // f16 [3][N_HITS][HD]
    __half* sp = agg + HN;                       // f16 [N_SPS][HD]
    __half* y_d = sp + (size_t)N_SPS * HD;       // f16 [3][N_HITS][HD]
    __half* y_s = y_d + HN;                      // f16 [3][N_HITS][HD]
    float* inv = (float*)(y_s + HN);             // [270000]
    int* cnt = (int*)(inv + 270000);             // [270000]
    __bf16* packs = (__bf16*)(cnt + 270000);     // [131072]
    __bf16* W1dP = packs;
    __bf16* W1sP = packs + 16384;
    __bf16* W2P = packs + 32768;
    __bf16* WuP = packs + 49152;
    __bf16* WnP = packs + 81920;
    __bf16* WspP = packs + 114688;

    wprep_kernel<<<512, 256, 0, stream>>>(W1, W2, W_upd, W_nx, W_sp, packs);
    (void)hipMemsetAsync(cnt, 0, 270000 * sizeof(int), stream);
    hist_all_kernel<<<(450000 + 255) / 256, 256, 0, stream>>>(eu, ev, ey, nu, nv, ny, cnt);
    inv_kernel<<<(270000 + 255) / 256, 256, 0, stream>>>(cnt, inv, 270000);

    enc_kernel<<<(3 * N_HITS * HD + 255) / 256, 256, 0, stream>>>(xu, xv, xy, W_enc, b_enc, h);
    y_init_kernel<<<(3 * N_HITS + 127) / 128, 256, 0, stream>>>(h, W1dP, W1sP, y_d, y_s);

    for (int it = 0; it < 3; ++it) {
        (void)hipMemsetAsync(agg, 0, HN * sizeof(__half), stream);
        edge_mfma_kernel<<<dim3((N_EDGES + 127) / 128, 3), 256, 0, stream>>>(
            y_d, y_s, eu, ev, ey, b1, W2P, b2, inv, agg);
        update_mfma_kernel<<<dim3((N_HITS + 127) / 128, 3), 256, 0, stream>>>(h, agg, WuP, b_upd);
        (void)hipMemsetAsync(sp, 0, (size_t)N_SPS * HD * sizeof(__half), stream);
        nx_scatter_kernel<<<(3 * N_SPS * 64) / 256, 256, 0, stream>>>(h, nu, nv, ny, inv + 90000, sp);
        sp_gemm_kernel<<<(N_SPS + 127) / 128, 256, 0, stream>>>(sp, WspP, b_sp);
        (void)hipMemsetAsync(agg, 0, HN * sizeof(__half), stream);
        back_scatter_kernel<<<(3 * N_SPS * 64) / 256, 256, 0, stream>>>(sp, nu, nv, ny, inv + 180000, agg);
        update_y_kernel<<<dim3((N_HITS + 127) / 128, 3), 256, 0, stream>>>(
            h, agg, WnP, b_nx, W1dP, W1sP, y_d, y_s);
    }

    dec_kernel<<<(3 * N_HITS + 255) / 256, 256, 0, stream>>>(h, W_sem, b_sem, (float*)d_out);
}

// Round 8
// 912.703 us; speedup vs baseline: 1.1636x; 1.0302x over previous
//
#include <hip/hip_runtime.h>
#include <hip/hip_fp16.h>

#define N_HITS 30000
#define N_EDGES 90000
#define N_SPS 30000
#define HD 128
#define NCLS 5

#define PADM 136  // 128 + 8 bf16 pad

typedef __attribute__((ext_vector_type(8))) __bf16 bf16x8;
typedef __attribute__((ext_vector_type(4))) float floatx4;

__device__ __forceinline__ void pk_add_f16(__half* addr, float a, float b) {
    unsafeAtomicAdd((__half2*)addr, __halves2half2(__float2half(a), __float2half(b)));
}

__device__ __forceinline__ uint4 cvt8_h2b(uint4 raw) {  // f16x8 -> bf16x8
    union { uint4 u; __half h[8]; } in; in.u = raw;
    union { __bf16 b[8]; uint4 u; } out;
#pragma unroll
    for (int k = 0; k < 8; ++k) out.b[k] = (__bf16)__half2float(in.h[k]);
    return out.u;
}

__device__ __forceinline__ float2 b2f2(uint u) {
    union { uint u; __bf16 b[2]; } x; x.u = u;
    return make_float2((float)x.b[0], (float)x.b[1]);
}
__device__ __forceinline__ uint f2b2(float a, float b) {
    union { uint u; __bf16 b[2]; } x; x.b[0] = (__bf16)a; x.b[1] = (__bf16)b;
    return x.u;
}

// ---------------- encoder: h = relu(x @ W_enc + b_enc), bf16 out ----------------
__global__ void enc_kernel(const float* __restrict__ xu, const float* __restrict__ xv,
                           const float* __restrict__ xy, const float* __restrict__ W,
                           const float* __restrict__ b, __bf16* __restrict__ h) {
    int gid = blockIdx.x * blockDim.x + threadIdx.x;
    if (gid >= 3 * N_HITS * HD) return;
    int j = gid & (HD - 1);
    int n = (gid >> 7) % N_HITS;
    int p = gid / (N_HITS * HD);
    const float* x = (p == 0) ? xu : (p == 1) ? xv : xy;
    float acc = b[j];
#pragma unroll
    for (int k = 0; k < 4; ++k) acc = fmaf(x[n * 4 + k], W[k * HD + j], acc);
    h[gid] = (__bf16)fmaxf(acc, 0.f);
}

// ---------------- merged histograms ----------------
__global__ void hist_all_kernel(const int* __restrict__ eu, const int* __restrict__ ev,
                                const int* __restrict__ ey, const int* __restrict__ nu,
                                const int* __restrict__ nv, const int* __restrict__ ny,
                                int* __restrict__ cnt) {
    int gid = blockIdx.x * blockDim.x + threadIdx.x;
    if (gid >= 450000) return;
    int p = gid / 150000;
    int r = gid - p * 150000;
    const int* e = (p == 0) ? eu : (p == 1) ? ev : ey;
    const int* nx = (p == 0) ? nu : (p == 1) ? nv : ny;
    if (r < N_EDGES) {
        atomicAdd(&cnt[p * N_HITS + e[N_EDGES + r]], 1);
    } else if (r < N_EDGES + N_SPS) {
        int i = r - N_EDGES;
        atomicAdd(&cnt[90000 + p * N_SPS + nx[N_SPS + i]], 1);
    } else {
        int i = r - N_EDGES - N_SPS;
        atomicAdd(&cnt[180000 + p * N_HITS + nx[i]], 1);
    }
}

__global__ void inv_kernel(const int* __restrict__ cnt, float* __restrict__ inv, int n) {
    int i = blockIdx.x * blockDim.x + threadIdx.x;
    if (i < n) inv[i] = 1.0f / (float)(cnt[i] > 1 ? cnt[i] : 1);
}

// ---------------- weight pre-pack ----------------
__device__ __forceinline__ void pack4(const float* __restrict__ W, __bf16* __restrict__ P,
                                      int idx, int koff) {
    int j = idx & 7, lane = (idx >> 3) & 63, ks = (idx >> 9) & 3, n = (idx >> 11) & 7;
    int k = ks * 32 + (lane >> 4) * 8 + j, col = n * 16 + (lane & 15);
    P[idx] = (__bf16)W[(k + koff) * 128 + col];
}
__device__ __forceinline__ void pack8(const float* __restrict__ W, __bf16* __restrict__ P, int idx) {
    int j = idx & 7, lane = (idx >> 3) & 63, ks = (idx >> 9) & 7, n = (idx >> 12) & 7;
    int k = ks * 32 + (lane >> 4) * 8 + j, col = n * 16 + (lane & 15);
    P[idx] = (__bf16)W[k * 128 + col];
}

__global__ void wprep_kernel(const float* __restrict__ W1, const float* __restrict__ W2,
                             const float* __restrict__ Wu, const float* __restrict__ Wn,
                             const float* __restrict__ Wsp, __bf16* __restrict__ packs) {
    int gid = blockIdx.x * blockDim.x + threadIdx.x;
    if (gid < 16384) { pack4(W1, packs, gid, 0); return; }            // W1d
    gid -= 16384;
    if (gid < 16384) { pack4(W1, packs + 16384, gid, 128); return; }  // W1s
    gid -= 16384;
    if (gid < 16384) { pack4(W2, packs + 32768, gid, 0); return; }    // W2
    gid -= 16384;
    if (gid < 32768) { pack8(Wu, packs + 49152, gid); return; }       // W_upd
    gid -= 32768;
    if (gid < 32768) { pack8(Wn, packs + 81920, gid); return; }       // W_nx
    gid -= 32768;
    if (gid < 16384) { pack4(Wsp, packs + 114688, gid, 0); }          // W_sp
}

// ---------------- y_init: y_d = h@W1d, y_s = h@W1s (all bf16) ----------------
__launch_bounds__(256, 4)
__global__ void y_init_kernel(const __bf16* __restrict__ h, const __bf16* __restrict__ W1dP,
                              const __bf16* __restrict__ W1sP, __bf16* __restrict__ y_d,
                              __bf16* __restrict__ y_s) {
    __shared__ __bf16 sA[128 * PADM];
    int t = threadIdx.x;
    int n0b = blockIdx.x * 128;
    const int M = 3 * N_HITS;
    for (int i = t; i < 2048; i += 256) {
        int row = i >> 4, c = i & 15;
        int n = n0b + row; if (n >= M) n = M - 1;
        *(uint4*)&sA[row * PADM + c * 8] = ((const uint4*)(h + (size_t)n * HD))[c];
    }
    __syncthreads();

    int lane = t & 63, wave = t >> 6;
    int lcol = lane & 15, quad = lane >> 4;
    int nt0 = wave * 2;
    bool odd = (lcol & 1) != 0;

    for (int half = 0; half < 2; ++half) {
        const bf16x8* wp = (const bf16x8*)(half == 0 ? W1dP : W1sP);
        __bf16* out = half == 0 ? y_d : y_s;
        bf16x8 B[2][4];
#pragma unroll
        for (int nt = 0; nt < 2; ++nt)
#pragma unroll
            for (int ks = 0; ks < 4; ++ks)
                B[nt][ks] = wp[((nt0 + nt) * 4 + ks) * 64 + lane];
        floatx4 acc[8][2];
#pragma unroll
        for (int mt = 0; mt < 8; ++mt) { acc[mt][0] = (floatx4){0,0,0,0}; acc[mt][1] = (floatx4){0,0,0,0}; }
#pragma unroll
        for (int mt = 0; mt < 8; ++mt)
#pragma unroll
            for (int ks = 0; ks < 4; ++ks) {
                bf16x8 a = *(const bf16x8*)&sA[(mt * 16 + lcol) * PADM + ks * 32 + quad * 8];
                acc[mt][0] = __builtin_amdgcn_mfma_f32_16x16x32_bf16(a, B[0][ks], acc[mt][0], 0, 0, 0);
                acc[mt][1] = __builtin_amdgcn_mfma_f32_16x16x32_bf16(a, B[1][ks], acc[mt][1], 0, 0, 0);
            }
#pragma unroll
        for (int mt = 0; mt < 8; ++mt)
#pragma unroll
            for (int r = 0; r < 4; ++r) {
                int m = n0b + mt * 16 + quad * 4 + r;
                float v0 = acc[mt][0][r], v1 = acc[mt][1][r];
                float p0 = __shfl_xor(v0, 1), p1 = __shfl_xor(v1, 1);
                float av = odd ? p1 : v0, bv = odd ? v1 : p0;
                int col = nt0 * 16 + (odd ? 15 + lcol : lcol);
                if (m < M) *(uint*)&out[(size_t)m * HD + col] = f2b2(av, bv);
            }
    }
}

// ---------------- edge kernel: M=64 tile for occupancy; A=relu(yd[dst]+ys[src]+b1) @ W2 ----------------
__launch_bounds__(256, 4)
__global__ void edge_mfma_kernel(const __bf16* __restrict__ y_d, const __bf16* __restrict__ y_s,
                                 const int* __restrict__ eu, const int* __restrict__ ev,
                                 const int* __restrict__ ey, const float* __restrict__ b1,
                                 const __bf16* __restrict__ W2P, const float* __restrict__ b2,
                                 const float* __restrict__ invd, __half* __restrict__ agg) {
    int p = blockIdx.y;
    const int* e = (p == 0) ? eu : (p == 1) ? ev : ey;
    const __bf16* ydp = y_d + (size_t)p * N_HITS * HD;
    const __bf16* ysp = y_s + (size_t)p * N_HITS * HD;
    __half* aggp = agg + (size_t)p * N_HITS * HD;
    const float* invp = invd + p * N_HITS;

    __shared__ __bf16 sA[64 * PADM];  // 17408 B
    __shared__ int sDst[64];
    __shared__ float sInv[64];

    int t = threadIdx.x;
    int e0 = blockIdx.x * 64;
    if (t < 64) {
        int ei = e0 + t;
        int d = 0; float iv = 0.f;
        if (ei < N_EDGES) { d = e[N_EDGES + ei]; iv = invp[d]; }
        sDst[t] = d; sInv[t] = iv;
    }
    // stage A = relu(yd[dst] + ys[src] + b1): 64 rows x 16 chunks, 4 per thread
    for (int i = t; i < 1024; i += 256) {
        int row = i >> 4, c = i & 15;
        int ei = e0 + row; if (ei >= N_EDGES) ei = N_EDGES - 1;
        int src = e[ei], dst = e[N_EDGES + ei];
        union { uint4 u; __bf16 b[8]; } da, sa;
        da.u = ((const uint4*)(ydp + (size_t)dst * HD))[c];
        sa.u = ((const uint4*)(ysp + (size_t)src * HD))[c];
        float4 b1a = *(const float4*)(b1 + c * 8);
        float4 b1b = *(const float4*)(b1 + c * 8 + 4);
        float bb[8] = {b1a.x, b1a.y, b1a.z, b1a.w, b1b.x, b1b.y, b1b.z, b1b.w};
        union { __bf16 o[8]; uint4 u; } out;
#pragma unroll
        for (int j = 0; j < 8; ++j)
            out.o[j] = (__bf16)fmaxf((float)da.b[j] + (float)sa.b[j] + bb[j], 0.f);
        *(uint4*)&sA[row * PADM + c * 8] = out.u;
    }
    __syncthreads();

    int lane = t & 63, wave = t >> 6;
    int lcol = lane & 15, quad = lane >> 4;
    int nt0 = wave * 2;

    const bf16x8* w2p = (const bf16x8*)W2P;
    bf16x8 B2[2][4];
#pragma unroll
    for (int nt = 0; nt < 2; ++nt)
#pragma unroll
        for (int ks = 0; ks < 4; ++ks)
            B2[nt][ks] = w2p[((nt0 + nt) * 4 + ks) * 64 + lane];

    floatx4 acc[4][2];
#pragma unroll
    for (int nt = 0; nt < 2; ++nt) {
        float bv = b2[(nt0 + nt) * 16 + lcol];
#pragma unroll
        for (int mt = 0; mt < 4; ++mt) acc[mt][nt] = (floatx4){bv, bv, bv, bv};
    }
#pragma unroll
    for (int mt = 0; mt < 4; ++mt)
#pragma unroll
        for (int ks = 0; ks < 4; ++ks) {
            bf16x8 a = *(const bf16x8*)&sA[(mt * 16 + lcol) * PADM + ks * 32 + quad * 8];
            acc[mt][0] = __builtin_amdgcn_mfma_f32_16x16x32_bf16(a, B2[0][ks], acc[mt][0], 0, 0, 0);
            acc[mt][1] = __builtin_amdgcn_mfma_f32_16x16x32_bf16(a, B2[1][ks], acc[mt][1], 0, 0, 0);
        }

    bool odd = (lcol & 1) != 0;
#pragma unroll
    for (int mt = 0; mt < 4; ++mt)
#pragma unroll
        for (int r = 0; r < 4; ++r) {
            int row = mt * 16 + quad * 4 + r;
            float s = sInv[row];
            float v0 = acc[mt][0][r] * s;
            float v1 = acc[mt][1][r] * s;
            float p0 = __shfl_xor(v0, 1), p1 = __shfl_xor(v1, 1);
            float av = odd ? p1 : v0, bv = odd ? v1 : p0;
            int col = nt0 * 16 + (odd ? 15 + lcol : lcol);
            pk_add_f16(&aggp[(size_t)sDst[row] * HD + col], av, bv);
        }
}

// ---------------- planar update: h += relu([h|aux]@W+b); also zeroes aux & sp for later stages ----------------
__launch_bounds__(256, 4)
__global__ void update_mfma_kernel(__bf16* __restrict__ h, __half* __restrict__ aux,
                                   const __bf16* __restrict__ WP, const float* __restrict__ b,
                                   __half* __restrict__ sp) {
    int p = blockIdx.y;
    __bf16* hp = h + (size_t)p * N_HITS * HD;
    __half* ap = aux + (size_t)p * N_HITS * HD;

    __shared__ __bf16 sA[128 * PADM];
    int t = threadIdx.x;
    int n0b = blockIdx.x * 128;

    int lane = t & 63, wave = t >> 6;
    int lcol = lane & 15, quad = lane >> 4;
    int nt0 = wave * 2;
    bool odd = (lcol & 1) != 0;

    const bf16x8* wp = (const bf16x8*)WP;
    floatx4 acc[8][2];
#pragma unroll
    for (int nt = 0; nt < 2; ++nt) {
        float bv = b[(nt0 + nt) * 16 + lcol];
#pragma unroll
        for (int mt = 0; mt < 8; ++mt) acc[mt][nt] = (floatx4){bv, bv, bv, bv};
    }

    // phase 1: h half (bf16, direct copy)
    for (int i = t; i < 2048; i += 256) {
        int row = i >> 4, c = i & 15;
        int n = n0b + row; if (n >= N_HITS) n = N_HITS - 1;
        *(uint4*)&sA[row * PADM + c * 8] = ((const uint4*)(hp + (size_t)n * HD))[c];
    }
    __syncthreads();
    {
        bf16x8 B[2][4];
#pragma unroll
        for (int nt = 0; nt < 2; ++nt)
#pragma unroll
            for (int ks = 0; ks < 4; ++ks)
                B[nt][ks] = wp[((nt0 + nt) * 8 + ks) * 64 + lane];
#pragma unroll
        for (int mt = 0; mt < 8; ++mt)
#pragma unroll
            for (int ks = 0; ks < 4; ++ks) {
                bf16x8 a = *(const bf16x8*)&sA[(mt * 16 + lcol) * PADM + ks * 32 + quad * 8];
                acc[mt][0] = __builtin_amdgcn_mfma_f32_16x16x32_bf16(a, B[0][ks], acc[mt][0], 0, 0, 0);
                acc[mt][1] = __builtin_amdgcn_mfma_f32_16x16x32_bf16(a, B[1][ks], acc[mt][1], 0, 0, 0);
            }
    }
    __syncthreads();
    // phase 2: aux half (f16 -> bf16)
    for (int i = t; i < 2048; i += 256) {
        int row = i >> 4, c = i & 15;
        int n = n0b + row; if (n >= N_HITS) n = N_HITS - 1;
        uint4 raw = ((const uint4*)(ap + (size_t)n * HD))[c];
        *(uint4*)&sA[row * PADM + c * 8] = cvt8_h2b(raw);
    }
    __syncthreads();
    // zero aux (ready for back_scatter) and sp slice (ready for nx_scatter); overlaps MFMA below
    {
        uint4 z = {0, 0, 0, 0};
        for (int i = t; i < 2048; i += 256) {
            int row = i >> 4, c = i & 15;
            int n = n0b + row;
            if (n < N_HITS) ((uint4*)(ap + (size_t)n * HD))[c] = z;
        }
        if (p == 0) {
            for (int i = t; i < 2048; i += 256) {
                int row = i >> 4, c = i & 15;
                int n = n0b + row;
                if (n < N_SPS) ((uint4*)(sp + (size_t)n * HD))[c] = z;
            }
        }
    }
    {
        bf16x8 B[2][4];
#pragma unroll
        for (int nt = 0; nt < 2; ++nt)
#pragma unroll
            for (int ks = 0; ks < 4; ++ks)
                B[nt][ks] = wp[((nt0 + nt) * 8 + 4 + ks) * 64 + lane];
#pragma unroll
        for (int mt = 0; mt < 8; ++mt)
#pragma unroll
            for (int ks = 0; ks < 4; ++ks) {
                bf16x8 a = *(const bf16x8*)&sA[(mt * 16 + lcol) * PADM + ks * 32 + quad * 8];
                acc[mt][0] = __builtin_amdgcn_mfma_f32_16x16x32_bf16(a, B[0][ks], acc[mt][0], 0, 0, 0);
                acc[mt][1] = __builtin_amdgcn_mfma_f32_16x16x32_bf16(a, B[1][ks], acc[mt][1], 0, 0, 0);
            }
    }
    // residual RMW on bf16 h, paired columns (4B)
#pragma unroll
    for (int mt = 0; mt < 8; ++mt)
#pragma unroll
        for (int r = 0; r < 4; ++r) {
            float v0 = fmaxf(acc[mt][0][r], 0.f), v1 = fmaxf(acc[mt][1][r], 0.f);
            float p0 = __shfl_xor(v0, 1), p1 = __shfl_xor(v1, 1);
            float av = odd ? p1 : v0, bv = odd ? v1 : p0;
            int col = nt0 * 16 + (odd ? 15 + lcol : lcol);
            int m = n0b + mt * 16 + quad * 4 + r;
            if (m < N_HITS) {
                uint* hp2 = (uint*)&hp[(size_t)m * HD + col];
                float2 ho = b2f2(*hp2);
                *hp2 = f2b2(ho.x + av, ho.y + bv);
            }
        }
}

// ---------------- nexus update + fused y emission; zeroes aux for next iteration ----------------
__launch_bounds__(256, 4)
__global__ void update_y_kernel(__bf16* __restrict__ h, __half* __restrict__ aux,
                                const __bf16* __restrict__ WP, const float* __restrict__ b,
                                const __bf16* __restrict__ W1dP, const __bf16* __restrict__ W1sP,
                                __bf16* __restrict__ y_d, __bf16* __restrict__ y_s) {
    int p = blockIdx.y;
    __bf16* hp = h + (size_t)p * N_HITS * HD;
    __half* ap = aux + (size_t)p * N_HITS * HD;
    __bf16* ydp = y_d + (size_t)p * N_HITS * HD;
    __bf16* ysp = y_s + (size_t)p * N_HITS * HD;

    __shared__ __bf16 sA[128 * PADM];
    int t = threadIdx.x;
    int n0b = blockIdx.x * 128;

    int lane = t & 63, wave = t >> 6;
    int lcol = lane & 15, quad = lane >> 4;
    int nt0 = wave * 2;
    bool odd = (lcol & 1) != 0;

    const bf16x8* wp = (const bf16x8*)WP;
    floatx4 acc[8][2];
#pragma unroll
    for (int nt = 0; nt < 2; ++nt) {
        float bv = b[(nt0 + nt) * 16 + lcol];
#pragma unroll
        for (int mt = 0; mt < 8; ++mt) acc[mt][nt] = (floatx4){bv, bv, bv, bv};
    }

    // phase 1: h half
    for (int i = t; i < 2048; i += 256) {
        int row = i >> 4, c = i & 15;
        int n = n0b + row; if (n >= N_HITS) n = N_HITS - 1;
        *(uint4*)&sA[row * PADM + c * 8] = ((const uint4*)(hp + (size_t)n * HD))[c];
    }
    __syncthreads();
    {
        bf16x8 B[2][4];
#pragma unroll
        for (int nt = 0; nt < 2; ++nt)
#pragma unroll
            for (int ks = 0; ks < 4; ++ks)
                B[nt][ks] = wp[((nt0 + nt) * 8 + ks) * 64 + lane];
#pragma unroll
        for (int mt = 0; mt < 8; ++mt)
#pragma unroll
            for (int ks = 0; ks < 4; ++ks) {
                bf16x8 a = *(const bf16x8*)&sA[(mt * 16 + lcol) * PADM + ks * 32 + quad * 8];
                acc[mt][0] = __builtin_amdgcn_mfma_f32_16x16x32_bf16(a, B[0][ks], acc[mt][0], 0, 0, 0);
                acc[mt][1] = __builtin_amdgcn_mfma_f32_16x16x32_bf16(a, B[1][ks], acc[mt][1], 0, 0, 0);
            }
    }
    __syncthreads();
    // phase 2: aux half (f16 -> bf16)
    for (int i = t; i < 2048; i += 256) {
        int row = i >> 4, c = i & 15;
        int n = n0b + row; if (n >= N_HITS) n = N_HITS - 1;
        uint4 raw = ((const uint4*)(ap + (size_t)n * HD))[c];
        *(uint4*)&sA[row * PADM + c * 8] = cvt8_h2b(raw);
    }
    __syncthreads();
    // zero aux (ready as planar agg for next iteration)
    {
        uint4 z = {0, 0, 0, 0};
        for (int i = t; i < 2048; i += 256) {
            int row = i >> 4, c = i & 15;
            int n = n0b + row;
            if (n < N_HITS) ((uint4*)(ap + (size_t)n * HD))[c] = z;
        }
    }
    {
        bf16x8 B[2][4];
#pragma unroll
        for (int nt = 0; nt < 2; ++nt)
#pragma unroll
            for (int ks = 0; ks < 4; ++ks)
                B[nt][ks] = wp[((nt0 + nt) * 8 + 4 + ks) * 64 + lane];
#pragma unroll
        for (int mt = 0; mt < 8; ++mt)
#pragma unroll
            for (int ks = 0; ks < 4; ++ks) {
                bf16x8 a = *(const bf16x8*)&sA[(mt * 16 + lcol) * PADM + ks * 32 + quad * 8];
                acc[mt][0] = __builtin_amdgcn_mfma_f32_16x16x32_bf16(a, B[0][ks], acc[mt][0], 0, 0, 0);
                acc[mt][1] = __builtin_amdgcn_mfma_f32_16x16x32_bf16(a, B[1][ks], acc[mt][1], 0, 0, 0);
            }
    }
    __syncthreads();  // aux tile reads done; safe to overwrite sA with h_new

    // epilogue: h_new = h_old + relu(acc); bf16 RMW + bf16 tile into sA
#pragma unroll
    for (int mt = 0; mt < 8; ++mt)
#pragma unroll
        for (int r = 0; r < 4; ++r) {
            float v0 = fmaxf(acc[mt][0][r], 0.f), v1 = fmaxf(acc[mt][1][r], 0.f);
            float p0 = __shfl_xor(v0, 1), p1 = __shfl_xor(v1, 1);
            float av = odd ? p1 : v0, bv = odd ? v1 : p0;
            int col = nt0 * 16 + (odd ? 15 + lcol : lcol);
            int row = mt * 16 + quad * 4 + r;
            int m = n0b + row;
            float n0v = 0.f, n1v = 0.f;
            if (m < N_HITS) {
                uint* hp2 = (uint*)&hp[(size_t)m * HD + col];
                float2 ho = b2f2(*hp2);
                n0v = ho.x + av; n1v = ho.y + bv;
                *hp2 = f2b2(n0v, n1v);
            }
            *(uint*)&sA[row * PADM + col] = f2b2(n0v, n1v);
        }
    __syncthreads();

    // y GEMMs: y_d = h_new @ W1d, y_s = h_new @ W1s
    for (int half = 0; half < 2; ++half) {
        const bf16x8* wyp = (const bf16x8*)(half == 0 ? W1dP : W1sP);
        __bf16* out = half == 0 ? ydp : ysp;
        bf16x8 B[2][4];
#pragma unroll
        for (int nt = 0; nt < 2; ++nt)
#pragma unroll
            for (int ks = 0; ks < 4; ++ks)
                B[nt][ks] = wyp[((nt0 + nt) * 4 + ks) * 64 + lane];
        floatx4 yacc[8][2];
#pragma unroll
        for (int mt = 0; mt < 8; ++mt) { yacc[mt][0] = (floatx4){0,0,0,0}; yacc[mt][1] = (floatx4){0,0,0,0}; }
#pragma unroll
        for (int mt = 0; mt < 8; ++mt)
#pragma unroll
            for (int ks = 0; ks < 4; ++ks) {
                bf16x8 a = *(const bf16x8*)&sA[(mt * 16 + lcol) * PADM + ks * 32 + quad * 8];
                yacc[mt][0] = __builtin_amdgcn_mfma_f32_16x16x32_bf16(a, B[0][ks], yacc[mt][0], 0, 0, 0);
                yacc[mt][1] = __builtin_amdgcn_mfma_f32_16x16x32_bf16(a, B[1][ks], yacc[mt][1], 0, 0, 0);
            }
#pragma unroll
        for (int mt = 0; mt < 8; ++mt)
#pragma unroll
            for (int r = 0; r < 4; ++r) {
                int m = n0b + mt * 16 + quad * 4 + r;
                float v0 = yacc[mt][0][r], v1 = yacc[mt][1][r];
                float p0 = __shfl_xor(v0, 1), p1 = __shfl_xor(v1, 1);
                float av = odd ? p1 : v0, bv = odd ? v1 : p0;
                int col = nt0 * 16 + (odd ? 15 + lcol : lcol);
                if (m < N_HITS) *(uint*)&out[(size_t)m * HD + col] = f2b2(av, bv);
            }
    }
}

// ---------------- nexus scatter: sp[spid] += h[hit]*inv (h bf16 -> sp f16 atomics) ----------------
__global__ void nx_scatter_kernel(const __bf16* __restrict__ h, const int* __restrict__ nu,
                                  const int* __restrict__ nv, const int* __restrict__ ny,
                                  const float* __restrict__ invsp, __half* __restrict__ sp) {
    int gt = blockIdx.x * blockDim.x + threadIdx.x;
    int wid = gt >> 6;
    int lane = gt & 63;
    if (wid >= 3 * N_SPS) return;
    int p = wid / N_SPS;
    int i = wid - p * N_SPS;
    const int* nx = (p == 0) ? nu : (p == 1) ? nv : ny;
    int hit = nx[i];
    int spid = nx[N_SPS + i];
    float s = invsp[p * N_SPS + spid];
    const __bf16* hrow = h + (size_t)(p * N_HITS + hit) * HD;
    __half* srow = sp + (size_t)spid * HD;
    float2 hv = b2f2(*(const uint*)&hrow[2 * lane]);
    pk_add_f16(&srow[2 * lane], hv.x * s, hv.y * s);
}

// ---------------- sp = relu(sp @ W_sp + b_sp) (f16 in/out) ----------------
__launch_bounds__(256, 4)
__global__ void sp_gemm_kernel(__half* __restrict__ spf, const __bf16* __restrict__ WspP,
                               const float* __restrict__ b) {
    __shared__ __bf16 sA[128 * PADM];
    int t = threadIdx.x;
    int n0b = blockIdx.x * 128;
    for (int i = t; i < 2048; i += 256) {
        int row = i >> 4, c = i & 15;
        int n = n0b + row; if (n >= N_SPS) n = N_SPS - 1;
        uint4 raw = ((const uint4*)(spf + (size_t)n * HD))[c];
        *(uint4*)&sA[row * PADM + c * 8] = cvt8_h2b(raw);
    }
    __syncthreads();

    int lane = t & 63, wave = t >> 6;
    int lcol = lane & 15, quad = lane >> 4;
    int nt0 = wave * 2;
    bool odd = (lcol & 1) != 0;

    const bf16x8* wp = (const bf16x8*)WspP;
    bf16x8 B[2][4];
#pragma unroll
    for (int nt = 0; nt < 2; ++nt)
#pragma unroll
        for (int ks = 0; ks < 4; ++ks)
            B[nt][ks] = wp[((nt0 + nt) * 4 + ks) * 64 + lane];

    floatx4 acc[8][2];
#pragma unroll
    for (int nt = 0; nt < 2; ++nt) {
        float bv = b[(nt0 + nt) * 16 + lcol];
#pragma unroll
        for (int mt = 0; mt < 8; ++mt) acc[mt][nt] = (floatx4){bv, bv, bv, bv};
    }
#pragma unroll
    for (int mt = 0; mt < 8; ++mt)
#pragma unroll
        for (int ks = 0; ks < 4; ++ks) {
            bf16x8 a = *(const bf16x8*)&sA[(mt * 16 + lcol) * PADM + ks * 32 + quad * 8];
            acc[mt][0] = __builtin_amdgcn_mfma_f32_16x16x32_bf16(a, B[0][ks], acc[mt][0], 0, 0, 0);
            acc[mt][1] = __builtin_amdgcn_mfma_f32_16x16x32_bf16(a, B[1][ks], acc[mt][1], 0, 0, 0);
        }
#pragma unroll
    for (int mt = 0; mt < 8; ++mt)
#pragma unroll
        for (int r = 0; r < 4; ++r) {
            int m = n0b + mt * 16 + quad * 4 + r;
            float v0 = fmaxf(acc[mt][0][r], 0.f), v1 = fmaxf(acc[mt][1][r], 0.f);
            float p0 = __shfl_xor(v0, 1), p1 = __shfl_xor(v1, 1);
            float av = odd ? p1 : v0, bv = odd ? v1 : p0;
            int col = nt0 * 16 + (odd ? 15 + lcol : lcol);
            if (m < N_SPS)
                *(__half2*)&spf[(size_t)m * HD + col] =
                    __halves2half2(__float2half(av), __float2half(bv));
        }
}

// ---------------- back scatter: back[hit] += sp[spid]*inv ----------------
__global__ void back_scatter_kernel(const __half* __restrict__ sp, const int* __restrict__ nu,
                                    const int* __restrict__ nv, const int* __restrict__ ny,
                                    const float* __restrict__ invhit, __half* __restrict__ back) {
    int gt = blockIdx.x * blockDim.x + threadIdx.x;
    int wid = gt >> 6;
    int lane = gt & 63;
    if (wid >= 3 * N_SPS) return;
    int p = wid / N_SPS;
    int i = wid - p * N_SPS;
    const int* nx = (p == 0) ? nu : (p == 1) ? nv : ny;
    int hit = nx[i];
    int spid = nx[N_SPS + i];
    float s = invhit[p * N_HITS + hit];
    const __half* srow = sp + (size_t)spid * HD;
    __half* brow = back + (size_t)(p * N_HITS + hit) * HD;
    float2 f = __half22float2(*(const __half2*)&srow[2 * lane]);
    pk_add_f16(&brow[2 * lane], f.x * s, f.y * s);
}

// ---------------- decoder: one thread per node, bf16 h row read once ----------------
__global__ void dec_kernel(const __bf16* __restrict__ h, const float* __restrict__ W,
                           const float* __restrict__ b, float* __restrict__ out) {
    __shared__ float sW[640];
    __shared__ float sB[8];
    int t = threadIdx.x;
    for (int i = t; i < 640; i += 256) sW[i] = W[i];
    if (t < 5) sB[t] = b[t];
    __syncthreads();
    int n = blockIdx.x * 256 + t;
    if (n >= 3 * N_HITS) return;
    const uint4* hr = (const uint4*)(h + (size_t)n * HD);
    float a0 = sB[0], a1 = sB[1], a2 = sB[2], a3 = sB[3], a4 = sB[4];
#pragma unroll 4
    for (int q = 0; q < 16; ++q) {
        union { uint4 u; __bf16 bb[8]; } v; v.u = hr[q];
        const float* w = &sW[q * 40];
#pragma unroll
        for (int j = 0; j < 8; ++j) {
            float x = (float)v.bb[j];
            a0 = fmaf(x, w[j * 5 + 0], a0);
            a1 = fmaf(x, w[j * 5 + 1], a1);
            a2 = fmaf(x, w[j * 5 + 2], a2);
            a3 = fmaf(x, w[j * 5 + 3], a3);
            a4 = fmaf(x, w[j * 5 + 4], a4);
        }
    }
    float* o = out + (size_t)n * NCLS;
    o[0] = a0; o[1] = a1; o[2] = a2; o[3] = a3; o[4] = a4;
}

extern "C" void kernel_launch(void* const* d_in, const int* in_sizes, int n_in,
                              void* d_out, int out_size, void* d_ws, size_t ws_size,
                              hipStream_t stream) {
    const float* xu = (const float*)d_in[0];
    const int* eu = (const int*)d_in[1];
    const int* nu = (const int*)d_in[2];
    const float* xv = (const float*)d_in[3];
    const int* ev = (const int*)d_in[4];
    const int* nv = (const int*)d_in[5];
    const float* xy = (const float*)d_in[6];
    const int* ey = (const int*)d_in[7];
    const int* ny = (const int*)d_in[8];
    const float* W_enc = (const float*)d_in[9];
    const float* b_enc = (const float*)d_in[10];
    const float* W1 = (const float*)d_in[11];
    const float* b1 = (const float*)d_in[12];
    const float* W2 = (const float*)d_in[13];
    const float* b2 = (const float*)d_in[14];
    const float* W_upd = (const float*)d_in[15];
    const float* b_upd = (const float*)d_in[16];
    const float* W_sp = (const float*)d_in[17];
    const float* b_sp = (const float*)d_in[18];
    const float* W_nx = (const float*)d_in[19];
    const float* b_nx = (const float*)d_in[20];
    const float* W_sem = (const float*)d_in[21];
    const float* b_sem = (const float*)d_in[22];

    const size_t HN = (size_t)3 * N_HITS * HD;  // 11,520,000
    __bf16* h = (__bf16*)d_ws;                   // bf16 [3][N_HITS][HD]
    __half* agg = (__half*)(h + HN);             // f16 [3][N_HITS][HD]
    __half* sp = agg + HN;                       // f16 [N_SPS][HD]
    __bf16* y_d = (__bf16*)(sp + (size_t)N_SPS * HD);  // bf16 [3][N_HITS][HD]
    __bf16* y_s = y_d + HN;                      // bf16 [3][N_HITS][HD]
    float* inv = (float*)(y_s + HN);             // [270000]
    int* cnt = (int*)(inv + 270000);             // [270000]
    __bf16* packs = (__bf16*)(cnt + 270000);     // [131072]
    __bf16* W1dP = packs;
    __bf16* W1sP = packs + 16384;
    __bf16* W2P = packs + 32768;
    __bf16* WuP = packs + 49152;
    __bf16* WnP = packs + 81920;
    __bf16* WspP = packs + 114688;

    wprep_kernel<<<512, 256, 0, stream>>>(W1, W2, W_upd, W_nx, W_sp, packs);
    (void)hipMemsetAsync(cnt, 0, 270000 * sizeof(int), stream);
    hist_all_kernel<<<(450000 + 255) / 256, 256, 0, stream>>>(eu, ev, ey, nu, nv, ny, cnt);
    inv_kernel<<<(270000 + 255) / 256, 256, 0, stream>>>(cnt, inv, 270000);

    enc_kernel<<<(3 * N_HITS * HD + 255) / 256, 256, 0, stream>>>(xu, xv, xy, W_enc, b_enc, h);
    y_init_kernel<<<(3 * N_HITS + 127) / 128, 256, 0, stream>>>(h, W1dP, W1sP, y_d, y_s);
    (void)hipMemsetAsync(agg, 0, HN * sizeof(__half), stream);  // once; kernels re-zero thereafter

    for (int it = 0; it < 3; ++it) {
        edge_mfma_kernel<<<dim3((N_EDGES + 63) / 64, 3), 256, 0, stream>>>(
            y_d, y_s, eu, ev, ey, b1, W2P, b2, inv, agg);
        update_mfma_kernel<<<dim3((N_HITS + 127) / 128, 3), 256, 0, stream>>>(h, agg, WuP, b_upd, sp);
        nx_scatter_kernel<<<(3 * N_SPS * 64) / 256, 256, 0, stream>>>(h, nu, nv, ny, inv + 90000, sp);
        sp_gemm_kernel<<<(N_SPS + 127) / 128, 256, 0, stream>>>(sp, WspP, b_sp);
        back_scatter_kernel<<<(3 * N_SPS * 64) / 256, 256, 0, stream>>>(sp, nu, nv, ny, inv + 180000, agg);
        update_y_kernel<<<dim3((N_HITS + 127) / 128, 3), 256, 0, stream>>>(
            h, agg, WnP, b_nx, W1dP, W1sP, y_d, y_s);
    }

    dec_kernel<<<(3 * N_HITS + 255) / 256, 256, 0, stream>>>(h, W_sem, b_sem, (float*)d_out);
}

// Round 9
// 844.349 us; speedup vs baseline: 1.2578x; 1.0810x over previous
//
#include <hip/hip_runtime.h>
#include <hip/hip_fp16.h>

#define N_HITS 30000
#define N_EDGES 90000
#define N_SPS 30000
#define HD 128
#define NCLS 5

#define PADM 136  // 128 + 8 bf16 pad

typedef __attribute__((ext_vector_type(8))) __bf16 bf16x8;
typedef __attribute__((ext_vector_type(4))) float floatx4;

__device__ __forceinline__ float2 b2f2(uint u) {
    union { uint u; __bf16 b[2]; } x; x.u = u;
    return make_float2((float)x.b[0], (float)x.b[1]);
}
__device__ __forceinline__ uint f2b2(float a, float b) {
    union { uint u; __bf16 b[2]; } x; x.b[0] = (__bf16)a; x.b[1] = (__bf16)b;
    return x.u;
}

// ---------------- encoder ----------------
__global__ void enc_kernel(const float* __restrict__ xu, const float* __restrict__ xv,
                           const float* __restrict__ xy, const float* __restrict__ W,
                           const float* __restrict__ b, __bf16* __restrict__ h) {
    int gid = blockIdx.x * blockDim.x + threadIdx.x;
    if (gid >= 3 * N_HITS * HD) return;
    int j = gid & (HD - 1);
    int n = (gid >> 7) % N_HITS;
    int p = gid / (N_HITS * HD);
    const float* x = (p == 0) ? xu : (p == 1) ? xv : xy;
    float acc = b[j];
#pragma unroll
    for (int k = 0; k < 4; ++k) acc = fmaf(x[n * 4 + k], W[k * HD + j], acc);
    h[gid] = (__bf16)fmaxf(acc, 0.f);
}

// ---------------- histograms: 9 segments of 30000 counts ----------------
__global__ void hist_all_kernel(const int* __restrict__ eu, const int* __restrict__ ev,
                                const int* __restrict__ ey, const int* __restrict__ nu,
                                const int* __restrict__ nv, const int* __restrict__ ny,
                                int* __restrict__ cnt) {
    int gid = blockIdx.x * blockDim.x + threadIdx.x;
    if (gid >= 450000) return;
    int p = gid / 150000;
    int r = gid - p * 150000;
    const int* e = (p == 0) ? eu : (p == 1) ? ev : ey;
    const int* nx = (p == 0) ? nu : (p == 1) ? nv : ny;
    if (r < N_EDGES) {
        atomicAdd(&cnt[p * 30000 + e[N_EDGES + r]], 1);            // seg p: edge-dst
    } else if (r < N_EDGES + N_SPS) {
        int i = r - N_EDGES;
        atomicAdd(&cnt[(3 + p) * 30000 + nx[N_SPS + i]], 1);       // seg 3+p: spid
    } else {
        int i = r - N_EDGES - N_SPS;
        atomicAdd(&cnt[(6 + p) * 30000 + nx[i]], 1);               // seg 6+p: hit
    }
}

// ---------------- exclusive scan of each 30000-count segment -> offsets + cursor ----------------
__launch_bounds__(1024)
__global__ void scan_kernel(const int* __restrict__ cnt, int* __restrict__ off,
                            int* __restrict__ cursor) {
    int seg = blockIdx.x;  // 0..8
    const int* c = cnt + seg * 30000;
    int* o = off + seg * 30001;
    int* cur = cursor + seg * 30000;
    int t = threadIdx.x;
    int base = t * 30;
    int lc[30];
    int sum = 0;
#pragma unroll
    for (int k = 0; k < 30; ++k) {
        int i = base + k;
        lc[k] = (i < 30000) ? c[i] : 0;
        sum += lc[k];
    }
    __shared__ int part[1024];
    part[t] = sum;
    __syncthreads();
    for (int d = 1; d < 1024; d <<= 1) {
        int x = (t >= d) ? part[t - d] : 0;
        __syncthreads();
        part[t] += x;
        __syncthreads();
    }
    int run = part[t] - sum;  // exclusive prefix of this chunk
#pragma unroll
    for (int k = 0; k < 30; ++k) {
        int i = base + k;
        if (i < 30000) { o[i] = run; cur[i] = run; run += lc[k]; }
    }
    if (t == 1023) o[30000] = part[1023];
}

// ---------------- CSR fill (bucket order arbitrary) ----------------
__global__ void fill_kernel(const int* __restrict__ eu, const int* __restrict__ ev,
                            const int* __restrict__ ey, const int* __restrict__ nu,
                            const int* __restrict__ nv, const int* __restrict__ ny,
                            int* __restrict__ cursor, int* __restrict__ csr_e,
                            int* __restrict__ csr_s, int* __restrict__ csr_h) {
    int gid = blockIdx.x * blockDim.x + threadIdx.x;
    if (gid >= 450000) return;
    int p = gid / 150000;
    int r = gid - p * 150000;
    const int* e = (p == 0) ? eu : (p == 1) ? ev : ey;
    const int* nx = (p == 0) ? nu : (p == 1) ? nv : ny;
    if (r < N_EDGES) {
        int d = e[N_EDGES + r];
        int pos = atomicAdd(&cursor[p * 30000 + d], 1);
        csr_e[p * N_EDGES + pos] = e[r];                 // src
    } else if (r < N_EDGES + N_SPS) {
        int i = r - N_EDGES;
        int spid = nx[N_SPS + i];
        int pos = atomicAdd(&cursor[(3 + p) * 30000 + spid], 1);
        csr_s[p * N_SPS + pos] = nx[i];                  // hit
    } else {
        int i = r - N_EDGES - N_SPS;
        int hit = nx[i];
        int pos = atomicAdd(&cursor[(6 + p) * 30000 + hit], 1);
        csr_h[p * N_SPS + pos] = nx[N_SPS + i];          // spid
    }
}

// ---------------- weight pre-pack ----------------
__device__ __forceinline__ void pack4(const float* __restrict__ W, __bf16* __restrict__ P,
                                      int idx, int koff) {
    int j = idx & 7, lane = (idx >> 3) & 63, ks = (idx >> 9) & 3, n = (idx >> 11) & 7;
    int k = ks * 32 + (lane >> 4) * 8 + j, col = n * 16 + (lane & 15);
    P[idx] = (__bf16)W[(k + koff) * 128 + col];
}
__device__ __forceinline__ void pack8(const float* __restrict__ W, __bf16* __restrict__ P, int idx) {
    int j = idx & 7, lane = (idx >> 3) & 63, ks = (idx >> 9) & 7, n = (idx >> 12) & 7;
    int k = ks * 32 + (lane >> 4) * 8 + j, col = n * 16 + (lane & 15);
    P[idx] = (__bf16)W[k * 128 + col];
}

__global__ void wprep_kernel(const float* __restrict__ W1, const float* __restrict__ W2,
                             const float* __restrict__ Wu, const float* __restrict__ Wn,
                             const float* __restrict__ Wsp, __bf16* __restrict__ packs) {
    int gid = blockIdx.x * blockDim.x + threadIdx.x;
    if (gid < 16384) { pack4(W1, packs, gid, 0); return; }            // W1d
    gid -= 16384;
    if (gid < 16384) { pack4(W1, packs + 16384, gid, 128); return; }  // W1s
    gid -= 16384;
    if (gid < 16384) { pack4(W2, packs + 32768, gid, 0); return; }    // W2
    gid -= 16384;
    if (gid < 32768) { pack8(Wu, packs + 49152, gid); return; }       // W_upd
    gid -= 32768;
    if (gid < 32768) { pack8(Wn, packs + 81920, gid); return; }       // W_nx
    gid -= 32768;
    if (gid < 16384) { pack4(Wsp, packs + 114688, gid, 0); }          // W_sp
}

// ---------------- y_init: y_d = h@W1d, y_s = h@W1s ----------------
__launch_bounds__(256, 4)
__global__ void y_init_kernel(const __bf16* __restrict__ h, const __bf16* __restrict__ W1dP,
                              const __bf16* __restrict__ W1sP, __bf16* __restrict__ y_d,
                              __bf16* __restrict__ y_s) {
    __shared__ __bf16 sA[128 * PADM];
    int t = threadIdx.x;
    int n0b = blockIdx.x * 128;
    const int M = 3 * N_HITS;
    for (int i = t; i < 2048; i += 256) {
        int row = i >> 4, c = i & 15;
        int n = n0b + row; if (n >= M) n = M - 1;
        *(uint4*)&sA[row * PADM + c * 8] = ((const uint4*)(h + (size_t)n * HD))[c];
    }
    __syncthreads();

    int lane = t & 63, wave = t >> 6;
    int lcol = lane & 15, quad = lane >> 4;
    int nt0 = wave * 2;
    bool odd = (lcol & 1) != 0;

    for (int half = 0; half < 2; ++half) {
        const bf16x8* wp = (const bf16x8*)(half == 0 ? W1dP : W1sP);
        __bf16* out = half == 0 ? y_d : y_s;
        bf16x8 B[2][4];
#pragma unroll
        for (int nt = 0; nt < 2; ++nt)
#pragma unroll
            for (int ks = 0; ks < 4; ++ks)
                B[nt][ks] = wp[((nt0 + nt) * 4 + ks) * 64 + lane];
        floatx4 acc[8][2];
#pragma unroll
        for (int mt = 0; mt < 8; ++mt) { acc[mt][0] = (floatx4){0,0,0,0}; acc[mt][1] = (floatx4){0,0,0,0}; }
#pragma unroll
        for (int mt = 0; mt < 8; ++mt)
#pragma unroll
            for (int ks = 0; ks < 4; ++ks) {
                bf16x8 a = *(const bf16x8*)&sA[(mt * 16 + lcol) * PADM + ks * 32 + quad * 8];
                acc[mt][0] = __builtin_amdgcn_mfma_f32_16x16x32_bf16(a, B[0][ks], acc[mt][0], 0, 0, 0);
                acc[mt][1] = __builtin_amdgcn_mfma_f32_16x16x32_bf16(a, B[1][ks], acc[mt][1], 0, 0, 0);
            }
#pragma unroll
        for (int mt = 0; mt < 8; ++mt)
#pragma unroll
            for (int r = 0; r < 4; ++r) {
                int m = n0b + mt * 16 + quad * 4 + r;
                float v0 = acc[mt][0][r], v1 = acc[mt][1][r];
                float p0 = __shfl_xor(v0, 1), p1 = __shfl_xor(v1, 1);
                float av = odd ? p1 : v0, bv = odd ? v1 : p0;
                int col = nt0 * 16 + (odd ? 15 + lcol : lcol);
                if (m < M) *(uint*)&out[(size_t)m * HD + col] = f2b2(av, bv);
            }
    }
}

// ---------------- edge gather-reduce: z[d] = mean_{e: dst=d} relu(y_d[d]+y_s[src]+b1) ----------------
__launch_bounds__(256)
__global__ void edge_gather_kernel(const __bf16* __restrict__ y_d, const __bf16* __restrict__ y_s,
                                   const int* __restrict__ off, const int* __restrict__ csr_e,
                                   const float* __restrict__ b1, __bf16* __restrict__ z) {
    int wid = (blockIdx.x * 256 + threadIdx.x) >> 6;
    int lane = threadIdx.x & 63;
    if (wid >= 3 * N_HITS) return;
    int p = wid / N_HITS;
    int d = wid - p * N_HITS;
    const int* o = off + p * 30001;
    int beg = o[d], end = o[d + 1];
    float2 yd = b2f2(*(const uint*)&y_d[((size_t)p * N_HITS + d) * HD + 2 * lane]);
    float b0 = b1[2 * lane], bb1 = b1[2 * lane + 1];
    float a0 = 0.f, a1 = 0.f;
    const int* csr = csr_e + p * N_EDGES;
    const __bf16* ysb = y_s + (size_t)p * N_HITS * HD;
    for (int k = beg; k < end; ++k) {
        int s = csr[k];
        float2 ys = b2f2(*(const uint*)&ysb[(size_t)s * HD + 2 * lane]);
        a0 += fmaxf(yd.x + ys.x + b0, 0.f);
        a1 += fmaxf(yd.y + ys.y + bb1, 0.f);
    }
    float iv = (end > beg) ? 1.f / (float)(end - beg) : 0.f;
    *(uint*)&z[((size_t)p * N_HITS + d) * HD + 2 * lane] = f2b2(a0 * iv, a1 * iv);
}

// ---------------- planar update: agg = z@W2+b2 (fused); h += relu([h|agg]@Wu+bu) ----------------
__launch_bounds__(256, 4)
__global__ void update_planar_kernel(__bf16* __restrict__ h, const __bf16* __restrict__ z,
                                     const __bf16* __restrict__ W2P, const float* __restrict__ b2,
                                     const __bf16* __restrict__ WuP, const float* __restrict__ bu) {
    int p = blockIdx.y;
    __bf16* hp = h + (size_t)p * N_HITS * HD;
    const __bf16* zp = z + (size_t)p * N_HITS * HD;

    __shared__ __bf16 sA[128 * PADM];
    int t = threadIdx.x;
    int n0b = blockIdx.x * 128;
    int lane = t & 63, wave = t >> 6;
    int lcol = lane & 15, quad = lane >> 4;
    int nt0 = wave * 2;
    bool odd = (lcol & 1) != 0;

    // phase 1: stage z tile
    for (int i = t; i < 2048; i += 256) {
        int row = i >> 4, c = i & 15;
        int n = n0b + row; if (n >= N_HITS) n = N_HITS - 1;
        *(uint4*)&sA[row * PADM + c * 8] = ((const uint4*)(zp + (size_t)n * HD))[c];
    }
    __syncthreads();
    // phase 2: agg = z @ W2 + b2
    floatx4 agg[8][2];
    {
        const bf16x8* w2p = (const bf16x8*)W2P;
        bf16x8 B[2][4];
#pragma unroll
        for (int nt = 0; nt < 2; ++nt)
#pragma unroll
            for (int ks = 0; ks < 4; ++ks)
                B[nt][ks] = w2p[((nt0 + nt) * 4 + ks) * 64 + lane];
#pragma unroll
        for (int nt = 0; nt < 2; ++nt) {
            float bv = b2[(nt0 + nt) * 16 + lcol];
#pragma unroll
            for (int mt = 0; mt < 8; ++mt) agg[mt][nt] = (floatx4){bv, bv, bv, bv};
        }
#pragma unroll
        for (int mt = 0; mt < 8; ++mt)
#pragma unroll
            for (int ks = 0; ks < 4; ++ks) {
                bf16x8 a = *(const bf16x8*)&sA[(mt * 16 + lcol) * PADM + ks * 32 + quad * 8];
                agg[mt][0] = __builtin_amdgcn_mfma_f32_16x16x32_bf16(a, B[0][ks], agg[mt][0], 0, 0, 0);
                agg[mt][1] = __builtin_amdgcn_mfma_f32_16x16x32_bf16(a, B[1][ks], agg[mt][1], 0, 0, 0);
            }
    }
    __syncthreads();
    // phase 3: write agg (C-layout) -> sA as A-operand tile (paired cols)
#pragma unroll
    for (int mt = 0; mt < 8; ++mt)
#pragma unroll
        for (int r = 0; r < 4; ++r) {
            float v0 = agg[mt][0][r], v1 = agg[mt][1][r];
            float p0 = __shfl_xor(v0, 1), p1 = __shfl_xor(v1, 1);
            float av = odd ? p1 : v0, bv = odd ? v1 : p0;
            int col = nt0 * 16 + (odd ? 15 + lcol : lcol);
            int row = mt * 16 + quad * 4 + r;
            *(uint*)&sA[row * PADM + col] = f2b2(av, bv);
        }
    __syncthreads();
    // phase 4: aux-half MFMA (Wu ks 4..7)
    floatx4 acc[8][2];
    {
        const bf16x8* wup = (const bf16x8*)WuP;
        bf16x8 B[2][4];
#pragma unroll
        for (int nt = 0; nt < 2; ++nt)
#pragma unroll
            for (int ks = 0; ks < 4; ++ks)
                B[nt][ks] = wup[((nt0 + nt) * 8 + 4 + ks) * 64 + lane];
#pragma unroll
        for (int nt = 0; nt < 2; ++nt) {
            float bv = bu[(nt0 + nt) * 16 + lcol];
#pragma unroll
            for (int mt = 0; mt < 8; ++mt) acc[mt][nt] = (floatx4){bv, bv, bv, bv};
        }
#pragma unroll
        for (int mt = 0; mt < 8; ++mt)
#pragma unroll
            for (int ks = 0; ks < 4; ++ks) {
                bf16x8 a = *(const bf16x8*)&sA[(mt * 16 + lcol) * PADM + ks * 32 + quad * 8];
                acc[mt][0] = __builtin_amdgcn_mfma_f32_16x16x32_bf16(a, B[0][ks], acc[mt][0], 0, 0, 0);
                acc[mt][1] = __builtin_amdgcn_mfma_f32_16x16x32_bf16(a, B[1][ks], acc[mt][1], 0, 0, 0);
            }
    }
    __syncthreads();
    // phase 5: stage h tile
    for (int i = t; i < 2048; i += 256) {
        int row = i >> 4, c = i & 15;
        int n = n0b + row; if (n >= N_HITS) n = N_HITS - 1;
        *(uint4*)&sA[row * PADM + c * 8] = ((const uint4*)(hp + (size_t)n * HD))[c];
    }
    __syncthreads();
    // phase 6: h-half MFMA (Wu ks 0..3)
    {
        const bf16x8* wup = (const bf16x8*)WuP;
        bf16x8 B[2][4];
#pragma unroll
        for (int nt = 0; nt < 2; ++nt)
#pragma unroll
            for (int ks = 0; ks < 4; ++ks)
                B[nt][ks] = wup[((nt0 + nt) * 8 + ks) * 64 + lane];
#pragma unroll
        for (int mt = 0; mt < 8; ++mt)
#pragma unroll
            for (int ks = 0; ks < 4; ++ks) {
                bf16x8 a = *(const bf16x8*)&sA[(mt * 16 + lcol) * PADM + ks * 32 + quad * 8];
                acc[mt][0] = __builtin_amdgcn_mfma_f32_16x16x32_bf16(a, B[0][ks], acc[mt][0], 0, 0, 0);
                acc[mt][1] = __builtin_amdgcn_mfma_f32_16x16x32_bf16(a, B[1][ks], acc[mt][1], 0, 0, 0);
            }
    }
    // phase 7: residual RMW on bf16 h (paired cols)
#pragma unroll
    for (int mt = 0; mt < 8; ++mt)
#pragma unroll
        for (int r = 0; r < 4; ++r) {
            float v0 = fmaxf(acc[mt][0][r], 0.f), v1 = fmaxf(acc[mt][1][r], 0.f);
            float p0 = __shfl_xor(v0, 1), p1 = __shfl_xor(v1, 1);
            float av = odd ? p1 : v0, bv = odd ? v1 : p0;
            int col = nt0 * 16 + (odd ? 15 + lcol : lcol);
            int m = n0b + mt * 16 + quad * 4 + r;
            if (m < N_HITS) {
                uint* hp2 = (uint*)&hp[(size_t)m * HD + col];
                float2 ho = b2f2(*hp2);
                *hp2 = f2b2(ho.x + av, ho.y + bv);
            }
        }
}

// ---------------- nexus gather: sp[s] = sum_p mean_{k in CSR(3+p)[s]} h[hit_k] ----------------
__launch_bounds__(256)
__global__ void nx_gather_kernel(const __bf16* __restrict__ h, const int* __restrict__ off,
                                 const int* __restrict__ csr_s, __bf16* __restrict__ sp) {
    int wid = (blockIdx.x * 256 + threadIdx.x) >> 6;
    int lane = threadIdx.x & 63;
    if (wid >= N_SPS) return;
    float a0 = 0.f, a1 = 0.f;
#pragma unroll
    for (int p = 0; p < 3; ++p) {
        const int* o = off + (3 + p) * 30001;
        int beg = o[wid], end = o[wid + 1];
        const int* csr = csr_s + p * N_SPS;
        const __bf16* hb = h + (size_t)p * N_HITS * HD;
        float s0 = 0.f, s1 = 0.f;
        for (int k = beg; k < end; ++k) {
            int hit = csr[k];
            float2 hv = b2f2(*(const uint*)&hb[(size_t)hit * HD + 2 * lane]);
            s0 += hv.x; s1 += hv.y;
        }
        float iv = (end > beg) ? 1.f / (float)(end - beg) : 0.f;
        a0 += s0 * iv; a1 += s1 * iv;
    }
    *(uint*)&sp[(size_t)wid * HD + 2 * lane] = f2b2(a0, a1);
}

// ---------------- sp = relu(sp @ W_sp + b_sp), bf16 in/out ----------------
__launch_bounds__(256, 4)
__global__ void sp_gemm_kernel(__bf16* __restrict__ spf, const __bf16* __restrict__ WspP,
                               const float* __restrict__ b) {
    __shared__ __bf16 sA[128 * PADM];
    int t = threadIdx.x;
    int n0b = blockIdx.x * 128;
    for (int i = t; i < 2048; i += 256) {
        int row = i >> 4, c = i & 15;
        int n = n0b + row; if (n >= N_SPS) n = N_SPS - 1;
        *(uint4*)&sA[row * PADM + c * 8] = ((const uint4*)(spf + (size_t)n * HD))[c];
    }
    __syncthreads();

    int lane = t & 63, wave = t >> 6;
    int lcol = lane & 15, quad = lane >> 4;
    int nt0 = wave * 2;
    bool odd = (lcol & 1) != 0;

    const bf16x8* wp = (const bf16x8*)WspP;
    bf16x8 B[2][4];
#pragma unroll
    for (int nt = 0; nt < 2; ++nt)
#pragma unroll
        for (int ks = 0; ks < 4; ++ks)
            B[nt][ks] = wp[((nt0 + nt) * 4 + ks) * 64 + lane];

    floatx4 acc[8][2];
#pragma unroll
    for (int nt = 0; nt < 2; ++nt) {
        float bv = b[(nt0 + nt) * 16 + lcol];
#pragma unroll
        for (int mt = 0; mt < 8; ++mt) acc[mt][nt] = (floatx4){bv, bv, bv, bv};
    }
#pragma unroll
    for (int mt = 0; mt < 8; ++mt)
#pragma unroll
        for (int ks = 0; ks < 4; ++ks) {
            bf16x8 a = *(const bf16x8*)&sA[(mt * 16 + lcol) * PADM + ks * 32 + quad * 8];
            acc[mt][0] = __builtin_amdgcn_mfma_f32_16x16x32_bf16(a, B[0][ks], acc[mt][0], 0, 0, 0);
            acc[mt][1] = __builtin_amdgcn_mfma_f32_16x16x32_bf16(a, B[1][ks], acc[mt][1], 0, 0, 0);
        }
#pragma unroll
    for (int mt = 0; mt < 8; ++mt)
#pragma unroll
        for (int r = 0; r < 4; ++r) {
            int m = n0b + mt * 16 + quad * 4 + r;
            float v0 = fmaxf(acc[mt][0][r], 0.f), v1 = fmaxf(acc[mt][1][r], 0.f);
            float p0 = __shfl_xor(v0, 1), p1 = __shfl_xor(v1, 1);
            float av = odd ? p1 : v0, bv = odd ? v1 : p0;
            int col = nt0 * 16 + (odd ? 15 + lcol : lcol);
            if (m < N_SPS) *(uint*)&spf[(size_t)m * HD + col] = f2b2(av, bv);
        }
}

// ---------------- back gather: z[p][hit] = mean_{k in CSR(6+p)[hit]} sp[spid_k] ----------------
__launch_bounds__(256)
__global__ void back_gather_kernel(const __bf16* __restrict__ sp, const int* __restrict__ off,
                                   const int* __restrict__ csr_h, __bf16* __restrict__ z) {
    int wid = (blockIdx.x * 256 + threadIdx.x) >> 6;
    int lane = threadIdx.x & 63;
    if (wid >= 3 * N_HITS) return;
    int p = wid / N_HITS;
    int hit = wid - p * N_HITS;
    const int* o = off + (6 + p) * 30001;
    int beg = o[hit], end = o[hit + 1];
    const int* csr = csr_h + p * N_SPS;
    float a0 = 0.f, a1 = 0.f;
    for (int k = beg; k < end; ++k) {
        int spid = csr[k];
        float2 sv = b2f2(*(const uint*)&sp[(size_t)spid * HD + 2 * lane]);
        a0 += sv.x; a1 += sv.y;
    }
    float iv = (end > beg) ? 1.f / (float)(end - beg) : 0.f;
    *(uint*)&z[((size_t)p * N_HITS + hit) * HD + 2 * lane] = f2b2(a0 * iv, a1 * iv);
}

// ---------------- nexus update + fused y emission (aux = dense bf16 z) ----------------
__launch_bounds__(256, 4)
__global__ void update_y_kernel(__bf16* __restrict__ h, const __bf16* __restrict__ aux,
                                const __bf16* __restrict__ WP, const float* __restrict__ b,
                                const __bf16* __restrict__ W1dP, const __bf16* __restrict__ W1sP,
                                __bf16* __restrict__ y_d, __bf16* __restrict__ y_s) {
    int p = blockIdx.y;
    __bf16* hp = h + (size_t)p * N_HITS * HD;
    const __bf16* ap = aux + (size_t)p * N_HITS * HD;
    __bf16* ydp = y_d + (size_t)p * N_HITS * HD;
    __bf16* ysp = y_s + (size_t)p * N_HITS * HD;

    __shared__ __bf16 sA[128 * PADM];
    int t = threadIdx.x;
    int n0b = blockIdx.x * 128;

    int lane = t & 63, wave = t >> 6;
    int lcol = lane & 15, quad = lane >> 4;
    int nt0 = wave * 2;
    bool odd = (lcol & 1) != 0;

    const bf16x8* wp = (const bf16x8*)WP;
    floatx4 acc[8][2];
#pragma unroll
    for (int nt = 0; nt < 2; ++nt) {
        float bv = b[(nt0 + nt) * 16 + lcol];
#pragma unroll
        for (int mt = 0; mt < 8; ++mt) acc[mt][nt] = (floatx4){bv, bv, bv, bv};
    }

    // phase 1: h half
    for (int i = t; i < 2048; i += 256) {
        int row = i >> 4, c = i & 15;
        int n = n0b + row; if (n >= N_HITS) n = N_HITS - 1;
        *(uint4*)&sA[row * PADM + c * 8] = ((const uint4*)(hp + (size_t)n * HD))[c];
    }
    __syncthreads();
    {
        bf16x8 B[2][4];
#pragma unroll
        for (int nt = 0; nt < 2; ++nt)
#pragma unroll
            for (int ks = 0; ks < 4; ++ks)
                B[nt][ks] = wp[((nt0 + nt) * 8 + ks) * 64 + lane];
#pragma unroll
        for (int mt = 0; mt < 8; ++mt)
#pragma unroll
            for (int ks = 0; ks < 4; ++ks) {
                bf16x8 a = *(const bf16x8*)&sA[(mt * 16 + lcol) * PADM + ks * 32 + quad * 8];
                acc[mt][0] = __builtin_amdgcn_mfma_f32_16x16x32_bf16(a, B[0][ks], acc[mt][0], 0, 0, 0);
                acc[mt][1] = __builtin_amdgcn_mfma_f32_16x16x32_bf16(a, B[1][ks], acc[mt][1], 0, 0, 0);
            }
    }
    __syncthreads();
    // phase 2: aux half (bf16 direct)
    for (int i = t; i < 2048; i += 256) {
        int row = i >> 4, c = i & 15;
        int n = n0b + row; if (n >= N_HITS) n = N_HITS - 1;
        *(uint4*)&sA[row * PADM + c * 8] = ((const uint4*)(ap + (size_t)n * HD))[c];
    }
    __syncthreads();
    {
        bf16x8 B[2][4];
#pragma unroll
        for (int nt = 0; nt < 2; ++nt)
#pragma unroll
            for (int ks = 0; ks < 4; ++ks)
                B[nt][ks] = wp[((nt0 + nt) * 8 + 4 + ks) * 64 + lane];
#pragma unroll
        for (int mt = 0; mt < 8; ++mt)
#pragma unroll
            for (int ks = 0; ks < 4; ++ks) {
                bf16x8 a = *(const bf16x8*)&sA[(mt * 16 + lcol) * PADM + ks * 32 + quad * 8];
                acc[mt][0] = __builtin_amdgcn_mfma_f32_16x16x32_bf16(a, B[0][ks], acc[mt][0], 0, 0, 0);
                acc[mt][1] = __builtin_amdgcn_mfma_f32_16x16x32_bf16(a, B[1][ks], acc[mt][1], 0, 0, 0);
            }
    }
    __syncthreads();  // aux reads done; overwrite sA with h_new

    // epilogue: h_new = h_old + relu(acc); bf16 RMW + tile into sA
#pragma unroll
    for (int mt = 0; mt < 8; ++mt)
#pragma unroll
        for (int r = 0; r < 4; ++r) {
            float v0 = fmaxf(acc[mt][0][r], 0.f), v1 = fmaxf(acc[mt][1][r], 0.f);
            float p0 = __shfl_xor(v0, 1), p1 = __shfl_xor(v1, 1);
            float av = odd ? p1 : v0, bv = odd ? v1 : p0;
            int col = nt0 * 16 + (odd ? 15 + lcol : lcol);
            int row = mt * 16 + quad * 4 + r;
            int m = n0b + row;
            float n0v = 0.f, n1v = 0.f;
            if (m < N_HITS) {
                uint* hp2 = (uint*)&hp[(size_t)m * HD + col];
                float2 ho = b2f2(*hp2);
                n0v = ho.x + av; n1v = ho.y + bv;
                *hp2 = f2b2(n0v, n1v);
            }
            *(uint*)&sA[row * PADM + col] = f2b2(n0v, n1v);
        }
    __syncthreads();

    // y GEMMs
    for (int half = 0; half < 2; ++half) {
        const bf16x8* wyp = (const bf16x8*)(half == 0 ? W1dP : W1sP);
        __bf16* out = half == 0 ? ydp : ysp;
        bf16x8 B[2][4];
#pragma unroll
        for (int nt = 0; nt < 2; ++nt)
#pragma unroll
            for (int ks = 0; ks < 4; ++ks)
                B[nt][ks] = wyp[((nt0 + nt) * 4 + ks) * 64 + lane];
        floatx4 yacc[8][2];
#pragma unroll
        for (int mt = 0; mt < 8; ++mt) { yacc[mt][0] = (floatx4){0,0,0,0}; yacc[mt][1] = (floatx4){0,0,0,0}; }
#pragma unroll
        for (int mt = 0; mt < 8; ++mt)
#pragma unroll
            for (int ks = 0; ks < 4; ++ks) {
                bf16x8 a = *(const bf16x8*)&sA[(mt * 16 + lcol) * PADM + ks * 32 + quad * 8];
                yacc[mt][0] = __builtin_amdgcn_mfma_f32_16x16x32_bf16(a, B[0][ks], yacc[mt][0], 0, 0, 0);
                yacc[mt][1] = __builtin_amdgcn_mfma_f32_16x16x32_bf16(a, B[1][ks], yacc[mt][1], 0, 0, 0);
            }
#pragma unroll
        for (int mt = 0; mt < 8; ++mt)
#pragma unroll
            for (int r = 0; r < 4; ++r) {
                int m = n0b + mt * 16 + quad * 4 + r;
                float v0 = yacc[mt][0][r], v1 = yacc[mt][1][r];
                float p0 = __shfl_xor(v0, 1), p1 = __shfl_xor(v1, 1);
                float av = odd ? p1 : v0, bv = odd ? v1 : p0;
                int col = nt0 * 16 + (odd ? 15 + lcol : lcol);
                if (m < N_HITS) *(uint*)&out[(size_t)m * HD + col] = f2b2(av, bv);
            }
    }
}

// ---------------- decoder ----------------
__global__ void dec_kernel(const __bf16* __restrict__ h, const float* __restrict__ W,
                           const float* __restrict__ b, float* __restrict__ out) {
    __shared__ float sW[640];
    __shared__ float sB[8];
    int t = threadIdx.x;
    for (int i = t; i < 640; i += 256) sW[i] = W[i];
    if (t < 5) sB[t] = b[t];
    __syncthreads();
    int n = blockIdx.x * 256 + t;
    if (n >= 3 * N_HITS) return;
    const uint4* hr = (const uint4*)(h + (size_t)n * HD);
    float a0 = sB[0], a1 = sB[1], a2 = sB[2], a3 = sB[3], a4 = sB[4];
#pragma unroll 4
    for (int q = 0; q < 16; ++q) {
        union { uint4 u; __bf16 bb[8]; } v; v.u = hr[q];
        const float* w = &sW[q * 40];
#pragma unroll
        for (int j = 0; j < 8; ++j) {
            float x = (float)v.bb[j];
            a0 = fmaf(x, w[j * 5 + 0], a0);
            a1 = fmaf(x, w[j * 5 + 1], a1);
            a2 = fmaf(x, w[j * 5 + 2], a2);
            a3 = fmaf(x, w[j * 5 + 3], a3);
            a4 = fmaf(x, w[j * 5 + 4], a4);
        }
    }
    float* o = out + (size_t)n * NCLS;
    o[0] = a0; o[1] = a1; o[2] = a2; o[3] = a3; o[4] = a4;
}

extern "C" void kernel_launch(void* const* d_in, const int* in_sizes, int n_in,
                              void* d_out, int out_size, void* d_ws, size_t ws_size,
                              hipStream_t stream) {
    const float* xu = (const float*)d_in[0];
    const int* eu = (const int*)d_in[1];
    const int* nu = (const int*)d_in[2];
    const float* xv = (const float*)d_in[3];
    const int* ev = (const int*)d_in[4];
    const int* nv = (const int*)d_in[5];
    const float* xy = (const float*)d_in[6];
    const int* ey = (const int*)d_in[7];
    const int* ny = (const int*)d_in[8];
    const float* W_enc = (const float*)d_in[9];
    const float* b_enc = (const float*)d_in[10];
    const float* W1 = (const float*)d_in[11];
    const float* b1 = (const float*)d_in[12];
    const float* W2 = (const float*)d_in[13];
    const float* b2 = (const float*)d_in[14];
    const float* W_upd = (const float*)d_in[15];
    const float* b_upd = (const float*)d_in[16];
    const float* W_sp = (const float*)d_in[17];
    const float* b_sp = (const float*)d_in[18];
    const float* W_nx = (const float*)d_in[19];
    const float* b_nx = (const float*)d_in[20];
    const float* W_sem = (const float*)d_in[21];
    const float* b_sem = (const float*)d_in[22];

    const size_t HN = (size_t)3 * N_HITS * HD;  // 11,520,000
    __bf16* h = (__bf16*)d_ws;                   // bf16 [3][N_HITS][HD]
    __bf16* z = h + HN;                          // bf16 [3][N_HITS][HD] (edge agg / nexus back)
    __bf16* y_d = z + HN;                        // bf16 [3][N_HITS][HD]
    __bf16* y_s = y_d + HN;                      // bf16 [3][N_HITS][HD]
    __bf16* sp = y_s + HN;                       // bf16 [N_SPS][HD]
    int* cnt = (int*)(sp + (size_t)N_SPS * HD);  // [270000]
    int* off = cnt + 270000;                     // [9*30001]
    int* cursor = off + 270009;                  // [270000]
    int* csr_e = cursor + 270000;                // [3*90000]
    int* csr_s = csr_e + 270000;                 // [3*30000]
    int* csr_h = csr_s + 90000;                  // [3*30000]
    __bf16* packs = (__bf16*)(csr_h + 90000);    // [131072]
    __bf16* W1dP = packs;
    __bf16* W1sP = packs + 16384;
    __bf16* W2P = packs + 32768;
    __bf16* WuP = packs + 49152;
    __bf16* WnP = packs + 81920;
    __bf16* WspP = packs + 114688;

    wprep_kernel<<<512, 256, 0, stream>>>(W1, W2, W_upd, W_nx, W_sp, packs);
    (void)hipMemsetAsync(cnt, 0, 270000 * sizeof(int), stream);
    hist_all_kernel<<<(450000 + 255) / 256, 256, 0, stream>>>(eu, ev, ey, nu, nv, ny, cnt);
    scan_kernel<<<9, 1024, 0, stream>>>(cnt, off, cursor);
    fill_kernel<<<(450000 + 255) / 256, 256, 0, stream>>>(eu, ev, ey, nu, nv, ny,
                                                          cursor, csr_e, csr_s, csr_h);

    enc_kernel<<<(3 * N_HITS * HD + 255) / 256, 256, 0, stream>>>(xu, xv, xy, W_enc, b_enc, h);
    y_init_kernel<<<(3 * N_HITS + 127) / 128, 256, 0, stream>>>(h, W1dP, W1sP, y_d, y_s);

    for (int it = 0; it < 3; ++it) {
        edge_gather_kernel<<<(3 * N_HITS * 64 + 255) / 256, 256, 0, stream>>>(
            y_d, y_s, off, csr_e, b1, z);
        update_planar_kernel<<<dim3((N_HITS + 127) / 128, 3), 256, 0, stream>>>(
            h, z, W2P, b2, WuP, b_upd);
        nx_gather_kernel<<<(N_SPS * 64 + 255) / 256, 256, 0, stream>>>(h, off, csr_s, sp);
        sp_gemm_kernel<<<(N_SPS + 127) / 128, 256, 0, stream>>>(sp, WspP, b_sp);
        back_gather_kernel<<<(3 * N_HITS * 64 + 255) / 256, 256, 0, stream>>>(sp, off, csr_h, z);
        update_y_kernel<<<dim3((N_HITS + 127) / 128, 3), 256, 0, stream>>>(
            h, z, WnP, b_nx, W1dP, W1sP, y_d, y_s);
    }

    dec_kernel<<<(3 * N_HITS + 255) / 256, 256, 0, stream>>>(h, W_sem, b_sem, (float*)d_out);
}

// Round 10
// 761.071 us; speedup vs baseline: 1.3955x; 1.1094x over previous
//
#include <hip/hip_runtime.h>
#include <hip/hip_fp16.h>

#define N_HITS 30000
#define N_EDGES 90000
#define N_SPS 30000
#define HD 128
#define NCLS 5

#define PADM 136  // 128 + 8 bf16 pad

typedef __attribute__((ext_vector_type(8))) __bf16 bf16x8;
typedef __attribute__((ext_vector_type(4))) float floatx4;

__device__ __forceinline__ float2 b2f2(uint u) {
    union { uint u; __bf16 b[2]; } x; x.u = u;
    return make_float2((float)x.b[0], (float)x.b[1]);
}
__device__ __forceinline__ uint f2b2(float a, float b) {
    union { uint u; __bf16 b[2]; } x; x.b[0] = (__bf16)a; x.b[1] = (__bf16)b;
    return x.u;
}

// ---------------- encoder ----------------
__global__ void enc_kernel(const float* __restrict__ xu, const float* __restrict__ xv,
                           const float* __restrict__ xy, const float* __restrict__ W,
                           const float* __restrict__ b, __bf16* __restrict__ h) {
    int gid = blockIdx.x * blockDim.x + threadIdx.x;
    if (gid >= 3 * N_HITS * HD) return;
    int j = gid & (HD - 1);
    int n = (gid >> 7) % N_HITS;
    int p = gid / (N_HITS * HD);
    const float* x = (p == 0) ? xu : (p == 1) ? xv : xy;
    float acc = b[j];
#pragma unroll
    for (int k = 0; k < 4; ++k) acc = fmaf(x[n * 4 + k], W[k * HD + j], acc);
    h[gid] = (__bf16)fmaxf(acc, 0.f);
}

// ---------------- histograms: 9 segments of 30000 counts ----------------
__global__ void hist_all_kernel(const int* __restrict__ eu, const int* __restrict__ ev,
                                const int* __restrict__ ey, const int* __restrict__ nu,
                                const int* __restrict__ nv, const int* __restrict__ ny,
                                int* __restrict__ cnt) {
    int gid = blockIdx.x * blockDim.x + threadIdx.x;
    if (gid >= 450000) return;
    int p = gid / 150000;
    int r = gid - p * 150000;
    const int* e = (p == 0) ? eu : (p == 1) ? ev : ey;
    const int* nx = (p == 0) ? nu : (p == 1) ? nv : ny;
    if (r < N_EDGES) {
        atomicAdd(&cnt[p * 30000 + e[N_EDGES + r]], 1);
    } else if (r < N_EDGES + N_SPS) {
        int i = r - N_EDGES;
        atomicAdd(&cnt[(3 + p) * 30000 + nx[N_SPS + i]], 1);
    } else {
        int i = r - N_EDGES - N_SPS;
        atomicAdd(&cnt[(6 + p) * 30000 + nx[i]], 1);
    }
}

// ---------------- exclusive scan per segment ----------------
__launch_bounds__(1024)
__global__ void scan_kernel(const int* __restrict__ cnt, int* __restrict__ off,
                            int* __restrict__ cursor) {
    int seg = blockIdx.x;
    const int* c = cnt + seg * 30000;
    int* o = off + seg * 30001;
    int* cur = cursor + seg * 30000;
    int t = threadIdx.x;
    int base = t * 30;
    int lc[30];
    int sum = 0;
#pragma unroll
    for (int k = 0; k < 30; ++k) {
        int i = base + k;
        lc[k] = (i < 30000) ? c[i] : 0;
        sum += lc[k];
    }
    __shared__ int part[1024];
    part[t] = sum;
    __syncthreads();
    for (int d = 1; d < 1024; d <<= 1) {
        int x = (t >= d) ? part[t - d] : 0;
        __syncthreads();
        part[t] += x;
        __syncthreads();
    }
    int run = part[t] - sum;
#pragma unroll
    for (int k = 0; k < 30; ++k) {
        int i = base + k;
        if (i < 30000) { o[i] = run; cur[i] = run; run += lc[k]; }
    }
    if (t == 1023) o[30000] = part[1023];
}

// ---------------- CSR fill ----------------
__global__ void fill_kernel(const int* __restrict__ eu, const int* __restrict__ ev,
                            const int* __restrict__ ey, const int* __restrict__ nu,
                            const int* __restrict__ nv, const int* __restrict__ ny,
                            int* __restrict__ cursor, int* __restrict__ csr_e,
                            int* __restrict__ csr_s, int* __restrict__ csr_h) {
    int gid = blockIdx.x * blockDim.x + threadIdx.x;
    if (gid >= 450000) return;
    int p = gid / 150000;
    int r = gid - p * 150000;
    const int* e = (p == 0) ? eu : (p == 1) ? ev : ey;
    const int* nx = (p == 0) ? nu : (p == 1) ? nv : ny;
    if (r < N_EDGES) {
        int d = e[N_EDGES + r];
        int pos = atomicAdd(&cursor[p * 30000 + d], 1);
        csr_e[p * N_EDGES + pos] = e[r];
    } else if (r < N_EDGES + N_SPS) {
        int i = r - N_EDGES;
        int spid = nx[N_SPS + i];
        int pos = atomicAdd(&cursor[(3 + p) * 30000 + spid], 1);
        csr_s[p * N_SPS + pos] = nx[i];
    } else {
        int i = r - N_EDGES - N_SPS;
        int hit = nx[i];
        int pos = atomicAdd(&cursor[(6 + p) * 30000 + hit], 1);
        csr_h[p * N_SPS + pos] = nx[N_SPS + i];
    }
}

// ---------------- weight pre-pack ----------------
__device__ __forceinline__ void pack4(const float* __restrict__ W, __bf16* __restrict__ P,
                                      int idx, int koff) {
    int j = idx & 7, lane = (idx >> 3) & 63, ks = (idx >> 9) & 3, n = (idx >> 11) & 7;
    int k = ks * 32 + (lane >> 4) * 8 + j, col = n * 16 + (lane & 15);
    P[idx] = (__bf16)W[(k + koff) * 128 + col];
}
__device__ __forceinline__ void pack8(const float* __restrict__ W, __bf16* __restrict__ P, int idx) {
    int j = idx & 7, lane = (idx >> 3) & 63, ks = (idx >> 9) & 7, n = (idx >> 12) & 7;
    int k = ks * 32 + (lane >> 4) * 8 + j, col = n * 16 + (lane & 15);
    P[idx] = (__bf16)W[k * 128 + col];
}

__global__ void wprep_kernel(const float* __restrict__ W1, const float* __restrict__ W2,
                             const float* __restrict__ Wu, const float* __restrict__ Wn,
                             const float* __restrict__ Wsp, __bf16* __restrict__ packs) {
    int gid = blockIdx.x * blockDim.x + threadIdx.x;
    if (gid < 16384) { pack4(W1, packs, gid, 0); return; }
    gid -= 16384;
    if (gid < 16384) { pack4(W1, packs + 16384, gid, 128); return; }
    gid -= 16384;
    if (gid < 16384) { pack4(W2, packs + 32768, gid, 0); return; }
    gid -= 16384;
    if (gid < 32768) { pack8(Wu, packs + 49152, gid); return; }
    gid -= 32768;
    if (gid < 32768) { pack8(Wn, packs + 81920, gid); return; }
    gid -= 32768;
    if (gid < 16384) { pack4(Wsp, packs + 114688, gid, 0); }
}

// ---------------- y_init ----------------
__launch_bounds__(256, 4)
__global__ void y_init_kernel(const __bf16* __restrict__ h, const __bf16* __restrict__ W1dP,
                              const __bf16* __restrict__ W1sP, __bf16* __restrict__ y_d,
                              __bf16* __restrict__ y_s) {
    __shared__ __bf16 sA[128 * PADM];
    int t = threadIdx.x;
    int n0b = blockIdx.x * 128;
    const int M = 3 * N_HITS;
    for (int i = t; i < 2048; i += 256) {
        int row = i >> 4, c = i & 15;
        int n = n0b + row; if (n >= M) n = M - 1;
        *(uint4*)&sA[row * PADM + c * 8] = ((const uint4*)(h + (size_t)n * HD))[c];
    }
    __syncthreads();

    int lane = t & 63, wave = t >> 6;
    int lcol = lane & 15, quad = lane >> 4;
    int nt0 = wave * 2;
    bool odd = (lcol & 1) != 0;

    for (int half = 0; half < 2; ++half) {
        const bf16x8* wp = (const bf16x8*)(half == 0 ? W1dP : W1sP);
        __bf16* out = half == 0 ? y_d : y_s;
        bf16x8 B[2][4];
#pragma unroll
        for (int nt = 0; nt < 2; ++nt)
#pragma unroll
            for (int ks = 0; ks < 4; ++ks)
                B[nt][ks] = wp[((nt0 + nt) * 4 + ks) * 64 + lane];
        floatx4 acc[8][2];
#pragma unroll
        for (int mt = 0; mt < 8; ++mt) { acc[mt][0] = (floatx4){0,0,0,0}; acc[mt][1] = (floatx4){0,0,0,0}; }
#pragma unroll
        for (int mt = 0; mt < 8; ++mt)
#pragma unroll
            for (int ks = 0; ks < 4; ++ks) {
                bf16x8 a = *(const bf16x8*)&sA[(mt * 16 + lcol) * PADM + ks * 32 + quad * 8];
                acc[mt][0] = __builtin_amdgcn_mfma_f32_16x16x32_bf16(a, B[0][ks], acc[mt][0], 0, 0, 0);
                acc[mt][1] = __builtin_amdgcn_mfma_f32_16x16x32_bf16(a, B[1][ks], acc[mt][1], 0, 0, 0);
            }
#pragma unroll
        for (int mt = 0; mt < 8; ++mt)
#pragma unroll
            for (int r = 0; r < 4; ++r) {
                int m = n0b + mt * 16 + quad * 4 + r;
                float v0 = acc[mt][0][r], v1 = acc[mt][1][r];
                float p0 = __shfl_xor(v0, 1), p1 = __shfl_xor(v1, 1);
                float av = odd ? p1 : v0, bv = odd ? v1 : p0;
                int col = nt0 * 16 + (odd ? 15 + lcol : lcol);
                if (m < M) *(uint*)&out[(size_t)m * HD + col] = f2b2(av, bv);
            }
    }
}

// ---------------- planar update, fused edge gather:
// z=mean relu(yd[d]+ys[src]+b1); agg=z@W2+b2; h += relu([h|agg]@Wu+bu) ----------------
__launch_bounds__(256, 4)
__global__ void update_planar_kernel(__bf16* __restrict__ h, const __bf16* __restrict__ y_d,
                                     const __bf16* __restrict__ y_s, const int* __restrict__ off,
                                     const int* __restrict__ csr_e, const float* __restrict__ b1,
                                     const __bf16* __restrict__ W2P, const float* __restrict__ b2,
                                     const __bf16* __restrict__ WuP, const float* __restrict__ bu) {
    int p = blockIdx.y;
    __bf16* hp = h + (size_t)p * N_HITS * HD;
    const __bf16* ydp = y_d + (size_t)p * N_HITS * HD;
    const __bf16* ysp = y_s + (size_t)p * N_HITS * HD;
    const int* o = off + p * 30001;
    const int* csr = csr_e + p * N_EDGES;

    __shared__ __bf16 sA[128 * PADM];
    int t = threadIdx.x;
    int n0b = blockIdx.x * 128;
    int lane = t & 63, wave = t >> 6;
    int lcol = lane & 15, quad = lane >> 4;
    int nt0 = wave * 2;
    bool odd = (lcol & 1) != 0;

    // phase A: stage z tile via CSR edge gather-reduce
    for (int i = t; i < 2048; i += 256) {
        int row = i >> 4, c = i & 15;
        int d = n0b + row; if (d >= N_HITS) d = N_HITS - 1;
        int beg = o[d], end = o[d + 1];
        union { uint4 u; __bf16 b[8]; } yd;
        yd.u = ((const uint4*)(ydp + (size_t)d * HD))[c];
        float4 b1a = *(const float4*)(b1 + c * 8);
        float4 b1b = *(const float4*)(b1 + c * 8 + 4);
        float bb[8] = {b1a.x, b1a.y, b1a.z, b1a.w, b1b.x, b1b.y, b1b.z, b1b.w};
        float a8[8] = {0, 0, 0, 0, 0, 0, 0, 0};
        for (int k = beg; k < end; ++k) {
            int s = csr[k];
            union { uint4 u; __bf16 b[8]; } ys;
            ys.u = ((const uint4*)(ysp + (size_t)s * HD))[c];
#pragma unroll
            for (int j = 0; j < 8; ++j)
                a8[j] += fmaxf((float)yd.b[j] + (float)ys.b[j] + bb[j], 0.f);
        }
        float iv = (end > beg) ? 1.f / (float)(end - beg) : 0.f;
        union { __bf16 o8[8]; uint4 u; } outv;
#pragma unroll
        for (int j = 0; j < 8; ++j) outv.o8[j] = (__bf16)(a8[j] * iv);
        *(uint4*)&sA[row * PADM + c * 8] = outv.u;
    }
    __syncthreads();

    // phase B: agg = z @ W2 + b2
    floatx4 agg[8][2];
    {
        const bf16x8* w2p = (const bf16x8*)W2P;
        bf16x8 B[2][4];
#pragma unroll
        for (int nt = 0; nt < 2; ++nt)
#pragma unroll
            for (int ks = 0; ks < 4; ++ks)
                B[nt][ks] = w2p[((nt0 + nt) * 4 + ks) * 64 + lane];
#pragma unroll
        for (int nt = 0; nt < 2; ++nt) {
            float bv = b2[(nt0 + nt) * 16 + lcol];
#pragma unroll
            for (int mt = 0; mt < 8; ++mt) agg[mt][nt] = (floatx4){bv, bv, bv, bv};
        }
#pragma unroll
        for (int mt = 0; mt < 8; ++mt)
#pragma unroll
            for (int ks = 0; ks < 4; ++ks) {
                bf16x8 a = *(const bf16x8*)&sA[(mt * 16 + lcol) * PADM + ks * 32 + quad * 8];
                agg[mt][0] = __builtin_amdgcn_mfma_f32_16x16x32_bf16(a, B[0][ks], agg[mt][0], 0, 0, 0);
                agg[mt][1] = __builtin_amdgcn_mfma_f32_16x16x32_bf16(a, B[1][ks], agg[mt][1], 0, 0, 0);
            }
    }
    __syncthreads();
    // phase C: agg (C-layout) -> sA as A-tile
#pragma unroll
    for (int mt = 0; mt < 8; ++mt)
#pragma unroll
        for (int r = 0; r < 4; ++r) {
            float v0 = agg[mt][0][r], v1 = agg[mt][1][r];
            float p0 = __shfl_xor(v0, 1), p1 = __shfl_xor(v1, 1);
            float av = odd ? p1 : v0, bv = odd ? v1 : p0;
            int col = nt0 * 16 + (odd ? 15 + lcol : lcol);
            *(uint*)&sA[(mt * 16 + quad * 4 + r) * PADM + col] = f2b2(av, bv);
        }
    __syncthreads();
    // phase D: acc = bu + agg-tile @ Wu[ks4..7]
    floatx4 acc[8][2];
    {
        const bf16x8* wup = (const bf16x8*)WuP;
        bf16x8 B[2][4];
#pragma unroll
        for (int nt = 0; nt < 2; ++nt)
#pragma unroll
            for (int ks = 0; ks < 4; ++ks)
                B[nt][ks] = wup[((nt0 + nt) * 8 + 4 + ks) * 64 + lane];
#pragma unroll
        for (int nt = 0; nt < 2; ++nt) {
            float bv = bu[(nt0 + nt) * 16 + lcol];
#pragma unroll
            for (int mt = 0; mt < 8; ++mt) acc[mt][nt] = (floatx4){bv, bv, bv, bv};
        }
#pragma unroll
        for (int mt = 0; mt < 8; ++mt)
#pragma unroll
            for (int ks = 0; ks < 4; ++ks) {
                bf16x8 a = *(const bf16x8*)&sA[(mt * 16 + lcol) * PADM + ks * 32 + quad * 8];
                acc[mt][0] = __builtin_amdgcn_mfma_f32_16x16x32_bf16(a, B[0][ks], acc[mt][0], 0, 0, 0);
                acc[mt][1] = __builtin_amdgcn_mfma_f32_16x16x32_bf16(a, B[1][ks], acc[mt][1], 0, 0, 0);
            }
    }
    __syncthreads();
    // phase E: stage h tile
    for (int i = t; i < 2048; i += 256) {
        int row = i >> 4, c = i & 15;
        int n = n0b + row; if (n >= N_HITS) n = N_HITS - 1;
        *(uint4*)&sA[row * PADM + c * 8] = ((const uint4*)(hp + (size_t)n * HD))[c];
    }
    __syncthreads();
    // phase F: acc += h-tile @ Wu[ks0..3]
    {
        const bf16x8* wup = (const bf16x8*)WuP;
        bf16x8 B[2][4];
#pragma unroll
        for (int nt = 0; nt < 2; ++nt)
#pragma unroll
            for (int ks = 0; ks < 4; ++ks)
                B[nt][ks] = wup[((nt0 + nt) * 8 + ks) * 64 + lane];
#pragma unroll
        for (int mt = 0; mt < 8; ++mt)
#pragma unroll
            for (int ks = 0; ks < 4; ++ks) {
                bf16x8 a = *(const bf16x8*)&sA[(mt * 16 + lcol) * PADM + ks * 32 + quad * 8];
                acc[mt][0] = __builtin_amdgcn_mfma_f32_16x16x32_bf16(a, B[0][ks], acc[mt][0], 0, 0, 0);
                acc[mt][1] = __builtin_amdgcn_mfma_f32_16x16x32_bf16(a, B[1][ks], acc[mt][1], 0, 0, 0);
            }
    }
    __syncthreads();
    // phase G: h_new = h_old(sA) + relu(acc) -> back into sA (paired cols)
#pragma unroll
    for (int mt = 0; mt < 8; ++mt)
#pragma unroll
        for (int r = 0; r < 4; ++r) {
            float v0 = fmaxf(acc[mt][0][r], 0.f), v1 = fmaxf(acc[mt][1][r], 0.f);
            float p0 = __shfl_xor(v0, 1), p1 = __shfl_xor(v1, 1);
            float av = odd ? p1 : v0, bv = odd ? v1 : p0;
            int col = nt0 * 16 + (odd ? 15 + lcol : lcol);
            int row = mt * 16 + quad * 4 + r;
            uint* sp2 = (uint*)&sA[row * PADM + col];
            float2 ho = b2f2(*sp2);
            *sp2 = f2b2(ho.x + av, ho.y + bv);
        }
    __syncthreads();
    // phase H: coalesced uint4 store sA -> h
    for (int i = t; i < 2048; i += 256) {
        int row = i >> 4, c = i & 15;
        int n = n0b + row;
        if (n < N_HITS) ((uint4*)(hp + (size_t)n * HD))[c] = *(uint4*)&sA[row * PADM + c * 8];
    }
}

// ---------------- sp fused: gather (3-plane mean of h) + GEMM + relu -> sp ----------------
__launch_bounds__(256, 4)
__global__ void sp_fused_kernel(const __bf16* __restrict__ h, const int* __restrict__ off,
                                const int* __restrict__ csr_s, const __bf16* __restrict__ WspP,
                                const float* __restrict__ b, __bf16* __restrict__ spf) {
    __shared__ __bf16 sA[128 * PADM];
    int t = threadIdx.x;
    int n0b = blockIdx.x * 128;
    int lane = t & 63, wave = t >> 6;
    int lcol = lane & 15, quad = lane >> 4;
    int nt0 = wave * 2;
    bool odd = (lcol & 1) != 0;

    // phase A: stage sp-input tile via CSR gather over 3 planes
    for (int i = t; i < 2048; i += 256) {
        int row = i >> 4, c = i & 15;
        int s = n0b + row; if (s >= N_SPS) s = N_SPS - 1;
        float a8[8] = {0, 0, 0, 0, 0, 0, 0, 0};
#pragma unroll
        for (int p = 0; p < 3; ++p) {
            const int* o = off + (3 + p) * 30001;
            int beg = o[s], end = o[s + 1];
            const int* csr = csr_s + p * N_SPS;
            const __bf16* hb = h + (size_t)p * N_HITS * HD;
            float s8[8] = {0, 0, 0, 0, 0, 0, 0, 0};
            for (int k = beg; k < end; ++k) {
                int hit = csr[k];
                union { uint4 u; __bf16 b[8]; } hv;
                hv.u = ((const uint4*)(hb + (size_t)hit * HD))[c];
#pragma unroll
                for (int j = 0; j < 8; ++j) s8[j] += (float)hv.b[j];
            }
            float iv = (end > beg) ? 1.f / (float)(end - beg) : 0.f;
#pragma unroll
            for (int j = 0; j < 8; ++j) a8[j] += s8[j] * iv;
        }
        union { __bf16 o8[8]; uint4 u; } outv;
#pragma unroll
        for (int j = 0; j < 8; ++j) outv.o8[j] = (__bf16)a8[j];
        *(uint4*)&sA[row * PADM + c * 8] = outv.u;
    }
    __syncthreads();

    const bf16x8* wp = (const bf16x8*)WspP;
    bf16x8 B[2][4];
#pragma unroll
    for (int nt = 0; nt < 2; ++nt)
#pragma unroll
        for (int ks = 0; ks < 4; ++ks)
            B[nt][ks] = wp[((nt0 + nt) * 4 + ks) * 64 + lane];

    floatx4 acc[8][2];
#pragma unroll
    for (int nt = 0; nt < 2; ++nt) {
        float bv = b[(nt0 + nt) * 16 + lcol];
#pragma unroll
        for (int mt = 0; mt < 8; ++mt) acc[mt][nt] = (floatx4){bv, bv, bv, bv};
    }
#pragma unroll
    for (int mt = 0; mt < 8; ++mt)
#pragma unroll
        for (int ks = 0; ks < 4; ++ks) {
            bf16x8 a = *(const bf16x8*)&sA[(mt * 16 + lcol) * PADM + ks * 32 + quad * 8];
            acc[mt][0] = __builtin_amdgcn_mfma_f32_16x16x32_bf16(a, B[0][ks], acc[mt][0], 0, 0, 0);
            acc[mt][1] = __builtin_amdgcn_mfma_f32_16x16x32_bf16(a, B[1][ks], acc[mt][1], 0, 0, 0);
        }
    __syncthreads();
    // relu -> sA (paired cols), then coalesced store
#pragma unroll
    for (int mt = 0; mt < 8; ++mt)
#pragma unroll
        for (int r = 0; r < 4; ++r) {
            float v0 = fmaxf(acc[mt][0][r], 0.f), v1 = fmaxf(acc[mt][1][r], 0.f);
            float p0 = __shfl_xor(v0, 1), p1 = __shfl_xor(v1, 1);
            float av = odd ? p1 : v0, bv = odd ? v1 : p0;
            int col = nt0 * 16 + (odd ? 15 + lcol : lcol);
            *(uint*)&sA[(mt * 16 + quad * 4 + r) * PADM + col] = f2b2(av, bv);
        }
    __syncthreads();
    for (int i = t; i < 2048; i += 256) {
        int row = i >> 4, c = i & 15;
        int n = n0b + row;
        if (n < N_SPS) ((uint4*)(spf + (size_t)n * HD))[c] = *(uint4*)&sA[row * PADM + c * 8];
    }
}

// ---------------- nexus update, fused back gather + y emission ----------------
__launch_bounds__(256, 4)
__global__ void update_y_kernel(__bf16* __restrict__ h, const __bf16* __restrict__ sp,
                                const int* __restrict__ off, const int* __restrict__ csr_h,
                                const __bf16* __restrict__ WP, const float* __restrict__ b,
                                const __bf16* __restrict__ W1dP, const __bf16* __restrict__ W1sP,
                                __bf16* __restrict__ y_d, __bf16* __restrict__ y_s) {
    int p = blockIdx.y;
    __bf16* hp = h + (size_t)p * N_HITS * HD;
    __bf16* ydp = y_d + (size_t)p * N_HITS * HD;
    __bf16* ysp = y_s + (size_t)p * N_HITS * HD;
    const int* o = off + (6 + p) * 30001;
    const int* csr = csr_h + p * N_SPS;

    __shared__ __bf16 sA[128 * PADM];
    int t = threadIdx.x;
    int n0b = blockIdx.x * 128;
    int lane = t & 63, wave = t >> 6;
    int lcol = lane & 15, quad = lane >> 4;
    int nt0 = wave * 2;
    bool odd = (lcol & 1) != 0;

    const bf16x8* wp = (const bf16x8*)WP;
    floatx4 acc[8][2];
#pragma unroll
    for (int nt = 0; nt < 2; ++nt) {
        float bv = b[(nt0 + nt) * 16 + lcol];
#pragma unroll
        for (int mt = 0; mt < 8; ++mt) acc[mt][nt] = (floatx4){bv, bv, bv, bv};
    }

    // phase A: stage aux = back-gather mean of sp rows
    for (int i = t; i < 2048; i += 256) {
        int row = i >> 4, c = i & 15;
        int hit = n0b + row; if (hit >= N_HITS) hit = N_HITS - 1;
        int beg = o[hit], end = o[hit + 1];
        float a8[8] = {0, 0, 0, 0, 0, 0, 0, 0};
        for (int k = beg; k < end; ++k) {
            int spid = csr[k];
            union { uint4 u; __bf16 b[8]; } sv;
            sv.u = ((const uint4*)(sp + (size_t)spid * HD))[c];
#pragma unroll
            for (int j = 0; j < 8; ++j) a8[j] += (float)sv.b[j];
        }
        float iv = (end > beg) ? 1.f / (float)(end - beg) : 0.f;
        union { __bf16 o8[8]; uint4 u; } outv;
#pragma unroll
        for (int j = 0; j < 8; ++j) outv.o8[j] = (__bf16)(a8[j] * iv);
        *(uint4*)&sA[row * PADM + c * 8] = outv.u;
    }
    __syncthreads();
    // phase B: acc += aux @ Wn[ks4..7]
    {
        bf16x8 B[2][4];
#pragma unroll
        for (int nt = 0; nt < 2; ++nt)
#pragma unroll
            for (int ks = 0; ks < 4; ++ks)
                B[nt][ks] = wp[((nt0 + nt) * 8 + 4 + ks) * 64 + lane];
#pragma unroll
        for (int mt = 0; mt < 8; ++mt)
#pragma unroll
            for (int ks = 0; ks < 4; ++ks) {
                bf16x8 a = *(const bf16x8*)&sA[(mt * 16 + lcol) * PADM + ks * 32 + quad * 8];
                acc[mt][0] = __builtin_amdgcn_mfma_f32_16x16x32_bf16(a, B[0][ks], acc[mt][0], 0, 0, 0);
                acc[mt][1] = __builtin_amdgcn_mfma_f32_16x16x32_bf16(a, B[1][ks], acc[mt][1], 0, 0, 0);
            }
    }
    __syncthreads();
    // phase C: stage h tile
    for (int i = t; i < 2048; i += 256) {
        int row = i >> 4, c = i & 15;
        int n = n0b + row; if (n >= N_HITS) n = N_HITS - 1;
        *(uint4*)&sA[row * PADM + c * 8] = ((const uint4*)(hp + (size_t)n * HD))[c];
    }
    __syncthreads();
    // phase D: acc += h @ Wn[ks0..3]
    {
        bf16x8 B[2][4];
#pragma unroll
        for (int nt = 0; nt < 2; ++nt)
#pragma unroll
            for (int ks = 0; ks < 4; ++ks)
                B[nt][ks] = wp[((nt0 + nt) * 8 + ks) * 64 + lane];
#pragma unroll
        for (int mt = 0; mt < 8; ++mt)
#pragma unroll
            for (int ks = 0; ks < 4; ++ks) {
                bf16x8 a = *(const bf16x8*)&sA[(mt * 16 + lcol) * PADM + ks * 32 + quad * 8];
                acc[mt][0] = __builtin_amdgcn_mfma_f32_16x16x32_bf16(a, B[0][ks], acc[mt][0], 0, 0, 0);
                acc[mt][1] = __builtin_amdgcn_mfma_f32_16x16x32_bf16(a, B[1][ks], acc[mt][1], 0, 0, 0);
            }
    }
    __syncthreads();
    // phase E: h_new = h_old(sA) + relu(acc) -> sA (paired cols)
#pragma unroll
    for (int mt = 0; mt < 8; ++mt)
#pragma unroll
        for (int r = 0; r < 4; ++r) {
            float v0 = fmaxf(acc[mt][0][r], 0.f), v1 = fmaxf(acc[mt][1][r], 0.f);
            float p0 = __shfl_xor(v0, 1), p1 = __shfl_xor(v1, 1);
            float av = odd ? p1 : v0, bv = odd ? v1 : p0;
            int col = nt0 * 16 + (odd ? 15 + lcol : lcol);
            int row = mt * 16 + quad * 4 + r;
            uint* sp2 = (uint*)&sA[row * PADM + col];
            float2 ho = b2f2(*sp2);
            *sp2 = f2b2(ho.x + av, ho.y + bv);
        }
    __syncthreads();
    // phase F: coalesced h store
    for (int i = t; i < 2048; i += 256) {
        int row = i >> 4, c = i & 15;
        int n = n0b + row;
        if (n < N_HITS) ((uint4*)(hp + (size_t)n * HD))[c] = *(uint4*)&sA[row * PADM + c * 8];
    }
    // phase G/H: y GEMMs from h_new tile
    for (int half = 0; half < 2; ++half) {
        const bf16x8* wyp = (const bf16x8*)(half == 0 ? W1dP : W1sP);
        __bf16* out = half == 0 ? ydp : ysp;
        bf16x8 B[2][4];
#pragma unroll
        for (int nt = 0; nt < 2; ++nt)
#pragma unroll
            for (int ks = 0; ks < 4; ++ks)
                B[nt][ks] = wyp[((nt0 + nt) * 4 + ks) * 64 + lane];
        floatx4 yacc[8][2];
#pragma unroll
        for (int mt = 0; mt < 8; ++mt) { yacc[mt][0] = (floatx4){0,0,0,0}; yacc[mt][1] = (floatx4){0,0,0,0}; }
#pragma unroll
        for (int mt = 0; mt < 8; ++mt)
#pragma unroll
            for (int ks = 0; ks < 4; ++ks) {
                bf16x8 a = *(const bf16x8*)&sA[(mt * 16 + lcol) * PADM + ks * 32 + quad * 8];
                yacc[mt][0] = __builtin_amdgcn_mfma_f32_16x16x32_bf16(a, B[0][ks], yacc[mt][0], 0, 0, 0);
                yacc[mt][1] = __builtin_amdgcn_mfma_f32_16x16x32_bf16(a, B[1][ks], yacc[mt][1], 0, 0, 0);
            }
#pragma unroll
        for (int mt = 0; mt < 8; ++mt)
#pragma unroll
            for (int r = 0; r < 4; ++r) {
                int m = n0b + mt * 16 + quad * 4 + r;
                float v0 = yacc[mt][0][r], v1 = yacc[mt][1][r];
                float p0 = __shfl_xor(v0, 1), p1 = __shfl_xor(v1, 1);
                float av = odd ? p1 : v0, bv = odd ? v1 : p0;
                int col = nt0 * 16 + (odd ? 15 + lcol : lcol);
                if (m < N_HITS) *(uint*)&out[(size_t)m * HD + col] = f2b2(av, bv);
            }
    }
}

// ---------------- decoder ----------------
__global__ void dec_kernel(const __bf16* __restrict__ h, const float* __restrict__ W,
                           const float* __restrict__ b, float* __restrict__ out) {
    __shared__ float sW[640];
    __shared__ float sB[8];
    int t = threadIdx.x;
    for (int i = t; i < 640; i += 256) sW[i] = W[i];
    if (t < 5) sB[t] = b[t];
    __syncthreads();
    int n = blockIdx.x * 256 + t;
    if (n >= 3 * N_HITS) return;
    const uint4* hr = (const uint4*)(h + (size_t)n * HD);
    float a0 = sB[0], a1 = sB[1], a2 = sB[2], a3 = sB[3], a4 = sB[4];
#pragma unroll 4
    for (int q = 0; q < 16; ++q) {
        union { uint4 u; __bf16 bb[8]; } v; v.u = hr[q];
        const float* w = &sW[q * 40];
#pragma unroll
        for (int j = 0; j < 8; ++j) {
            float x = (float)v.bb[j];
            a0 = fmaf(x, w[j * 5 + 0], a0);
            a1 = fmaf(x, w[j * 5 + 1], a1);
            a2 = fmaf(x, w[j * 5 + 2], a2);
            a3 = fmaf(x, w[j * 5 + 3], a3);
            a4 = fmaf(x, w[j * 5 + 4], a4);
        }
    }
    float* oo = out + (size_t)n * NCLS;
    oo[0] = a0; oo[1] = a1; oo[2] = a2; oo[3] = a3; oo[4] = a4;
}

extern "C" void kernel_launch(void* const* d_in, const int* in_sizes, int n_in,
                              void* d_out, int out_size, void* d_ws, size_t ws_size,
                              hipStream_t stream) {
    const float* xu = (const float*)d_in[0];
    const int* eu = (const int*)d_in[1];
    const int* nu = (const int*)d_in[2];
    const float* xv = (const float*)d_in[3];
    const int* ev = (const int*)d_in[4];
    const int* nv = (const int*)d_in[5];
    const float* xy = (const float*)d_in[6];
    const int* ey = (const int*)d_in[7];
    const int* ny = (const int*)d_in[8];
    const float* W_enc = (const float*)d_in[9];
    const float* b_enc = (const float*)d_in[10];
    const float* W1 = (const float*)d_in[11];
    const float* b1 = (const float*)d_in[12];
    const float* W2 = (const float*)d_in[13];
    const float* b2 = (const float*)d_in[14];
    const float* W_upd = (const float*)d_in[15];
    const float* b_upd = (const float*)d_in[16];
    const float* W_sp = (const float*)d_in[17];
    const float* b_sp = (const float*)d_in[18];
    const float* W_nx = (const float*)d_in[19];
    const float* b_nx = (const float*)d_in[20];
    const float* W_sem = (const float*)d_in[21];
    const float* b_sem = (const float*)d_in[22];

    const size_t HN = (size_t)3 * N_HITS * HD;
    __bf16* h = (__bf16*)d_ws;                   // bf16 [3][N_HITS][HD]
    __bf16* y_d = h + HN;                        // bf16 [3][N_HITS][HD]
    __bf16* y_s = y_d + HN;                      // bf16 [3][N_HITS][HD]
    __bf16* sp = y_s + HN;                       // bf16 [N_SPS][HD]
    int* cnt = (int*)(sp + (size_t)N_SPS * HD);  // [270000]
    int* off = cnt + 270000;                     // [9*30001]
    int* cursor = off + 270009;                  // [270000]
    int* csr_e = cursor + 270000;                // [3*90000]
    int* csr_s = csr_e + 270000;                 // [3*30000]
    int* csr_h = csr_s + 90000;                  // [3*30000]
    __bf16* packs = (__bf16*)(csr_h + 90000);    // [131072]
    __bf16* W1dP = packs;
    __bf16* W1sP = packs + 16384;
    __bf16* W2P = packs + 32768;
    __bf16* WuP = packs + 49152;
    __bf16* WnP = packs + 81920;
    __bf16* WspP = packs + 114688;

    wprep_kernel<<<512, 256, 0, stream>>>(W1, W2, W_upd, W_nx, W_sp, packs);
    (void)hipMemsetAsync(cnt, 0, 270000 * sizeof(int), stream);
    hist_all_kernel<<<(450000 + 255) / 256, 256, 0, stream>>>(eu, ev, ey, nu, nv, ny, cnt);
    scan_kernel<<<9, 1024, 0, stream>>>(cnt, off, cursor);
    fill_kernel<<<(450000 + 255) / 256, 256, 0, stream>>>(eu, ev, ey, nu, nv, ny,
                                                          cursor, csr_e, csr_s, csr_h);

    enc_kernel<<<(3 * N_HITS * HD + 255) / 256, 256, 0, stream>>>(xu, xv, xy, W_enc, b_enc, h);
    y_init_kernel<<<(3 * N_HITS + 127) / 128, 256, 0, stream>>>(h, W1dP, W1sP, y_d, y_s);

    for (int it = 0; it < 3; ++it) {
        update_planar_kernel<<<dim3((N_HITS + 127) / 128, 3), 256, 0, stream>>>(
            h, y_d, y_s, off, csr_e, b1, W2P, b2, WuP, b_upd);
        sp_fused_kernel<<<(N_SPS + 127) / 128, 256, 0, stream>>>(h, off, csr_s, WspP, b_sp, sp);
        update_y_kernel<<<dim3((N_HITS + 127) / 128, 3), 256, 0, stream>>>(
            h, sp, off, csr_h, WnP, b_nx, W1dP, W1sP, y_d, y_s);
    }

    dec_kernel<<<(3 * N_HITS + 255) / 256, 256, 0, stream>>>(h, W_sem, b_sem, (float*)d_out);
}

// Round 11
// 670.714 us; speedup vs baseline: 1.5835x; 1.1347x over previous
//
#include <hip/hip_runtime.h>
#include <hip/hip_fp16.h>

#define N_HITS 30000
#define N_EDGES 90000
#define N_SPS 30000
#define HD 128
#define NCLS 5

#define PADM 136  // 128 + 8 bf16 pad

typedef __attribute__((ext_vector_type(8))) __bf16 bf16x8;
typedef __attribute__((ext_vector_type(4))) float floatx4;

__device__ __forceinline__ float2 b2f2(uint u) {
    union { uint u; __bf16 b[2]; } x; x.u = u;
    return make_float2((float)x.b[0], (float)x.b[1]);
}
__device__ __forceinline__ uint f2b2(float a, float b) {
    union { uint u; __bf16 b[2]; } x; x.b[0] = (__bf16)a; x.b[1] = (__bf16)b;
    return x.u;
}

// ---------------- encoder ----------------
__global__ void enc_kernel(const float* __restrict__ xu, const float* __restrict__ xv,
                           const float* __restrict__ xy, const float* __restrict__ W,
                           const float* __restrict__ b, __bf16* __restrict__ h) {
    int gid = blockIdx.x * blockDim.x + threadIdx.x;
    if (gid >= 3 * N_HITS * HD) return;
    int j = gid & (HD - 1);
    int n = (gid >> 7) % N_HITS;
    int p = gid / (N_HITS * HD);
    const float* x = (p == 0) ? xu : (p == 1) ? xv : xy;
    float acc = b[j];
#pragma unroll
    for (int k = 0; k < 4; ++k) acc = fmaf(x[n * 4 + k], W[k * HD + j], acc);
    h[gid] = (__bf16)fmaxf(acc, 0.f);
}

// ---------------- histograms ----------------
__global__ void hist_all_kernel(const int* __restrict__ eu, const int* __restrict__ ev,
                                const int* __restrict__ ey, const int* __restrict__ nu,
                                const int* __restrict__ nv, const int* __restrict__ ny,
                                int* __restrict__ cnt) {
    int gid = blockIdx.x * blockDim.x + threadIdx.x;
    if (gid >= 450000) return;
    int p = gid / 150000;
    int r = gid - p * 150000;
    const int* e = (p == 0) ? eu : (p == 1) ? ev : ey;
    const int* nx = (p == 0) ? nu : (p == 1) ? nv : ny;
    if (r < N_EDGES) {
        atomicAdd(&cnt[p * 30000 + e[N_EDGES + r]], 1);
    } else if (r < N_EDGES + N_SPS) {
        int i = r - N_EDGES;
        atomicAdd(&cnt[(3 + p) * 30000 + nx[N_SPS + i]], 1);
    } else {
        int i = r - N_EDGES - N_SPS;
        atomicAdd(&cnt[(6 + p) * 30000 + nx[i]], 1);
    }
}

// ---------------- exclusive scan per segment ----------------
__launch_bounds__(1024)
__global__ void scan_kernel(const int* __restrict__ cnt, int* __restrict__ off,
                            int* __restrict__ cursor) {
    int seg = blockIdx.x;
    const int* c = cnt + seg * 30000;
    int* o = off + seg * 30001;
    int* cur = cursor + seg * 30000;
    int t = threadIdx.x;
    int base = t * 30;
    int lc[30];
    int sum = 0;
#pragma unroll
    for (int k = 0; k < 30; ++k) {
        int i = base + k;
        lc[k] = (i < 30000) ? c[i] : 0;
        sum += lc[k];
    }
    __shared__ int part[1024];
    part[t] = sum;
    __syncthreads();
    for (int d = 1; d < 1024; d <<= 1) {
        int x = (t >= d) ? part[t - d] : 0;
        __syncthreads();
        part[t] += x;
        __syncthreads();
    }
    int run = part[t] - sum;
#pragma unroll
    for (int k = 0; k < 30; ++k) {
        int i = base + k;
        if (i < 30000) { o[i] = run; cur[i] = run; run += lc[k]; }
    }
    if (t == 1023) o[30000] = part[1023];
}

// ---------------- CSR fill ----------------
__global__ void fill_kernel(const int* __restrict__ eu, const int* __restrict__ ev,
                            const int* __restrict__ ey, const int* __restrict__ nu,
                            const int* __restrict__ nv, const int* __restrict__ ny,
                            int* __restrict__ cursor, int* __restrict__ csr_e,
                            int* __restrict__ csr_s, int* __restrict__ csr_h) {
    int gid = blockIdx.x * blockDim.x + threadIdx.x;
    if (gid >= 450000) return;
    int p = gid / 150000;
    int r = gid - p * 150000;
    const int* e = (p == 0) ? eu : (p == 1) ? ev : ey;
    const int* nx = (p == 0) ? nu : (p == 1) ? nv : ny;
    if (r < N_EDGES) {
        int d = e[N_EDGES + r];
        int pos = atomicAdd(&cursor[p * 30000 + d], 1);
        csr_e[p * N_EDGES + pos] = e[r];
    } else if (r < N_EDGES + N_SPS) {
        int i = r - N_EDGES;
        int spid = nx[N_SPS + i];
        int pos = atomicAdd(&cursor[(3 + p) * 30000 + spid], 1);
        csr_s[p * N_SPS + pos] = nx[i];
    } else {
        int i = r - N_EDGES - N_SPS;
        int hit = nx[i];
        int pos = atomicAdd(&cursor[(6 + p) * 30000 + hit], 1);
        csr_h[p * N_SPS + pos] = nx[N_SPS + i];
    }
}

// ---------------- weight pre-pack ----------------
__device__ __forceinline__ void pack4(const float* __restrict__ W, __bf16* __restrict__ P,
                                      int idx, int koff) {
    int j = idx & 7, lane = (idx >> 3) & 63, ks = (idx >> 9) & 3, n = (idx >> 11) & 7;
    int k = ks * 32 + (lane >> 4) * 8 + j, col = n * 16 + (lane & 15);
    P[idx] = (__bf16)W[(k + koff) * 128 + col];
}
__device__ __forceinline__ void pack8(const float* __restrict__ W, __bf16* __restrict__ P, int idx) {
    int j = idx & 7, lane = (idx >> 3) & 63, ks = (idx >> 9) & 7, n = (idx >> 12) & 7;
    int k = ks * 32 + (lane >> 4) * 8 + j, col = n * 16 + (lane & 15);
    P[idx] = (__bf16)W[k * 128 + col];
}

__global__ void wprep_kernel(const float* __restrict__ W1, const float* __restrict__ W2,
                             const float* __restrict__ Wu, const float* __restrict__ Wn,
                             const float* __restrict__ Wsp, __bf16* __restrict__ packs) {
    int gid = blockIdx.x * blockDim.x + threadIdx.x;
    if (gid < 16384) { pack4(W1, packs, gid, 0); return; }            // W1d
    gid -= 16384;
    if (gid < 16384) { pack4(W1, packs + 16384, gid, 128); return; }  // W1s
    gid -= 16384;
    if (gid < 16384) { pack4(W2, packs + 32768, gid, 0); return; }    // W2
    gid -= 16384;
    if (gid < 32768) { pack8(Wu, packs + 49152, gid); return; }       // W_upd
    gid -= 32768;
    if (gid < 32768) { pack8(Wn, packs + 81920, gid); return; }       // W_nx
    gid -= 32768;
    if (gid < 16384) { pack4(Wsp, packs + 114688, gid, 0); }          // W_sp
}

// ---------------- y_init: y_s = h@W1s (coalesced LDS-round-trip store) ----------------
__launch_bounds__(256, 4)
__global__ void y_init_kernel(const __bf16* __restrict__ h, const __bf16* __restrict__ W1sP,
                              __bf16* __restrict__ y_s) {
    __shared__ __bf16 sA[128 * PADM];
    int t = threadIdx.x;
    int n0b = blockIdx.x * 128;
    const int M = 3 * N_HITS;
    for (int i = t; i < 2048; i += 256) {
        int row = i >> 4, c = i & 15;
        int n = n0b + row; if (n >= M) n = M - 1;
        *(uint4*)&sA[row * PADM + c * 8] = ((const uint4*)(h + (size_t)n * HD))[c];
    }
    __syncthreads();

    int lane = t & 63, wave = t >> 6;
    int lcol = lane & 15, quad = lane >> 4;
    int nt0 = wave * 2;
    bool odd = (lcol & 1) != 0;

    const bf16x8* wp = (const bf16x8*)W1sP;
    bf16x8 B[2][4];
#pragma unroll
    for (int nt = 0; nt < 2; ++nt)
#pragma unroll
        for (int ks = 0; ks < 4; ++ks)
            B[nt][ks] = wp[((nt0 + nt) * 4 + ks) * 64 + lane];
    floatx4 acc[8][2];
#pragma unroll
    for (int mt = 0; mt < 8; ++mt) { acc[mt][0] = (floatx4){0,0,0,0}; acc[mt][1] = (floatx4){0,0,0,0}; }
#pragma unroll
    for (int mt = 0; mt < 8; ++mt)
#pragma unroll
        for (int ks = 0; ks < 4; ++ks) {
            bf16x8 a = *(const bf16x8*)&sA[(mt * 16 + lcol) * PADM + ks * 32 + quad * 8];
            acc[mt][0] = __builtin_amdgcn_mfma_f32_16x16x32_bf16(a, B[0][ks], acc[mt][0], 0, 0, 0);
            acc[mt][1] = __builtin_amdgcn_mfma_f32_16x16x32_bf16(a, B[1][ks], acc[mt][1], 0, 0, 0);
        }
    __syncthreads();  // sA reads done
#pragma unroll
    for (int mt = 0; mt < 8; ++mt)
#pragma unroll
        for (int r = 0; r < 4; ++r) {
            float v0 = acc[mt][0][r], v1 = acc[mt][1][r];
            float p0 = __shfl_xor(v0, 1), p1 = __shfl_xor(v1, 1);
            float av = odd ? p1 : v0, bv = odd ? v1 : p0;
            int col = nt0 * 16 + (odd ? 15 + lcol : lcol);
            *(uint*)&sA[(mt * 16 + quad * 4 + r) * PADM + col] = f2b2(av, bv);
        }
    __syncthreads();
    for (int i = t; i < 2048; i += 256) {
        int row = i >> 4, c = i & 15;
        int n = n0b + row;
        if (n < M) ((uint4*)(y_s + (size_t)n * HD))[c] = *(uint4*)&sA[row * PADM + c * 8];
    }
}

// ---------------- planar update (y_d computed in-kernel):
// yd = h@W1d (LDS tile); z = mean relu(yd+ys[src]+b1) in-place; agg=z@W2+b2;
// h += relu([h|agg]@Wu+bu) ----------------
__launch_bounds__(256, 4)
__global__ void update_planar_kernel(__bf16* __restrict__ h, const __bf16* __restrict__ y_s,
                                     const int* __restrict__ off, const int* __restrict__ csr_e,
                                     const float* __restrict__ b1, const __bf16* __restrict__ W1dP,
                                     const __bf16* __restrict__ W2P, const float* __restrict__ b2,
                                     const __bf16* __restrict__ WuP, const float* __restrict__ bu) {
    int p = blockIdx.y;
    __bf16* hp = h + (size_t)p * N_HITS * HD;
    const __bf16* ysp = y_s + (size_t)p * N_HITS * HD;
    const int* o = off + p * 30001;
    const int* csr = csr_e + p * N_EDGES;

    __shared__ __bf16 sA[128 * PADM];
    int t = threadIdx.x;
    int n0b = blockIdx.x * 128;
    int lane = t & 63, wave = t >> 6;
    int lcol = lane & 15, quad = lane >> 4;
    int nt0 = wave * 2;
    bool odd = (lcol & 1) != 0;

    // phase 0: stage h tile
    for (int i = t; i < 2048; i += 256) {
        int row = i >> 4, c = i & 15;
        int n = n0b + row; if (n >= N_HITS) n = N_HITS - 1;
        *(uint4*)&sA[row * PADM + c * 8] = ((const uint4*)(hp + (size_t)n * HD))[c];
    }
    __syncthreads();
    // phase 1: yd = h @ W1d
    floatx4 yd[8][2];
    {
        const bf16x8* wp = (const bf16x8*)W1dP;
        bf16x8 B[2][4];
#pragma unroll
        for (int nt = 0; nt < 2; ++nt)
#pragma unroll
            for (int ks = 0; ks < 4; ++ks)
                B[nt][ks] = wp[((nt0 + nt) * 4 + ks) * 64 + lane];
#pragma unroll
        for (int mt = 0; mt < 8; ++mt) { yd[mt][0] = (floatx4){0,0,0,0}; yd[mt][1] = (floatx4){0,0,0,0}; }
#pragma unroll
        for (int mt = 0; mt < 8; ++mt)
#pragma unroll
            for (int ks = 0; ks < 4; ++ks) {
                bf16x8 a = *(const bf16x8*)&sA[(mt * 16 + lcol) * PADM + ks * 32 + quad * 8];
                yd[mt][0] = __builtin_amdgcn_mfma_f32_16x16x32_bf16(a, B[0][ks], yd[mt][0], 0, 0, 0);
                yd[mt][1] = __builtin_amdgcn_mfma_f32_16x16x32_bf16(a, B[1][ks], yd[mt][1], 0, 0, 0);
            }
    }
    __syncthreads();  // h-tile reads done
    // yd (C-layout) -> sA row-major (paired cols)
#pragma unroll
    for (int mt = 0; mt < 8; ++mt)
#pragma unroll
        for (int r = 0; r < 4; ++r) {
            float v0 = yd[mt][0][r], v1 = yd[mt][1][r];
            float p0 = __shfl_xor(v0, 1), p1 = __shfl_xor(v1, 1);
            float av = odd ? p1 : v0, bv = odd ? v1 : p0;
            int col = nt0 * 16 + (odd ? 15 + lcol : lcol);
            *(uint*)&sA[(mt * 16 + quad * 4 + r) * PADM + col] = f2b2(av, bv);
        }
    __syncthreads();
    // phase A: in-place CSR edge gather: sA[row,c] = mean relu(yd(sA) + ys[src] + b1)
    for (int i = t; i < 2048; i += 256) {
        int row = i >> 4, c = i & 15;
        int d = n0b + row; if (d >= N_HITS) d = N_HITS - 1;
        int beg = o[d], end = o[d + 1];
        union { uint4 u; __bf16 b[8]; } ydv;
        ydv.u = *(uint4*)&sA[row * PADM + c * 8];
        float4 b1a = *(const float4*)(b1 + c * 8);
        float4 b1b = *(const float4*)(b1 + c * 8 + 4);
        float bb[8] = {b1a.x, b1a.y, b1a.z, b1a.w, b1b.x, b1b.y, b1b.z, b1b.w};
        float a8[8] = {0, 0, 0, 0, 0, 0, 0, 0};
        for (int k = beg; k < end; ++k) {
            int s = csr[k];
            union { uint4 u; __bf16 b[8]; } ys;
            ys.u = ((const uint4*)(ysp + (size_t)s * HD))[c];
#pragma unroll
            for (int j = 0; j < 8; ++j)
                a8[j] += fmaxf((float)ydv.b[j] + (float)ys.b[j] + bb[j], 0.f);
        }
        float iv = (end > beg) ? 1.f / (float)(end - beg) : 0.f;
        union { __bf16 o8[8]; uint4 u; } outv;
#pragma unroll
        for (int j = 0; j < 8; ++j) outv.o8[j] = (__bf16)(a8[j] * iv);
        *(uint4*)&sA[row * PADM + c * 8] = outv.u;
    }
    __syncthreads();
    // phase B: agg = z @ W2 + b2
    floatx4 agg[8][2];
    {
        const bf16x8* w2p = (const bf16x8*)W2P;
        bf16x8 B[2][4];
#pragma unroll
        for (int nt = 0; nt < 2; ++nt)
#pragma unroll
            for (int ks = 0; ks < 4; ++ks)
                B[nt][ks] = w2p[((nt0 + nt) * 4 + ks) * 64 + lane];
#pragma unroll
        for (int nt = 0; nt < 2; ++nt) {
            float bv = b2[(nt0 + nt) * 16 + lcol];
#pragma unroll
            for (int mt = 0; mt < 8; ++mt) agg[mt][nt] = (floatx4){bv, bv, bv, bv};
        }
#pragma unroll
        for (int mt = 0; mt < 8; ++mt)
#pragma unroll
            for (int ks = 0; ks < 4; ++ks) {
                bf16x8 a = *(const bf16x8*)&sA[(mt * 16 + lcol) * PADM + ks * 32 + quad * 8];
                agg[mt][0] = __builtin_amdgcn_mfma_f32_16x16x32_bf16(a, B[0][ks], agg[mt][0], 0, 0, 0);
                agg[mt][1] = __builtin_amdgcn_mfma_f32_16x16x32_bf16(a, B[1][ks], agg[mt][1], 0, 0, 0);
            }
    }
    __syncthreads();
    // phase C: agg -> sA
#pragma unroll
    for (int mt = 0; mt < 8; ++mt)
#pragma unroll
        for (int r = 0; r < 4; ++r) {
            float v0 = agg[mt][0][r], v1 = agg[mt][1][r];
            float p0 = __shfl_xor(v0, 1), p1 = __shfl_xor(v1, 1);
            float av = odd ? p1 : v0, bv = odd ? v1 : p0;
            int col = nt0 * 16 + (odd ? 15 + lcol : lcol);
            *(uint*)&sA[(mt * 16 + quad * 4 + r) * PADM + col] = f2b2(av, bv);
        }
    __syncthreads();
    // phase D: acc = bu + agg @ Wu[ks4..7]
    floatx4 acc[8][2];
    {
        const bf16x8* wup = (const bf16x8*)WuP;
        bf16x8 B[2][4];
#pragma unroll
        for (int nt = 0; nt < 2; ++nt)
#pragma unroll
            for (int ks = 0; ks < 4; ++ks)
                B[nt][ks] = wup[((nt0 + nt) * 8 + 4 + ks) * 64 + lane];
#pragma unroll
        for (int nt = 0; nt < 2; ++nt) {
            float bv = bu[(nt0 + nt) * 16 + lcol];
#pragma unroll
            for (int mt = 0; mt < 8; ++mt) acc[mt][nt] = (floatx4){bv, bv, bv, bv};
        }
#pragma unroll
        for (int mt = 0; mt < 8; ++mt)
#pragma unroll
            for (int ks = 0; ks < 4; ++ks) {
                bf16x8 a = *(const bf16x8*)&sA[(mt * 16 + lcol) * PADM + ks * 32 + quad * 8];
                acc[mt][0] = __builtin_amdgcn_mfma_f32_16x16x32_bf16(a, B[0][ks], acc[mt][0], 0, 0, 0);
                acc[mt][1] = __builtin_amdgcn_mfma_f32_16x16x32_bf16(a, B[1][ks], acc[mt][1], 0, 0, 0);
            }
    }
    __syncthreads();
    // phase E: re-stage h tile (L2-warm)
    for (int i = t; i < 2048; i += 256) {
        int row = i >> 4, c = i & 15;
        int n = n0b + row; if (n >= N_HITS) n = N_HITS - 1;
        *(uint4*)&sA[row * PADM + c * 8] = ((const uint4*)(hp + (size_t)n * HD))[c];
    }
    __syncthreads();
    // phase F: acc += h @ Wu[ks0..3]
    {
        const bf16x8* wup = (const bf16x8*)WuP;
        bf16x8 B[2][4];
#pragma unroll
        for (int nt = 0; nt < 2; ++nt)
#pragma unroll
            for (int ks = 0; ks < 4; ++ks)
                B[nt][ks] = wup[((nt0 + nt) * 8 + ks) * 64 + lane];
#pragma unroll
        for (int mt = 0; mt < 8; ++mt)
#pragma unroll
            for (int ks = 0; ks < 4; ++ks) {
                bf16x8 a = *(const bf16x8*)&sA[(mt * 16 + lcol) * PADM + ks * 32 + quad * 8];
                acc[mt][0] = __builtin_amdgcn_mfma_f32_16x16x32_bf16(a, B[0][ks], acc[mt][0], 0, 0, 0);
                acc[mt][1] = __builtin_amdgcn_mfma_f32_16x16x32_bf16(a, B[1][ks], acc[mt][1], 0, 0, 0);
            }
    }
    __syncthreads();
    // phase G: h_new = h_old(sA) + relu(acc) -> sA
#pragma unroll
    for (int mt = 0; mt < 8; ++mt)
#pragma unroll
        for (int r = 0; r < 4; ++r) {
            float v0 = fmaxf(acc[mt][0][r], 0.f), v1 = fmaxf(acc[mt][1][r], 0.f);
            float p0 = __shfl_xor(v0, 1), p1 = __shfl_xor(v1, 1);
            float av = odd ? p1 : v0, bv = odd ? v1 : p0;
            int col = nt0 * 16 + (odd ? 15 + lcol : lcol);
            uint* sp2 = (uint*)&sA[(mt * 16 + quad * 4 + r) * PADM + col];
            float2 ho = b2f2(*sp2);
            *sp2 = f2b2(ho.x + av, ho.y + bv);
        }
    __syncthreads();
    // phase H: coalesced store
    for (int i = t; i < 2048; i += 256) {
        int row = i >> 4, c = i & 15;
        int n = n0b + row;
        if (n < N_HITS) ((uint4*)(hp + (size_t)n * HD))[c] = *(uint4*)&sA[row * PADM + c * 8];
    }
}

// ---------------- sp fused: gather (3-plane mean of h) + GEMM + relu -> sp ----------------
__launch_bounds__(256, 4)
__global__ void sp_fused_kernel(const __bf16* __restrict__ h, const int* __restrict__ off,
                                const int* __restrict__ csr_s, const __bf16* __restrict__ WspP,
                                const float* __restrict__ b, __bf16* __restrict__ spf) {
    __shared__ __bf16 sA[128 * PADM];
    int t = threadIdx.x;
    int n0b = blockIdx.x * 128;
    int lane = t & 63, wave = t >> 6;
    int lcol = lane & 15, quad = lane >> 4;
    int nt0 = wave * 2;
    bool odd = (lcol & 1) != 0;

    for (int i = t; i < 2048; i += 256) {
        int row = i >> 4, c = i & 15;
        int s = n0b + row; if (s >= N_SPS) s = N_SPS - 1;
        float a8[8] = {0, 0, 0, 0, 0, 0, 0, 0};
#pragma unroll
        for (int p = 0; p < 3; ++p) {
            const int* o = off + (3 + p) * 30001;
            int beg = o[s], end = o[s + 1];
            const int* csr = csr_s + p * N_SPS;
            const __bf16* hb = h + (size_t)p * N_HITS * HD;
            float s8[8] = {0, 0, 0, 0, 0, 0, 0, 0};
            for (int k = beg; k < end; ++k) {
                int hit = csr[k];
                union { uint4 u; __bf16 b[8]; } hv;
                hv.u = ((const uint4*)(hb + (size_t)hit * HD))[c];
#pragma unroll
                for (int j = 0; j < 8; ++j) s8[j] += (float)hv.b[j];
            }
            float iv = (end > beg) ? 1.f / (float)(end - beg) : 0.f;
#pragma unroll
            for (int j = 0; j < 8; ++j) a8[j] += s8[j] * iv;
        }
        union { __bf16 o8[8]; uint4 u; } outv;
#pragma unroll
        for (int j = 0; j < 8; ++j) outv.o8[j] = (__bf16)a8[j];
        *(uint4*)&sA[row * PADM + c * 8] = outv.u;
    }
    __syncthreads();

    const bf16x8* wp = (const bf16x8*)WspP;
    bf16x8 B[2][4];
#pragma unroll
    for (int nt = 0; nt < 2; ++nt)
#pragma unroll
        for (int ks = 0; ks < 4; ++ks)
            B[nt][ks] = wp[((nt0 + nt) * 4 + ks) * 64 + lane];

    floatx4 acc[8][2];
#pragma unroll
    for (int nt = 0; nt < 2; ++nt) {
        float bv = b[(nt0 + nt) * 16 + lcol];
#pragma unroll
        for (int mt = 0; mt < 8; ++mt) acc[mt][nt] = (floatx4){bv, bv, bv, bv};
    }
#pragma unroll
    for (int mt = 0; mt < 8; ++mt)
#pragma unroll
        for (int ks = 0; ks < 4; ++ks) {
            bf16x8 a = *(const bf16x8*)&sA[(mt * 16 + lcol) * PADM + ks * 32 + quad * 8];
            acc[mt][0] = __builtin_amdgcn_mfma_f32_16x16x32_bf16(a, B[0][ks], acc[mt][0], 0, 0, 0);
            acc[mt][1] = __builtin_amdgcn_mfma_f32_16x16x32_bf16(a, B[1][ks], acc[mt][1], 0, 0, 0);
        }
    __syncthreads();
#pragma unroll
    for (int mt = 0; mt < 8; ++mt)
#pragma unroll
        for (int r = 0; r < 4; ++r) {
            float v0 = fmaxf(acc[mt][0][r], 0.f), v1 = fmaxf(acc[mt][1][r], 0.f);
            float p0 = __shfl_xor(v0, 1), p1 = __shfl_xor(v1, 1);
            float av = odd ? p1 : v0, bv = odd ? v1 : p0;
            int col = nt0 * 16 + (odd ? 15 + lcol : lcol);
            *(uint*)&sA[(mt * 16 + quad * 4 + r) * PADM + col] = f2b2(av, bv);
        }
    __syncthreads();
    for (int i = t; i < 2048; i += 256) {
        int row = i >> 4, c = i & 15;
        int n = n0b + row;
        if (n < N_SPS) ((uint4*)(spf + (size_t)n * HD))[c] = *(uint4*)&sA[row * PADM + c * 8];
    }
}

// ---------------- nexus update, fused back gather; emits y_s only (coalesced) ----------------
__launch_bounds__(256, 4)
__global__ void update_y_kernel(__bf16* __restrict__ h, const __bf16* __restrict__ sp,
                                const int* __restrict__ off, const int* __restrict__ csr_h,
                                const __bf16* __restrict__ WP, const float* __restrict__ b,
                                const __bf16* __restrict__ W1sP, __bf16* __restrict__ y_s) {
    int p = blockIdx.y;
    __bf16* hp = h + (size_t)p * N_HITS * HD;
    __bf16* ysp = y_s + (size_t)p * N_HITS * HD;
    const int* o = off + (6 + p) * 30001;
    const int* csr = csr_h + p * N_SPS;

    __shared__ __bf16 sA[128 * PADM];
    int t = threadIdx.x;
    int n0b = blockIdx.x * 128;
    int lane = t & 63, wave = t >> 6;
    int lcol = lane & 15, quad = lane >> 4;
    int nt0 = wave * 2;
    bool odd = (lcol & 1) != 0;

    const bf16x8* wp = (const bf16x8*)WP;
    floatx4 acc[8][2];
#pragma unroll
    for (int nt = 0; nt < 2; ++nt) {
        float bv = b[(nt0 + nt) * 16 + lcol];
#pragma unroll
        for (int mt = 0; mt < 8; ++mt) acc[mt][nt] = (floatx4){bv, bv, bv, bv};
    }

    // phase A: stage aux = back-gather mean of sp rows
    for (int i = t; i < 2048; i += 256) {
        int row = i >> 4, c = i & 15;
        int hit = n0b + row; if (hit >= N_HITS) hit = N_HITS - 1;
        int beg = o[hit], end = o[hit + 1];
        float a8[8] = {0, 0, 0, 0, 0, 0, 0, 0};
        for (int k = beg; k < end; ++k) {
            int spid = csr[k];
            union { uint4 u; __bf16 b[8]; } sv;
            sv.u = ((const uint4*)(sp + (size_t)spid * HD))[c];
#pragma unroll
            for (int j = 0; j < 8; ++j) a8[j] += (float)sv.b[j];
        }
        float iv = (end > beg) ? 1.f / (float)(end - beg) : 0.f;
        union { __bf16 o8[8]; uint4 u; } outv;
#pragma unroll
        for (int j = 0; j < 8; ++j) outv.o8[j] = (__bf16)(a8[j] * iv);
        *(uint4*)&sA[row * PADM + c * 8] = outv.u;
    }
    __syncthreads();
    // phase B: acc += aux @ Wn[ks4..7]
    {
        bf16x8 B[2][4];
#pragma unroll
        for (int nt = 0; nt < 2; ++nt)
#pragma unroll
            for (int ks = 0; ks < 4; ++ks)
                B[nt][ks] = wp[((nt0 + nt) * 8 + 4 + ks) * 64 + lane];
#pragma unroll
        for (int mt = 0; mt < 8; ++mt)
#pragma unroll
            for (int ks = 0; ks < 4; ++ks) {
                bf16x8 a = *(const bf16x8*)&sA[(mt * 16 + lcol) * PADM + ks * 32 + quad * 8];
                acc[mt][0] = __builtin_amdgcn_mfma_f32_16x16x32_bf16(a, B[0][ks], acc[mt][0], 0, 0, 0);
                acc[mt][1] = __builtin_amdgcn_mfma_f32_16x16x32_bf16(a, B[1][ks], acc[mt][1], 0, 0, 0);
            }
    }
    __syncthreads();
    // phase C: stage h tile
    for (int i = t; i < 2048; i += 256) {
        int row = i >> 4, c = i & 15;
        int n = n0b + row; if (n >= N_HITS) n = N_HITS - 1;
        *(uint4*)&sA[row * PADM + c * 8] = ((const uint4*)(hp + (size_t)n * HD))[c];
    }
    __syncthreads();
    // phase D: acc += h @ Wn[ks0..3]
    {
        bf16x8 B[2][4];
#pragma unroll
        for (int nt = 0; nt < 2; ++nt)
#pragma unroll
            for (int ks = 0; ks < 4; ++ks)
                B[nt][ks] = wp[((nt0 + nt) * 8 + ks) * 64 + lane];
#pragma unroll
        for (int mt = 0; mt < 8; ++mt)
#pragma unroll
            for (int ks = 0; ks < 4; ++ks) {
                bf16x8 a = *(const bf16x8*)&sA[(mt * 16 + lcol) * PADM + ks * 32 + quad * 8];
                acc[mt][0] = __builtin_amdgcn_mfma_f32_16x16x32_bf16(a, B[0][ks], acc[mt][0], 0, 0, 0);
                acc[mt][1] = __builtin_amdgcn_mfma_f32_16x16x32_bf16(a, B[1][ks], acc[mt][1], 0, 0, 0);
            }
    }
    __syncthreads();
    // phase E: h_new = h_old(sA) + relu(acc) -> sA
#pragma unroll
    for (int mt = 0; mt < 8; ++mt)
#pragma unroll
        for (int r = 0; r < 4; ++r) {
            float v0 = fmaxf(acc[mt][0][r], 0.f), v1 = fmaxf(acc[mt][1][r], 0.f);
            float p0 = __shfl_xor(v0, 1), p1 = __shfl_xor(v1, 1);
            float av = odd ? p1 : v0, bv = odd ? v1 : p0;
            int col = nt0 * 16 + (odd ? 15 + lcol : lcol);
            uint* sp2 = (uint*)&sA[(mt * 16 + quad * 4 + r) * PADM + col];
            float2 ho = b2f2(*sp2);
            *sp2 = f2b2(ho.x + av, ho.y + bv);
        }
    __syncthreads();
    // phase F: coalesced h store
    for (int i = t; i < 2048; i += 256) {
        int row = i >> 4, c = i & 15;
        int n = n0b + row;
        if (n < N_HITS) ((uint4*)(hp + (size_t)n * HD))[c] = *(uint4*)&sA[row * PADM + c * 8];
    }
    // phase G: y_s = h_new @ W1s (reads sA)
    {
        const bf16x8* wyp = (const bf16x8*)W1sP;
        bf16x8 B[2][4];
#pragma unroll
        for (int nt = 0; nt < 2; ++nt)
#pragma unroll
            for (int ks = 0; ks < 4; ++ks)
                B[nt][ks] = wyp[((nt0 + nt) * 4 + ks) * 64 + lane];
        floatx4 yacc[8][2];
#pragma unroll
        for (int mt = 0; mt < 8; ++mt) { yacc[mt][0] = (floatx4){0,0,0,0}; yacc[mt][1] = (floatx4){0,0,0,0}; }
#pragma unroll
        for (int mt = 0; mt < 8; ++mt)
#pragma unroll
            for (int ks = 0; ks < 4; ++ks) {
                bf16x8 a = *(const bf16x8*)&sA[(mt * 16 + lcol) * PADM + ks * 32 + quad * 8];
                yacc[mt][0] = __builtin_amdgcn_mfma_f32_16x16x32_bf16(a, B[0][ks], yacc[mt][0], 0, 0, 0);
                yacc[mt][1] = __builtin_amdgcn_mfma_f32_16x16x32_bf16(a, B[1][ks], yacc[mt][1], 0, 0, 0);
            }
        __syncthreads();  // sA reads done before overwrite
#pragma unroll
        for (int mt = 0; mt < 8; ++mt)
#pragma unroll
            for (int r = 0; r < 4; ++r) {
                float v0 = yacc[mt][0][r], v1 = yacc[mt][1][r];
                float p0 = __shfl_xor(v0, 1), p1 = __shfl_xor(v1, 1);
                float av = odd ? p1 : v0, bv = odd ? v1 : p0;
                int col = nt0 * 16 + (odd ? 15 + lcol : lcol);
                *(uint*)&sA[(mt * 16 + quad * 4 + r) * PADM + col] = f2b2(av, bv);
            }
        __syncthreads();
        // coalesced y_s store
        for (int i = t; i < 2048; i += 256) {
            int row = i >> 4, c = i & 15;
            int n = n0b + row;
            if (n < N_HITS) ((uint4*)(ysp + (size_t)n * HD))[c] = *(uint4*)&sA[row * PADM + c * 8];
        }
    }
}

// ---------------- decoder ----------------
__global__ void dec_kernel(const __bf16* __restrict__ h, const float* __restrict__ W,
                           const float* __restrict__ b, float* __restrict__ out) {
    __shared__ float sW[640];
    __shared__ float sB[8];
    int t = threadIdx.x;
    for (int i = t; i < 640; i += 256) sW[i] = W[i];
    if (t < 5) sB[t] = b[t];
    __syncthreads();
    int n = blockIdx.x * 256 + t;
    if (n >= 3 * N_HITS) return;
    const uint4* hr = (const uint4*)(h + (size_t)n * HD);
    float a0 = sB[0], a1 = sB[1], a2 = sB[2], a3 = sB[3], a4 = sB[4];
#pragma unroll 4
    for (int q = 0; q < 16; ++q) {
        union { uint4 u; __bf16 bb[8]; } v; v.u = hr[q];
        const float* w = &sW[q * 40];
#pragma unroll
        for (int j = 0; j < 8; ++j) {
            float x = (float)v.bb[j];
            a0 = fmaf(x, w[j * 5 + 0], a0);
            a1 = fmaf(x, w[j * 5 + 1], a1);
            a2 = fmaf(x, w[j * 5 + 2], a2);
            a3 = fmaf(x, w[j * 5 + 3], a3);
            a4 = fmaf(x, w[j * 5 + 4], a4);
        }
    }
    float* oo = out + (size_t)n * NCLS;
    oo[0] = a0; oo[1] = a1; oo[2] = a2; oo[3] = a3; oo[4] = a4;
}

extern "C" void kernel_launch(void* const* d_in, const int* in_sizes, int n_in,
                              void* d_out, int out_size, void* d_ws, size_t ws_size,
                              hipStream_t stream) {
    const float* xu = (const float*)d_in[0];
    const int* eu = (const int*)d_in[1];
    const int* nu = (const int*)d_in[2];
    const float* xv = (const float*)d_in[3];
    const int* ev = (const int*)d_in[4];
    const int* nv = (const int*)d_in[5];
    const float* xy = (const float*)d_in[6];
    const int* ey = (const int*)d_in[7];
    const int* ny = (const int*)d_in[8];
    const float* W_enc = (const float*)d_in[9];
    const float* b_enc = (const float*)d_in[10];
    const float* W1 = (const float*)d_in[11];
    const float* b1 = (const float*)d_in[12];
    const float* W2 = (const float*)d_in[13];
    const float* b2 = (const float*)d_in[14];
    const float* W_upd = (const float*)d_in[15];
    const float* b_upd = (const float*)d_in[16];
    const float* W_sp = (const float*)d_in[17];
    const float* b_sp = (const float*)d_in[18];
    const float* W_nx = (const float*)d_in[19];
    const float* b_nx = (const float*)d_in[20];
    const float* W_sem = (const float*)d_in[21];
    const float* b_sem = (const float*)d_in[22];

    const size_t HN = (size_t)3 * N_HITS * HD;
    __bf16* h = (__bf16*)d_ws;                   // bf16 [3][N_HITS][HD]
    __bf16* y_s = h + HN;                        // bf16 [3][N_HITS][HD]
    __bf16* sp = y_s + HN;                       // bf16 [N_SPS][HD]
    int* cnt = (int*)(sp + (size_t)N_SPS * HD);  // [270000]
    int* off = cnt + 270000;                     // [9*30001]
    int* cursor = off + 270009;                  // [270000]
    int* csr_e = cursor + 270000;                // [3*90000]
    int* csr_s = csr_e + 270000;                 // [3*30000]
    int* csr_h = csr_s + 90000;                  // [3*30000]
    __bf16* packs = (__bf16*)(csr_h + 90000);    // [131072]
    __bf16* W1dP = packs;
    __bf16* W1sP = packs + 16384;
    __bf16* W2P = packs + 32768;
    __bf16* WuP = packs + 49152;
    __bf16* WnP = packs + 81920;
    __bf16* WspP = packs + 114688;

    wprep_kernel<<<512, 256, 0, stream>>>(W1, W2, W_upd, W_nx, W_sp, packs);
    (void)hipMemsetAsync(cnt, 0, 270000 * sizeof(int), stream);
    hist_all_kernel<<<(450000 + 255) / 256, 256, 0, stream>>>(eu, ev, ey, nu, nv, ny, cnt);
    scan_kernel<<<9, 1024, 0, stream>>>(cnt, off, cursor);
    fill_kernel<<<(450000 + 255) / 256, 256, 0, stream>>>(eu, ev, ey, nu, nv, ny,
                                                          cursor, csr_e, csr_s, csr_h);

    enc_kernel<<<(3 * N_HITS * HD + 255) / 256, 256, 0, stream>>>(xu, xv, xy, W_enc, b_enc, h);
    y_init_kernel<<<(3 * N_HITS + 127) / 128, 256, 0, stream>>>(h, W1sP, y_s);

    for (int it = 0; it < 3; ++it) {
        update_planar_kernel<<<dim3((N_HITS + 127) / 128, 3), 256, 0, stream>>>(
            h, y_s, off, csr_e, b1, W1dP, W2P, b2, WuP, b_upd);
        sp_fused_kernel<<<(N_SPS + 127) / 128, 256, 0, stream>>>(h, off, csr_s, WspP, b_sp, sp);
        update_y_kernel<<<dim3((N_HITS + 127) / 128, 3), 256, 0, stream>>>(
            h, sp, off, csr_h, WnP, b_nx, W1sP, y_s);
    }

    dec_kernel<<<(3 * N_HITS + 255) / 256, 256, 0, stream>>>(h, W_sem, b_sem, (float*)d_out);
}

// Round 12
// 599.786 us; speedup vs baseline: 1.7707x; 1.1183x over previous
//
#include <hip/hip_runtime.h>
#include <hip/hip_fp16.h>

#define N_HITS 30000
#define N_EDGES 90000
#define N_SPS 30000
#define HD 128
#define NCLS 5

#define PADM 136  // 128 + 8 bf16 pad

typedef __attribute__((ext_vector_type(8))) __bf16 bf16x8;
typedef __attribute__((ext_vector_type(4))) float floatx4;

__device__ __forceinline__ float2 b2f2(uint u) {
    union { uint u; __bf16 b[2]; } x; x.u = u;
    return make_float2((float)x.b[0], (float)x.b[1]);
}
__device__ __forceinline__ uint f2b2(float a, float b) {
    union { uint u; __bf16 b[2]; } x; x.b[0] = (__bf16)a; x.b[1] = (__bf16)b;
    return x.u;
}

// ---------------- encoder ----------------
__global__ void enc_kernel(const float* __restrict__ xu, const float* __restrict__ xv,
                           const float* __restrict__ xy, const float* __restrict__ W,
                           const float* __restrict__ b, __bf16* __restrict__ h) {
    int gid = blockIdx.x * blockDim.x + threadIdx.x;
    if (gid >= 3 * N_HITS * HD) return;
    int j = gid & (HD - 1);
    int n = (gid >> 7) % N_HITS;
    int p = gid / (N_HITS * HD);
    const float* x = (p == 0) ? xu : (p == 1) ? xv : xy;
    float acc = b[j];
#pragma unroll
    for (int k = 0; k < 4; ++k) acc = fmaf(x[n * 4 + k], W[k * HD + j], acc);
    h[gid] = (__bf16)fmaxf(acc, 0.f);
}

// ---------------- histograms ----------------
__global__ void hist_all_kernel(const int* __restrict__ eu, const int* __restrict__ ev,
                                const int* __restrict__ ey, const int* __restrict__ nu,
                                const int* __restrict__ nv, const int* __restrict__ ny,
                                int* __restrict__ cnt) {
    int gid = blockIdx.x * blockDim.x + threadIdx.x;
    if (gid >= 450000) return;
    int p = gid / 150000;
    int r = gid - p * 150000;
    const int* e = (p == 0) ? eu : (p == 1) ? ev : ey;
    const int* nx = (p == 0) ? nu : (p == 1) ? nv : ny;
    if (r < N_EDGES) {
        atomicAdd(&cnt[p * 30000 + e[N_EDGES + r]], 1);
    } else if (r < N_EDGES + N_SPS) {
        int i = r - N_EDGES;
        atomicAdd(&cnt[(3 + p) * 30000 + nx[N_SPS + i]], 1);
    } else {
        int i = r - N_EDGES - N_SPS;
        atomicAdd(&cnt[(6 + p) * 30000 + nx[i]], 1);
    }
}

// ---------------- exclusive scan per segment ----------------
__launch_bounds__(1024)
__global__ void scan_kernel(const int* __restrict__ cnt, int* __restrict__ off,
                            int* __restrict__ cursor) {
    int seg = blockIdx.x;
    const int* c = cnt + seg * 30000;
    int* o = off + seg * 30001;
    int* cur = cursor + seg * 30000;
    int t = threadIdx.x;
    int base = t * 30;
    int lc[30];
    int sum = 0;
#pragma unroll
    for (int k = 0; k < 30; ++k) {
        int i = base + k;
        lc[k] = (i < 30000) ? c[i] : 0;
        sum += lc[k];
    }
    __shared__ int part[1024];
    part[t] = sum;
    __syncthreads();
    for (int d = 1; d < 1024; d <<= 1) {
        int x = (t >= d) ? part[t - d] : 0;
        __syncthreads();
        part[t] += x;
        __syncthreads();
    }
    int run = part[t] - sum;
#pragma unroll
    for (int k = 0; k < 30; ++k) {
        int i = base + k;
        if (i < 30000) { o[i] = run; cur[i] = run; run += lc[k]; }
    }
    if (t == 1023) o[30000] = part[1023];
}

// ---------------- CSR fill ----------------
__global__ void fill_kernel(const int* __restrict__ eu, const int* __restrict__ ev,
                            const int* __restrict__ ey, const int* __restrict__ nu,
                            const int* __restrict__ nv, const int* __restrict__ ny,
                            int* __restrict__ cursor, int* __restrict__ csr_e,
                            int* __restrict__ csr_s, int* __restrict__ csr_h) {
    int gid = blockIdx.x * blockDim.x + threadIdx.x;
    if (gid >= 450000) return;
    int p = gid / 150000;
    int r = gid - p * 150000;
    const int* e = (p == 0) ? eu : (p == 1) ? ev : ey;
    const int* nx = (p == 0) ? nu : (p == 1) ? nv : ny;
    if (r < N_EDGES) {
        int d = e[N_EDGES + r];
        int pos = atomicAdd(&cursor[p * 30000 + d], 1);
        csr_e[p * N_EDGES + pos] = e[r];
    } else if (r < N_EDGES + N_SPS) {
        int i = r - N_EDGES;
        int spid = nx[N_SPS + i];
        int pos = atomicAdd(&cursor[(3 + p) * 30000 + spid], 1);
        csr_s[p * N_SPS + pos] = nx[i];
    } else {
        int i = r - N_EDGES - N_SPS;
        int hit = nx[i];
        int pos = atomicAdd(&cursor[(6 + p) * 30000 + hit], 1);
        csr_h[p * N_SPS + pos] = nx[N_SPS + i];
    }
}

// ---------------- weight pre-pack ----------------
__device__ __forceinline__ void pack4(const float* __restrict__ W, __bf16* __restrict__ P,
                                      int idx, int koff) {
    int j = idx & 7, lane = (idx >> 3) & 63, ks = (idx >> 9) & 3, n = (idx >> 11) & 7;
    int k = ks * 32 + (lane >> 4) * 8 + j, col = n * 16 + (lane & 15);
    P[idx] = (__bf16)W[(k + koff) * 128 + col];
}
__device__ __forceinline__ void pack8(const float* __restrict__ W, __bf16* __restrict__ P, int idx) {
    int j = idx & 7, lane = (idx >> 3) & 63, ks = (idx >> 9) & 7, n = (idx >> 12) & 7;
    int k = ks * 32 + (lane >> 4) * 8 + j, col = n * 16 + (lane & 15);
    P[idx] = (__bf16)W[k * 128 + col];
}

__global__ void wprep_kernel(const float* __restrict__ W1, const float* __restrict__ W2,
                             const float* __restrict__ Wu, const float* __restrict__ Wn,
                             const float* __restrict__ Wsp, __bf16* __restrict__ packs) {
    int gid = blockIdx.x * blockDim.x + threadIdx.x;
    if (gid < 16384) { pack4(W1, packs, gid, 0); return; }            // W1d
    gid -= 16384;
    if (gid < 16384) { pack4(W1, packs + 16384, gid, 128); return; }  // W1s
    gid -= 16384;
    if (gid < 16384) { pack4(W2, packs + 32768, gid, 0); return; }    // W2
    gid -= 16384;
    if (gid < 32768) { pack8(Wu, packs + 49152, gid); return; }       // W_upd
    gid -= 32768;
    if (gid < 32768) { pack8(Wn, packs + 81920, gid); return; }       // W_nx
    gid -= 32768;
    if (gid < 16384) { pack4(Wsp, packs + 114688, gid, 0); }          // W_sp
}

// ---------------- y_init: y_s = h@W1s ----------------
__launch_bounds__(256, 4)
__global__ void y_init_kernel(const __bf16* __restrict__ h, const __bf16* __restrict__ W1sP,
                              __bf16* __restrict__ y_s) {
    __shared__ __bf16 sA[128 * PADM];
    int t = threadIdx.x;
    int n0b = blockIdx.x * 128;
    const int M = 3 * N_HITS;
    for (int i = t; i < 2048; i += 256) {
        int row = i >> 4, c = i & 15;
        int n = n0b + row; if (n >= M) n = M - 1;
        *(uint4*)&sA[row * PADM + c * 8] = ((const uint4*)(h + (size_t)n * HD))[c];
    }
    __syncthreads();

    int lane = t & 63, wave = t >> 6;
    int lcol = lane & 15, quad = lane >> 4;
    int nt0 = wave * 2;
    bool odd = (lcol & 1) != 0;

    const bf16x8* wp = (const bf16x8*)W1sP;
    bf16x8 B[2][4];
#pragma unroll
    for (int nt = 0; nt < 2; ++nt)
#pragma unroll
        for (int ks = 0; ks < 4; ++ks)
            B[nt][ks] = wp[((nt0 + nt) * 4 + ks) * 64 + lane];
    floatx4 acc[8][2];
#pragma unroll
    for (int mt = 0; mt < 8; ++mt) { acc[mt][0] = (floatx4){0,0,0,0}; acc[mt][1] = (floatx4){0,0,0,0}; }
#pragma unroll
    for (int mt = 0; mt < 8; ++mt)
#pragma unroll
        for (int ks = 0; ks < 4; ++ks) {
            bf16x8 a = *(const bf16x8*)&sA[(mt * 16 + lcol) * PADM + ks * 32 + quad * 8];
            acc[mt][0] = __builtin_amdgcn_mfma_f32_16x16x32_bf16(a, B[0][ks], acc[mt][0], 0, 0, 0);
            acc[mt][1] = __builtin_amdgcn_mfma_f32_16x16x32_bf16(a, B[1][ks], acc[mt][1], 0, 0, 0);
        }
    __syncthreads();
#pragma unroll
    for (int mt = 0; mt < 8; ++mt)
#pragma unroll
        for (int r = 0; r < 4; ++r) {
            float v0 = acc[mt][0][r], v1 = acc[mt][1][r];
            float p0 = __shfl_xor(v0, 1), p1 = __shfl_xor(v1, 1);
            float av = odd ? p1 : v0, bv = odd ? v1 : p0;
            int col = nt0 * 16 + (odd ? 15 + lcol : lcol);
            *(uint*)&sA[(mt * 16 + quad * 4 + r) * PADM + col] = f2b2(av, bv);
        }
    __syncthreads();
    for (int i = t; i < 2048; i += 256) {
        int row = i >> 4, c = i & 15;
        int n = n0b + row;
        if (n < M) ((uint4*)(y_s + (size_t)n * HD))[c] = *(uint4*)&sA[row * PADM + c * 8];
    }
}

// ---------------- planar update, M=64 + persistent h buffer:
// yd=h@W1d; z=mean relu(yd+ys[src]+b1); agg=z@W2+b2; h += relu([h|agg]@Wu+bu) ----------------
__launch_bounds__(256, 4)
__global__ void update_planar_kernel(__bf16* __restrict__ h, const __bf16* __restrict__ y_s,
                                     const int* __restrict__ off, const int* __restrict__ csr_e,
                                     const float* __restrict__ b1, const __bf16* __restrict__ W1dP,
                                     const __bf16* __restrict__ W2P, const float* __restrict__ b2,
                                     const __bf16* __restrict__ WuP, const float* __restrict__ bu) {
    int p = blockIdx.y;
    __bf16* hp = h + (size_t)p * N_HITS * HD;
    const __bf16* ysp = y_s + (size_t)p * N_HITS * HD;
    const int* o = off + p * 30001;
    const int* csr = csr_e + p * N_EDGES;

    __shared__ __bf16 sH[64 * PADM];  // persistent h tile
    __shared__ __bf16 sA[64 * PADM];  // work tile
    int t = threadIdx.x;
    int n0b = blockIdx.x * 64;
    int lane = t & 63, wave = t >> 6;
    int lcol = lane & 15, quad = lane >> 4;
    int nt0 = wave * 2;
    bool odd = (lcol & 1) != 0;

    // phase 0: stage h -> sH (once)
    for (int i = t; i < 1024; i += 256) {
        int row = i >> 4, c = i & 15;
        int n = n0b + row; if (n >= N_HITS) n = N_HITS - 1;
        *(uint4*)&sH[row * PADM + c * 8] = ((const uint4*)(hp + (size_t)n * HD))[c];
    }
    __syncthreads();
    // phase 1: yd = sH@W1d ; accU = bu + sH@Wu[ks0..3]
    floatx4 yd[4][2], accU[4][2];
    {
        const bf16x8* w1 = (const bf16x8*)W1dP;
        const bf16x8* wu = (const bf16x8*)WuP;
        bf16x8 B1[2][4], BU[2][4];
#pragma unroll
        for (int nt = 0; nt < 2; ++nt)
#pragma unroll
            for (int ks = 0; ks < 4; ++ks) {
                B1[nt][ks] = w1[((nt0 + nt) * 4 + ks) * 64 + lane];
                BU[nt][ks] = wu[((nt0 + nt) * 8 + ks) * 64 + lane];
            }
#pragma unroll
        for (int nt = 0; nt < 2; ++nt) {
            float bv = bu[(nt0 + nt) * 16 + lcol];
#pragma unroll
            for (int mt = 0; mt < 4; ++mt) {
                yd[mt][nt] = (floatx4){0, 0, 0, 0};
                accU[mt][nt] = (floatx4){bv, bv, bv, bv};
            }
        }
#pragma unroll
        for (int mt = 0; mt < 4; ++mt)
#pragma unroll
            for (int ks = 0; ks < 4; ++ks) {
                bf16x8 a = *(const bf16x8*)&sH[(mt * 16 + lcol) * PADM + ks * 32 + quad * 8];
                yd[mt][0] = __builtin_amdgcn_mfma_f32_16x16x32_bf16(a, B1[0][ks], yd[mt][0], 0, 0, 0);
                yd[mt][1] = __builtin_amdgcn_mfma_f32_16x16x32_bf16(a, B1[1][ks], yd[mt][1], 0, 0, 0);
                accU[mt][0] = __builtin_amdgcn_mfma_f32_16x16x32_bf16(a, BU[0][ks], accU[mt][0], 0, 0, 0);
                accU[mt][1] = __builtin_amdgcn_mfma_f32_16x16x32_bf16(a, BU[1][ks], accU[mt][1], 0, 0, 0);
            }
    }
    // yd -> sA (paired cols)
#pragma unroll
    for (int mt = 0; mt < 4; ++mt)
#pragma unroll
        for (int r = 0; r < 4; ++r) {
            float v0 = yd[mt][0][r], v1 = yd[mt][1][r];
            float p0 = __shfl_xor(v0, 1), p1 = __shfl_xor(v1, 1);
            float av = odd ? p1 : v0, bv = odd ? v1 : p0;
            int col = nt0 * 16 + (odd ? 15 + lcol : lcol);
            *(uint*)&sA[(mt * 16 + quad * 4 + r) * PADM + col] = f2b2(av, bv);
        }
    __syncthreads();
    // phase A: in-place CSR edge gather on sA
    for (int i = t; i < 1024; i += 256) {
        int row = i >> 4, c = i & 15;
        int d = n0b + row; if (d >= N_HITS) d = N_HITS - 1;
        int beg = o[d], end = o[d + 1];
        union { uint4 u; __bf16 b[8]; } ydv;
        ydv.u = *(uint4*)&sA[row * PADM + c * 8];
        float4 b1a = *(const float4*)(b1 + c * 8);
        float4 b1b = *(const float4*)(b1 + c * 8 + 4);
        float bb[8] = {b1a.x, b1a.y, b1a.z, b1a.w, b1b.x, b1b.y, b1b.z, b1b.w};
        float a8[8] = {0, 0, 0, 0, 0, 0, 0, 0};
        for (int k = beg; k < end; ++k) {
            int s = csr[k];
            union { uint4 u; __bf16 b[8]; } ys;
            ys.u = ((const uint4*)(ysp + (size_t)s * HD))[c];
#pragma unroll
            for (int j = 0; j < 8; ++j)
                a8[j] += fmaxf((float)ydv.b[j] + (float)ys.b[j] + bb[j], 0.f);
        }
        float iv = (end > beg) ? 1.f / (float)(end - beg) : 0.f;
        union { __bf16 o8[8]; uint4 u; } outv;
#pragma unroll
        for (int j = 0; j < 8; ++j) outv.o8[j] = (__bf16)(a8[j] * iv);
        *(uint4*)&sA[row * PADM + c * 8] = outv.u;
    }
    __syncthreads();
    // phase B: agg = z @ W2 + b2
    floatx4 agg[4][2];
    {
        const bf16x8* w2p = (const bf16x8*)W2P;
        bf16x8 B[2][4];
#pragma unroll
        for (int nt = 0; nt < 2; ++nt)
#pragma unroll
            for (int ks = 0; ks < 4; ++ks)
                B[nt][ks] = w2p[((nt0 + nt) * 4 + ks) * 64 + lane];
#pragma unroll
        for (int nt = 0; nt < 2; ++nt) {
            float bv = b2[(nt0 + nt) * 16 + lcol];
#pragma unroll
            for (int mt = 0; mt < 4; ++mt) agg[mt][nt] = (floatx4){bv, bv, bv, bv};
        }
#pragma unroll
        for (int mt = 0; mt < 4; ++mt)
#pragma unroll
            for (int ks = 0; ks < 4; ++ks) {
                bf16x8 a = *(const bf16x8*)&sA[(mt * 16 + lcol) * PADM + ks * 32 + quad * 8];
                agg[mt][0] = __builtin_amdgcn_mfma_f32_16x16x32_bf16(a, B[0][ks], agg[mt][0], 0, 0, 0);
                agg[mt][1] = __builtin_amdgcn_mfma_f32_16x16x32_bf16(a, B[1][ks], agg[mt][1], 0, 0, 0);
            }
    }
    __syncthreads();
    // phase C: agg -> sA
#pragma unroll
    for (int mt = 0; mt < 4; ++mt)
#pragma unroll
        for (int r = 0; r < 4; ++r) {
            float v0 = agg[mt][0][r], v1 = agg[mt][1][r];
            float p0 = __shfl_xor(v0, 1), p1 = __shfl_xor(v1, 1);
            float av = odd ? p1 : v0, bv = odd ? v1 : p0;
            int col = nt0 * 16 + (odd ? 15 + lcol : lcol);
            *(uint*)&sA[(mt * 16 + quad * 4 + r) * PADM + col] = f2b2(av, bv);
        }
    __syncthreads();
    // phase D: accU += agg @ Wu[ks4..7]
    {
        const bf16x8* wu = (const bf16x8*)WuP;
        bf16x8 B[2][4];
#pragma unroll
        for (int nt = 0; nt < 2; ++nt)
#pragma unroll
            for (int ks = 0; ks < 4; ++ks)
                B[nt][ks] = wu[((nt0 + nt) * 8 + 4 + ks) * 64 + lane];
#pragma unroll
        for (int mt = 0; mt < 4; ++mt)
#pragma unroll
            for (int ks = 0; ks < 4; ++ks) {
                bf16x8 a = *(const bf16x8*)&sA[(mt * 16 + lcol) * PADM + ks * 32 + quad * 8];
                accU[mt][0] = __builtin_amdgcn_mfma_f32_16x16x32_bf16(a, B[0][ks], accU[mt][0], 0, 0, 0);
                accU[mt][1] = __builtin_amdgcn_mfma_f32_16x16x32_bf16(a, B[1][ks], accU[mt][1], 0, 0, 0);
            }
    }
    __syncthreads();
    // phase G: h_new = sH + relu(accU) -> sH (paired cols)
#pragma unroll
    for (int mt = 0; mt < 4; ++mt)
#pragma unroll
        for (int r = 0; r < 4; ++r) {
            float v0 = fmaxf(accU[mt][0][r], 0.f), v1 = fmaxf(accU[mt][1][r], 0.f);
            float p0 = __shfl_xor(v0, 1), p1 = __shfl_xor(v1, 1);
            float av = odd ? p1 : v0, bv = odd ? v1 : p0;
            int col = nt0 * 16 + (odd ? 15 + lcol : lcol);
            uint* sp2 = (uint*)&sH[(mt * 16 + quad * 4 + r) * PADM + col];
            float2 ho = b2f2(*sp2);
            *sp2 = f2b2(ho.x + av, ho.y + bv);
        }
    __syncthreads();
    // phase H: coalesced store sH -> h
    for (int i = t; i < 1024; i += 256) {
        int row = i >> 4, c = i & 15;
        int n = n0b + row;
        if (n < N_HITS) ((uint4*)(hp + (size_t)n * HD))[c] = *(uint4*)&sH[row * PADM + c * 8];
    }
}

// ---------------- sp fused (M=64): gather (3-plane mean of h) + GEMM + relu -> sp ----------------
__launch_bounds__(256, 4)
__global__ void sp_fused_kernel(const __bf16* __restrict__ h, const int* __restrict__ off,
                                const int* __restrict__ csr_s, const __bf16* __restrict__ WspP,
                                const float* __restrict__ b, __bf16* __restrict__ spf) {
    __shared__ __bf16 sA[64 * PADM];
    int t = threadIdx.x;
    int n0b = blockIdx.x * 64;
    int lane = t & 63, wave = t >> 6;
    int lcol = lane & 15, quad = lane >> 4;
    int nt0 = wave * 2;
    bool odd = (lcol & 1) != 0;

    for (int i = t; i < 1024; i += 256) {
        int row = i >> 4, c = i & 15;
        int s = n0b + row; if (s >= N_SPS) s = N_SPS - 1;
        float a8[8] = {0, 0, 0, 0, 0, 0, 0, 0};
#pragma unroll
        for (int p = 0; p < 3; ++p) {
            const int* o = off + (3 + p) * 30001;
            int beg = o[s], end = o[s + 1];
            const int* csr = csr_s + p * N_SPS;
            const __bf16* hb = h + (size_t)p * N_HITS * HD;
            float s8[8] = {0, 0, 0, 0, 0, 0, 0, 0};
            for (int k = beg; k < end; ++k) {
                int hit = csr[k];
                union { uint4 u; __bf16 b[8]; } hv;
                hv.u = ((const uint4*)(hb + (size_t)hit * HD))[c];
#pragma unroll
                for (int j = 0; j < 8; ++j) s8[j] += (float)hv.b[j];
            }
            float iv = (end > beg) ? 1.f / (float)(end - beg) : 0.f;
#pragma unroll
            for (int j = 0; j < 8; ++j) a8[j] += s8[j] * iv;
        }
        union { __bf16 o8[8]; uint4 u; } outv;
#pragma unroll
        for (int j = 0; j < 8; ++j) outv.o8[j] = (__bf16)a8[j];
        *(uint4*)&sA[row * PADM + c * 8] = outv.u;
    }
    __syncthreads();

    const bf16x8* wp = (const bf16x8*)WspP;
    bf16x8 B[2][4];
#pragma unroll
    for (int nt = 0; nt < 2; ++nt)
#pragma unroll
        for (int ks = 0; ks < 4; ++ks)
            B[nt][ks] = wp[((nt0 + nt) * 4 + ks) * 64 + lane];

    floatx4 acc[4][2];
#pragma unroll
    for (int nt = 0; nt < 2; ++nt) {
        float bv = b[(nt0 + nt) * 16 + lcol];
#pragma unroll
        for (int mt = 0; mt < 4; ++mt) acc[mt][nt] = (floatx4){bv, bv, bv, bv};
    }
#pragma unroll
    for (int mt = 0; mt < 4; ++mt)
#pragma unroll
        for (int ks = 0; ks < 4; ++ks) {
            bf16x8 a = *(const bf16x8*)&sA[(mt * 16 + lcol) * PADM + ks * 32 + quad * 8];
            acc[mt][0] = __builtin_amdgcn_mfma_f32_16x16x32_bf16(a, B[0][ks], acc[mt][0], 0, 0, 0);
            acc[mt][1] = __builtin_amdgcn_mfma_f32_16x16x32_bf16(a, B[1][ks], acc[mt][1], 0, 0, 0);
        }
    __syncthreads();
#pragma unroll
    for (int mt = 0; mt < 4; ++mt)
#pragma unroll
        for (int r = 0; r < 4; ++r) {
            float v0 = fmaxf(acc[mt][0][r], 0.f), v1 = fmaxf(acc[mt][1][r], 0.f);
            float p0 = __shfl_xor(v0, 1), p1 = __shfl_xor(v1, 1);
            float av = odd ? p1 : v0, bv = odd ? v1 : p0;
            int col = nt0 * 16 + (odd ? 15 + lcol : lcol);
            *(uint*)&sA[(mt * 16 + quad * 4 + r) * PADM + col] = f2b2(av, bv);
        }
    __syncthreads();
    for (int i = t; i < 1024; i += 256) {
        int row = i >> 4, c = i & 15;
        int n = n0b + row;
        if (n < N_SPS) ((uint4*)(spf + (size_t)n * HD))[c] = *(uint4*)&sA[row * PADM + c * 8];
    }
}

// ---------------- nexus update (M=64, two buffers), fused back gather; emits y_s ----------------
__launch_bounds__(256, 4)
__global__ void update_y_kernel(__bf16* __restrict__ h, const __bf16* __restrict__ sp,
                                const int* __restrict__ off, const int* __restrict__ csr_h,
                                const __bf16* __restrict__ WP, const float* __restrict__ b,
                                const __bf16* __restrict__ W1sP, __bf16* __restrict__ y_s) {
    int p = blockIdx.y;
    __bf16* hp = h + (size_t)p * N_HITS * HD;
    __bf16* ysp = y_s + (size_t)p * N_HITS * HD;
    const int* o = off + (6 + p) * 30001;
    const int* csr = csr_h + p * N_SPS;

    __shared__ __bf16 sH[64 * PADM];  // persistent h tile
    __shared__ __bf16 sA[64 * PADM];  // work tile (aux, then y_s)
    int t = threadIdx.x;
    int n0b = blockIdx.x * 64;
    int lane = t & 63, wave = t >> 6;
    int lcol = lane & 15, quad = lane >> 4;
    int nt0 = wave * 2;
    bool odd = (lcol & 1) != 0;

    // phase A: gather aux -> sA ; stage h -> sH
    for (int i = t; i < 1024; i += 256) {
        int row = i >> 4, c = i & 15;
        int hit = n0b + row; if (hit >= N_HITS) hit = N_HITS - 1;
        int beg = o[hit], end = o[hit + 1];
        float a8[8] = {0, 0, 0, 0, 0, 0, 0, 0};
        for (int k = beg; k < end; ++k) {
            int spid = csr[k];
            union { uint4 u; __bf16 b[8]; } sv;
            sv.u = ((const uint4*)(sp + (size_t)spid * HD))[c];
#pragma unroll
            for (int j = 0; j < 8; ++j) a8[j] += (float)sv.b[j];
        }
        float iv = (end > beg) ? 1.f / (float)(end - beg) : 0.f;
        union { __bf16 o8[8]; uint4 u; } outv;
#pragma unroll
        for (int j = 0; j < 8; ++j) outv.o8[j] = (__bf16)(a8[j] * iv);
        *(uint4*)&sA[row * PADM + c * 8] = outv.u;
    }
    for (int i = t; i < 1024; i += 256) {
        int row = i >> 4, c = i & 15;
        int n = n0b + row; if (n >= N_HITS) n = N_HITS - 1;
        *(uint4*)&sH[row * PADM + c * 8] = ((const uint4*)(hp + (size_t)n * HD))[c];
    }
    __syncthreads();
    // phase B: acc = b + sH@Wn[ks0..3] + sA@Wn[ks4..7]
    floatx4 acc[4][2];
    {
        const bf16x8* wp = (const bf16x8*)WP;
        bf16x8 BH[2][4], BA[2][4];
#pragma unroll
        for (int nt = 0; nt < 2; ++nt)
#pragma unroll
            for (int ks = 0; ks < 4; ++ks) {
                BH[nt][ks] = wp[((nt0 + nt) * 8 + ks) * 64 + lane];
                BA[nt][ks] = wp[((nt0 + nt) * 8 + 4 + ks) * 64 + lane];
            }
#pragma unroll
        for (int nt = 0; nt < 2; ++nt) {
            float bv = b[(nt0 + nt) * 16 + lcol];
#pragma unroll
            for (int mt = 0; mt < 4; ++mt) acc[mt][nt] = (floatx4){bv, bv, bv, bv};
        }
#pragma unroll
        for (int mt = 0; mt < 4; ++mt)
#pragma unroll
            for (int ks = 0; ks < 4; ++ks) {
                bf16x8 ah = *(const bf16x8*)&sH[(mt * 16 + lcol) * PADM + ks * 32 + quad * 8];
                bf16x8 aa = *(const bf16x8*)&sA[(mt * 16 + lcol) * PADM + ks * 32 + quad * 8];
                acc[mt][0] = __builtin_amdgcn_mfma_f32_16x16x32_bf16(ah, BH[0][ks], acc[mt][0], 0, 0, 0);
                acc[mt][1] = __builtin_amdgcn_mfma_f32_16x16x32_bf16(ah, BH[1][ks], acc[mt][1], 0, 0, 0);
                acc[mt][0] = __builtin_amdgcn_mfma_f32_16x16x32_bf16(aa, BA[0][ks], acc[mt][0], 0, 0, 0);
                acc[mt][1] = __builtin_amdgcn_mfma_f32_16x16x32_bf16(aa, BA[1][ks], acc[mt][1], 0, 0, 0);
            }
    }
    __syncthreads();
    // phase C: h_new = sH + relu(acc) -> sH
#pragma unroll
    for (int mt = 0; mt < 4; ++mt)
#pragma unroll
        for (int r = 0; r < 4; ++r) {
            float v0 = fmaxf(acc[mt][0][r], 0.f), v1 = fmaxf(acc[mt][1][r], 0.f);
            float p0 = __shfl_xor(v0, 1), p1 = __shfl_xor(v1, 1);
            float av = odd ? p1 : v0, bv = odd ? v1 : p0;
            int col = nt0 * 16 + (odd ? 15 + lcol : lcol);
            uint* sp2 = (uint*)&sH[(mt * 16 + quad * 4 + r) * PADM + col];
            float2 ho = b2f2(*sp2);
            *sp2 = f2b2(ho.x + av, ho.y + bv);
        }
    __syncthreads();
    // phase D: coalesced h store + yacc = sH@W1s
    for (int i = t; i < 1024; i += 256) {
        int row = i >> 4, c = i & 15;
        int n = n0b + row;
        if (n < N_HITS) ((uint4*)(hp + (size_t)n * HD))[c] = *(uint4*)&sH[row * PADM + c * 8];
    }
    {
        const bf16x8* wyp = (const bf16x8*)W1sP;
        bf16x8 B[2][4];
#pragma unroll
        for (int nt = 0; nt < 2; ++nt)
#pragma unroll
            for (int ks = 0; ks < 4; ++ks)
                B[nt][ks] = wyp[((nt0 + nt) * 4 + ks) * 64 + lane];
        floatx4 yacc[4][2];
#pragma unroll
        for (int mt = 0; mt < 4; ++mt) { yacc[mt][0] = (floatx4){0,0,0,0}; yacc[mt][1] = (floatx4){0,0,0,0}; }
#pragma unroll
        for (int mt = 0; mt < 4; ++mt)
#pragma unroll
            for (int ks = 0; ks < 4; ++ks) {
                bf16x8 a = *(const bf16x8*)&sH[(mt * 16 + lcol) * PADM + ks * 32 + quad * 8];
                yacc[mt][0] = __builtin_amdgcn_mfma_f32_16x16x32_bf16(a, B[0][ks], yacc[mt][0], 0, 0, 0);
                yacc[mt][1] = __builtin_amdgcn_mfma_f32_16x16x32_bf16(a, B[1][ks], yacc[mt][1], 0, 0, 0);
            }
#pragma unroll
        for (int mt = 0; mt < 4; ++mt)
#pragma unroll
            for (int r = 0; r < 4; ++r) {
                float v0 = yacc[mt][0][r], v1 = yacc[mt][1][r];
                float p0 = __shfl_xor(v0, 1), p1 = __shfl_xor(v1, 1);
                float av = odd ? p1 : v0, bv = odd ? v1 : p0;
                int col = nt0 * 16 + (odd ? 15 + lcol : lcol);
                *(uint*)&sA[(mt * 16 + quad * 4 + r) * PADM + col] = f2b2(av, bv);
            }
    }
    __syncthreads();
    // phase E: coalesced y_s store
    for (int i = t; i < 1024; i += 256) {
        int row = i >> 4, c = i & 15;
        int n = n0b + row;
        if (n < N_HITS) ((uint4*)(ysp + (size_t)n * HD))[c] = *(uint4*)&sA[row * PADM + c * 8];
    }
}

// ---------------- decoder ----------------
__global__ void dec_kernel(const __bf16* __restrict__ h, const float* __restrict__ W,
                           const float* __restrict__ b, float* __restrict__ out) {
    __shared__ float sW[640];
    __shared__ float sB[8];
    int t = threadIdx.x;
    for (int i = t; i < 640; i += 256) sW[i] = W[i];
    if (t < 5) sB[t] = b[t];
    __syncthreads();
    int n = blockIdx.x * 256 + t;
    if (n >= 3 * N_HITS) return;
    const uint4* hr = (const uint4*)(h + (size_t)n * HD);
    float a0 = sB[0], a1 = sB[1], a2 = sB[2], a3 = sB[3], a4 = sB[4];
#pragma unroll 4
    for (int q = 0; q < 16; ++q) {
        union { uint4 u; __bf16 bb[8]; } v; v.u = hr[q];
        const float* w = &sW[q * 40];
#pragma unroll
        for (int j = 0; j < 8; ++j) {
            float x = (float)v.bb[j];
            a0 = fmaf(x, w[j * 5 + 0], a0);
            a1 = fmaf(x, w[j * 5 + 1], a1);
            a2 = fmaf(x, w[j * 5 + 2], a2);
            a3 = fmaf(x, w[j * 5 + 3], a3);
            a4 = fmaf(x, w[j * 5 + 4], a4);
        }
    }
    float* oo = out + (size_t)n * NCLS;
    oo[0] = a0; oo[1] = a1; oo[2] = a2; oo[3] = a3; oo[4] = a4;
}

extern "C" void kernel_launch(void* const* d_in, const int* in_sizes, int n_in,
                              void* d_out, int out_size, void* d_ws, size_t ws_size,
                              hipStream_t stream) {
    const float* xu = (const float*)d_in[0];
    const int* eu = (const int*)d_in[1];
    const int* nu = (const int*)d_in[2];
    const float* xv = (const float*)d_in[3];
    const int* ev = (const int*)d_in[4];
    const int* nv = (const int*)d_in[5];
    const float* xy = (const float*)d_in[6];
    const int* ey = (const int*)d_in[7];
    const int* ny = (const int*)d_in[8];
    const float* W_enc = (const float*)d_in[9];
    const float* b_enc = (const float*)d_in[10];
    const float* W1 = (const float*)d_in[11];
    const float* b1 = (const float*)d_in[12];
    const float* W2 = (const float*)d_in[13];
    const float* b2 = (const float*)d_in[14];
    const float* W_upd = (const float*)d_in[15];
    const float* b_upd = (const float*)d_in[16];
    const float* W_sp = (const float*)d_in[17];
    const float* b_sp = (const float*)d_in[18];
    const float* W_nx = (const float*)d_in[19];
    const float* b_nx = (const float*)d_in[20];
    const float* W_sem = (const float*)d_in[21];
    const float* b_sem = (const float*)d_in[22];

    const size_t HN = (size_t)3 * N_HITS * HD;
    __bf16* h = (__bf16*)d_ws;                   // bf16 [3][N_HITS][HD]
    __bf16* y_s = h + HN;                        // bf16 [3][N_HITS][HD]
    __bf16* sp = y_s + HN;                       // bf16 [N_SPS][HD]
    int* cnt = (int*)(sp + (size_t)N_SPS * HD);  // [270000]
    int* off = cnt + 270000;                     // [9*30001]
    int* cursor = off + 270009;                  // [270000]
    int* csr_e = cursor + 270000;                // [3*90000]
    int* csr_s = csr_e + 270000;                 // [3*30000]
    int* csr_h = csr_s + 90000;                  // [3*30000]
    __bf16* packs = (__bf16*)(csr_h + 90000);    // [131072]
    __bf16* W1dP = packs;
    __bf16* W1sP = packs + 16384;
    __bf16* W2P = packs + 32768;
    __bf16* WuP = packs + 49152;
    __bf16* WnP = packs + 81920;
    __bf16* WspP = packs + 114688;

    wprep_kernel<<<512, 256, 0, stream>>>(W1, W2, W_upd, W_nx, W_sp, packs);
    (void)hipMemsetAsync(cnt, 0, 270000 * sizeof(int), stream);
    hist_all_kernel<<<(450000 + 255) / 256, 256, 0, stream>>>(eu, ev, ey, nu, nv, ny, cnt);
    scan_kernel<<<9, 1024, 0, stream>>>(cnt, off, cursor);
    fill_kernel<<<(450000 + 255) / 256, 256, 0, stream>>>(eu, ev, ey, nu, nv, ny,
                                                          cursor, csr_e, csr_s, csr_h);

    enc_kernel<<<(3 * N_HITS * HD + 255) / 256, 256, 0, stream>>>(xu, xv, xy, W_enc, b_enc, h);
    y_init_kernel<<<(3 * N_HITS + 127) / 128, 256, 0, stream>>>(h, W1sP, y_s);

    for (int it = 0; it < 3; ++it) {
        update_planar_kernel<<<dim3((N_HITS + 63) / 64, 3), 256, 0, stream>>>(
            h, y_s, off, csr_e, b1, W1dP, W2P, b2, WuP, b_upd);
        sp_fused_kernel<<<(N_SPS + 63) / 64, 256, 0, stream>>>(h, off, csr_s, WspP, b_sp, sp);
        update_y_kernel<<<dim3((N_HITS + 63) / 64, 3), 256, 0, stream>>>(
            h, sp, off, csr_h, WnP, b_nx, W1sP, y_s);
    }

    dec_kernel<<<(3 * N_HITS + 255) / 256, 256, 0, stream>>>(h, W_sem, b_sem, (float*)d_out);
}

// Round 13
// 518.248 us; speedup vs baseline: 2.0493x; 1.1573x over previous
//
#include <hip/hip_runtime.h>
#include <hip/hip_fp16.h>

#define N_HITS 30000
#define N_EDGES 90000
#define N_SPS 30000
#define HD 128
#define NCLS 5

#define PADM 136  // 128 + 8 bf16 pad

typedef __attribute__((ext_vector_type(8))) __bf16 bf16x8;
typedef __attribute__((ext_vector_type(4))) float floatx4;

__device__ __forceinline__ float2 b2f2(uint u) {
    union { uint u; __bf16 b[2]; } x; x.u = u;
    return make_float2((float)x.b[0], (float)x.b[1]);
}
__device__ __forceinline__ uint f2b2(float a, float b) {
    union { uint u; __bf16 b[2]; } x; x.b[0] = (__bf16)a; x.b[1] = (__bf16)b;
    return x.u;
}

// ---------------- histograms ----------------
__global__ void hist_all_kernel(const int* __restrict__ eu, const int* __restrict__ ev,
                                const int* __restrict__ ey, const int* __restrict__ nu,
                                const int* __restrict__ nv, const int* __restrict__ ny,
                                int* __restrict__ cnt) {
    int gid = blockIdx.x * blockDim.x + threadIdx.x;
    if (gid >= 450000) return;
    int p = gid / 150000;
    int r = gid - p * 150000;
    const int* e = (p == 0) ? eu : (p == 1) ? ev : ey;
    const int* nx = (p == 0) ? nu : (p == 1) ? nv : ny;
    if (r < N_EDGES) {
        atomicAdd(&cnt[p * 30000 + e[N_EDGES + r]], 1);
    } else if (r < N_EDGES + N_SPS) {
        int i = r - N_EDGES;
        atomicAdd(&cnt[(3 + p) * 30000 + nx[N_SPS + i]], 1);
    } else {
        int i = r - N_EDGES - N_SPS;
        atomicAdd(&cnt[(6 + p) * 30000 + nx[i]], 1);
    }
}

// ---------------- exclusive scan per segment ----------------
__launch_bounds__(1024)
__global__ void scan_kernel(const int* __restrict__ cnt, int* __restrict__ off,
                            int* __restrict__ cursor) {
    int seg = blockIdx.x;
    const int* c = cnt + seg * 30000;
    int* o = off + seg * 30001;
    int* cur = cursor + seg * 30000;
    int t = threadIdx.x;
    int base = t * 30;
    int lc[30];
    int sum = 0;
#pragma unroll
    for (int k = 0; k < 30; ++k) {
        int i = base + k;
        lc[k] = (i < 30000) ? c[i] : 0;
        sum += lc[k];
    }
    __shared__ int part[1024];
    part[t] = sum;
    __syncthreads();
    for (int d = 1; d < 1024; d <<= 1) {
        int x = (t >= d) ? part[t - d] : 0;
        __syncthreads();
        part[t] += x;
        __syncthreads();
    }
    int run = part[t] - sum;
#pragma unroll
    for (int k = 0; k < 30; ++k) {
        int i = base + k;
        if (i < 30000) { o[i] = run; cur[i] = run; run += lc[k]; }
    }
    if (t == 1023) o[30000] = part[1023];
}

// ---------------- CSR fill ----------------
__global__ void fill_kernel(const int* __restrict__ eu, const int* __restrict__ ev,
                            const int* __restrict__ ey, const int* __restrict__ nu,
                            const int* __restrict__ nv, const int* __restrict__ ny,
                            int* __restrict__ cursor, int* __restrict__ csr_e,
                            int* __restrict__ csr_s, int* __restrict__ csr_h) {
    int gid = blockIdx.x * blockDim.x + threadIdx.x;
    if (gid >= 450000) return;
    int p = gid / 150000;
    int r = gid - p * 150000;
    const int* e = (p == 0) ? eu : (p == 1) ? ev : ey;
    const int* nx = (p == 0) ? nu : (p == 1) ? nv : ny;
    if (r < N_EDGES) {
        int d = e[N_EDGES + r];
        int pos = atomicAdd(&cursor[p * 30000 + d], 1);
        csr_e[p * N_EDGES + pos] = e[r];
    } else if (r < N_EDGES + N_SPS) {
        int i = r - N_EDGES;
        int spid = nx[N_SPS + i];
        int pos = atomicAdd(&cursor[(3 + p) * 30000 + spid], 1);
        csr_s[p * N_SPS + pos] = nx[i];
    } else {
        int i = r - N_EDGES - N_SPS;
        int hit = nx[i];
        int pos = atomicAdd(&cursor[(6 + p) * 30000 + hit], 1);
        csr_h[p * N_SPS + pos] = nx[N_SPS + i];
    }
}

// ---------------- weight pre-pack ----------------
__device__ __forceinline__ void pack4(const float* __restrict__ W, __bf16* __restrict__ P,
                                      int idx, int koff) {
    int j = idx & 7, lane = (idx >> 3) & 63, ks = (idx >> 9) & 3, n = (idx >> 11) & 7;
    int k = ks * 32 + (lane >> 4) * 8 + j, col = n * 16 + (lane & 15);
    P[idx] = (__bf16)W[(k + koff) * 128 + col];
}
__device__ __forceinline__ void pack8(const float* __restrict__ W, __bf16* __restrict__ P, int idx) {
    int j = idx & 7, lane = (idx >> 3) & 63, ks = (idx >> 9) & 7, n = (idx >> 12) & 7;
    int k = ks * 32 + (lane >> 4) * 8 + j, col = n * 16 + (lane & 15);
    P[idx] = (__bf16)W[k * 128 + col];
}

__global__ void wprep_kernel(const float* __restrict__ W1, const float* __restrict__ W2,
                             const float* __restrict__ Wu, const float* __restrict__ Wn,
                             const float* __restrict__ Wsp, __bf16* __restrict__ packs) {
    int gid = blockIdx.x * blockDim.x + threadIdx.x;
    if (gid < 16384) { pack4(W1, packs, gid, 0); return; }            // W1d
    gid -= 16384;
    if (gid < 16384) { pack4(W1, packs + 16384, gid, 128); return; }  // W1s
    gid -= 16384;
    if (gid < 16384) { pack4(W2, packs + 32768, gid, 0); return; }    // W2
    gid -= 16384;
    if (gid < 32768) { pack8(Wu, packs + 49152, gid); return; }       // W_upd
    gid -= 32768;
    if (gid < 32768) { pack8(Wn, packs + 81920, gid); return; }       // W_nx
    gid -= 32768;
    if (gid < 16384) { pack4(Wsp, packs + 114688, gid, 0); }          // W_sp
}

// ---------------- fused encoder + y_init: h = relu(x@Wenc+benc); y_s = h@W1s ----------------
__launch_bounds__(256, 4)
__global__ void enc_y_kernel(const float* __restrict__ xu, const float* __restrict__ xv,
                             const float* __restrict__ xy, const float* __restrict__ We,
                             const float* __restrict__ be, const __bf16* __restrict__ W1sP,
                             __bf16* __restrict__ h, __bf16* __restrict__ y_s) {
    __shared__ __bf16 sA[128 * PADM];
    int t = threadIdx.x;
    int n0b = blockIdx.x * 128;
    const int M = 3 * N_HITS;
    // stage: compute h tile from x
    for (int i = t; i < 2048; i += 256) {
        int row = i >> 4, c = i & 15;
        int n = n0b + row; if (n >= M) n = M - 1;
        int p = n / N_HITS;
        int nn = n - p * N_HITS;
        const float* x = (p == 0) ? xu : (p == 1) ? xv : xy;
        float4 xv4 = *(const float4*)(x + nn * 4);
        union { __bf16 o8[8]; uint4 u; } outv;
#pragma unroll
        for (int j = 0; j < 8; ++j) {
            int col = c * 8 + j;
            float acc = be[col];
            acc = fmaf(xv4.x, We[0 * HD + col], acc);
            acc = fmaf(xv4.y, We[1 * HD + col], acc);
            acc = fmaf(xv4.z, We[2 * HD + col], acc);
            acc = fmaf(xv4.w, We[3 * HD + col], acc);
            outv.o8[j] = (__bf16)fmaxf(acc, 0.f);
        }
        *(uint4*)&sA[row * PADM + c * 8] = outv.u;
        if (n0b + row < M) ((uint4*)(h + (size_t)n * HD))[c] = outv.u;
    }
    __syncthreads();

    int lane = t & 63, wave = t >> 6;
    int lcol = lane & 15, quad = lane >> 4;
    int nt0 = wave * 2;
    bool odd = (lcol & 1) != 0;

    const bf16x8* wp = (const bf16x8*)W1sP;
    bf16x8 B[2][4];
#pragma unroll
    for (int nt = 0; nt < 2; ++nt)
#pragma unroll
        for (int ks = 0; ks < 4; ++ks)
            B[nt][ks] = wp[((nt0 + nt) * 4 + ks) * 64 + lane];
    floatx4 acc[8][2];
#pragma unroll
    for (int mt = 0; mt < 8; ++mt) { acc[mt][0] = (floatx4){0,0,0,0}; acc[mt][1] = (floatx4){0,0,0,0}; }
#pragma unroll
    for (int mt = 0; mt < 8; ++mt)
#pragma unroll
        for (int ks = 0; ks < 4; ++ks) {
            bf16x8 a = *(const bf16x8*)&sA[(mt * 16 + lcol) * PADM + ks * 32 + quad * 8];
            acc[mt][0] = __builtin_amdgcn_mfma_f32_16x16x32_bf16(a, B[0][ks], acc[mt][0], 0, 0, 0);
            acc[mt][1] = __builtin_amdgcn_mfma_f32_16x16x32_bf16(a, B[1][ks], acc[mt][1], 0, 0, 0);
        }
    __syncthreads();
#pragma unroll
    for (int mt = 0; mt < 8; ++mt)
#pragma unroll
        for (int r = 0; r < 4; ++r) {
            float v0 = acc[mt][0][r], v1 = acc[mt][1][r];
            float p0 = __shfl_xor(v0, 1), p1 = __shfl_xor(v1, 1);
            float av = odd ? p1 : v0, bv = odd ? v1 : p0;
            int col = nt0 * 16 + (odd ? 15 + lcol : lcol);
            *(uint*)&sA[(mt * 16 + quad * 4 + r) * PADM + col] = f2b2(av, bv);
        }
    __syncthreads();
    for (int i = t; i < 2048; i += 256) {
        int row = i >> 4, c = i & 15;
        int n = n0b + row;
        if (n < M) ((uint4*)(y_s + (size_t)n * HD))[c] = *(uint4*)&sA[row * PADM + c * 8];
    }
}

// ---------------- planar update, M=64, CSR-in-LDS gather ----------------
#define ECAP 640
__launch_bounds__(256, 4)
__global__ void update_planar_kernel(__bf16* __restrict__ h, const __bf16* __restrict__ y_s,
                                     const int* __restrict__ off, const int* __restrict__ csr_e,
                                     const float* __restrict__ b1, const __bf16* __restrict__ W1dP,
                                     const __bf16* __restrict__ W2P, const float* __restrict__ b2,
                                     const __bf16* __restrict__ WuP, const float* __restrict__ bu) {
    int p = blockIdx.y;
    __bf16* hp = h + (size_t)p * N_HITS * HD;
    const __bf16* ysp = y_s + (size_t)p * N_HITS * HD;
    const int* o = off + p * 30001;
    const int* csr = csr_e + p * N_EDGES;

    __shared__ __bf16 sH[64 * PADM];
    __shared__ __bf16 sA[64 * PADM];
    __shared__ int sOff[65];
    __shared__ int sIdx[ECAP];
    int t = threadIdx.x;
    int n0b = blockIdx.x * 64;
    int lane = t & 63, wave = t >> 6;
    int lcol = lane & 15, quad = lane >> 4;
    int nt0 = wave * 2;
    bool odd = (lcol & 1) != 0;

    // phase A0: offsets + h tile
    if (t < 65) {
        int idx = n0b + t; if (idx > N_HITS) idx = N_HITS;
        sOff[t] = o[idx];
    }
    for (int i = t; i < 1024; i += 256) {
        int row = i >> 4, c = i & 15;
        int n = n0b + row; if (n >= N_HITS) n = N_HITS - 1;
        *(uint4*)&sH[row * PADM + c * 8] = ((const uint4*)(hp + (size_t)n * HD))[c];
    }
    __syncthreads();
    int base = sOff[0];
    int total = sOff[64] - base;
    bool useL = (total <= ECAP);
    if (useL) for (int i = t; i < total; i += 256) sIdx[i] = csr[base + i];

    // phase 1: yd = sH@W1d ; accU = bu + sH@Wu[ks0..3]
    floatx4 yd[4][2], accU[4][2];
    {
        const bf16x8* w1 = (const bf16x8*)W1dP;
        const bf16x8* wu = (const bf16x8*)WuP;
        bf16x8 B1[2][4], BU[2][4];
#pragma unroll
        for (int nt = 0; nt < 2; ++nt)
#pragma unroll
            for (int ks = 0; ks < 4; ++ks) {
                B1[nt][ks] = w1[((nt0 + nt) * 4 + ks) * 64 + lane];
                BU[nt][ks] = wu[((nt0 + nt) * 8 + ks) * 64 + lane];
            }
#pragma unroll
        for (int nt = 0; nt < 2; ++nt) {
            float bv = bu[(nt0 + nt) * 16 + lcol];
#pragma unroll
            for (int mt = 0; mt < 4; ++mt) {
                yd[mt][nt] = (floatx4){0, 0, 0, 0};
                accU[mt][nt] = (floatx4){bv, bv, bv, bv};
            }
        }
#pragma unroll
        for (int mt = 0; mt < 4; ++mt)
#pragma unroll
            for (int ks = 0; ks < 4; ++ks) {
                bf16x8 a = *(const bf16x8*)&sH[(mt * 16 + lcol) * PADM + ks * 32 + quad * 8];
                yd[mt][0] = __builtin_amdgcn_mfma_f32_16x16x32_bf16(a, B1[0][ks], yd[mt][0], 0, 0, 0);
                yd[mt][1] = __builtin_amdgcn_mfma_f32_16x16x32_bf16(a, B1[1][ks], yd[mt][1], 0, 0, 0);
                accU[mt][0] = __builtin_amdgcn_mfma_f32_16x16x32_bf16(a, BU[0][ks], accU[mt][0], 0, 0, 0);
                accU[mt][1] = __builtin_amdgcn_mfma_f32_16x16x32_bf16(a, BU[1][ks], accU[mt][1], 0, 0, 0);
            }
    }
    // yd -> sA
#pragma unroll
    for (int mt = 0; mt < 4; ++mt)
#pragma unroll
        for (int r = 0; r < 4; ++r) {
            float v0 = yd[mt][0][r], v1 = yd[mt][1][r];
            float p0 = __shfl_xor(v0, 1), p1 = __shfl_xor(v1, 1);
            float av = odd ? p1 : v0, bv = odd ? v1 : p0;
            int col = nt0 * 16 + (odd ? 15 + lcol : lcol);
            *(uint*)&sA[(mt * 16 + quad * 4 + r) * PADM + col] = f2b2(av, bv);
        }
    __syncthreads();
    // phase A: in-place CSR edge gather on sA (indices from LDS)
    for (int i = t; i < 1024; i += 256) {
        int row = i >> 4, c = i & 15;
        int d = n0b + row;
        int beg = 0, end = 0;
        if (d < N_HITS) { beg = sOff[row]; end = sOff[row + 1]; }
        union { uint4 u; __bf16 b[8]; } ydv;
        ydv.u = *(uint4*)&sA[row * PADM + c * 8];
        float4 b1a = *(const float4*)(b1 + c * 8);
        float4 b1b = *(const float4*)(b1 + c * 8 + 4);
        float bb[8] = {b1a.x, b1a.y, b1a.z, b1a.w, b1b.x, b1b.y, b1b.z, b1b.w};
        float a8[8] = {0, 0, 0, 0, 0, 0, 0, 0};
        for (int k = beg; k < end; ++k) {
            int s = useL ? sIdx[k - base] : csr[k];
            union { uint4 u; __bf16 b[8]; } ys;
            ys.u = ((const uint4*)(ysp + (size_t)s * HD))[c];
#pragma unroll
            for (int j = 0; j < 8; ++j)
                a8[j] += fmaxf((float)ydv.b[j] + (float)ys.b[j] + bb[j], 0.f);
        }
        float iv = (end > beg) ? 1.f / (float)(end - beg) : 0.f;
        union { __bf16 o8[8]; uint4 u; } outv;
#pragma unroll
        for (int j = 0; j < 8; ++j) outv.o8[j] = (__bf16)(a8[j] * iv);
        *(uint4*)&sA[row * PADM + c * 8] = outv.u;
    }
    __syncthreads();
    // phase B: agg = z @ W2 + b2
    floatx4 agg[4][2];
    {
        const bf16x8* w2p = (const bf16x8*)W2P;
        bf16x8 B[2][4];
#pragma unroll
        for (int nt = 0; nt < 2; ++nt)
#pragma unroll
            for (int ks = 0; ks < 4; ++ks)
                B[nt][ks] = w2p[((nt0 + nt) * 4 + ks) * 64 + lane];
#pragma unroll
        for (int nt = 0; nt < 2; ++nt) {
            float bv = b2[(nt0 + nt) * 16 + lcol];
#pragma unroll
            for (int mt = 0; mt < 4; ++mt) agg[mt][nt] = (floatx4){bv, bv, bv, bv};
        }
#pragma unroll
        for (int mt = 0; mt < 4; ++mt)
#pragma unroll
            for (int ks = 0; ks < 4; ++ks) {
                bf16x8 a = *(const bf16x8*)&sA[(mt * 16 + lcol) * PADM + ks * 32 + quad * 8];
                agg[mt][0] = __builtin_amdgcn_mfma_f32_16x16x32_bf16(a, B[0][ks], agg[mt][0], 0, 0, 0);
                agg[mt][1] = __builtin_amdgcn_mfma_f32_16x16x32_bf16(a, B[1][ks], agg[mt][1], 0, 0, 0);
            }
    }
    __syncthreads();
    // phase C: agg -> sA
#pragma unroll
    for (int mt = 0; mt < 4; ++mt)
#pragma unroll
        for (int r = 0; r < 4; ++r) {
            float v0 = agg[mt][0][r], v1 = agg[mt][1][r];
            float p0 = __shfl_xor(v0, 1), p1 = __shfl_xor(v1, 1);
            float av = odd ? p1 : v0, bv = odd ? v1 : p0;
            int col = nt0 * 16 + (odd ? 15 + lcol : lcol);
            *(uint*)&sA[(mt * 16 + quad * 4 + r) * PADM + col] = f2b2(av, bv);
        }
    __syncthreads();
    // phase D: accU += agg @ Wu[ks4..7]
    {
        const bf16x8* wu = (const bf16x8*)WuP;
        bf16x8 B[2][4];
#pragma unroll
        for (int nt = 0; nt < 2; ++nt)
#pragma unroll
            for (int ks = 0; ks < 4; ++ks)
                B[nt][ks] = wu[((nt0 + nt) * 8 + 4 + ks) * 64 + lane];
#pragma unroll
        for (int mt = 0; mt < 4; ++mt)
#pragma unroll
            for (int ks = 0; ks < 4; ++ks) {
                bf16x8 a = *(const bf16x8*)&sA[(mt * 16 + lcol) * PADM + ks * 32 + quad * 8];
                accU[mt][0] = __builtin_amdgcn_mfma_f32_16x16x32_bf16(a, B[0][ks], accU[mt][0], 0, 0, 0);
                accU[mt][1] = __builtin_amdgcn_mfma_f32_16x16x32_bf16(a, B[1][ks], accU[mt][1], 0, 0, 0);
            }
    }
    __syncthreads();
    // phase G: h_new = sH + relu(accU) -> sH
#pragma unroll
    for (int mt = 0; mt < 4; ++mt)
#pragma unroll
        for (int r = 0; r < 4; ++r) {
            float v0 = fmaxf(accU[mt][0][r], 0.f), v1 = fmaxf(accU[mt][1][r], 0.f);
            float p0 = __shfl_xor(v0, 1), p1 = __shfl_xor(v1, 1);
            float av = odd ? p1 : v0, bv = odd ? v1 : p0;
            int col = nt0 * 16 + (odd ? 15 + lcol : lcol);
            uint* sp2 = (uint*)&sH[(mt * 16 + quad * 4 + r) * PADM + col];
            float2 ho = b2f2(*sp2);
            *sp2 = f2b2(ho.x + av, ho.y + bv);
        }
    __syncthreads();
    // phase H: coalesced store sH -> h
    for (int i = t; i < 1024; i += 256) {
        int row = i >> 4, c = i & 15;
        int n = n0b + row;
        if (n < N_HITS) ((uint4*)(hp + (size_t)n * HD))[c] = *(uint4*)&sH[row * PADM + c * 8];
    }
}

// ---------------- sp fused (M=64), CSR-in-LDS 3-plane gather ----------------
#define SCAP 576
__launch_bounds__(256, 4)
__global__ void sp_fused_kernel(const __bf16* __restrict__ h, const int* __restrict__ off,
                                const int* __restrict__ csr_s, const __bf16* __restrict__ WspP,
                                const float* __restrict__ b, __bf16* __restrict__ spf) {
    __shared__ __bf16 sA[64 * PADM];
    __shared__ int sOff[3][65];
    __shared__ int sIdx[SCAP];
    int t = threadIdx.x;
    int n0b = blockIdx.x * 64;
    int lane = t & 63, wave = t >> 6;
    int lcol = lane & 15, quad = lane >> 4;
    int nt0 = wave * 2;
    bool odd = (lcol & 1) != 0;

    if (t < 195) {
        int p = t / 65, i = t - p * 65;
        int idx = n0b + i; if (idx > N_SPS) idx = N_SPS;
        sOff[p][i] = off[(3 + p) * 30001 + idx];
    }
    __syncthreads();
    int base0 = sOff[0][0], len0 = sOff[0][64] - base0;
    int base1 = sOff[1][0], len1 = sOff[1][64] - base1;
    int base2 = sOff[2][0], len2 = sOff[2][64] - base2;
    int ofs1 = len0, ofs2 = len0 + len1;
    bool useL = (ofs2 + len2 <= SCAP);
    if (useL) {
        for (int i = t; i < len0; i += 256) sIdx[i] = csr_s[base0 + i];
        for (int i = t; i < len1; i += 256) sIdx[ofs1 + i] = csr_s[N_SPS + base1 + i];
        for (int i = t; i < len2; i += 256) sIdx[ofs2 + i] = csr_s[2 * N_SPS + base2 + i];
    }
    __syncthreads();

    for (int i = t; i < 1024; i += 256) {
        int row = i >> 4, c = i & 15;
        int s = n0b + row;
        float a8[8] = {0, 0, 0, 0, 0, 0, 0, 0};
        if (s < N_SPS) {
#pragma unroll
            for (int p = 0; p < 3; ++p) {
                int beg = sOff[p][row], end = sOff[p][row + 1];
                int bb = (p == 0) ? base0 : (p == 1) ? base1 : base2;
                int oo = (p == 0) ? 0 : (p == 1) ? ofs1 : ofs2;
                const int* csr = csr_s + p * N_SPS;
                const __bf16* hb = h + (size_t)p * N_HITS * HD;
                float s8[8] = {0, 0, 0, 0, 0, 0, 0, 0};
                for (int k = beg; k < end; ++k) {
                    int hit = useL ? sIdx[oo + (k - bb)] : csr[k];
                    union { uint4 u; __bf16 b[8]; } hv;
                    hv.u = ((const uint4*)(hb + (size_t)hit * HD))[c];
#pragma unroll
                    for (int j = 0; j < 8; ++j) s8[j] += (float)hv.b[j];
                }
                float iv = (end > beg) ? 1.f / (float)(end - beg) : 0.f;
#pragma unroll
                for (int j = 0; j < 8; ++j) a8[j] += s8[j] * iv;
            }
        }
        union { __bf16 o8[8]; uint4 u; } outv;
#pragma unroll
        for (int j = 0; j < 8; ++j) outv.o8[j] = (__bf16)a8[j];
        *(uint4*)&sA[row * PADM + c * 8] = outv.u;
    }
    __syncthreads();

    const bf16x8* wp = (const bf16x8*)WspP;
    bf16x8 B[2][4];
#pragma unroll
    for (int nt = 0; nt < 2; ++nt)
#pragma unroll
        for (int ks = 0; ks < 4; ++ks)
            B[nt][ks] = wp[((nt0 + nt) * 4 + ks) * 64 + lane];

    floatx4 acc[4][2];
#pragma unroll
    for (int nt = 0; nt < 2; ++nt) {
        float bv = b[(nt0 + nt) * 16 + lcol];
#pragma unroll
        for (int mt = 0; mt < 4; ++mt) acc[mt][nt] = (floatx4){bv, bv, bv, bv};
    }
#pragma unroll
    for (int mt = 0; mt < 4; ++mt)
#pragma unroll
        for (int ks = 0; ks < 4; ++ks) {
            bf16x8 a = *(const bf16x8*)&sA[(mt * 16 + lcol) * PADM + ks * 32 + quad * 8];
            acc[mt][0] = __builtin_amdgcn_mfma_f32_16x16x32_bf16(a, B[0][ks], acc[mt][0], 0, 0, 0);
            acc[mt][1] = __builtin_amdgcn_mfma_f32_16x16x32_bf16(a, B[1][ks], acc[mt][1], 0, 0, 0);
        }
    __syncthreads();
#pragma unroll
    for (int mt = 0; mt < 4; ++mt)
#pragma unroll
        for (int r = 0; r < 4; ++r) {
            float v0 = fmaxf(acc[mt][0][r], 0.f), v1 = fmaxf(acc[mt][1][r], 0.f);
            float p0 = __shfl_xor(v0, 1), p1 = __shfl_xor(v1, 1);
            float av = odd ? p1 : v0, bv = odd ? v1 : p0;
            int col = nt0 * 16 + (odd ? 15 + lcol : lcol);
            *(uint*)&sA[(mt * 16 + quad * 4 + r) * PADM + col] = f2b2(av, bv);
        }
    __syncthreads();
    for (int i = t; i < 1024; i += 256) {
        int row = i >> 4, c = i & 15;
        int n = n0b + row;
        if (n < N_SPS) ((uint4*)(spf + (size_t)n * HD))[c] = *(uint4*)&sA[row * PADM + c * 8];
    }
}

// ---------------- nexus update (M=64), CSR-in-LDS back gather; emits y_s ----------------
#define HCAP 320
__launch_bounds__(256, 4)
__global__ void update_y_kernel(__bf16* __restrict__ h, const __bf16* __restrict__ sp,
                                const int* __restrict__ off, const int* __restrict__ csr_h,
                                const __bf16* __restrict__ WP, const float* __restrict__ b,
                                const __bf16* __restrict__ W1sP, __bf16* __restrict__ y_s) {
    int p = blockIdx.y;
    __bf16* hp = h + (size_t)p * N_HITS * HD;
    __bf16* ysp = y_s + (size_t)p * N_HITS * HD;
    const int* o = off + (6 + p) * 30001;
    const int* csr = csr_h + p * N_SPS;

    __shared__ __bf16 sH[64 * PADM];
    __shared__ __bf16 sA[64 * PADM];
    __shared__ int sOff[65];
    __shared__ int sIdx[HCAP];
    int t = threadIdx.x;
    int n0b = blockIdx.x * 64;
    int lane = t & 63, wave = t >> 6;
    int lcol = lane & 15, quad = lane >> 4;
    int nt0 = wave * 2;
    bool odd = (lcol & 1) != 0;

    if (t < 65) {
        int idx = n0b + t; if (idx > N_HITS) idx = N_HITS;
        sOff[t] = o[idx];
    }
    // stage h -> sH
    for (int i = t; i < 1024; i += 256) {
        int row = i >> 4, c = i & 15;
        int n = n0b + row; if (n >= N_HITS) n = N_HITS - 1;
        *(uint4*)&sH[row * PADM + c * 8] = ((const uint4*)(hp + (size_t)n * HD))[c];
    }
    __syncthreads();
    int base = sOff[0];
    int total = sOff[64] - base;
    bool useL = (total <= HCAP);
    if (useL) for (int i = t; i < total; i += 256) sIdx[i] = csr[base + i];
    __syncthreads();

    // phase A: gather aux -> sA
    for (int i = t; i < 1024; i += 256) {
        int row = i >> 4, c = i & 15;
        int hit = n0b + row;
        int beg = 0, end = 0;
        if (hit < N_HITS) { beg = sOff[row]; end = sOff[row + 1]; }
        float a8[8] = {0, 0, 0, 0, 0, 0, 0, 0};
        for (int k = beg; k < end; ++k) {
            int spid = useL ? sIdx[k - base] : csr[k];
            union { uint4 u; __bf16 b[8]; } sv;
            sv.u = ((const uint4*)(sp + (size_t)spid * HD))[c];
#pragma unroll
            for (int j = 0; j < 8; ++j) a8[j] += (float)sv.b[j];
        }
        float iv = (end > beg) ? 1.f / (float)(end - beg) : 0.f;
        union { __bf16 o8[8]; uint4 u; } outv;
#pragma unroll
        for (int j = 0; j < 8; ++j) outv.o8[j] = (__bf16)(a8[j] * iv);
        *(uint4*)&sA[row * PADM + c * 8] = outv.u;
    }
    __syncthreads();
    // phase B: acc = b + sH@Wn[ks0..3] + sA@Wn[ks4..7]
    floatx4 acc[4][2];
    {
        const bf16x8* wp = (const bf16x8*)WP;
        bf16x8 BH[2][4], BA[2][4];
#pragma unroll
        for (int nt = 0; nt < 2; ++nt)
#pragma unroll
            for (int ks = 0; ks < 4; ++ks) {
                BH[nt][ks] = wp[((nt0 + nt) * 8 + ks) * 64 + lane];
                BA[nt][ks] = wp[((nt0 + nt) * 8 + 4 + ks) * 64 + lane];
            }
#pragma unroll
        for (int nt = 0; nt < 2; ++nt) {
            float bv = b[(nt0 + nt) * 16 + lcol];
#pragma unroll
            for (int mt = 0; mt < 4; ++mt) acc[mt][nt] = (floatx4){bv, bv, bv, bv};
        }
#pragma unroll
        for (int mt = 0; mt < 4; ++mt)
#pragma unroll
            for (int ks = 0; ks < 4; ++ks) {
                bf16x8 ah = *(const bf16x8*)&sH[(mt * 16 + lcol) * PADM + ks * 32 + quad * 8];
                bf16x8 aa = *(const bf16x8*)&sA[(mt * 16 + lcol) * PADM + ks * 32 + quad * 8];
                acc[mt][0] = __builtin_amdgcn_mfma_f32_16x16x32_bf16(ah, BH[0][ks], acc[mt][0], 0, 0, 0);
                acc[mt][1] = __builtin_amdgcn_mfma_f32_16x16x32_bf16(ah, BH[1][ks], acc[mt][1], 0, 0, 0);
                acc[mt][0] = __builtin_amdgcn_mfma_f32_16x16x32_bf16(aa, BA[0][ks], acc[mt][0], 0, 0, 0);
                acc[mt][1] = __builtin_amdgcn_mfma_f32_16x16x32_bf16(aa, BA[1][ks], acc[mt][1], 0, 0, 0);
            }
    }
    __syncthreads();
    // phase C: h_new = sH + relu(acc) -> sH
#pragma unroll
    for (int mt = 0; mt < 4; ++mt)
#pragma unroll
        for (int r = 0; r < 4; ++r) {
            float v0 = fmaxf(acc[mt][0][r], 0.f), v1 = fmaxf(acc[mt][1][r], 0.f);
            float p0 = __shfl_xor(v0, 1), p1 = __shfl_xor(v1, 1);
            float av = odd ? p1 : v0, bv = odd ? v1 : p0;
            int col = nt0 * 16 + (odd ? 15 + lcol : lcol);
            uint* sp2 = (uint*)&sH[(mt * 16 + quad * 4 + r) * PADM + col];
            float2 ho = b2f2(*sp2);
            *sp2 = f2b2(ho.x + av, ho.y + bv);
        }
    __syncthreads();
    // phase D: coalesced h store + yacc = sH@W1s
    for (int i = t; i < 1024; i += 256) {
        int row = i >> 4, c = i & 15;
        int n = n0b + row;
        if (n < N_HITS) ((uint4*)(hp + (size_t)n * HD))[c] = *(uint4*)&sH[row * PADM + c * 8];
    }
    {
        const bf16x8* wyp = (const bf16x8*)W1sP;
        bf16x8 B[2][4];
#pragma unroll
        for (int nt = 0; nt < 2; ++nt)
#pragma unroll
            for (int ks = 0; ks < 4; ++ks)
                B[nt][ks] = wyp[((nt0 + nt) * 4 + ks) * 64 + lane];
        floatx4 yacc[4][2];
#pragma unroll
        for (int mt = 0; mt < 4; ++mt) { yacc[mt][0] = (floatx4){0,0,0,0}; yacc[mt][1] = (floatx4){0,0,0,0}; }
#pragma unroll
        for (int mt = 0; mt < 4; ++mt)
#pragma unroll
            for (int ks = 0; ks < 4; ++ks) {
                bf16x8 a = *(const bf16x8*)&sH[(mt * 16 + lcol) * PADM + ks * 32 + quad * 8];
                yacc[mt][0] = __builtin_amdgcn_mfma_f32_16x16x32_bf16(a, B[0][ks], yacc[mt][0], 0, 0, 0);
                yacc[mt][1] = __builtin_amdgcn_mfma_f32_16x16x32_bf16(a, B[1][ks], yacc[mt][1], 0, 0, 0);
            }
#pragma unroll
        for (int mt = 0; mt < 4; ++mt)
#pragma unroll
            for (int r = 0; r < 4; ++r) {
                float v0 = yacc[mt][0][r], v1 = yacc[mt][1][r];
                float p0 = __shfl_xor(v0, 1), p1 = __shfl_xor(v1, 1);
                float av = odd ? p1 : v0, bv = odd ? v1 : p0;
                int col = nt0 * 16 + (odd ? 15 + lcol : lcol);
                *(uint*)&sA[(mt * 16 + quad * 4 + r) * PADM + col] = f2b2(av, bv);
            }
    }
    __syncthreads();
    // phase E: coalesced y_s store
    for (int i = t; i < 1024; i += 256) {
        int row = i >> 4, c = i & 15;
        int n = n0b + row;
        if (n < N_HITS) ((uint4*)(ysp + (size_t)n * HD))[c] = *(uint4*)&sA[row * PADM + c * 8];
    }
}

// ---------------- decoder ----------------
__global__ void dec_kernel(const __bf16* __restrict__ h, const float* __restrict__ W,
                           const float* __restrict__ b, float* __restrict__ out) {
    __shared__ float sW[640];
    __shared__ float sB[8];
    int t = threadIdx.x;
    for (int i = t; i < 640; i += 256) sW[i] = W[i];
    if (t < 5) sB[t] = b[t];
    __syncthreads();
    int n = blockIdx.x * 256 + t;
    if (n >= 3 * N_HITS) return;
    const uint4* hr = (const uint4*)(h + (size_t)n * HD);
    float a0 = sB[0], a1 = sB[1], a2 = sB[2], a3 = sB[3], a4 = sB[4];
#pragma unroll 4
    for (int q = 0; q < 16; ++q) {
        union { uint4 u; __bf16 bb[8]; } v; v.u = hr[q];
        const float* w = &sW[q * 40];
#pragma unroll
        for (int j = 0; j < 8; ++j) {
            float x = (float)v.bb[j];
            a0 = fmaf(x, w[j * 5 + 0], a0);
            a1 = fmaf(x, w[j * 5 + 1], a1);
            a2 = fmaf(x, w[j * 5 + 2], a2);
            a3 = fmaf(x, w[j * 5 + 3], a3);
            a4 = fmaf(x, w[j * 5 + 4], a4);
        }
    }
    float* oo = out + (size_t)n * NCLS;
    oo[0] = a0; oo[1] = a1; oo[2] = a2; oo[3] = a3; oo[4] = a4;
}

extern "C" void kernel_launch(void* const* d_in, const int* in_sizes, int n_in,
                              void* d_out, int out_size, void* d_ws, size_t ws_size,
                              hipStream_t stream) {
    const float* xu = (const float*)d_in[0];
    const int* eu = (const int*)d_in[1];
    const int* nu = (const int*)d_in[2];
    const float* xv = (const float*)d_in[3];
    const int* ev = (const int*)d_in[4];
    const int* nv = (const int*)d_in[5];
    const float* xy = (const float*)d_in[6];
    const int* ey = (const int*)d_in[7];
    const int* ny = (const int*)d_in[8];
    const float* W_enc = (const float*)d_in[9];
    const float* b_enc = (const float*)d_in[10];
    const float* W1 = (const float*)d_in[11];
    const float* b1 = (const float*)d_in[12];
    const float* W2 = (const float*)d_in[13];
    const float* b2 = (const float*)d_in[14];
    const float* W_upd = (const float*)d_in[15];
    const float* b_upd = (const float*)d_in[16];
    const float* W_sp = (const float*)d_in[17];
    const float* b_sp = (const float*)d_in[18];
    const float* W_nx = (const float*)d_in[19];
    const float* b_nx = (const float*)d_in[20];
    const float* W_sem = (const float*)d_in[21];
    const float* b_sem = (const float*)d_in[22];

    const size_t HN = (size_t)3 * N_HITS * HD;
    __bf16* h = (__bf16*)d_ws;                   // bf16 [3][N_HITS][HD]
    __bf16* y_s = h + HN;                        // bf16 [3][N_HITS][HD]
    __bf16* sp = y_s + HN;                       // bf16 [N_SPS][HD]
    int* cnt = (int*)(sp + (size_t)N_SPS * HD);  // [270000]
    int* off = cnt + 270000;                     // [9*30001]
    int* cursor = off + 270009;                  // [270000]
    int* csr_e = cursor + 270000;                // [3*90000]
    int* csr_s = csr_e + 270000;                 // [3*30000]
    int* csr_h = csr_s + 90000;                  // [3*30000]
    __bf16* packs = (__bf16*)(csr_h + 90000);    // [131072]
    __bf16* W1dP = packs;
    __bf16* W1sP = packs + 16384;
    __bf16* W2P = packs + 32768;
    __bf16* WuP = packs + 49152;
    __bf16* WnP = packs + 81920;
    __bf16* WspP = packs + 114688;

    wprep_kernel<<<512, 256, 0, stream>>>(W1, W2, W_upd, W_nx, W_sp, packs);
    (void)hipMemsetAsync(cnt, 0, 270000 * sizeof(int), stream);
    hist_all_kernel<<<(450000 + 255) / 256, 256, 0, stream>>>(eu, ev, ey, nu, nv, ny, cnt);
    scan_kernel<<<9, 1024, 0, stream>>>(cnt, off, cursor);
    fill_kernel<<<(450000 + 255) / 256, 256, 0, stream>>>(eu, ev, ey, nu, nv, ny,
                                                          cursor, csr_e, csr_s, csr_h);

    enc_y_kernel<<<(3 * N_HITS + 127) / 128, 256, 0, stream>>>(xu, xv, xy, W_enc, b_enc,
                                                               W1sP, h, y_s);

    for (int it = 0; it < 3; ++it) {
        update_planar_kernel<<<dim3((N_HITS + 63) / 64, 3), 256, 0, stream>>>(
            h, y_s, off, csr_e, b1, W1dP, W2P, b2, WuP, b_upd);
        sp_fused_kernel<<<(N_SPS + 63) / 64, 256, 0, stream>>>(h, off, csr_s, WspP, b_sp, sp);
        update_y_kernel<<<dim3((N_HITS + 63) / 64, 3), 256, 0, stream>>>(
            h, sp, off, csr_h, WnP, b_nx, W1sP, y_s);
    }

    dec_kernel<<<(3 * N_HITS + 255) / 256, 256, 0, stream>>>(h, W_sem, b_sem, (float*)d_out);
}

// Round 15
// 515.652 us; speedup vs baseline: 2.0596x; 1.0050x over previous
//
#include <hip/hip_runtime.h>
#include <hip/hip_fp16.h>

#define N_HITS 30000
#define N_EDGES 90000
#define N_SPS 30000
#define HD 128
#define NCLS 5

#define PADM 136  // 128 + 8 f16 pad

typedef __attribute__((ext_vector_type(8))) _Float16 f16x8;
typedef __attribute__((ext_vector_type(4))) float floatx4;

__device__ __forceinline__ float2 h2f2(uint u) {
    union { uint u; __half2 h; } x; x.u = u;
    return __half22float2(x.h);
}
__device__ __forceinline__ uint f2h2(float a, float b) {
    union { uint u; __half2 h; } x;
    x.h = __halves2half2(__float2half(a), __float2half(b));
    return x.u;
}

// ---------------- histograms ----------------
__global__ void hist_all_kernel(const int* __restrict__ eu, const int* __restrict__ ev,
                                const int* __restrict__ ey, const int* __restrict__ nu,
                                const int* __restrict__ nv, const int* __restrict__ ny,
                                int* __restrict__ cnt) {
    int gid = blockIdx.x * blockDim.x + threadIdx.x;
    if (gid >= 450000) return;
    int p = gid / 150000;
    int r = gid - p * 150000;
    const int* e = (p == 0) ? eu : (p == 1) ? ev : ey;
    const int* nx = (p == 0) ? nu : (p == 1) ? nv : ny;
    if (r < N_EDGES) {
        atomicAdd(&cnt[p * 30000 + e[N_EDGES + r]], 1);
    } else if (r < N_EDGES + N_SPS) {
        int i = r - N_EDGES;
        atomicAdd(&cnt[(3 + p) * 30000 + nx[N_SPS + i]], 1);
    } else {
        int i = r - N_EDGES - N_SPS;
        atomicAdd(&cnt[(6 + p) * 30000 + nx[i]], 1);
    }
}

// ---------------- exclusive scan per segment ----------------
__launch_bounds__(1024)
__global__ void scan_kernel(const int* __restrict__ cnt, int* __restrict__ off,
                            int* __restrict__ cursor) {
    int seg = blockIdx.x;
    const int* c = cnt + seg * 30000;
    int* o = off + seg * 30001;
    int* cur = cursor + seg * 30000;
    int t = threadIdx.x;
    int base = t * 30;
    int lc[30];
    int sum = 0;
#pragma unroll
    for (int k = 0; k < 30; ++k) {
        int i = base + k;
        lc[k] = (i < 30000) ? c[i] : 0;
        sum += lc[k];
    }
    __shared__ int part[1024];
    part[t] = sum;
    __syncthreads();
    for (int d = 1; d < 1024; d <<= 1) {
        int x = (t >= d) ? part[t - d] : 0;
        __syncthreads();
        part[t] += x;
        __syncthreads();
    }
    int run = part[t] - sum;
#pragma unroll
    for (int k = 0; k < 30; ++k) {
        int i = base + k;
        if (i < 30000) { o[i] = run; cur[i] = run; run += lc[k]; }
    }
    if (t == 1023) o[30000] = part[1023];
}

// ---------------- CSR fill ----------------
__global__ void fill_kernel(const int* __restrict__ eu, const int* __restrict__ ev,
                            const int* __restrict__ ey, const int* __restrict__ nu,
                            const int* __restrict__ nv, const int* __restrict__ ny,
                            int* __restrict__ cursor, int* __restrict__ csr_e,
                            int* __restrict__ csr_s, int* __restrict__ csr_h) {
    int gid = blockIdx.x * blockDim.x + threadIdx.x;
    if (gid >= 450000) return;
    int p = gid / 150000;
    int r = gid - p * 150000;
    const int* e = (p == 0) ? eu : (p == 1) ? ev : ey;
    const int* nx = (p == 0) ? nu : (p == 1) ? nv : ny;
    if (r < N_EDGES) {
        int d = e[N_EDGES + r];
        int pos = atomicAdd(&cursor[p * 30000 + d], 1);
        csr_e[p * N_EDGES + pos] = e[r];
    } else if (r < N_EDGES + N_SPS) {
        int i = r - N_EDGES;
        int spid = nx[N_SPS + i];
        int pos = atomicAdd(&cursor[(3 + p) * 30000 + spid], 1);
        csr_s[p * N_SPS + pos] = nx[i];
    } else {
        int i = r - N_EDGES - N_SPS;
        int hit = nx[i];
        int pos = atomicAdd(&cursor[(6 + p) * 30000 + hit], 1);
        csr_h[p * N_SPS + pos] = nx[N_SPS + i];
    }
}

// ---------------- weight pre-pack (f16) ----------------
__device__ __forceinline__ void pack4(const float* __restrict__ W, _Float16* __restrict__ P,
                                      int idx, int koff) {
    int j = idx & 7, lane = (idx >> 3) & 63, ks = (idx >> 9) & 3, n = (idx >> 11) & 7;
    int k = ks * 32 + (lane >> 4) * 8 + j, col = n * 16 + (lane & 15);
    P[idx] = (_Float16)W[(k + koff) * 128 + col];
}
__device__ __forceinline__ void pack8(const float* __restrict__ W, _Float16* __restrict__ P, int idx) {
    int j = idx & 7, lane = (idx >> 3) & 63, ks = (idx >> 9) & 7, n = (idx >> 12) & 7;
    int k = ks * 32 + (lane >> 4) * 8 + j, col = n * 16 + (lane & 15);
    P[idx] = (_Float16)W[k * 128 + col];
}

__global__ void wprep_kernel(const float* __restrict__ W1, const float* __restrict__ W2,
                             const float* __restrict__ Wu, const float* __restrict__ Wn,
                             const float* __restrict__ Wsp, _Float16* __restrict__ packs) {
    int gid = blockIdx.x * blockDim.x + threadIdx.x;
    if (gid < 16384) { pack4(W1, packs, gid, 0); return; }            // W1d
    gid -= 16384;
    if (gid < 16384) { pack4(W1, packs + 16384, gid, 128); return; }  // W1s
    gid -= 16384;
    if (gid < 16384) { pack4(W2, packs + 32768, gid, 0); return; }    // W2
    gid -= 16384;
    if (gid < 32768) { pack8(Wu, packs + 49152, gid); return; }       // W_upd
    gid -= 32768;
    if (gid < 32768) { pack8(Wn, packs + 81920, gid); return; }       // W_nx
    gid -= 32768;
    if (gid < 16384) { pack4(Wsp, packs + 114688, gid, 0); }          // W_sp
}

// ---------------- fused encoder + y_init ----------------
__launch_bounds__(256, 4)
__global__ void enc_y_kernel(const float* __restrict__ xu, const float* __restrict__ xv,
                             const float* __restrict__ xy, const float* __restrict__ We,
                             const float* __restrict__ be, const _Float16* __restrict__ W1sP,
                             _Float16* __restrict__ h, _Float16* __restrict__ y_s) {
    __shared__ _Float16 sA[128 * PADM];
    int t = threadIdx.x;
    int n0b = blockIdx.x * 128;
    const int M = 3 * N_HITS;
    for (int i = t; i < 2048; i += 256) {
        int row = i >> 4, c = i & 15;
        int n = n0b + row; if (n >= M) n = M - 1;
        int p = n / N_HITS;
        int nn = n - p * N_HITS;
        const float* x = (p == 0) ? xu : (p == 1) ? xv : xy;
        float4 xv4 = *(const float4*)(x + nn * 4);
        union { _Float16 o8[8]; uint4 u; } outv;
#pragma unroll
        for (int j = 0; j < 8; ++j) {
            int col = c * 8 + j;
            float acc = be[col];
            acc = fmaf(xv4.x, We[0 * HD + col], acc);
            acc = fmaf(xv4.y, We[1 * HD + col], acc);
            acc = fmaf(xv4.z, We[2 * HD + col], acc);
            acc = fmaf(xv4.w, We[3 * HD + col], acc);
            outv.o8[j] = (_Float16)fmaxf(acc, 0.f);
        }
        *(uint4*)&sA[row * PADM + c * 8] = outv.u;
        if (n0b + row < M) ((uint4*)(h + (size_t)n * HD))[c] = outv.u;
    }
    __syncthreads();

    int lane = t & 63, wave = t >> 6;
    int lcol = lane & 15, quad = lane >> 4;
    int nt0 = wave * 2;
    bool odd = (lcol & 1) != 0;

    const f16x8* wp = (const f16x8*)W1sP;
    f16x8 B[2][4];
#pragma unroll
    for (int nt = 0; nt < 2; ++nt)
#pragma unroll
        for (int ks = 0; ks < 4; ++ks)
            B[nt][ks] = wp[((nt0 + nt) * 4 + ks) * 64 + lane];
    floatx4 acc[8][2];
#pragma unroll
    for (int mt = 0; mt < 8; ++mt) { acc[mt][0] = (floatx4){0,0,0,0}; acc[mt][1] = (floatx4){0,0,0,0}; }
#pragma unroll
    for (int mt = 0; mt < 8; ++mt)
#pragma unroll
        for (int ks = 0; ks < 4; ++ks) {
            f16x8 a = *(const f16x8*)&sA[(mt * 16 + lcol) * PADM + ks * 32 + quad * 8];
            acc[mt][0] = __builtin_amdgcn_mfma_f32_16x16x32_f16(a, B[0][ks], acc[mt][0], 0, 0, 0);
            acc[mt][1] = __builtin_amdgcn_mfma_f32_16x16x32_f16(a, B[1][ks], acc[mt][1], 0, 0, 0);
        }
    __syncthreads();
#pragma unroll
    for (int mt = 0; mt < 8; ++mt)
#pragma unroll
        for (int r = 0; r < 4; ++r) {
            float v0 = acc[mt][0][r], v1 = acc[mt][1][r];
            float p0 = __shfl_xor(v0, 1), p1 = __shfl_xor(v1, 1);
            float av = odd ? p1 : v0, bv = odd ? v1 : p0;
            int col = nt0 * 16 + (odd ? 15 + lcol : lcol);
            *(uint*)&sA[(mt * 16 + quad * 4 + r) * PADM + col] = f2h2(av, bv);
        }
    __syncthreads();
    for (int i = t; i < 2048; i += 256) {
        int row = i >> 4, c = i & 15;
        int n = n0b + row;
        if (n < M) ((uint4*)(y_s + (size_t)n * HD))[c] = *(uint4*)&sA[row * PADM + c * 8];
    }
}

// ---------------- planar update, M=64, CSR-in-LDS, packed-f16 gather ----------------
#define ECAP 640
__launch_bounds__(256, 4)
__global__ void update_planar_kernel(_Float16* __restrict__ h, const _Float16* __restrict__ y_s,
                                     const int* __restrict__ off, const int* __restrict__ csr_e,
                                     const float* __restrict__ b1, const _Float16* __restrict__ W1dP,
                                     const _Float16* __restrict__ W2P, const float* __restrict__ b2,
                                     const _Float16* __restrict__ WuP, const float* __restrict__ bu) {
    int p = blockIdx.y;
    _Float16* hp = h + (size_t)p * N_HITS * HD;
    const _Float16* ysp = y_s + (size_t)p * N_HITS * HD;
    const int* o = off + p * 30001;
    const int* csr = csr_e + p * N_EDGES;

    __shared__ _Float16 sH[64 * PADM];
    __shared__ _Float16 sA[64 * PADM];
    __shared__ int sOff[65];
    __shared__ int sIdx[ECAP];
    int t = threadIdx.x;
    int n0b = blockIdx.x * 64;
    int lane = t & 63, wave = t >> 6;
    int lcol = lane & 15, quad = lane >> 4;
    int nt0 = wave * 2;
    bool odd = (lcol & 1) != 0;

    if (t < 65) {
        int idx = n0b + t; if (idx > N_HITS) idx = N_HITS;
        sOff[t] = o[idx];
    }
    for (int i = t; i < 1024; i += 256) {
        int row = i >> 4, c = i & 15;
        int n = n0b + row; if (n >= N_HITS) n = N_HITS - 1;
        *(uint4*)&sH[row * PADM + c * 8] = ((const uint4*)(hp + (size_t)n * HD))[c];
    }
    __syncthreads();
    int base = sOff[0];
    int total = sOff[64] - base;
    bool useL = (total <= ECAP);
    if (useL) for (int i = t; i < total; i += 256) sIdx[i] = csr[base + i];

    // phase 1: yd = sH@W1d ; accU = bu + sH@Wu[ks0..3]
    floatx4 yd[4][2], accU[4][2];
    {
        const f16x8* w1 = (const f16x8*)W1dP;
        const f16x8* wu = (const f16x8*)WuP;
        f16x8 B1[2][4], BU[2][4];
#pragma unroll
        for (int nt = 0; nt < 2; ++nt)
#pragma unroll
            for (int ks = 0; ks < 4; ++ks) {
                B1[nt][ks] = w1[((nt0 + nt) * 4 + ks) * 64 + lane];
                BU[nt][ks] = wu[((nt0 + nt) * 8 + ks) * 64 + lane];
            }
#pragma unroll
        for (int nt = 0; nt < 2; ++nt) {
            float bv = bu[(nt0 + nt) * 16 + lcol];
#pragma unroll
            for (int mt = 0; mt < 4; ++mt) {
                yd[mt][nt] = (floatx4){0, 0, 0, 0};
                accU[mt][nt] = (floatx4){bv, bv, bv, bv};
            }
        }
#pragma unroll
        for (int mt = 0; mt < 4; ++mt)
#pragma unroll
            for (int ks = 0; ks < 4; ++ks) {
                f16x8 a = *(const f16x8*)&sH[(mt * 16 + lcol) * PADM + ks * 32 + quad * 8];
                yd[mt][0] = __builtin_amdgcn_mfma_f32_16x16x32_f16(a, B1[0][ks], yd[mt][0], 0, 0, 0);
                yd[mt][1] = __builtin_amdgcn_mfma_f32_16x16x32_f16(a, B1[1][ks], yd[mt][1], 0, 0, 0);
                accU[mt][0] = __builtin_amdgcn_mfma_f32_16x16x32_f16(a, BU[0][ks], accU[mt][0], 0, 0, 0);
                accU[mt][1] = __builtin_amdgcn_mfma_f32_16x16x32_f16(a, BU[1][ks], accU[mt][1], 0, 0, 0);
            }
    }
    // yd + b1 -> sA (paired cols)
#pragma unroll
    for (int mt = 0; mt < 4; ++mt)
#pragma unroll
        for (int r = 0; r < 4; ++r) {
            float v0 = yd[mt][0][r], v1 = yd[mt][1][r];
            float p0 = __shfl_xor(v0, 1), p1 = __shfl_xor(v1, 1);
            float av = odd ? p1 : v0, bv = odd ? v1 : p0;
            int col = nt0 * 16 + (odd ? 15 + lcol : lcol);
            av += b1[col]; bv += b1[col + 1];
            *(uint*)&sA[(mt * 16 + quad * 4 + r) * PADM + col] = f2h2(av, bv);
        }
    __syncthreads();
    // phase A: in-place CSR edge gather on sA, packed f16 vector math
    for (int i = t; i < 1024; i += 256) {
        int row = i >> 4, c = i & 15;
        int d = n0b + row;
        int beg = 0, end = 0;
        if (d < N_HITS) { beg = sOff[row]; end = sOff[row + 1]; }
        f16x8 ydv = *(const f16x8*)&sA[row * PADM + c * 8];
        f16x8 accv = (f16x8)(_Float16)0;
        for (int k = beg; k < end; ++k) {
            int s = useL ? sIdx[k - base] : csr[k];
            f16x8 ys = *(const f16x8*)&ysp[(size_t)s * HD + c * 8];
            accv += __builtin_elementwise_max(ys + ydv, (f16x8)(_Float16)0);
        }
        _Float16 iv = (_Float16)((end > beg) ? 1.f / (float)(end - beg) : 0.f);
        accv *= iv;
        *(f16x8*)&sA[row * PADM + c * 8] = accv;
    }
    __syncthreads();
    // phase B: agg = z @ W2 + b2
    floatx4 agg[4][2];
    {
        const f16x8* w2p = (const f16x8*)W2P;
        f16x8 B[2][4];
#pragma unroll
        for (int nt = 0; nt < 2; ++nt)
#pragma unroll
            for (int ks = 0; ks < 4; ++ks)
                B[nt][ks] = w2p[((nt0 + nt) * 4 + ks) * 64 + lane];
#pragma unroll
        for (int nt = 0; nt < 2; ++nt) {
            float bv = b2[(nt0 + nt) * 16 + lcol];
#pragma unroll
            for (int mt = 0; mt < 4; ++mt) agg[mt][nt] = (floatx4){bv, bv, bv, bv};
        }
#pragma unroll
        for (int mt = 0; mt < 4; ++mt)
#pragma unroll
            for (int ks = 0; ks < 4; ++ks) {
                f16x8 a = *(const f16x8*)&sA[(mt * 16 + lcol) * PADM + ks * 32 + quad * 8];
                agg[mt][0] = __builtin_amdgcn_mfma_f32_16x16x32_f16(a, B[0][ks], agg[mt][0], 0, 0, 0);
                agg[mt][1] = __builtin_amdgcn_mfma_f32_16x16x32_f16(a, B[1][ks], agg[mt][1], 0, 0, 0);
            }
    }
    __syncthreads();
    // phase C: agg -> sA
#pragma unroll
    for (int mt = 0; mt < 4; ++mt)
#pragma unroll
        for (int r = 0; r < 4; ++r) {
            float v0 = agg[mt][0][r], v1 = agg[mt][1][r];
            float p0 = __shfl_xor(v0, 1), p1 = __shfl_xor(v1, 1);
            float av = odd ? p1 : v0, bv = odd ? v1 : p0;
            int col = nt0 * 16 + (odd ? 15 + lcol : lcol);
            *(uint*)&sA[(mt * 16 + quad * 4 + r) * PADM + col] = f2h2(av, bv);
        }
    __syncthreads();
    // phase D: accU += agg @ Wu[ks4..7]
    {
        const f16x8* wu = (const f16x8*)WuP;
        f16x8 B[2][4];
#pragma unroll
        for (int nt = 0; nt < 2; ++nt)
#pragma unroll
            for (int ks = 0; ks < 4; ++ks)
                B[nt][ks] = wu[((nt0 + nt) * 8 + 4 + ks) * 64 + lane];
#pragma unroll
        for (int mt = 0; mt < 4; ++mt)
#pragma unroll
            for (int ks = 0; ks < 4; ++ks) {
                f16x8 a = *(const f16x8*)&sA[(mt * 16 + lcol) * PADM + ks * 32 + quad * 8];
                accU[mt][0] = __builtin_amdgcn_mfma_f32_16x16x32_f16(a, B[0][ks], accU[mt][0], 0, 0, 0);
                accU[mt][1] = __builtin_amdgcn_mfma_f32_16x16x32_f16(a, B[1][ks], accU[mt][1], 0, 0, 0);
            }
    }
    __syncthreads();
    // phase G: h_new = sH + relu(accU) -> sH
#pragma unroll
    for (int mt = 0; mt < 4; ++mt)
#pragma unroll
        for (int r = 0; r < 4; ++r) {
            float v0 = fmaxf(accU[mt][0][r], 0.f), v1 = fmaxf(accU[mt][1][r], 0.f);
            float p0 = __shfl_xor(v0, 1), p1 = __shfl_xor(v1, 1);
            float av = odd ? p1 : v0, bv = odd ? v1 : p0;
            int col = nt0 * 16 + (odd ? 15 + lcol : lcol);
            uint* sp2 = (uint*)&sH[(mt * 16 + quad * 4 + r) * PADM + col];
            float2 ho = h2f2(*sp2);
            *sp2 = f2h2(ho.x + av, ho.y + bv);
        }
    __syncthreads();
    // phase H: coalesced store sH -> h
    for (int i = t; i < 1024; i += 256) {
        int row = i >> 4, c = i & 15;
        int n = n0b + row;
        if (n < N_HITS) ((uint4*)(hp + (size_t)n * HD))[c] = *(uint4*)&sH[row * PADM + c * 8];
    }
}

// ---------------- sp fused (M=64), CSR-in-LDS 3-plane packed gather ----------------
#define SCAP 576
__launch_bounds__(256, 4)
__global__ void sp_fused_kernel(const _Float16* __restrict__ h, const int* __restrict__ off,
                                const int* __restrict__ csr_s, const _Float16* __restrict__ WspP,
                                const float* __restrict__ b, _Float16* __restrict__ spf) {
    __shared__ _Float16 sA[64 * PADM];
    __shared__ int sOff[3][65];
    __shared__ int sIdx[SCAP];
    int t = threadIdx.x;
    int n0b = blockIdx.x * 64;
    int lane = t & 63, wave = t >> 6;
    int lcol = lane & 15, quad = lane >> 4;
    int nt0 = wave * 2;
    bool odd = (lcol & 1) != 0;

    if (t < 195) {
        int p = t / 65, i = t - p * 65;
        int idx = n0b + i; if (idx > N_SPS) idx = N_SPS;
        sOff[p][i] = off[(3 + p) * 30001 + idx];
    }
    __syncthreads();
    int base0 = sOff[0][0], len0 = sOff[0][64] - base0;
    int base1 = sOff[1][0], len1 = sOff[1][64] - base1;
    int base2 = sOff[2][0], len2 = sOff[2][64] - base2;
    int ofs1 = len0, ofs2 = len0 + len1;
    bool useL = (ofs2 + len2 <= SCAP);
    if (useL) {
        for (int i = t; i < len0; i += 256) sIdx[i] = csr_s[base0 + i];
        for (int i = t; i < len1; i += 256) sIdx[ofs1 + i] = csr_s[N_SPS + base1 + i];
        for (int i = t; i < len2; i += 256) sIdx[ofs2 + i] = csr_s[2 * N_SPS + base2 + i];
    }
    __syncthreads();

    for (int i = t; i < 1024; i += 256) {
        int row = i >> 4, c = i & 15;
        int s = n0b + row;
        f16x8 tv = (f16x8)(_Float16)0;
        if (s < N_SPS) {
#pragma unroll
            for (int p = 0; p < 3; ++p) {
                int beg = sOff[p][row], end = sOff[p][row + 1];
                int bb = (p == 0) ? base0 : (p == 1) ? base1 : base2;
                int oo = (p == 0) ? 0 : (p == 1) ? ofs1 : ofs2;
                const int* csr = csr_s + p * N_SPS;
                const _Float16* hb = h + (size_t)p * N_HITS * HD;
                f16x8 sv = (f16x8)(_Float16)0;
                for (int k = beg; k < end; ++k) {
                    int hit = useL ? sIdx[oo + (k - bb)] : csr[k];
                    sv += *(const f16x8*)&hb[(size_t)hit * HD + c * 8];
                }
                _Float16 iv = (_Float16)((end > beg) ? 1.f / (float)(end - beg) : 0.f);
                tv += sv * iv;
            }
        }
        *(f16x8*)&sA[row * PADM + c * 8] = tv;
    }
    __syncthreads();

    const f16x8* wp = (const f16x8*)WspP;
    f16x8 B[2][4];
#pragma unroll
    for (int nt = 0; nt < 2; ++nt)
#pragma unroll
        for (int ks = 0; ks < 4; ++ks)
            B[nt][ks] = wp[((nt0 + nt) * 4 + ks) * 64 + lane];

    floatx4 acc[4][2];
#pragma unroll
    for (int nt = 0; nt < 2; ++nt) {
        float bv = b[(nt0 + nt) * 16 + lcol];
#pragma unroll
        for (int mt = 0; mt < 4; ++mt) acc[mt][nt] = (floatx4){bv, bv, bv, bv};
    }
#pragma unroll
    for (int mt = 0; mt < 4; ++mt)
#pragma unroll
        for (int ks = 0; ks < 4; ++ks) {
            f16x8 a = *(const f16x8*)&sA[(mt * 16 + lcol) * PADM + ks * 32 + quad * 8];
            acc[mt][0] = __builtin_amdgcn_mfma_f32_16x16x32_f16(a, B[0][ks], acc[mt][0], 0, 0, 0);
            acc[mt][1] = __builtin_amdgcn_mfma_f32_16x16x32_f16(a, B[1][ks], acc[mt][1], 0, 0, 0);
        }
    __syncthreads();
#pragma unroll
    for (int mt = 0; mt < 4; ++mt)
#pragma unroll
        for (int r = 0; r < 4; ++r) {
            float v0 = fmaxf(acc[mt][0][r], 0.f), v1 = fmaxf(acc[mt][1][r], 0.f);
            float p0 = __shfl_xor(v0, 1), p1 = __shfl_xor(v1, 1);
            float av = odd ? p1 : v0, bv = odd ? v1 : p0;
            int col = nt0 * 16 + (odd ? 15 + lcol : lcol);
            *(uint*)&sA[(mt * 16 + quad * 4 + r) * PADM + col] = f2h2(av, bv);
        }
    __syncthreads();
    for (int i = t; i < 1024; i += 256) {
        int row = i >> 4, c = i & 15;
        int n = n0b + row;
        if (n < N_SPS) ((uint4*)(spf + (size_t)n * HD))[c] = *(uint4*)&sA[row * PADM + c * 8];
    }
}

// ---------------- nexus update (M=64), packed back gather; emits y_s ----------------
#define HCAP 320
__launch_bounds__(256, 4)
__global__ void update_y_kernel(_Float16* __restrict__ h, const _Float16* __restrict__ sp,
                                const int* __restrict__ off, const int* __restrict__ csr_h,
                                const _Float16* __restrict__ WP, const float* __restrict__ b,
                                const _Float16* __restrict__ W1sP, _Float16* __restrict__ y_s) {
    int p = blockIdx.y;
    _Float16* hp = h + (size_t)p * N_HITS * HD;
    _Float16* ysp = y_s + (size_t)p * N_HITS * HD;
    const int* o = off + (6 + p) * 30001;
    const int* csr = csr_h + p * N_SPS;

    __shared__ _Float16 sH[64 * PADM];
    __shared__ _Float16 sA[64 * PADM];
    __shared__ int sOff[65];
    __shared__ int sIdx[HCAP];
    int t = threadIdx.x;
    int n0b = blockIdx.x * 64;
    int lane = t & 63, wave = t >> 6;
    int lcol = lane & 15, quad = lane >> 4;
    int nt0 = wave * 2;
    bool odd = (lcol & 1) != 0;

    if (t < 65) {
        int idx = n0b + t; if (idx > N_HITS) idx = N_HITS;
        sOff[t] = o[idx];
    }
    for (int i = t; i < 1024; i += 256) {
        int row = i >> 4, c = i & 15;
        int n = n0b + row; if (n >= N_HITS) n = N_HITS - 1;
        *(uint4*)&sH[row * PADM + c * 8] = ((const uint4*)(hp + (size_t)n * HD))[c];
    }
    __syncthreads();
    int base = sOff[0];
    int total = sOff[64] - base;
    bool useL = (total <= HCAP);
    if (useL) for (int i = t; i < total; i += 256) sIdx[i] = csr[base + i];
    __syncthreads();

    // phase A: gather aux -> sA (packed)
    for (int i = t; i < 1024; i += 256) {
        int row = i >> 4, c = i & 15;
        int hit = n0b + row;
        int beg = 0, end = 0;
        if (hit < N_HITS) { beg = sOff[row]; end = sOff[row + 1]; }
        f16x8 av8 = (f16x8)(_Float16)0;
        for (int k = beg; k < end; ++k) {
            int spid = useL ? sIdx[k - base] : csr[k];
            av8 += *(const f16x8*)&sp[(size_t)spid * HD + c * 8];
        }
        _Float16 iv = (_Float16)((end > beg) ? 1.f / (float)(end - beg) : 0.f);
        av8 *= iv;
        *(f16x8*)&sA[row * PADM + c * 8] = av8;
    }
    __syncthreads();
    // phase B: acc = b + sH@Wn[ks0..3] + sA@Wn[ks4..7]
    floatx4 acc[4][2];
    {
        const f16x8* wp = (const f16x8*)WP;
        f16x8 BH[2][4], BA[2][4];
#pragma unroll
        for (int nt = 0; nt < 2; ++nt)
#pragma unroll
            for (int ks = 0; ks < 4; ++ks) {
                BH[nt][ks] = wp[((nt0 + nt) * 8 + ks) * 64 + lane];
                BA[nt][ks] = wp[((nt0 + nt) * 8 + 4 + ks) * 64 + lane];
            }
#pragma unroll
        for (int nt = 0; nt < 2; ++nt) {
            float bv = b[(nt0 + nt) * 16 + lcol];
#pragma unroll
            for (int mt = 0; mt < 4; ++mt) acc[mt][nt] = (floatx4){bv, bv, bv, bv};
        }
#pragma unroll
        for (int mt = 0; mt < 4; ++mt)
#pragma unroll
            for (int ks = 0; ks < 4; ++ks) {
                f16x8 ah = *(const f16x8*)&sH[(mt * 16 + lcol) * PADM + ks * 32 + quad * 8];
                f16x8 aa = *(const f16x8*)&sA[(mt * 16 + lcol) * PADM + ks * 32 + quad * 8];
                acc[mt][0] = __builtin_amdgcn_mfma_f32_16x16x32_f16(ah, BH[0][ks], acc[mt][0], 0, 0, 0);
                acc[mt][1] = __builtin_amdgcn_mfma_f32_16x16x32_f16(ah, BH[1][ks], acc[mt][1], 0, 0, 0);
                acc[mt][0] = __builtin_amdgcn_mfma_f32_16x16x32_f16(aa, BA[0][ks], acc[mt][0], 0, 0, 0);
                acc[mt][1] = __builtin_amdgcn_mfma_f32_16x16x32_f16(aa, BA[1][ks], acc[mt][1], 0, 0, 0);
            }
    }
    __syncthreads();
    // phase C: h_new = sH + relu(acc) -> sH
#pragma unroll
    for (int mt = 0; mt < 4; ++mt)
#pragma unroll
        for (int r = 0; r < 4; ++r) {
            float v0 = fmaxf(acc[mt][0][r], 0.f), v1 = fmaxf(acc[mt][1][r], 0.f);
            float p0 = __shfl_xor(v0, 1), p1 = __shfl_xor(v1, 1);
            float av = odd ? p1 : v0, bv = odd ? v1 : p0;
            int col = nt0 * 16 + (odd ? 15 + lcol : lcol);
            uint* sp2 = (uint*)&sH[(mt * 16 + quad * 4 + r) * PADM + col];
            float2 ho = h2f2(*sp2);
            *sp2 = f2h2(ho.x + av, ho.y + bv);
        }
    __syncthreads();
    // phase D: coalesced h store + yacc = sH@W1s
    for (int i = t; i < 1024; i += 256) {
        int row = i >> 4, c = i & 15;
        int n = n0b + row;
        if (n < N_HITS) ((uint4*)(hp + (size_t)n * HD))[c] = *(uint4*)&sH[row * PADM + c * 8];
    }
    {
        const f16x8* wyp = (const f16x8*)W1sP;
        f16x8 B[2][4];
#pragma unroll
        for (int nt = 0; nt < 2; ++nt)
#pragma unroll
            for (int ks = 0; ks < 4; ++ks)
                B[nt][ks] = wyp[((nt0 + nt) * 4 + ks) * 64 + lane];
        floatx4 yacc[4][2];
#pragma unroll
        for (int mt = 0; mt < 4; ++mt) { yacc[mt][0] = (floatx4){0,0,0,0}; yacc[mt][1] = (floatx4){0,0,0,0}; }
#pragma unroll
        for (int mt = 0; mt < 4; ++mt)
#pragma unroll
            for (int ks = 0; ks < 4; ++ks) {
                f16x8 a = *(const f16x8*)&sH[(mt * 16 + lcol) * PADM + ks * 32 + quad * 8];
                yacc[mt][0] = __builtin_amdgcn_mfma_f32_16x16x32_f16(a, B[0][ks], yacc[mt][0], 0, 0, 0);
                yacc[mt][1] = __builtin_amdgcn_mfma_f32_16x16x32_f16(a, B[1][ks], yacc[mt][1], 0, 0, 0);
            }
#pragma unroll
        for (int mt = 0; mt < 4; ++mt)
#pragma unroll
            for (int r = 0; r < 4; ++r) {
                float v0 = yacc[mt][0][r], v1 = yacc[mt][1][r];
                float p0 = __shfl_xor(v0, 1), p1 = __shfl_xor(v1, 1);
                float av = odd ? p1 : v0, bv = odd ? v1 : p0;
                int col = nt0 * 16 + (odd ? 15 + lcol : lcol);
                *(uint*)&sA[(mt * 16 + quad * 4 + r) * PADM + col] = f2h2(av, bv);
            }
    }
    __syncthreads();
    // phase E: coalesced y_s store
    for (int i = t; i < 1024; i += 256) {
        int row = i >> 4, c = i & 15;
        int n = n0b + row;
        if (n < N_HITS) ((uint4*)(ysp + (size_t)n * HD))[c] = *(uint4*)&sA[row * PADM + c * 8];
    }
}

// ---------------- decoder ----------------
__global__ void dec_kernel(const _Float16* __restrict__ h, const float* __restrict__ W,
                           const float* __restrict__ b, float* __restrict__ out) {
    __shared__ float sW[640];
    __shared__ float sB[8];
    int t = threadIdx.x;
    for (int i = t; i < 640; i += 256) sW[i] = W[i];
    if (t < 5) sB[t] = b[t];
    __syncthreads();
    int n = blockIdx.x * 256 + t;
    if (n >= 3 * N_HITS) return;
    const uint4* hr = (const uint4*)(h + (size_t)n * HD);
    float a0 = sB[0], a1 = sB[1], a2 = sB[2], a3 = sB[3], a4 = sB[4];
#pragma unroll 4
    for (int q = 0; q < 16; ++q) {
        union { uint4 u; _Float16 hh[8]; } v; v.u = hr[q];
        const float* w = &sW[q * 40];
#pragma unroll
        for (int j = 0; j < 8; ++j) {
            float x = (float)v.hh[j];
            a0 = fmaf(x, w[j * 5 + 0], a0);
            a1 = fmaf(x, w[j * 5 + 1], a1);
            a2 = fmaf(x, w[j * 5 + 2], a2);
            a3 = fmaf(x, w[j * 5 + 3], a3);
            a4 = fmaf(x, w[j * 5 + 4], a4);
        }
    }
    float* oo = out + (size_t)n * NCLS;
    oo[0] = a0; oo[1] = a1; oo[2] = a2; oo[3] = a3; oo[4] = a4;
}

extern "C" void kernel_launch(void* const* d_in, const int* in_sizes, int n_in,
                              void* d_out, int out_size, void* d_ws, size_t ws_size,
                              hipStream_t stream) {
    const float* xu = (const float*)d_in[0];
    const int* eu = (const int*)d_in[1];
    const int* nu = (const int*)d_in[2];
    const float* xv = (const float*)d_in[3];
    const int* ev = (const int*)d_in[4];
    const int* nv = (const int*)d_in[5];
    const float* xy = (const float*)d_in[6];
    const int* ey = (const int*)d_in[7];
    const int* ny = (const int*)d_in[8];
    const float* W_enc = (const float*)d_in[9];
    const float* b_enc = (const float*)d_in[10];
    const float* W1 = (const float*)d_in[11];
    const float* b1 = (const float*)d_in[12];
    const float* W2 = (const float*)d_in[13];
    const float* b2 = (const float*)d_in[14];
    const float* W_upd = (const float*)d_in[15];
    const float* b_upd = (const float*)d_in[16];
    const float* W_sp = (const float*)d_in[17];
    const float* b_sp = (const float*)d_in[18];
    const float* W_nx = (const float*)d_in[19];
    const float* b_nx = (const float*)d_in[20];
    const float* W_sem = (const float*)d_in[21];
    const float* b_sem = (const float*)d_in[22];

    const size_t HN = (size_t)3 * N_HITS * HD;
    _Float16* h = (_Float16*)d_ws;                 // f16 [3][N_HITS][HD]
    _Float16* y_s = h + HN;                        // f16 [3][N_HITS][HD]
    _Float16* sp = y_s + HN;                       // f16 [N_SPS][HD]
    int* cnt = (int*)(sp + (size_t)N_SPS * HD);    // [270000]
    int* off = cnt + 270000;                       // [9*30001]
    int* cursor = off + 270009;                    // [270000]
    int* csr_e = cursor + 270000;                  // [3*90000]
    int* csr_s = csr_e + 270000;                   // [3*30000]
    int* csr_h = csr_s + 90000;                    // [3*30000]
    _Float16* packs = (_Float16*)(csr_h + 90000);  // [131072]
    _Float16* W1dP = packs;
    _Float16* W1sP = packs + 16384;
    _Float16* W2P = packs + 32768;
    _Float16* WuP = packs + 49152;
    _Float16* WnP = packs + 81920;
    _Float16* WspP = packs + 114688;

    wprep_kernel<<<512, 256, 0, stream>>>(W1, W2, W_upd, W_nx, W_sp, packs);
    (void)hipMemsetAsync(cnt, 0, 270000 * sizeof(int), stream);
    hist_all_kernel<<<(450000 + 255) / 256, 256, 0, stream>>>(eu, ev, ey, nu, nv, ny, cnt);
    scan_kernel<<<9, 1024, 0, stream>>>(cnt, off, cursor);
    fill_kernel<<<(450000 + 255) / 256, 256, 0, stream>>>(eu, ev, ey, nu, nv, ny,
                                                          cursor, csr_e, csr_s, csr_h);

    enc_y_kernel<<<(3 * N_HITS + 127) / 128, 256, 0, stream>>>(xu, xv, xy, W_enc, b_enc,
                                                               W1sP, h, y_s);

    for (int it = 0; it < 3; ++it) {
        update_planar_kernel<<<dim3((N_HITS + 63) / 64, 3), 256, 0, stream>>>(
            h, y_s, off, csr_e, b1, W1dP, W2P, b2, WuP, b_upd);
        sp_fused_kernel<<<(N_SPS + 63) / 64, 256, 0, stream>>>(h, off, csr_s, WspP, b_sp, sp);
        update_y_kernel<<<dim3((N_HITS + 63) / 64, 3), 256, 0, stream>>>(
            h, sp, off, csr_h, WnP, b_nx, W1sP, y_s);
    }

    dec_kernel<<<(3 * N_HITS + 255) / 256, 256, 0, stream>>>(h, W_sem, b_sem, (float*)d_out);
}

// Round 16
// 513.999 us; speedup vs baseline: 2.0662x; 1.0032x over previous
//
#include <hip/hip_runtime.h>
#include <hip/hip_fp16.h>

#define N_HITS 30000
#define N_EDGES 90000
#define N_SPS 30000
#define HD 128
#define NCLS 5

#define PADM 136  // 128 + 8 f16 pad

typedef __attribute__((ext_vector_type(8))) _Float16 f16x8;
typedef __attribute__((ext_vector_type(4))) float floatx4;

__device__ __forceinline__ float2 h2f2(uint u) {
    union { uint u; __half2 h; } x; x.u = u;
    return __half22float2(x.h);
}
__device__ __forceinline__ uint f2h2(float a, float b) {
    union { uint u; __half2 h; } x;
    x.h = __halves2half2(__float2half(a), __float2half(b));
    return x.u;
}

// ---------------- histograms ----------------
__global__ void hist_all_kernel(const int* __restrict__ eu, const int* __restrict__ ev,
                                const int* __restrict__ ey, const int* __restrict__ nu,
                                const int* __restrict__ nv, const int* __restrict__ ny,
                                int* __restrict__ cnt) {
    int gid = blockIdx.x * blockDim.x + threadIdx.x;
    if (gid >= 450000) return;
    int p = gid / 150000;
    int r = gid - p * 150000;
    const int* e = (p == 0) ? eu : (p == 1) ? ev : ey;
    const int* nx = (p == 0) ? nu : (p == 1) ? nv : ny;
    if (r < N_EDGES) {
        atomicAdd(&cnt[p * 30000 + e[N_EDGES + r]], 1);
    } else if (r < N_EDGES + N_SPS) {
        int i = r - N_EDGES;
        atomicAdd(&cnt[(3 + p) * 30000 + nx[N_SPS + i]], 1);
    } else {
        int i = r - N_EDGES - N_SPS;
        atomicAdd(&cnt[(6 + p) * 30000 + nx[i]], 1);
    }
}

// ---------------- exclusive scan per segment ----------------
__launch_bounds__(1024)
__global__ void scan_kernel(const int* __restrict__ cnt, int* __restrict__ off,
                            int* __restrict__ cursor) {
    int seg = blockIdx.x;
    const int* c = cnt + seg * 30000;
    int* o = off + seg * 30001;
    int* cur = cursor + seg * 30000;
    int t = threadIdx.x;
    int base = t * 30;
    int lc[30];
    int sum = 0;
#pragma unroll
    for (int k = 0; k < 30; ++k) {
        int i = base + k;
        lc[k] = (i < 30000) ? c[i] : 0;
        sum += lc[k];
    }
    __shared__ int part[1024];
    part[t] = sum;
    __syncthreads();
    for (int d = 1; d < 1024; d <<= 1) {
        int x = (t >= d) ? part[t - d] : 0;
        __syncthreads();
        part[t] += x;
        __syncthreads();
    }
    int run = part[t] - sum;
#pragma unroll
    for (int k = 0; k < 30; ++k) {
        int i = base + k;
        if (i < 30000) { o[i] = run; cur[i] = run; run += lc[k]; }
    }
    if (t == 1023) o[30000] = part[1023];
}

// ---------------- CSR fill ----------------
__global__ void fill_kernel(const int* __restrict__ eu, const int* __restrict__ ev,
                            const int* __restrict__ ey, const int* __restrict__ nu,
                            const int* __restrict__ nv, const int* __restrict__ ny,
                            int* __restrict__ cursor, int* __restrict__ csr_e,
                            int* __restrict__ csr_s, int* __restrict__ csr_h) {
    int gid = blockIdx.x * blockDim.x + threadIdx.x;
    if (gid >= 450000) return;
    int p = gid / 150000;
    int r = gid - p * 150000;
    const int* e = (p == 0) ? eu : (p == 1) ? ev : ey;
    const int* nx = (p == 0) ? nu : (p == 1) ? nv : ny;
    if (r < N_EDGES) {
        int d = e[N_EDGES + r];
        int pos = atomicAdd(&cursor[p * 30000 + d], 1);
        csr_e[p * N_EDGES + pos] = e[r];
    } else if (r < N_EDGES + N_SPS) {
        int i = r - N_EDGES;
        int spid = nx[N_SPS + i];
        int pos = atomicAdd(&cursor[(3 + p) * 30000 + spid], 1);
        csr_s[p * N_SPS + pos] = nx[i];
    } else {
        int i = r - N_EDGES - N_SPS;
        int hit = nx[i];
        int pos = atomicAdd(&cursor[(6 + p) * 30000 + hit], 1);
        csr_h[p * N_SPS + pos] = nx[N_SPS + i];
    }
}

// ---------------- weight pre-pack (f16) ----------------
__device__ __forceinline__ void pack4(const float* __restrict__ W, _Float16* __restrict__ P,
                                      int idx, int koff) {
    int j = idx & 7, lane = (idx >> 3) & 63, ks = (idx >> 9) & 3, n = (idx >> 11) & 7;
    int k = ks * 32 + (lane >> 4) * 8 + j, col = n * 16 + (lane & 15);
    P[idx] = (_Float16)W[(k + koff) * 128 + col];
}
__device__ __forceinline__ void pack8(const float* __restrict__ W, _Float16* __restrict__ P, int idx) {
    int j = idx & 7, lane = (idx >> 3) & 63, ks = (idx >> 9) & 7, n = (idx >> 12) & 7;
    int k = ks * 32 + (lane >> 4) * 8 + j, col = n * 16 + (lane & 15);
    P[idx] = (_Float16)W[k * 128 + col];
}

__global__ void wprep_kernel(const float* __restrict__ W1, const float* __restrict__ W2,
                             const float* __restrict__ Wu, const float* __restrict__ Wn,
                             const float* __restrict__ Wsp, _Float16* __restrict__ packs) {
    int gid = blockIdx.x * blockDim.x + threadIdx.x;
    if (gid < 16384) { pack4(W1, packs, gid, 0); return; }            // W1d
    gid -= 16384;
    if (gid < 16384) { pack4(W1, packs + 16384, gid, 128); return; }  // W1s
    gid -= 16384;
    if (gid < 16384) { pack4(W2, packs + 32768, gid, 0); return; }    // W2
    gid -= 16384;
    if (gid < 32768) { pack8(Wu, packs + 49152, gid); return; }       // W_upd
    gid -= 32768;
    if (gid < 32768) { pack8(Wn, packs + 81920, gid); return; }       // W_nx
    gid -= 32768;
    if (gid < 16384) { pack4(Wsp, packs + 114688, gid, 0); }          // W_sp
}

// ---------------- fused encoder + y emission: h = relu(x@Wenc+benc); y_d/y_s = h@W1d/W1s ----------------
__launch_bounds__(256, 4)
__global__ void enc_y_kernel(const float* __restrict__ xu, const float* __restrict__ xv,
                             const float* __restrict__ xy, const float* __restrict__ We,
                             const float* __restrict__ be, const _Float16* __restrict__ W1dP,
                             const _Float16* __restrict__ W1sP, _Float16* __restrict__ h,
                             _Float16* __restrict__ y_d, _Float16* __restrict__ y_s) {
    __shared__ _Float16 sA[128 * PADM];
    __shared__ _Float16 sO[128 * PADM];
    int t = threadIdx.x;
    int n0b = blockIdx.x * 128;
    const int M = 3 * N_HITS;
    for (int i = t; i < 2048; i += 256) {
        int row = i >> 4, c = i & 15;
        int n = n0b + row; if (n >= M) n = M - 1;
        int p = n / N_HITS;
        int nn = n - p * N_HITS;
        const float* x = (p == 0) ? xu : (p == 1) ? xv : xy;
        float4 xv4 = *(const float4*)(x + nn * 4);
        union { _Float16 o8[8]; uint4 u; } outv;
#pragma unroll
        for (int j = 0; j < 8; ++j) {
            int col = c * 8 + j;
            float acc = be[col];
            acc = fmaf(xv4.x, We[0 * HD + col], acc);
            acc = fmaf(xv4.y, We[1 * HD + col], acc);
            acc = fmaf(xv4.z, We[2 * HD + col], acc);
            acc = fmaf(xv4.w, We[3 * HD + col], acc);
            outv.o8[j] = (_Float16)fmaxf(acc, 0.f);
        }
        *(uint4*)&sA[row * PADM + c * 8] = outv.u;
        if (n0b + row < M) ((uint4*)(h + (size_t)n * HD))[c] = outv.u;
    }
    __syncthreads();

    int lane = t & 63, wave = t >> 6;
    int lcol = lane & 15, quad = lane >> 4;
    int nt0 = wave * 2;
    bool odd = (lcol & 1) != 0;

    for (int half = 0; half < 2; ++half) {
        const f16x8* wp = (const f16x8*)(half == 0 ? W1dP : W1sP);
        _Float16* out = half == 0 ? y_d : y_s;
        f16x8 B[2][4];
#pragma unroll
        for (int nt = 0; nt < 2; ++nt)
#pragma unroll
            for (int ks = 0; ks < 4; ++ks)
                B[nt][ks] = wp[((nt0 + nt) * 4 + ks) * 64 + lane];
        floatx4 acc[8][2];
#pragma unroll
        for (int mt = 0; mt < 8; ++mt) { acc[mt][0] = (floatx4){0,0,0,0}; acc[mt][1] = (floatx4){0,0,0,0}; }
#pragma unroll
        for (int mt = 0; mt < 8; ++mt)
#pragma unroll
            for (int ks = 0; ks < 4; ++ks) {
                f16x8 a = *(const f16x8*)&sA[(mt * 16 + lcol) * PADM + ks * 32 + quad * 8];
                acc[mt][0] = __builtin_amdgcn_mfma_f32_16x16x32_f16(a, B[0][ks], acc[mt][0], 0, 0, 0);
                acc[mt][1] = __builtin_amdgcn_mfma_f32_16x16x32_f16(a, B[1][ks], acc[mt][1], 0, 0, 0);
            }
#pragma unroll
        for (int mt = 0; mt < 8; ++mt)
#pragma unroll
            for (int r = 0; r < 4; ++r) {
                float v0 = acc[mt][0][r], v1 = acc[mt][1][r];
                float p0 = __shfl_xor(v0, 1), p1 = __shfl_xor(v1, 1);
                float av = odd ? p1 : v0, bv = odd ? v1 : p0;
                int col = nt0 * 16 + (odd ? 15 + lcol : lcol);
                *(uint*)&sO[(mt * 16 + quad * 4 + r) * PADM + col] = f2h2(av, bv);
            }
        __syncthreads();
        for (int i = t; i < 2048; i += 256) {
            int row = i >> 4, c = i & 15;
            int n = n0b + row;
            if (n < M) ((uint4*)(out + (size_t)n * HD))[c] = *(uint4*)&sO[row * PADM + c * 8];
        }
        __syncthreads();
    }
}

// ---------------- planar update, M=64, single LDS buffer, y_d read from global ----------------
#define ECAP 640
__launch_bounds__(256, 5)
__global__ void update_planar_kernel(_Float16* __restrict__ h, const _Float16* __restrict__ y_d,
                                     const _Float16* __restrict__ y_s,
                                     const int* __restrict__ off, const int* __restrict__ csr_e,
                                     const float* __restrict__ b1,
                                     const _Float16* __restrict__ W2P, const float* __restrict__ b2,
                                     const _Float16* __restrict__ WuP, const float* __restrict__ bu) {
    int p = blockIdx.y;
    _Float16* hp = h + (size_t)p * N_HITS * HD;
    const _Float16* ydp = y_d + (size_t)p * N_HITS * HD;
    const _Float16* ysp = y_s + (size_t)p * N_HITS * HD;
    const int* o = off + p * 30001;
    const int* csr = csr_e + p * N_EDGES;

    __shared__ _Float16 sA[64 * PADM];
    __shared__ int sOff[65];
    __shared__ int sIdx[ECAP];
    int t = threadIdx.x;
    int n0b = blockIdx.x * 64;
    int lane = t & 63, wave = t >> 6;
    int lcol = lane & 15, quad = lane >> 4;
    int nt0 = wave * 2;
    bool odd = (lcol & 1) != 0;

    if (t < 65) {
        int idx = n0b + t; if (idx > N_HITS) idx = N_HITS;
        sOff[t] = o[idx];
    }
    // phase 0: stage y_d tile (+b1 folded) -> sA
    for (int i = t; i < 1024; i += 256) {
        int row = i >> 4, c = i & 15;
        int n = n0b + row; if (n >= N_HITS) n = N_HITS - 1;
        f16x8 yv = *(const f16x8*)&ydp[(size_t)n * HD + c * 8];
        float4 b1a = *(const float4*)(b1 + c * 8);
        float4 b1b = *(const float4*)(b1 + c * 8 + 4);
        float bb[8] = {b1a.x, b1a.y, b1a.z, b1a.w, b1b.x, b1b.y, b1b.z, b1b.w};
        f16x8 ov;
#pragma unroll
        for (int j = 0; j < 8; ++j) ov[j] = (_Float16)((float)yv[j] + bb[j]);
        *(f16x8*)&sA[row * PADM + c * 8] = ov;
    }
    __syncthreads();  // B1: sOff + yd tile visible
    int base = sOff[0];
    int total = sOff[64] - base;
    bool useL = (total <= ECAP);
    if (useL) for (int i = t; i < total; i += 256) sIdx[i] = csr[base + i];
    __syncthreads();  // B2: sIdx visible

    // phase A: in-place CSR edge gather on sA (packed f16)
    for (int i = t; i < 1024; i += 256) {
        int row = i >> 4, c = i & 15;
        int d = n0b + row;
        int beg = 0, end = 0;
        if (d < N_HITS) { beg = sOff[row]; end = sOff[row + 1]; }
        f16x8 ydv = *(const f16x8*)&sA[row * PADM + c * 8];
        f16x8 accv = (f16x8)(_Float16)0;
        for (int k = beg; k < end; ++k) {
            int s = useL ? sIdx[k - base] : csr[k];
            f16x8 ys = *(const f16x8*)&ysp[(size_t)s * HD + c * 8];
            accv += __builtin_elementwise_max(ys + ydv, (f16x8)(_Float16)0);
        }
        _Float16 iv = (_Float16)((end > beg) ? 1.f / (float)(end - beg) : 0.f);
        accv *= iv;
        *(f16x8*)&sA[row * PADM + c * 8] = accv;
    }
    __syncthreads();  // B3: z visible
    // phase B: agg = z @ W2 + b2
    floatx4 acc[4][2];
    {
        const f16x8* w2p = (const f16x8*)W2P;
        f16x8 B[2][4];
#pragma unroll
        for (int nt = 0; nt < 2; ++nt)
#pragma unroll
            for (int ks = 0; ks < 4; ++ks)
                B[nt][ks] = w2p[((nt0 + nt) * 4 + ks) * 64 + lane];
#pragma unroll
        for (int nt = 0; nt < 2; ++nt) {
            float bv = b2[(nt0 + nt) * 16 + lcol];
#pragma unroll
            for (int mt = 0; mt < 4; ++mt) acc[mt][nt] = (floatx4){bv, bv, bv, bv};
        }
#pragma unroll
        for (int mt = 0; mt < 4; ++mt)
#pragma unroll
            for (int ks = 0; ks < 4; ++ks) {
                f16x8 a = *(const f16x8*)&sA[(mt * 16 + lcol) * PADM + ks * 32 + quad * 8];
                acc[mt][0] = __builtin_amdgcn_mfma_f32_16x16x32_f16(a, B[0][ks], acc[mt][0], 0, 0, 0);
                acc[mt][1] = __builtin_amdgcn_mfma_f32_16x16x32_f16(a, B[1][ks], acc[mt][1], 0, 0, 0);
            }
    }
    __syncthreads();  // B4: z reads done
    // phase C: agg -> sA
#pragma unroll
    for (int mt = 0; mt < 4; ++mt)
#pragma unroll
        for (int r = 0; r < 4; ++r) {
            float v0 = acc[mt][0][r], v1 = acc[mt][1][r];
            float p0 = __shfl_xor(v0, 1), p1 = __shfl_xor(v1, 1);
            float av = odd ? p1 : v0, bv = odd ? v1 : p0;
            int col = nt0 * 16 + (odd ? 15 + lcol : lcol);
            *(uint*)&sA[(mt * 16 + quad * 4 + r) * PADM + col] = f2h2(av, bv);
        }
    __syncthreads();  // B5
    // phase D: accU = bu + agg @ Wu[ks4..7]  (reuse acc regs)
    {
        const f16x8* wu = (const f16x8*)WuP;
        f16x8 B[2][4];
#pragma unroll
        for (int nt = 0; nt < 2; ++nt)
#pragma unroll
            for (int ks = 0; ks < 4; ++ks)
                B[nt][ks] = wu[((nt0 + nt) * 8 + 4 + ks) * 64 + lane];
        floatx4 tmp[4][2];
#pragma unroll
        for (int nt = 0; nt < 2; ++nt) {
            float bv = bu[(nt0 + nt) * 16 + lcol];
#pragma unroll
            for (int mt = 0; mt < 4; ++mt) tmp[mt][nt] = (floatx4){bv, bv, bv, bv};
        }
#pragma unroll
        for (int mt = 0; mt < 4; ++mt)
#pragma unroll
            for (int ks = 0; ks < 4; ++ks) {
                f16x8 a = *(const f16x8*)&sA[(mt * 16 + lcol) * PADM + ks * 32 + quad * 8];
                tmp[mt][0] = __builtin_amdgcn_mfma_f32_16x16x32_f16(a, B[0][ks], tmp[mt][0], 0, 0, 0);
                tmp[mt][1] = __builtin_amdgcn_mfma_f32_16x16x32_f16(a, B[1][ks], tmp[mt][1], 0, 0, 0);
            }
#pragma unroll
        for (int mt = 0; mt < 4; ++mt) { acc[mt][0] = tmp[mt][0]; acc[mt][1] = tmp[mt][1]; }
    }
    __syncthreads();  // B6: agg reads done
    // phase E: stage h -> sA
    for (int i = t; i < 1024; i += 256) {
        int row = i >> 4, c = i & 15;
        int n = n0b + row; if (n >= N_HITS) n = N_HITS - 1;
        *(uint4*)&sA[row * PADM + c * 8] = ((const uint4*)(hp + (size_t)n * HD))[c];
    }
    __syncthreads();  // B7
    // phase F: accU += h @ Wu[ks0..3]
    {
        const f16x8* wu = (const f16x8*)WuP;
        f16x8 B[2][4];
#pragma unroll
        for (int nt = 0; nt < 2; ++nt)
#pragma unroll
            for (int ks = 0; ks < 4; ++ks)
                B[nt][ks] = wu[((nt0 + nt) * 8 + ks) * 64 + lane];
#pragma unroll
        for (int mt = 0; mt < 4; ++mt)
#pragma unroll
            for (int ks = 0; ks < 4; ++ks) {
                f16x8 a = *(const f16x8*)&sA[(mt * 16 + lcol) * PADM + ks * 32 + quad * 8];
                acc[mt][0] = __builtin_amdgcn_mfma_f32_16x16x32_f16(a, B[0][ks], acc[mt][0], 0, 0, 0);
                acc[mt][1] = __builtin_amdgcn_mfma_f32_16x16x32_f16(a, B[1][ks], acc[mt][1], 0, 0, 0);
            }
    }
    __syncthreads();  // B8: h reads done before residual RMW
    // phase G: h_new = h(sA) + relu(accU) -> sA (paired cols)
#pragma unroll
    for (int mt = 0; mt < 4; ++mt)
#pragma unroll
        for (int r = 0; r < 4; ++r) {
            float v0 = fmaxf(acc[mt][0][r], 0.f), v1 = fmaxf(acc[mt][1][r], 0.f);
            float p0 = __shfl_xor(v0, 1), p1 = __shfl_xor(v1, 1);
            float av = odd ? p1 : v0, bv = odd ? v1 : p0;
            int col = nt0 * 16 + (odd ? 15 + lcol : lcol);
            uint* sp2 = (uint*)&sA[(mt * 16 + quad * 4 + r) * PADM + col];
            float2 ho = h2f2(*sp2);
            *sp2 = f2h2(ho.x + av, ho.y + bv);
        }
    __syncthreads();  // B9
    // phase H: coalesced store sA -> h
    for (int i = t; i < 1024; i += 256) {
        int row = i >> 4, c = i & 15;
        int n = n0b + row;
        if (n < N_HITS) ((uint4*)(hp + (size_t)n * HD))[c] = *(uint4*)&sA[row * PADM + c * 8];
    }
}

// ---------------- sp fused (M=64), CSR-in-LDS 3-plane packed gather ----------------
#define SCAP 576
__launch_bounds__(256, 6)
__global__ void sp_fused_kernel(const _Float16* __restrict__ h, const int* __restrict__ off,
                                const int* __restrict__ csr_s, const _Float16* __restrict__ WspP,
                                const float* __restrict__ b, _Float16* __restrict__ spf) {
    __shared__ _Float16 sA[64 * PADM];
    __shared__ int sOff[3][65];
    __shared__ int sIdx[SCAP];
    int t = threadIdx.x;
    int n0b = blockIdx.x * 64;
    int lane = t & 63, wave = t >> 6;
    int lcol = lane & 15, quad = lane >> 4;
    int nt0 = wave * 2;
    bool odd = (lcol & 1) != 0;

    if (t < 195) {
        int p = t / 65, i = t - p * 65;
        int idx = n0b + i; if (idx > N_SPS) idx = N_SPS;
        sOff[p][i] = off[(3 + p) * 30001 + idx];
    }
    __syncthreads();
    int base0 = sOff[0][0], len0 = sOff[0][64] - base0;
    int base1 = sOff[1][0], len1 = sOff[1][64] - base1;
    int base2 = sOff[2][0], len2 = sOff[2][64] - base2;
    int ofs1 = len0, ofs2 = len0 + len1;
    bool useL = (ofs2 + len2 <= SCAP);
    if (useL) {
        for (int i = t; i < len0; i += 256) sIdx[i] = csr_s[base0 + i];
        for (int i = t; i < len1; i += 256) sIdx[ofs1 + i] = csr_s[N_SPS + base1 + i];
        for (int i = t; i < len2; i += 256) sIdx[ofs2 + i] = csr_s[2 * N_SPS + base2 + i];
    }
    __syncthreads();

    for (int i = t; i < 1024; i += 256) {
        int row = i >> 4, c = i & 15;
        int s = n0b + row;
        f16x8 tv = (f16x8)(_Float16)0;
        if (s < N_SPS) {
#pragma unroll
            for (int p = 0; p < 3; ++p) {
                int beg = sOff[p][row], end = sOff[p][row + 1];
                int bb = (p == 0) ? base0 : (p == 1) ? base1 : base2;
                int oo = (p == 0) ? 0 : (p == 1) ? ofs1 : ofs2;
                const int* csr = csr_s + p * N_SPS;
                const _Float16* hb = h + (size_t)p * N_HITS * HD;
                f16x8 sv = (f16x8)(_Float16)0;
                for (int k = beg; k < end; ++k) {
                    int hit = useL ? sIdx[oo + (k - bb)] : csr[k];
                    sv += *(const f16x8*)&hb[(size_t)hit * HD + c * 8];
                }
                _Float16 iv = (_Float16)((end > beg) ? 1.f / (float)(end - beg) : 0.f);
                tv += sv * iv;
            }
        }
        *(f16x8*)&sA[row * PADM + c * 8] = tv;
    }
    __syncthreads();

    const f16x8* wp = (const f16x8*)WspP;
    f16x8 B[2][4];
#pragma unroll
    for (int nt = 0; nt < 2; ++nt)
#pragma unroll
        for (int ks = 0; ks < 4; ++ks)
            B[nt][ks] = wp[((nt0 + nt) * 4 + ks) * 64 + lane];

    floatx4 acc[4][2];
#pragma unroll
    for (int nt = 0; nt < 2; ++nt) {
        float bv = b[(nt0 + nt) * 16 + lcol];
#pragma unroll
        for (int mt = 0; mt < 4; ++mt) acc[mt][nt] = (floatx4){bv, bv, bv, bv};
    }
#pragma unroll
    for (int mt = 0; mt < 4; ++mt)
#pragma unroll
        for (int ks = 0; ks < 4; ++ks) {
            f16x8 a = *(const f16x8*)&sA[(mt * 16 + lcol) * PADM + ks * 32 + quad * 8];
            acc[mt][0] = __builtin_amdgcn_mfma_f32_16x16x32_f16(a, B[0][ks], acc[mt][0], 0, 0, 0);
            acc[mt][1] = __builtin_amdgcn_mfma_f32_16x16x32_f16(a, B[1][ks], acc[mt][1], 0, 0, 0);
        }
    __syncthreads();
#pragma unroll
    for (int mt = 0; mt < 4; ++mt)
#pragma unroll
        for (int r = 0; r < 4; ++r) {
            float v0 = fmaxf(acc[mt][0][r], 0.f), v1 = fmaxf(acc[mt][1][r], 0.f);
            float p0 = __shfl_xor(v0, 1), p1 = __shfl_xor(v1, 1);
            float av = odd ? p1 : v0, bv = odd ? v1 : p0;
            int col = nt0 * 16 + (odd ? 15 + lcol : lcol);
            *(uint*)&sA[(mt * 16 + quad * 4 + r) * PADM + col] = f2h2(av, bv);
        }
    __syncthreads();
    for (int i = t; i < 1024; i += 256) {
        int row = i >> 4, c = i & 15;
        int n = n0b + row;
        if (n < N_SPS) ((uint4*)(spf + (size_t)n * HD))[c] = *(uint4*)&sA[row * PADM + c * 8];
    }
}

// ---------------- nexus update (M=64), packed back gather; emits y_s AND y_d ----------------
#define HCAP 320
__launch_bounds__(256, 4)
__global__ void update_y_kernel(_Float16* __restrict__ h, const _Float16* __restrict__ sp,
                                const int* __restrict__ off, const int* __restrict__ csr_h,
                                const _Float16* __restrict__ WP, const float* __restrict__ b,
                                const _Float16* __restrict__ W1dP, const _Float16* __restrict__ W1sP,
                                _Float16* __restrict__ y_d, _Float16* __restrict__ y_s) {
    int p = blockIdx.y;
    _Float16* hp = h + (size_t)p * N_HITS * HD;
    _Float16* ydp = y_d + (size_t)p * N_HITS * HD;
    _Float16* ysp = y_s + (size_t)p * N_HITS * HD;
    const int* o = off + (6 + p) * 30001;
    const int* csr = csr_h + p * N_SPS;

    __shared__ _Float16 sH[64 * PADM];
    __shared__ _Float16 sA[64 * PADM];
    __shared__ int sOff[65];
    __shared__ int sIdx[HCAP];
    int t = threadIdx.x;
    int n0b = blockIdx.x * 64;
    int lane = t & 63, wave = t >> 6;
    int lcol = lane & 15, quad = lane >> 4;
    int nt0 = wave * 2;
    bool odd = (lcol & 1) != 0;

    if (t < 65) {
        int idx = n0b + t; if (idx > N_HITS) idx = N_HITS;
        sOff[t] = o[idx];
    }
    for (int i = t; i < 1024; i += 256) {
        int row = i >> 4, c = i & 15;
        int n = n0b + row; if (n >= N_HITS) n = N_HITS - 1;
        *(uint4*)&sH[row * PADM + c * 8] = ((const uint4*)(hp + (size_t)n * HD))[c];
    }
    __syncthreads();
    int base = sOff[0];
    int total = sOff[64] - base;
    bool useL = (total <= HCAP);
    if (useL) for (int i = t; i < total; i += 256) sIdx[i] = csr[base + i];
    __syncthreads();

    // phase A: gather aux -> sA (packed)
    for (int i = t; i < 1024; i += 256) {
        int row = i >> 4, c = i & 15;
        int hit = n0b + row;
        int beg = 0, end = 0;
        if (hit < N_HITS) { beg = sOff[row]; end = sOff[row + 1]; }
        f16x8 av8 = (f16x8)(_Float16)0;
        for (int k = beg; k < end; ++k) {
            int spid = useL ? sIdx[k - base] : csr[k];
            av8 += *(const f16x8*)&sp[(size_t)spid * HD + c * 8];
        }
        _Float16 iv = (_Float16)((end > beg) ? 1.f / (float)(end - beg) : 0.f);
        av8 *= iv;
        *(f16x8*)&sA[row * PADM + c * 8] = av8;
    }
    __syncthreads();
    // phase B: acc = b + sH@Wn[ks0..3] + sA@Wn[ks4..7]
    floatx4 acc[4][2];
    {
        const f16x8* wp = (const f16x8*)WP;
        f16x8 BH[2][4], BA[2][4];
#pragma unroll
        for (int nt = 0; nt < 2; ++nt)
#pragma unroll
            for (int ks = 0; ks < 4; ++ks) {
                BH[nt][ks] = wp[((nt0 + nt) * 8 + ks) * 64 + lane];
                BA[nt][ks] = wp[((nt0 + nt) * 8 + 4 + ks) * 64 + lane];
            }
#pragma unroll
        for (int nt = 0; nt < 2; ++nt) {
            float bv = b[(nt0 + nt) * 16 + lcol];
#pragma unroll
            for (int mt = 0; mt < 4; ++mt) acc[mt][nt] = (floatx4){bv, bv, bv, bv};
        }
#pragma unroll
        for (int mt = 0; mt < 4; ++mt)
#pragma unroll
            for (int ks = 0; ks < 4; ++ks) {
                f16x8 ah = *(const f16x8*)&sH[(mt * 16 + lcol) * PADM + ks * 32 + quad * 8];
                f16x8 aa = *(const f16x8*)&sA[(mt * 16 + lcol) * PADM + ks * 32 + quad * 8];
                acc[mt][0] = __builtin_amdgcn_mfma_f32_16x16x32_f16(ah, BH[0][ks], acc[mt][0], 0, 0, 0);
                acc[mt][1] = __builtin_amdgcn_mfma_f32_16x16x32_f16(ah, BH[1][ks], acc[mt][1], 0, 0, 0);
                acc[mt][0] = __builtin_amdgcn_mfma_f32_16x16x32_f16(aa, BA[0][ks], acc[mt][0], 0, 0, 0);
                acc[mt][1] = __builtin_amdgcn_mfma_f32_16x16x32_f16(aa, BA[1][ks], acc[mt][1], 0, 0, 0);
            }
    }
    __syncthreads();
    // phase C: h_new = sH + relu(acc) -> sH
#pragma unroll
    for (int mt = 0; mt < 4; ++mt)
#pragma unroll
        for (int r = 0; r < 4; ++r) {
            float v0 = fmaxf(acc[mt][0][r], 0.f), v1 = fmaxf(acc[mt][1][r], 0.f);
            float p0 = __shfl_xor(v0, 1), p1 = __shfl_xor(v1, 1);
            float av = odd ? p1 : v0, bv = odd ? v1 : p0;
            int col = nt0 * 16 + (odd ? 15 + lcol : lcol);
            uint* sp2 = (uint*)&sH[(mt * 16 + quad * 4 + r) * PADM + col];
            float2 ho = h2f2(*sp2);
            *sp2 = f2h2(ho.x + av, ho.y + bv);
        }
    __syncthreads();
    // phase D: coalesced h store + y GEMMs from sH
    for (int i = t; i < 1024; i += 256) {
        int row = i >> 4, c = i & 15;
        int n = n0b + row;
        if (n < N_HITS) ((uint4*)(hp + (size_t)n * HD))[c] = *(uint4*)&sH[row * PADM + c * 8];
    }
    for (int half = 0; half < 2; ++half) {
        const f16x8* wyp = (const f16x8*)(half == 0 ? W1sP : W1dP);
        _Float16* out = half == 0 ? ysp : ydp;
        f16x8 B[2][4];
#pragma unroll
        for (int nt = 0; nt < 2; ++nt)
#pragma unroll
            for (int ks = 0; ks < 4; ++ks)
                B[nt][ks] = wyp[((nt0 + nt) * 4 + ks) * 64 + lane];
        floatx4 yacc[4][2];
#pragma unroll
        for (int mt = 0; mt < 4; ++mt) { yacc[mt][0] = (floatx4){0,0,0,0}; yacc[mt][1] = (floatx4){0,0,0,0}; }
#pragma unroll
        for (int mt = 0; mt < 4; ++mt)
#pragma unroll
            for (int ks = 0; ks < 4; ++ks) {
                f16x8 a = *(const f16x8*)&sH[(mt * 16 + lcol) * PADM + ks * 32 + quad * 8];
                yacc[mt][0] = __builtin_amdgcn_mfma_f32_16x16x32_f16(a, B[0][ks], yacc[mt][0], 0, 0, 0);
                yacc[mt][1] = __builtin_amdgcn_mfma_f32_16x16x32_f16(a, B[1][ks], yacc[mt][1], 0, 0, 0);
            }
        __syncthreads();  // prior sA reads (gather/GEMM/store) complete
#pragma unroll
        for (int mt = 0; mt < 4; ++mt)
#pragma unroll
            for (int r = 0; r < 4; ++r) {
                float v0 = yacc[mt][0][r], v1 = yacc[mt][1][r];
                float p0 = __shfl_xor(v0, 1), p1 = __shfl_xor(v1, 1);
                float av = odd ? p1 : v0, bv = odd ? v1 : p0;
                int col = nt0 * 16 + (odd ? 15 + lcol : lcol);
                *(uint*)&sA[(mt * 16 + quad * 4 + r) * PADM + col] = f2h2(av, bv);
            }
        __syncthreads();
        for (int i = t; i < 1024; i += 256) {
            int row = i >> 4, c = i & 15;
            int n = n0b + row;
            if (n < N_HITS) ((uint4*)(out + (size_t)n * HD))[c] = *(uint4*)&sA[row * PADM + c * 8];
        }
    }
}

// ---------------- decoder ----------------
__global__ void dec_kernel(const _Float16* __restrict__ h, const float* __restrict__ W,
                           const float* __restrict__ b, float* __restrict__ out) {
    __shared__ float sW[640];
    __shared__ float sB[8];
    int t = threadIdx.x;
    for (int i = t; i < 640; i += 256) sW[i] = W[i];
    if (t < 5) sB[t] = b[t];
    __syncthreads();
    int n = blockIdx.x * 256 + t;
    if (n >= 3 * N_HITS) return;
    const uint4* hr = (const uint4*)(h + (size_t)n * HD);
    float a0 = sB[0], a1 = sB[1], a2 = sB[2], a3 = sB[3], a4 = sB[4];
#pragma unroll 4
    for (int q = 0; q < 16; ++q) {
        union { uint4 u; _Float16 hh[8]; } v; v.u = hr[q];
        const float* w = &sW[q * 40];
#pragma unroll
        for (int j = 0; j < 8; ++j) {
            float x = (float)v.hh[j];
            a0 = fmaf(x, w[j * 5 + 0], a0);
            a1 = fmaf(x, w[j * 5 + 1], a1);
            a2 = fmaf(x, w[j * 5 + 2], a2);
            a3 = fmaf(x, w[j * 5 + 3], a3);
            a4 = fmaf(x, w[j * 5 + 4], a4);
        }
    }
    float* oo = out + (size_t)n * NCLS;
    oo[0] = a0; oo[1] = a1; oo[2] = a2; oo[3] = a3; oo[4] = a4;
}

extern "C" void kernel_launch(void* const* d_in, const int* in_sizes, int n_in,
                              void* d_out, int out_size, void* d_ws, size_t ws_size,
                              hipStream_t stream) {
    const float* xu = (const float*)d_in[0];
    const int* eu = (const int*)d_in[1];
    const int* nu = (const int*)d_in[2];
    const float* xv = (const float*)d_in[3];
    const int* ev = (const int*)d_in[4];
    const int* nv = (const int*)d_in[5];
    const float* xy = (const float*)d_in[6];
    const int* ey = (const int*)d_in[7];
    const int* ny = (const int*)d_in[8];
    const float* W_enc = (const float*)d_in[9];
    const float* b_enc = (const float*)d_in[10];
    const float* W1 = (const float*)d_in[11];
    const float* b1 = (const float*)d_in[12];
    const float* W2 = (const float*)d_in[13];
    const float* b2 = (const float*)d_in[14];
    const float* W_upd = (const float*)d_in[15];
    const float* b_upd = (const float*)d_in[16];
    const float* W_sp = (const float*)d_in[17];
    const float* b_sp = (const float*)d_in[18];
    const float* W_nx = (const float*)d_in[19];
    const float* b_nx = (const float*)d_in[20];
    const float* W_sem = (const float*)d_in[21];
    const float* b_sem = (const float*)d_in[22];

    const size_t HN = (size_t)3 * N_HITS * HD;
    _Float16* h = (_Float16*)d_ws;                 // f16 [3][N_HITS][HD]
    _Float16* y_s = h + HN;                        // f16 [3][N_HITS][HD]
    _Float16* y_d = y_s + HN;                      // f16 [3][N_HITS][HD]
    _Float16* sp = y_d + HN;                       // f16 [N_SPS][HD]
    int* cnt = (int*)(sp + (size_t)N_SPS * HD);    // [270000]
    int* off = cnt + 270000;                       // [9*30001]
    int* cursor = off + 270009;                    // [270000]
    int* csr_e = cursor + 270000;                  // [3*90000]
    int* csr_s = csr_e + 270000;                   // [3*30000]
    int* csr_h = csr_s + 90000;                    // [3*30000]
    _Float16* packs = (_Float16*)(csr_h + 90000);  // [131072]
    _Float16* W1dP = packs;
    _Float16* W1sP = packs + 16384;
    _Float16* W2P = packs + 32768;
    _Float16* WuP = packs + 49152;
    _Float16* WnP = packs + 81920;
    _Float16* WspP = packs + 114688;

    wprep_kernel<<<512, 256, 0, stream>>>(W1, W2, W_upd, W_nx, W_sp, packs);
    (void)hipMemsetAsync(cnt, 0, 270000 * sizeof(int), stream);
    hist_all_kernel<<<(450000 + 255) / 256, 256, 0, stream>>>(eu, ev, ey, nu, nv, ny, cnt);
    scan_kernel<<<9, 1024, 0, stream>>>(cnt, off, cursor);
    fill_kernel<<<(450000 + 255) / 256, 256, 0, stream>>>(eu, ev, ey, nu, nv, ny,
                                                          cursor, csr_e, csr_s, csr_h);

    enc_y_kernel<<<(3 * N_HITS + 127) / 128, 256, 0, stream>>>(xu, xv, xy, W_enc, b_enc,
                                                               W1dP, W1sP, h, y_d, y_s);

    for (int it = 0; it < 3; ++it) {
        update_planar_kernel<<<dim3((N_HITS + 63) / 64, 3), 256, 0, stream>>>(
            h, y_d, y_s, off, csr_e, b1, W2P, b2, WuP, b_upd);
        sp_fused_kernel<<<(N_SPS + 63) / 64, 256, 0, stream>>>(h, off, csr_s, WspP, b_sp, sp);
        update_y_kernel<<<dim3((N_HITS + 63) / 64, 3), 256, 0, stream>>>(
            h, sp, off, csr_h, WnP, b_nx, W1dP, W1sP, y_d, y_s);
    }

    dec_kernel<<<(3 * N_HITS + 255) / 256, 256, 0, stream>>>(h, W_sem, b_sem, (float*)d_out);
}

// Round 17
// 493.841 us; speedup vs baseline: 2.1506x; 1.0408x over previous
//
#include <hip/hip_runtime.h>
#include <hip/hip_fp16.h>

#define N_HITS 30000
#define N_EDGES 90000
#define N_SPS 30000
#define HD 128
#define NCLS 5

#define PADM 136  // 128 + 8 f16 pad

typedef __attribute__((ext_vector_type(8))) _Float16 f16x8;
typedef __attribute__((ext_vector_type(4))) float floatx4;

__device__ __forceinline__ float2 h2f2(uint u) {
    union { uint u; __half2 h; } x; x.u = u;
    return __half22float2(x.h);
}
__device__ __forceinline__ uint f2h2(float a, float b) {
    union { uint u; __half2 h; } x;
    x.h = __halves2half2(__float2half(a), __float2half(b));
    return x.u;
}

// ---------------- histograms ----------------
__global__ void hist_all_kernel(const int* __restrict__ eu, const int* __restrict__ ev,
                                const int* __restrict__ ey, const int* __restrict__ nu,
                                const int* __restrict__ nv, const int* __restrict__ ny,
                                int* __restrict__ cnt) {
    int gid = blockIdx.x * blockDim.x + threadIdx.x;
    if (gid >= 450000) return;
    int p = gid / 150000;
    int r = gid - p * 150000;
    const int* e = (p == 0) ? eu : (p == 1) ? ev : ey;
    const int* nx = (p == 0) ? nu : (p == 1) ? nv : ny;
    if (r < N_EDGES) {
        atomicAdd(&cnt[p * 30000 + e[N_EDGES + r]], 1);
    } else if (r < N_EDGES + N_SPS) {
        int i = r - N_EDGES;
        atomicAdd(&cnt[(3 + p) * 30000 + nx[N_SPS + i]], 1);
    } else {
        int i = r - N_EDGES - N_SPS;
        atomicAdd(&cnt[(6 + p) * 30000 + nx[i]], 1);
    }
}

// ---------------- exclusive scan per segment ----------------
__launch_bounds__(1024)
__global__ void scan_kernel(const int* __restrict__ cnt, int* __restrict__ off,
                            int* __restrict__ cursor) {
    int seg = blockIdx.x;
    const int* c = cnt + seg * 30000;
    int* o = off + seg * 30001;
    int* cur = cursor + seg * 30000;
    int t = threadIdx.x;
    int base = t * 30;
    int lc[30];
    int sum = 0;
#pragma unroll
    for (int k = 0; k < 30; ++k) {
        int i = base + k;
        lc[k] = (i < 30000) ? c[i] : 0;
        sum += lc[k];
    }
    __shared__ int part[1024];
    part[t] = sum;
    __syncthreads();
    for (int d = 1; d < 1024; d <<= 1) {
        int x = (t >= d) ? part[t - d] : 0;
        __syncthreads();
        part[t] += x;
        __syncthreads();
    }
    int run = part[t] - sum;
#pragma unroll
    for (int k = 0; k < 30; ++k) {
        int i = base + k;
        if (i < 30000) { o[i] = run; cur[i] = run; run += lc[k]; }
    }
    if (t == 1023) o[30000] = part[1023];
}

// ---------------- CSR fill ----------------
__global__ void fill_kernel(const int* __restrict__ eu, const int* __restrict__ ev,
                            const int* __restrict__ ey, const int* __restrict__ nu,
                            const int* __restrict__ nv, const int* __restrict__ ny,
                            int* __restrict__ cursor, int* __restrict__ csr_e,
                            int* __restrict__ csr_s, int* __restrict__ csr_h) {
    int gid = blockIdx.x * blockDim.x + threadIdx.x;
    if (gid >= 450000) return;
    int p = gid / 150000;
    int r = gid - p * 150000;
    const int* e = (p == 0) ? eu : (p == 1) ? ev : ey;
    const int* nx = (p == 0) ? nu : (p == 1) ? nv : ny;
    if (r < N_EDGES) {
        int d = e[N_EDGES + r];
        int pos = atomicAdd(&cursor[p * 30000 + d], 1);
        csr_e[p * N_EDGES + pos] = e[r];
    } else if (r < N_EDGES + N_SPS) {
        int i = r - N_EDGES;
        int spid = nx[N_SPS + i];
        int pos = atomicAdd(&cursor[(3 + p) * 30000 + spid], 1);
        csr_s[p * N_SPS + pos] = nx[i];
    } else {
        int i = r - N_EDGES - N_SPS;
        int hit = nx[i];
        int pos = atomicAdd(&cursor[(6 + p) * 30000 + hit], 1);
        csr_h[p * N_SPS + pos] = nx[N_SPS + i];
    }
}

// ---------------- weight pre-pack (f16) ----------------
__device__ __forceinline__ void pack4(const float* __restrict__ W, _Float16* __restrict__ P,
                                      int idx, int koff) {
    int j = idx & 7, lane = (idx >> 3) & 63, ks = (idx >> 9) & 3, n = (idx >> 11) & 7;
    int k = ks * 32 + (lane >> 4) * 8 + j, col = n * 16 + (lane & 15);
    P[idx] = (_Float16)W[(k + koff) * 128 + col];
}
__device__ __forceinline__ void pack8(const float* __restrict__ W, _Float16* __restrict__ P, int idx) {
    int j = idx & 7, lane = (idx >> 3) & 63, ks = (idx >> 9) & 7, n = (idx >> 12) & 7;
    int k = ks * 32 + (lane >> 4) * 8 + j, col = n * 16 + (lane & 15);
    P[idx] = (_Float16)W[k * 128 + col];
}

__global__ void wprep_kernel(const float* __restrict__ W1, const float* __restrict__ W2,
                             const float* __restrict__ Wu, const float* __restrict__ Wn,
                             const float* __restrict__ Wsp, _Float16* __restrict__ packs) {
    int gid = blockIdx.x * blockDim.x + threadIdx.x;
    if (gid < 16384) { pack4(W1, packs, gid, 0); return; }            // W1d
    gid -= 16384;
    if (gid < 16384) { pack4(W1, packs + 16384, gid, 128); return; }  // W1s
    gid -= 16384;
    if (gid < 16384) { pack4(W2, packs + 32768, gid, 0); return; }    // W2
    gid -= 16384;
    if (gid < 32768) { pack8(Wu, packs + 49152, gid); return; }       // W_upd
    gid -= 32768;
    if (gid < 32768) { pack8(Wn, packs + 81920, gid); return; }       // W_nx
    gid -= 32768;
    if (gid < 16384) { pack4(Wsp, packs + 114688, gid, 0); }          // W_sp
}

// ---------------- fused encoder + y emission ----------------
__launch_bounds__(256, 4)
__global__ void enc_y_kernel(const float* __restrict__ xu, const float* __restrict__ xv,
                             const float* __restrict__ xy, const float* __restrict__ We,
                             const float* __restrict__ be, const _Float16* __restrict__ W1dP,
                             const _Float16* __restrict__ W1sP, _Float16* __restrict__ h,
                             _Float16* __restrict__ y_d, _Float16* __restrict__ y_s) {
    __shared__ _Float16 sA[128 * PADM];
    __shared__ _Float16 sO[128 * PADM];
    int t = threadIdx.x;
    int n0b = blockIdx.x * 128;
    const int M = 3 * N_HITS;
    for (int i = t; i < 2048; i += 256) {
        int row = i >> 4, c = i & 15;
        int n = n0b + row; if (n >= M) n = M - 1;
        int p = n / N_HITS;
        int nn = n - p * N_HITS;
        const float* x = (p == 0) ? xu : (p == 1) ? xv : xy;
        float4 xv4 = *(const float4*)(x + nn * 4);
        union { _Float16 o8[8]; uint4 u; } outv;
#pragma unroll
        for (int j = 0; j < 8; ++j) {
            int col = c * 8 + j;
            float acc = be[col];
            acc = fmaf(xv4.x, We[0 * HD + col], acc);
            acc = fmaf(xv4.y, We[1 * HD + col], acc);
            acc = fmaf(xv4.z, We[2 * HD + col], acc);
            acc = fmaf(xv4.w, We[3 * HD + col], acc);
            outv.o8[j] = (_Float16)fmaxf(acc, 0.f);
        }
        *(uint4*)&sA[row * PADM + c * 8] = outv.u;
        if (n0b + row < M) ((uint4*)(h + (size_t)n * HD))[c] = outv.u;
    }
    __syncthreads();

    int lane = t & 63, wave = t >> 6;
    int lcol = lane & 15, quad = lane >> 4;
    int nt0 = wave * 2;
    bool odd = (lcol & 1) != 0;

    for (int half = 0; half < 2; ++half) {
        const f16x8* wp = (const f16x8*)(half == 0 ? W1dP : W1sP);
        _Float16* out = half == 0 ? y_d : y_s;
        f16x8 B[2][4];
#pragma unroll
        for (int nt = 0; nt < 2; ++nt)
#pragma unroll
            for (int ks = 0; ks < 4; ++ks)
                B[nt][ks] = wp[((nt0 + nt) * 4 + ks) * 64 + lane];
        floatx4 acc[8][2];
#pragma unroll
        for (int mt = 0; mt < 8; ++mt) { acc[mt][0] = (floatx4){0,0,0,0}; acc[mt][1] = (floatx4){0,0,0,0}; }
#pragma unroll
        for (int mt = 0; mt < 8; ++mt)
#pragma unroll
            for (int ks = 0; ks < 4; ++ks) {
                f16x8 a = *(const f16x8*)&sA[(mt * 16 + lcol) * PADM + ks * 32 + quad * 8];
                acc[mt][0] = __builtin_amdgcn_mfma_f32_16x16x32_f16(a, B[0][ks], acc[mt][0], 0, 0, 0);
                acc[mt][1] = __builtin_amdgcn_mfma_f32_16x16x32_f16(a, B[1][ks], acc[mt][1], 0, 0, 0);
            }
#pragma unroll
        for (int mt = 0; mt < 8; ++mt)
#pragma unroll
            for (int r = 0; r < 4; ++r) {
                float v0 = acc[mt][0][r], v1 = acc[mt][1][r];
                float p0 = __shfl_xor(v0, 1), p1 = __shfl_xor(v1, 1);
                float av = odd ? p1 : v0, bv = odd ? v1 : p0;
                int col = nt0 * 16 + (odd ? 15 + lcol : lcol);
                *(uint*)&sO[(mt * 16 + quad * 4 + r) * PADM + col] = f2h2(av, bv);
            }
        __syncthreads();
        for (int i = t; i < 2048; i += 256) {
            int row = i >> 4, c = i & 15;
            int n = n0b + row;
            if (n < M) ((uint4*)(out + (size_t)n * HD))[c] = *(uint4*)&sO[row * PADM + c * 8];
        }
        __syncthreads();
    }
}

// ---------------- planar update, M=64, single LDS buffer, 2-way unrolled gather ----------------
#define ECAP 640
__launch_bounds__(256, 5)
__global__ void update_planar_kernel(_Float16* __restrict__ h, const _Float16* __restrict__ y_d,
                                     const _Float16* __restrict__ y_s,
                                     const int* __restrict__ off, const int* __restrict__ csr_e,
                                     const float* __restrict__ b1,
                                     const _Float16* __restrict__ W2P, const float* __restrict__ b2,
                                     const _Float16* __restrict__ WuP, const float* __restrict__ bu) {
    int p = blockIdx.y;
    _Float16* hp = h + (size_t)p * N_HITS * HD;
    const _Float16* ydp = y_d + (size_t)p * N_HITS * HD;
    const _Float16* ysp = y_s + (size_t)p * N_HITS * HD;
    const int* o = off + p * 30001;
    const int* csr = csr_e + p * N_EDGES;

    __shared__ _Float16 sA[64 * PADM];
    __shared__ int sOff[65];
    __shared__ int sIdx[ECAP];
    int t = threadIdx.x;
    int n0b = blockIdx.x * 64;
    int lane = t & 63, wave = t >> 6;
    int lcol = lane & 15, quad = lane >> 4;
    int nt0 = wave * 2;
    bool odd = (lcol & 1) != 0;

    if (t < 65) {
        int idx = n0b + t; if (idx > N_HITS) idx = N_HITS;
        sOff[t] = o[idx];
    }
    // phase 0: stage y_d tile (+b1 folded) -> sA
    for (int i = t; i < 1024; i += 256) {
        int row = i >> 4, c = i & 15;
        int n = n0b + row; if (n >= N_HITS) n = N_HITS - 1;
        f16x8 yv = *(const f16x8*)&ydp[(size_t)n * HD + c * 8];
        float4 b1a = *(const float4*)(b1 + c * 8);
        float4 b1b = *(const float4*)(b1 + c * 8 + 4);
        float bb[8] = {b1a.x, b1a.y, b1a.z, b1a.w, b1b.x, b1b.y, b1b.z, b1b.w};
        f16x8 ov;
#pragma unroll
        for (int j = 0; j < 8; ++j) ov[j] = (_Float16)((float)yv[j] + bb[j]);
        *(f16x8*)&sA[row * PADM + c * 8] = ov;
    }
    __syncthreads();
    int base = sOff[0];
    int total = sOff[64] - base;
    bool useL = (total <= ECAP);
    if (useL) for (int i = t; i < total; i += 256) sIdx[i] = csr[base + i];
    __syncthreads();

    // phase A: in-place CSR edge gather, 2-way unrolled for MLP
    for (int i = t; i < 1024; i += 256) {
        int row = i >> 4, c = i & 15;
        int d = n0b + row;
        int beg = 0, end = 0;
        if (d < N_HITS) { beg = sOff[row]; end = sOff[row + 1]; }
        f16x8 ydv = *(const f16x8*)&sA[row * PADM + c * 8];
        f16x8 a0 = (f16x8)(_Float16)0, a1 = (f16x8)(_Float16)0;
        int k = beg;
        for (; k + 2 <= end; k += 2) {
            int s0 = useL ? sIdx[k - base] : csr[k];
            int s1 = useL ? sIdx[k + 1 - base] : csr[k + 1];
            f16x8 y0 = *(const f16x8*)&ysp[(size_t)s0 * HD + c * 8];
            f16x8 y1 = *(const f16x8*)&ysp[(size_t)s1 * HD + c * 8];
            a0 += __builtin_elementwise_max(y0 + ydv, (f16x8)(_Float16)0);
            a1 += __builtin_elementwise_max(y1 + ydv, (f16x8)(_Float16)0);
        }
        if (k < end) {
            int s0 = useL ? sIdx[k - base] : csr[k];
            f16x8 y0 = *(const f16x8*)&ysp[(size_t)s0 * HD + c * 8];
            a0 += __builtin_elementwise_max(y0 + ydv, (f16x8)(_Float16)0);
        }
        f16x8 accv = a0 + a1;
        _Float16 iv = (_Float16)((end > beg) ? 1.f / (float)(end - beg) : 0.f);
        accv *= iv;
        *(f16x8*)&sA[row * PADM + c * 8] = accv;
    }
    __syncthreads();
    // phase B: agg = z @ W2 + b2
    floatx4 acc[4][2];
    {
        const f16x8* w2p = (const f16x8*)W2P;
        f16x8 B[2][4];
#pragma unroll
        for (int nt = 0; nt < 2; ++nt)
#pragma unroll
            for (int ks = 0; ks < 4; ++ks)
                B[nt][ks] = w2p[((nt0 + nt) * 4 + ks) * 64 + lane];
#pragma unroll
        for (int nt = 0; nt < 2; ++nt) {
            float bv = b2[(nt0 + nt) * 16 + lcol];
#pragma unroll
            for (int mt = 0; mt < 4; ++mt) acc[mt][nt] = (floatx4){bv, bv, bv, bv};
        }
#pragma unroll
        for (int mt = 0; mt < 4; ++mt)
#pragma unroll
            for (int ks = 0; ks < 4; ++ks) {
                f16x8 a = *(const f16x8*)&sA[(mt * 16 + lcol) * PADM + ks * 32 + quad * 8];
                acc[mt][0] = __builtin_amdgcn_mfma_f32_16x16x32_f16(a, B[0][ks], acc[mt][0], 0, 0, 0);
                acc[mt][1] = __builtin_amdgcn_mfma_f32_16x16x32_f16(a, B[1][ks], acc[mt][1], 0, 0, 0);
            }
    }
    __syncthreads();
    // phase C: agg -> sA
#pragma unroll
    for (int mt = 0; mt < 4; ++mt)
#pragma unroll
        for (int r = 0; r < 4; ++r) {
            float v0 = acc[mt][0][r], v1 = acc[mt][1][r];
            float p0 = __shfl_xor(v0, 1), p1 = __shfl_xor(v1, 1);
            float av = odd ? p1 : v0, bv = odd ? v1 : p0;
            int col = nt0 * 16 + (odd ? 15 + lcol : lcol);
            *(uint*)&sA[(mt * 16 + quad * 4 + r) * PADM + col] = f2h2(av, bv);
        }
    __syncthreads();
    // phase D: accU = bu + agg @ Wu[ks4..7]
    {
        const f16x8* wu = (const f16x8*)WuP;
        f16x8 B[2][4];
#pragma unroll
        for (int nt = 0; nt < 2; ++nt)
#pragma unroll
            for (int ks = 0; ks < 4; ++ks)
                B[nt][ks] = wu[((nt0 + nt) * 8 + 4 + ks) * 64 + lane];
        floatx4 tmp[4][2];
#pragma unroll
        for (int nt = 0; nt < 2; ++nt) {
            float bv = bu[(nt0 + nt) * 16 + lcol];
#pragma unroll
            for (int mt = 0; mt < 4; ++mt) tmp[mt][nt] = (floatx4){bv, bv, bv, bv};
        }
#pragma unroll
        for (int mt = 0; mt < 4; ++mt)
#pragma unroll
            for (int ks = 0; ks < 4; ++ks) {
                f16x8 a = *(const f16x8*)&sA[(mt * 16 + lcol) * PADM + ks * 32 + quad * 8];
                tmp[mt][0] = __builtin_amdgcn_mfma_f32_16x16x32_f16(a, B[0][ks], tmp[mt][0], 0, 0, 0);
                tmp[mt][1] = __builtin_amdgcn_mfma_f32_16x16x32_f16(a, B[1][ks], tmp[mt][1], 0, 0, 0);
            }
#pragma unroll
        for (int mt = 0; mt < 4; ++mt) { acc[mt][0] = tmp[mt][0]; acc[mt][1] = tmp[mt][1]; }
    }
    __syncthreads();
    // phase E: stage h -> sA
    for (int i = t; i < 1024; i += 256) {
        int row = i >> 4, c = i & 15;
        int n = n0b + row; if (n >= N_HITS) n = N_HITS - 1;
        *(uint4*)&sA[row * PADM + c * 8] = ((const uint4*)(hp + (size_t)n * HD))[c];
    }
    __syncthreads();
    // phase F: accU += h @ Wu[ks0..3]
    {
        const f16x8* wu = (const f16x8*)WuP;
        f16x8 B[2][4];
#pragma unroll
        for (int nt = 0; nt < 2; ++nt)
#pragma unroll
            for (int ks = 0; ks < 4; ++ks)
                B[nt][ks] = wu[((nt0 + nt) * 8 + ks) * 64 + lane];
#pragma unroll
        for (int mt = 0; mt < 4; ++mt)
#pragma unroll
            for (int ks = 0; ks < 4; ++ks) {
                f16x8 a = *(const f16x8*)&sA[(mt * 16 + lcol) * PADM + ks * 32 + quad * 8];
                acc[mt][0] = __builtin_amdgcn_mfma_f32_16x16x32_f16(a, B[0][ks], acc[mt][0], 0, 0, 0);
                acc[mt][1] = __builtin_amdgcn_mfma_f32_16x16x32_f16(a, B[1][ks], acc[mt][1], 0, 0, 0);
            }
    }
    __syncthreads();
    // phase G: h_new = h(sA) + relu(accU) -> sA
#pragma unroll
    for (int mt = 0; mt < 4; ++mt)
#pragma unroll
        for (int r = 0; r < 4; ++r) {
            float v0 = fmaxf(acc[mt][0][r], 0.f), v1 = fmaxf(acc[mt][1][r], 0.f);
            float p0 = __shfl_xor(v0, 1), p1 = __shfl_xor(v1, 1);
            float av = odd ? p1 : v0, bv = odd ? v1 : p0;
            int col = nt0 * 16 + (odd ? 15 + lcol : lcol);
            uint* sp2 = (uint*)&sA[(mt * 16 + quad * 4 + r) * PADM + col];
            float2 ho = h2f2(*sp2);
            *sp2 = f2h2(ho.x + av, ho.y + bv);
        }
    __syncthreads();
    // phase H: coalesced store sA -> h
    for (int i = t; i < 1024; i += 256) {
        int row = i >> 4, c = i & 15;
        int n = n0b + row;
        if (n < N_HITS) ((uint4*)(hp + (size_t)n * HD))[c] = *(uint4*)&sA[row * PADM + c * 8];
    }
}

// ---------------- sp fused (M=64), 2-way unrolled 3-plane gather ----------------
#define SCAP 576
__launch_bounds__(256, 6)
__global__ void sp_fused_kernel(const _Float16* __restrict__ h, const int* __restrict__ off,
                                const int* __restrict__ csr_s, const _Float16* __restrict__ WspP,
                                const float* __restrict__ b, _Float16* __restrict__ spf) {
    __shared__ _Float16 sA[64 * PADM];
    __shared__ int sOff[3][65];
    __shared__ int sIdx[SCAP];
    int t = threadIdx.x;
    int n0b = blockIdx.x * 64;
    int lane = t & 63, wave = t >> 6;
    int lcol = lane & 15, quad = lane >> 4;
    int nt0 = wave * 2;
    bool odd = (lcol & 1) != 0;

    if (t < 195) {
        int p = t / 65, i = t - p * 65;
        int idx = n0b + i; if (idx > N_SPS) idx = N_SPS;
        sOff[p][i] = off[(3 + p) * 30001 + idx];
    }
    __syncthreads();
    int base0 = sOff[0][0], len0 = sOff[0][64] - base0;
    int base1 = sOff[1][0], len1 = sOff[1][64] - base1;
    int base2 = sOff[2][0], len2 = sOff[2][64] - base2;
    int ofs1 = len0, ofs2 = len0 + len1;
    bool useL = (ofs2 + len2 <= SCAP);
    if (useL) {
        for (int i = t; i < len0; i += 256) sIdx[i] = csr_s[base0 + i];
        for (int i = t; i < len1; i += 256) sIdx[ofs1 + i] = csr_s[N_SPS + base1 + i];
        for (int i = t; i < len2; i += 256) sIdx[ofs2 + i] = csr_s[2 * N_SPS + base2 + i];
    }
    __syncthreads();

    for (int i = t; i < 1024; i += 256) {
        int row = i >> 4, c = i & 15;
        int s = n0b + row;
        f16x8 tv = (f16x8)(_Float16)0;
        if (s < N_SPS) {
#pragma unroll
            for (int p = 0; p < 3; ++p) {
                int beg = sOff[p][row], end = sOff[p][row + 1];
                int bb = (p == 0) ? base0 : (p == 1) ? base1 : base2;
                int oo = (p == 0) ? 0 : (p == 1) ? ofs1 : ofs2;
                const int* csr = csr_s + p * N_SPS;
                const _Float16* hb = h + (size_t)p * N_HITS * HD;
                f16x8 s0v = (f16x8)(_Float16)0, s1v = (f16x8)(_Float16)0;
                int k = beg;
                for (; k + 2 <= end; k += 2) {
                    int h0 = useL ? sIdx[oo + (k - bb)] : csr[k];
                    int h1 = useL ? sIdx[oo + (k + 1 - bb)] : csr[k + 1];
                    f16x8 v0 = *(const f16x8*)&hb[(size_t)h0 * HD + c * 8];
                    f16x8 v1 = *(const f16x8*)&hb[(size_t)h1 * HD + c * 8];
                    s0v += v0; s1v += v1;
                }
                if (k < end) {
                    int h0 = useL ? sIdx[oo + (k - bb)] : csr[k];
                    s0v += *(const f16x8*)&hb[(size_t)h0 * HD + c * 8];
                }
                f16x8 sv = s0v + s1v;
                _Float16 iv = (_Float16)((end > beg) ? 1.f / (float)(end - beg) : 0.f);
                tv += sv * iv;
            }
        }
        *(f16x8*)&sA[row * PADM + c * 8] = tv;
    }
    __syncthreads();

    const f16x8* wp = (const f16x8*)WspP;
    f16x8 B[2][4];
#pragma unroll
    for (int nt = 0; nt < 2; ++nt)
#pragma unroll
        for (int ks = 0; ks < 4; ++ks)
            B[nt][ks] = wp[((nt0 + nt) * 4 + ks) * 64 + lane];

    floatx4 acc[4][2];
#pragma unroll
    for (int nt = 0; nt < 2; ++nt) {
        float bv = b[(nt0 + nt) * 16 + lcol];
#pragma unroll
        for (int mt = 0; mt < 4; ++mt) acc[mt][nt] = (floatx4){bv, bv, bv, bv};
    }
#pragma unroll
    for (int mt = 0; mt < 4; ++mt)
#pragma unroll
        for (int ks = 0; ks < 4; ++ks) {
            f16x8 a = *(const f16x8*)&sA[(mt * 16 + lcol) * PADM + ks * 32 + quad * 8];
            acc[mt][0] = __builtin_amdgcn_mfma_f32_16x16x32_f16(a, B[0][ks], acc[mt][0], 0, 0, 0);
            acc[mt][1] = __builtin_amdgcn_mfma_f32_16x16x32_f16(a, B[1][ks], acc[mt][1], 0, 0, 0);
        }
    __syncthreads();
#pragma unroll
    for (int mt = 0; mt < 4; ++mt)
#pragma unroll
        for (int r = 0; r < 4; ++r) {
            float v0 = fmaxf(acc[mt][0][r], 0.f), v1 = fmaxf(acc[mt][1][r], 0.f);
            float p0 = __shfl_xor(v0, 1), p1 = __shfl_xor(v1, 1);
            float av = odd ? p1 : v0, bv = odd ? v1 : p0;
            int col = nt0 * 16 + (odd ? 15 + lcol : lcol);
            *(uint*)&sA[(mt * 16 + quad * 4 + r) * PADM + col] = f2h2(av, bv);
        }
    __syncthreads();
    for (int i = t; i < 1024; i += 256) {
        int row = i >> 4, c = i & 15;
        int n = n0b + row;
        if (n < N_SPS) ((uint4*)(spf + (size_t)n * HD))[c] = *(uint4*)&sA[row * PADM + c * 8];
    }
}

// ---------------- nexus update (M=64), 2-way unrolled back gather; emits y_s AND y_d ----------------
#define HCAP 320
__launch_bounds__(256, 4)
__global__ void update_y_kernel(_Float16* __restrict__ h, const _Float16* __restrict__ sp,
                                const int* __restrict__ off, const int* __restrict__ csr_h,
                                const _Float16* __restrict__ WP, const float* __restrict__ b,
                                const _Float16* __restrict__ W1dP, const _Float16* __restrict__ W1sP,
                                _Float16* __restrict__ y_d, _Float16* __restrict__ y_s) {
    int p = blockIdx.y;
    _Float16* hp = h + (size_t)p * N_HITS * HD;
    _Float16* ydp = y_d + (size_t)p * N_HITS * HD;
    _Float16* ysp = y_s + (size_t)p * N_HITS * HD;
    const int* o = off + (6 + p) * 30001;
    const int* csr = csr_h + p * N_SPS;

    __shared__ _Float16 sH[64 * PADM];
    __shared__ _Float16 sA[64 * PADM];
    __shared__ int sOff[65];
    __shared__ int sIdx[HCAP];
    int t = threadIdx.x;
    int n0b = blockIdx.x * 64;
    int lane = t & 63, wave = t >> 6;
    int lcol = lane & 15, quad = lane >> 4;
    int nt0 = wave * 2;
    bool odd = (lcol & 1) != 0;

    if (t < 65) {
        int idx = n0b + t; if (idx > N_HITS) idx = N_HITS;
        sOff[t] = o[idx];
    }
    for (int i = t; i < 1024; i += 256) {
        int row = i >> 4, c = i & 15;
        int n = n0b + row; if (n >= N_HITS) n = N_HITS - 1;
        *(uint4*)&sH[row * PADM + c * 8] = ((const uint4*)(hp + (size_t)n * HD))[c];
    }
    __syncthreads();
    int base = sOff[0];
    int total = sOff[64] - base;
    bool useL = (total <= HCAP);
    if (useL) for (int i = t; i < total; i += 256) sIdx[i] = csr[base + i];
    __syncthreads();

    // phase A: gather aux -> sA (packed, 2-way unrolled)
    for (int i = t; i < 1024; i += 256) {
        int row = i >> 4, c = i & 15;
        int hit = n0b + row;
        int beg = 0, end = 0;
        if (hit < N_HITS) { beg = sOff[row]; end = sOff[row + 1]; }
        f16x8 a0 = (f16x8)(_Float16)0, a1 = (f16x8)(_Float16)0;
        int k = beg;
        for (; k + 2 <= end; k += 2) {
            int s0 = useL ? sIdx[k - base] : csr[k];
            int s1 = useL ? sIdx[k + 1 - base] : csr[k + 1];
            f16x8 v0 = *(const f16x8*)&sp[(size_t)s0 * HD + c * 8];
            f16x8 v1 = *(const f16x8*)&sp[(size_t)s1 * HD + c * 8];
            a0 += v0; a1 += v1;
        }
        if (k < end) {
            int s0 = useL ? sIdx[k - base] : csr[k];
            a0 += *(const f16x8*)&sp[(size_t)s0 * HD + c * 8];
        }
        f16x8 av8 = a0 + a1;
        _Float16 iv = (_Float16)((end > beg) ? 1.f / (float)(end - beg) : 0.f);
        av8 *= iv;
        *(f16x8*)&sA[row * PADM + c * 8] = av8;
    }
    __syncthreads();
    // phase B: acc = b + sH@Wn[ks0..3] + sA@Wn[ks4..7]
    floatx4 acc[4][2];
    {
        const f16x8* wp = (const f16x8*)WP;
        f16x8 BH[2][4], BA[2][4];
#pragma unroll
        for (int nt = 0; nt < 2; ++nt)
#pragma unroll
            for (int ks = 0; ks < 4; ++ks) {
                BH[nt][ks] = wp[((nt0 + nt) * 8 + ks) * 64 + lane];
                BA[nt][ks] = wp[((nt0 + nt) * 8 + 4 + ks) * 64 + lane];
            }
#pragma unroll
        for (int nt = 0; nt < 2; ++nt) {
            float bv = b[(nt0 + nt) * 16 + lcol];
#pragma unroll
            for (int mt = 0; mt < 4; ++mt) acc[mt][nt] = (floatx4){bv, bv, bv, bv};
        }
#pragma unroll
        for (int mt = 0; mt < 4; ++mt)
#pragma unroll
            for (int ks = 0; ks < 4; ++ks) {
                f16x8 ah = *(const f16x8*)&sH[(mt * 16 + lcol) * PADM + ks * 32 + quad * 8];
                f16x8 aa = *(const f16x8*)&sA[(mt * 16 + lcol) * PADM + ks * 32 + quad * 8];
                acc[mt][0] = __builtin_amdgcn_mfma_f32_16x16x32_f16(ah, BH[0][ks], acc[mt][0], 0, 0, 0);
                acc[mt][1] = __builtin_amdgcn_mfma_f32_16x16x32_f16(ah, BH[1][ks], acc[mt][1], 0, 0, 0);
                acc[mt][0] = __builtin_amdgcn_mfma_f32_16x16x32_f16(aa, BA[0][ks], acc[mt][0], 0, 0, 0);
                acc[mt][1] = __builtin_amdgcn_mfma_f32_16x16x32_f16(aa, BA[1][ks], acc[mt][1], 0, 0, 0);
            }
    }
    __syncthreads();
    // phase C: h_new = sH + relu(acc) -> sH
#pragma unroll
    for (int mt = 0; mt < 4; ++mt)
#pragma unroll
        for (int r = 0; r < 4; ++r) {
            float v0 = fmaxf(acc[mt][0][r], 0.f), v1 = fmaxf(acc[mt][1][r], 0.f);
            float p0 = __shfl_xor(v0, 1), p1 = __shfl_xor(v1, 1);
            float av = odd ? p1 : v0, bv = odd ? v1 : p0;
            int col = nt0 * 16 + (odd ? 15 + lcol : lcol);
            uint* sp2 = (uint*)&sH[(mt * 16 + quad * 4 + r) * PADM + col];
            float2 ho = h2f2(*sp2);
            *sp2 = f2h2(ho.x + av, ho.y + bv);
        }
    __syncthreads();
    // phase D: coalesced h store + y GEMMs from sH
    for (int i = t; i < 1024; i += 256) {
        int row = i >> 4, c = i & 15;
        int n = n0b + row;
        if (n < N_HITS) ((uint4*)(hp + (size_t)n * HD))[c] = *(uint4*)&sH[row * PADM + c * 8];
    }
    for (int half = 0; half < 2; ++half) {
        const f16x8* wyp = (const f16x8*)(half == 0 ? W1sP : W1dP);
        _Float16* out = half == 0 ? ysp : ydp;
        f16x8 B[2][4];
#pragma unroll
        for (int nt = 0; nt < 2; ++nt)
#pragma unroll
            for (int ks = 0; ks < 4; ++ks)
                B[nt][ks] = wyp[((nt0 + nt) * 4 + ks) * 64 + lane];
        floatx4 yacc[4][2];
#pragma unroll
        for (int mt = 0; mt < 4; ++mt) { yacc[mt][0] = (floatx4){0,0,0,0}; yacc[mt][1] = (floatx4){0,0,0,0}; }
#pragma unroll
        for (int mt = 0; mt < 4; ++mt)
#pragma unroll
            for (int ks = 0; ks < 4; ++ks) {
                f16x8 a = *(const f16x8*)&sH[(mt * 16 + lcol) * PADM + ks * 32 + quad * 8];
                yacc[mt][0] = __builtin_amdgcn_mfma_f32_16x16x32_f16(a, B[0][ks], yacc[mt][0], 0, 0, 0);
                yacc[mt][1] = __builtin_amdgcn_mfma_f32_16x16x32_f16(a, B[1][ks], yacc[mt][1], 0, 0, 0);
            }
        __syncthreads();
#pragma unroll
        for (int mt = 0; mt < 4; ++mt)
#pragma unroll
            for (int r = 0; r < 4; ++r) {
                float v0 = yacc[mt][0][r], v1 = yacc[mt][1][r];
                float p0 = __shfl_xor(v0, 1), p1 = __shfl_xor(v1, 1);
                float av = odd ? p1 : v0, bv = odd ? v1 : p0;
                int col = nt0 * 16 + (odd ? 15 + lcol : lcol);
                *(uint*)&sA[(mt * 16 + quad * 4 + r) * PADM + col] = f2h2(av, bv);
            }
        __syncthreads();
        for (int i = t; i < 1024; i += 256) {
            int row = i >> 4, c = i & 15;
            int n = n0b + row;
            if (n < N_HITS) ((uint4*)(out + (size_t)n * HD))[c] = *(uint4*)&sA[row * PADM + c * 8];
        }
    }
}

// ---------------- decoder ----------------
__global__ void dec_kernel(const _Float16* __restrict__ h, const float* __restrict__ W,
                           const float* __restrict__ b, float* __restrict__ out) {
    __shared__ float sW[640];
    __shared__ float sB[8];
    int t = threadIdx.x;
    for (int i = t; i < 640; i += 256) sW[i] = W[i];
    if (t < 5) sB[t] = b[t];
    __syncthreads();
    int n = blockIdx.x * 256 + t;
    if (n >= 3 * N_HITS) return;
    const uint4* hr = (const uint4*)(h + (size_t)n * HD);
    float a0 = sB[0], a1 = sB[1], a2 = sB[2], a3 = sB[3], a4 = sB[4];
#pragma unroll 4
    for (int q = 0; q < 16; ++q) {
        union { uint4 u; _Float16 hh[8]; } v; v.u = hr[q];
        const float* w = &sW[q * 40];
#pragma unroll
        for (int j = 0; j < 8; ++j) {
            float x = (float)v.hh[j];
            a0 = fmaf(x, w[j * 5 + 0], a0);
            a1 = fmaf(x, w[j * 5 + 1], a1);
            a2 = fmaf(x, w[j * 5 + 2], a2);
            a3 = fmaf(x, w[j * 5 + 3], a3);
            a4 = fmaf(x, w[j * 5 + 4], a4);
        }
    }
    float* oo = out + (size_t)n * NCLS;
    oo[0] = a0; oo[1] = a1; oo[2] = a2; oo[3] = a3; oo[4] = a4;
}

extern "C" void kernel_launch(void* const* d_in, const int* in_sizes, int n_in,
                              void* d_out, int out_size, void* d_ws, size_t ws_size,
                              hipStream_t stream) {
    const float* xu = (const float*)d_in[0];
    const int* eu = (const int*)d_in[1];
    const int* nu = (const int*)d_in[2];
    const float* xv = (const float*)d_in[3];
    const int* ev = (const int*)d_in[4];
    const int* nv = (const int*)d_in[5];
    const float* xy = (const float*)d_in[6];
    const int* ey = (const int*)d_in[7];
    const int* ny = (const int*)d_in[8];
    const float* W_enc = (const float*)d_in[9];
    const float* b_enc = (const float*)d_in[10];
    const float* W1 = (const float*)d_in[11];
    const float* b1 = (const float*)d_in[12];
    const float* W2 = (const float*)d_in[13];
    const float* b2 = (const float*)d_in[14];
    const float* W_upd = (const float*)d_in[15];
    const float* b_upd = (const float*)d_in[16];
    const float* W_sp = (const float*)d_in[17];
    const float* b_sp = (const float*)d_in[18];
    const float* W_nx = (const float*)d_in[19];
    const float* b_nx = (const float*)d_in[20];
    const float* W_sem = (const float*)d_in[21];
    const float* b_sem = (const float*)d_in[22];

    const size_t HN = (size_t)3 * N_HITS * HD;
    _Float16* h = (_Float16*)d_ws;                 // f16 [3][N_HITS][HD]
    _Float16* y_s = h + HN;                        // f16 [3][N_HITS][HD]
    _Float16* y_d = y_s + HN;                      // f16 [3][N_HITS][HD]
    _Float16* sp = y_d + HN;                       // f16 [N_SPS][HD]
    int* cnt = (int*)(sp + (size_t)N_SPS * HD);    // [270000]
    int* off = cnt + 270000;                       // [9*30001]
    int* cursor = off + 270009;                    // [270000]
    int* csr_e = cursor + 270000;                  // [3*90000]
    int* csr_s = csr_e + 270000;                   // [3*30000]
    int* csr_h = csr_s + 90000;                    // [3*30000]
    _Float16* packs = (_Float16*)(csr_h + 90000);  // [131072]
    _Float16* W1dP = packs;
    _Float16* W1sP = packs + 16384;
    _Float16* W2P = packs + 32768;
    _Float16* WuP = packs + 49152;
    _Float16* WnP = packs + 81920;
    _Float16* WspP = packs + 114688;

    wprep_kernel<<<512, 256, 0, stream>>>(W1, W2, W_upd, W_nx, W_sp, packs);
    (void)hipMemsetAsync(cnt, 0, 270000 * sizeof(int), stream);
    hist_all_kernel<<<(450000 + 255) / 256, 256, 0, stream>>>(eu, ev, ey, nu, nv, ny, cnt);
    scan_kernel<<<9, 1024, 0, stream>>>(cnt, off, cursor);
    fill_kernel<<<(450000 + 255) / 256, 256, 0, stream>>>(eu, ev, ey, nu, nv, ny,
                                                          cursor, csr_e, csr_s, csr_h);

    enc_y_kernel<<<(3 * N_HITS + 127) / 128, 256, 0, stream>>>(xu, xv, xy, W_enc, b_enc,
                                                               W1dP, W1sP, h, y_d, y_s);

    for (int it = 0; it < 3; ++it) {
        update_planar_kernel<<<dim3((N_HITS + 63) / 64, 3), 256, 0, stream>>>(
            h, y_d, y_s, off, csr_e, b1, W2P, b2, WuP, b_upd);
        sp_fused_kernel<<<(N_SPS + 63) / 64, 256, 0, stream>>>(h, off, csr_s, WspP, b_sp, sp);
        update_y_kernel<<<dim3((N_HITS + 63) / 64, 3), 256, 0, stream>>>(
            h, sp, off, csr_h, WnP, b_nx, W1dP, W1sP, y_d, y_s);
    }

    dec_kernel<<<(3 * N_HITS + 255) / 256, 256, 0, stream>>>(h, W_sem, b_sem, (float*)d_out);
}

// Round 18
// 492.084 us; speedup vs baseline: 2.1583x; 1.0036x over previous
//
#include <hip/hip_runtime.h>
#include <hip/hip_fp16.h>

#define N_HITS 30000
#define N_EDGES 90000
#define N_SPS 30000
#define HD 128
#define NCLS 5

#define PADM 136  // 128 + 8 f16 pad

typedef __attribute__((ext_vector_type(8))) _Float16 f16x8;
typedef __attribute__((ext_vector_type(4))) float floatx4;

__device__ __forceinline__ float2 h2f2(uint u) {
    union { uint u; __half2 h; } x; x.u = u;
    return __half22float2(x.h);
}
__device__ __forceinline__ uint f2h2(float a, float b) {
    union { uint u; __half2 h; } x;
    x.h = __halves2half2(__float2half(a), __float2half(b));
    return x.u;
}

// ---------------- histograms ----------------
__global__ void hist_all_kernel(const int* __restrict__ eu, const int* __restrict__ ev,
                                const int* __restrict__ ey, const int* __restrict__ nu,
                                const int* __restrict__ nv, const int* __restrict__ ny,
                                int* __restrict__ cnt) {
    int gid = blockIdx.x * blockDim.x + threadIdx.x;
    if (gid >= 450000) return;
    int p = gid / 150000;
    int r = gid - p * 150000;
    const int* e = (p == 0) ? eu : (p == 1) ? ev : ey;
    const int* nx = (p == 0) ? nu : (p == 1) ? nv : ny;
    if (r < N_EDGES) {
        atomicAdd(&cnt[p * 30000 + e[N_EDGES + r]], 1);
    } else if (r < N_EDGES + N_SPS) {
        int i = r - N_EDGES;
        atomicAdd(&cnt[(3 + p) * 30000 + nx[N_SPS + i]], 1);
    } else {
        int i = r - N_EDGES - N_SPS;
        atomicAdd(&cnt[(6 + p) * 30000 + nx[i]], 1);
    }
}

// ---------------- exclusive scan per segment ----------------
__launch_bounds__(1024)
__global__ void scan_kernel(const int* __restrict__ cnt, int* __restrict__ off,
                            int* __restrict__ cursor) {
    int seg = blockIdx.x;
    const int* c = cnt + seg * 30000;
    int* o = off + seg * 30001;
    int* cur = cursor + seg * 30000;
    int t = threadIdx.x;
    int base = t * 30;
    int lc[30];
    int sum = 0;
#pragma unroll
    for (int k = 0; k < 30; ++k) {
        int i = base + k;
        lc[k] = (i < 30000) ? c[i] : 0;
        sum += lc[k];
    }
    __shared__ int part[1024];
    part[t] = sum;
    __syncthreads();
    for (int d = 1; d < 1024; d <<= 1) {
        int x = (t >= d) ? part[t - d] : 0;
        __syncthreads();
        part[t] += x;
        __syncthreads();
    }
    int run = part[t] - sum;
#pragma unroll
    for (int k = 0; k < 30; ++k) {
        int i = base + k;
        if (i < 30000) { o[i] = run; cur[i] = run; run += lc[k]; }
    }
    if (t == 1023) o[30000] = part[1023];
}

// ---------------- CSR fill ----------------
__global__ void fill_kernel(const int* __restrict__ eu, const int* __restrict__ ev,
                            const int* __restrict__ ey, const int* __restrict__ nu,
                            const int* __restrict__ nv, const int* __restrict__ ny,
                            int* __restrict__ cursor, int* __restrict__ csr_e,
                            int* __restrict__ csr_s, int* __restrict__ csr_h) {
    int gid = blockIdx.x * blockDim.x + threadIdx.x;
    if (gid >= 450000) return;
    int p = gid / 150000;
    int r = gid - p * 150000;
    const int* e = (p == 0) ? eu : (p == 1) ? ev : ey;
    const int* nx = (p == 0) ? nu : (p == 1) ? nv : ny;
    if (r < N_EDGES) {
        int d = e[N_EDGES + r];
        int pos = atomicAdd(&cursor[p * 30000 + d], 1);
        csr_e[p * N_EDGES + pos] = e[r];
    } else if (r < N_EDGES + N_SPS) {
        int i = r - N_EDGES;
        int spid = nx[N_SPS + i];
        int pos = atomicAdd(&cursor[(3 + p) * 30000 + spid], 1);
        csr_s[p * N_SPS + pos] = nx[i];
    } else {
        int i = r - N_EDGES - N_SPS;
        int hit = nx[i];
        int pos = atomicAdd(&cursor[(6 + p) * 30000 + hit], 1);
        csr_h[p * N_SPS + pos] = nx[N_SPS + i];
    }
}

// ---------------- weight pre-pack (f16) ----------------
__device__ __forceinline__ void pack4(const float* __restrict__ W, _Float16* __restrict__ P,
                                      int idx, int koff) {
    int j = idx & 7, lane = (idx >> 3) & 63, ks = (idx >> 9) & 3, n = (idx >> 11) & 7;
    int k = ks * 32 + (lane >> 4) * 8 + j, col = n * 16 + (lane & 15);
    P[idx] = (_Float16)W[(k + koff) * 128 + col];
}
__device__ __forceinline__ void pack8(const float* __restrict__ W, _Float16* __restrict__ P, int idx) {
    int j = idx & 7, lane = (idx >> 3) & 63, ks = (idx >> 9) & 7, n = (idx >> 12) & 7;
    int k = ks * 32 + (lane >> 4) * 8 + j, col = n * 16 + (lane & 15);
    P[idx] = (_Float16)W[k * 128 + col];
}

__global__ void wprep_kernel(const float* __restrict__ W1, const float* __restrict__ W2,
                             const float* __restrict__ Wu, const float* __restrict__ Wn,
                             const float* __restrict__ Wsp, _Float16* __restrict__ packs) {
    int gid = blockIdx.x * blockDim.x + threadIdx.x;
    if (gid < 16384) { pack4(W1, packs, gid, 0); return; }            // W1d
    gid -= 16384;
    if (gid < 16384) { pack4(W1, packs + 16384, gid, 128); return; }  // W1s
    gid -= 16384;
    if (gid < 16384) { pack4(W2, packs + 32768, gid, 0); return; }    // W2
    gid -= 16384;
    if (gid < 32768) { pack8(Wu, packs + 49152, gid); return; }       // W_upd
    gid -= 32768;
    if (gid < 32768) { pack8(Wn, packs + 81920, gid); return; }       // W_nx
    gid -= 32768;
    if (gid < 16384) { pack4(Wsp, packs + 114688, gid, 0); }          // W_sp
}

// ---------------- fused encoder + y emission ----------------
__launch_bounds__(256, 4)
__global__ void enc_y_kernel(const float* __restrict__ xu, const float* __restrict__ xv,
                             const float* __restrict__ xy, const float* __restrict__ We,
                             const float* __restrict__ be, const _Float16* __restrict__ W1dP,
                             const _Float16* __restrict__ W1sP, _Float16* __restrict__ h,
                             _Float16* __restrict__ y_d, _Float16* __restrict__ y_s) {
    __shared__ _Float16 sA[128 * PADM];
    __shared__ _Float16 sO[128 * PADM];
    int t = threadIdx.x;
    int n0b = blockIdx.x * 128;
    const int M = 3 * N_HITS;
    for (int i = t; i < 2048; i += 256) {
        int row = i >> 4, c = i & 15;
        int n = n0b + row; if (n >= M) n = M - 1;
        int p = n / N_HITS;
        int nn = n - p * N_HITS;
        const float* x = (p == 0) ? xu : (p == 1) ? xv : xy;
        float4 xv4 = *(const float4*)(x + nn * 4);
        union { _Float16 o8[8]; uint4 u; } outv;
#pragma unroll
        for (int j = 0; j < 8; ++j) {
            int col = c * 8 + j;
            float acc = be[col];
            acc = fmaf(xv4.x, We[0 * HD + col], acc);
            acc = fmaf(xv4.y, We[1 * HD + col], acc);
            acc = fmaf(xv4.z, We[2 * HD + col], acc);
            acc = fmaf(xv4.w, We[3 * HD + col], acc);
            outv.o8[j] = (_Float16)fmaxf(acc, 0.f);
        }
        *(uint4*)&sA[row * PADM + c * 8] = outv.u;
        if (n0b + row < M) ((uint4*)(h + (size_t)n * HD))[c] = outv.u;
    }
    __syncthreads();

    int lane = t & 63, wave = t >> 6;
    int lcol = lane & 15, quad = lane >> 4;
    int nt0 = wave * 2;
    bool odd = (lcol & 1) != 0;

    for (int half = 0; half < 2; ++half) {
        const f16x8* wp = (const f16x8*)(half == 0 ? W1dP : W1sP);
        _Float16* out = half == 0 ? y_d : y_s;
        f16x8 B[2][4];
#pragma unroll
        for (int nt = 0; nt < 2; ++nt)
#pragma unroll
            for (int ks = 0; ks < 4; ++ks)
                B[nt][ks] = wp[((nt0 + nt) * 4 + ks) * 64 + lane];
        floatx4 acc[8][2];
#pragma unroll
        for (int mt = 0; mt < 8; ++mt) { acc[mt][0] = (floatx4){0,0,0,0}; acc[mt][1] = (floatx4){0,0,0,0}; }
#pragma unroll
        for (int mt = 0; mt < 8; ++mt)
#pragma unroll
            for (int ks = 0; ks < 4; ++ks) {
                f16x8 a = *(const f16x8*)&sA[(mt * 16 + lcol) * PADM + ks * 32 + quad * 8];
                acc[mt][0] = __builtin_amdgcn_mfma_f32_16x16x32_f16(a, B[0][ks], acc[mt][0], 0, 0, 0);
                acc[mt][1] = __builtin_amdgcn_mfma_f32_16x16x32_f16(a, B[1][ks], acc[mt][1], 0, 0, 0);
            }
#pragma unroll
        for (int mt = 0; mt < 8; ++mt)
#pragma unroll
            for (int r = 0; r < 4; ++r) {
                float v0 = acc[mt][0][r], v1 = acc[mt][1][r];
                float p0 = __shfl_xor(v0, 1), p1 = __shfl_xor(v1, 1);
                float av = odd ? p1 : v0, bv = odd ? v1 : p0;
                int col = nt0 * 16 + (odd ? 15 + lcol : lcol);
                *(uint*)&sO[(mt * 16 + quad * 4 + r) * PADM + col] = f2h2(av, bv);
            }
        __syncthreads();
        for (int i = t; i < 2048; i += 256) {
            int row = i >> 4, c = i & 15;
            int n = n0b + row;
            if (n < M) ((uint4*)(out + (size_t)n * HD))[c] = *(uint4*)&sO[row * PADM + c * 8];
        }
        __syncthreads();
    }
}

// ---------------- planar update, M=64, single LDS buffer, 4-peel gather ----------------
#define ECAP 640
__launch_bounds__(256, 5)
__global__ void update_planar_kernel(_Float16* __restrict__ h, const _Float16* __restrict__ y_d,
                                     const _Float16* __restrict__ y_s,
                                     const int* __restrict__ off, const int* __restrict__ csr_e,
                                     const float* __restrict__ b1,
                                     const _Float16* __restrict__ W2P, const float* __restrict__ b2,
                                     const _Float16* __restrict__ WuP, const float* __restrict__ bu) {
    int p = blockIdx.y;
    _Float16* hp = h + (size_t)p * N_HITS * HD;
    const _Float16* ydp = y_d + (size_t)p * N_HITS * HD;
    const _Float16* ysp = y_s + (size_t)p * N_HITS * HD;
    const int* o = off + p * 30001;
    const int* csr = csr_e + p * N_EDGES;

    __shared__ _Float16 sA[64 * PADM];
    __shared__ int sOff[65];
    __shared__ int sIdx[ECAP];
    int t = threadIdx.x;
    int n0b = blockIdx.x * 64;
    int lane = t & 63, wave = t >> 6;
    int lcol = lane & 15, quad = lane >> 4;
    int nt0 = wave * 2;
    bool odd = (lcol & 1) != 0;

    if (t < 65) {
        int idx = n0b + t; if (idx > N_HITS) idx = N_HITS;
        sOff[t] = o[idx];
    }
    for (int i = t; i < 1024; i += 256) {
        int row = i >> 4, c = i & 15;
        int n = n0b + row; if (n >= N_HITS) n = N_HITS - 1;
        f16x8 yv = *(const f16x8*)&ydp[(size_t)n * HD + c * 8];
        float4 b1a = *(const float4*)(b1 + c * 8);
        float4 b1b = *(const float4*)(b1 + c * 8 + 4);
        float bb[8] = {b1a.x, b1a.y, b1a.z, b1a.w, b1b.x, b1b.y, b1b.z, b1b.w};
        f16x8 ov;
#pragma unroll
        for (int j = 0; j < 8; ++j) ov[j] = (_Float16)((float)yv[j] + bb[j]);
        *(f16x8*)&sA[row * PADM + c * 8] = ov;
    }
    __syncthreads();
    int base = sOff[0];
    int total = sOff[64] - base;
    bool useL = (total <= ECAP);
    if (useL) for (int i = t; i < total; i += 256) sIdx[i] = csr[base + i];
    __syncthreads();

    // phase A: in-place CSR edge gather, 4-peel + 2-way loop
    for (int i = t; i < 1024; i += 256) {
        int row = i >> 4, c = i & 15;
        int d = n0b + row;
        int beg = 0, end = 0;
        if (d < N_HITS) { beg = sOff[row]; end = sOff[row + 1]; }
        f16x8 ydv = *(const f16x8*)&sA[row * PADM + c * 8];
        f16x8 a0 = (f16x8)(_Float16)0, a1 = (f16x8)(_Float16)0;
        f16x8 a2 = (f16x8)(_Float16)0, a3 = (f16x8)(_Float16)0;
        int k = beg;
        int rem = end - beg;
        if (rem > 0) {
            int s0 = useL ? sIdx[k - base] : csr[k];
            int s1 = (rem > 1) ? (useL ? sIdx[k + 1 - base] : csr[k + 1]) : s0;
            int s2 = (rem > 2) ? (useL ? sIdx[k + 2 - base] : csr[k + 2]) : s0;
            int s3 = (rem > 3) ? (useL ? sIdx[k + 3 - base] : csr[k + 3]) : s0;
            f16x8 v0 = *(const f16x8*)&ysp[(size_t)s0 * HD + c * 8];
            f16x8 v1 = *(const f16x8*)&ysp[(size_t)s1 * HD + c * 8];
            f16x8 v2 = *(const f16x8*)&ysp[(size_t)s2 * HD + c * 8];
            f16x8 v3 = *(const f16x8*)&ysp[(size_t)s3 * HD + c * 8];
            a0 += __builtin_elementwise_max(v0 + ydv, (f16x8)(_Float16)0);
            if (rem > 1) a1 += __builtin_elementwise_max(v1 + ydv, (f16x8)(_Float16)0);
            if (rem > 2) a2 += __builtin_elementwise_max(v2 + ydv, (f16x8)(_Float16)0);
            if (rem > 3) a3 += __builtin_elementwise_max(v3 + ydv, (f16x8)(_Float16)0);
            k += (rem < 4) ? rem : 4;
        }
        for (; k + 2 <= end; k += 2) {
            int s0 = useL ? sIdx[k - base] : csr[k];
            int s1 = useL ? sIdx[k + 1 - base] : csr[k + 1];
            f16x8 v0 = *(const f16x8*)&ysp[(size_t)s0 * HD + c * 8];
            f16x8 v1 = *(const f16x8*)&ysp[(size_t)s1 * HD + c * 8];
            a0 += __builtin_elementwise_max(v0 + ydv, (f16x8)(_Float16)0);
            a1 += __builtin_elementwise_max(v1 + ydv, (f16x8)(_Float16)0);
        }
        if (k < end) {
            int s0 = useL ? sIdx[k - base] : csr[k];
            f16x8 v0 = *(const f16x8*)&ysp[(size_t)s0 * HD + c * 8];
            a0 += __builtin_elementwise_max(v0 + ydv, (f16x8)(_Float16)0);
        }
        f16x8 accv = (a0 + a1) + (a2 + a3);
        _Float16 iv = (_Float16)((end > beg) ? 1.f / (float)(end - beg) : 0.f);
        accv *= iv;
        *(f16x8*)&sA[row * PADM + c * 8] = accv;
    }
    __syncthreads();
    // phase B: agg = z @ W2 + b2
    floatx4 acc[4][2];
    {
        const f16x8* w2p = (const f16x8*)W2P;
        f16x8 B[2][4];
#pragma unroll
        for (int nt = 0; nt < 2; ++nt)
#pragma unroll
            for (int ks = 0; ks < 4; ++ks)
                B[nt][ks] = w2p[((nt0 + nt) * 4 + ks) * 64 + lane];
#pragma unroll
        for (int nt = 0; nt < 2; ++nt) {
            float bv = b2[(nt0 + nt) * 16 + lcol];
#pragma unroll
            for (int mt = 0; mt < 4; ++mt) acc[mt][nt] = (floatx4){bv, bv, bv, bv};
        }
#pragma unroll
        for (int mt = 0; mt < 4; ++mt)
#pragma unroll
            for (int ks = 0; ks < 4; ++ks) {
                f16x8 a = *(const f16x8*)&sA[(mt * 16 + lcol) * PADM + ks * 32 + quad * 8];
                acc[mt][0] = __builtin_amdgcn_mfma_f32_16x16x32_f16(a, B[0][ks], acc[mt][0], 0, 0, 0);
                acc[mt][1] = __builtin_amdgcn_mfma_f32_16x16x32_f16(a, B[1][ks], acc[mt][1], 0, 0, 0);
            }
    }
    __syncthreads();
    // phase C: agg -> sA
#pragma unroll
    for (int mt = 0; mt < 4; ++mt)
#pragma unroll
        for (int r = 0; r < 4; ++r) {
            float v0 = acc[mt][0][r], v1 = acc[mt][1][r];
            float p0 = __shfl_xor(v0, 1), p1 = __shfl_xor(v1, 1);
            float av = odd ? p1 : v0, bv = odd ? v1 : p0;
            int col = nt0 * 16 + (odd ? 15 + lcol : lcol);
            *(uint*)&sA[(mt * 16 + quad * 4 + r) * PADM + col] = f2h2(av, bv);
        }
    __syncthreads();
    // phase D: accU = bu + agg @ Wu[ks4..7]
    {
        const f16x8* wu = (const f16x8*)WuP;
        f16x8 B[2][4];
#pragma unroll
        for (int nt = 0; nt < 2; ++nt)
#pragma unroll
            for (int ks = 0; ks < 4; ++ks)
                B[nt][ks] = wu[((nt0 + nt) * 8 + 4 + ks) * 64 + lane];
        floatx4 tmp[4][2];
#pragma unroll
        for (int nt = 0; nt < 2; ++nt) {
            float bv = bu[(nt0 + nt) * 16 + lcol];
#pragma unroll
            for (int mt = 0; mt < 4; ++mt) tmp[mt][nt] = (floatx4){bv, bv, bv, bv};
        }
#pragma unroll
        for (int mt = 0; mt < 4; ++mt)
#pragma unroll
            for (int ks = 0; ks < 4; ++ks) {
                f16x8 a = *(const f16x8*)&sA[(mt * 16 + lcol) * PADM + ks * 32 + quad * 8];
                tmp[mt][0] = __builtin_amdgcn_mfma_f32_16x16x32_f16(a, B[0][ks], tmp[mt][0], 0, 0, 0);
                tmp[mt][1] = __builtin_amdgcn_mfma_f32_16x16x32_f16(a, B[1][ks], tmp[mt][1], 0, 0, 0);
            }
#pragma unroll
        for (int mt = 0; mt < 4; ++mt) { acc[mt][0] = tmp[mt][0]; acc[mt][1] = tmp[mt][1]; }
    }
    __syncthreads();
    // phase E: stage h -> sA
    for (int i = t; i < 1024; i += 256) {
        int row = i >> 4, c = i & 15;
        int n = n0b + row; if (n >= N_HITS) n = N_HITS - 1;
        *(uint4*)&sA[row * PADM + c * 8] = ((const uint4*)(hp + (size_t)n * HD))[c];
    }
    __syncthreads();
    // phase F: accU += h @ Wu[ks0..3]
    {
        const f16x8* wu = (const f16x8*)WuP;
        f16x8 B[2][4];
#pragma unroll
        for (int nt = 0; nt < 2; ++nt)
#pragma unroll
            for (int ks = 0; ks < 4; ++ks)
                B[nt][ks] = wu[((nt0 + nt) * 8 + ks) * 64 + lane];
#pragma unroll
        for (int mt = 0; mt < 4; ++mt)
#pragma unroll
            for (int ks = 0; ks < 4; ++ks) {
                f16x8 a = *(const f16x8*)&sA[(mt * 16 + lcol) * PADM + ks * 32 + quad * 8];
                acc[mt][0] = __builtin_amdgcn_mfma_f32_16x16x32_f16(a, B[0][ks], acc[mt][0], 0, 0, 0);
                acc[mt][1] = __builtin_amdgcn_mfma_f32_16x16x32_f16(a, B[1][ks], acc[mt][1], 0, 0, 0);
            }
    }
    __syncthreads();
    // phase G: h_new = h(sA) + relu(accU) -> sA
#pragma unroll
    for (int mt = 0; mt < 4; ++mt)
#pragma unroll
        for (int r = 0; r < 4; ++r) {
            float v0 = fmaxf(acc[mt][0][r], 0.f), v1 = fmaxf(acc[mt][1][r], 0.f);
            float p0 = __shfl_xor(v0, 1), p1 = __shfl_xor(v1, 1);
            float av = odd ? p1 : v0, bv = odd ? v1 : p0;
            int col = nt0 * 16 + (odd ? 15 + lcol : lcol);
            uint* sp2 = (uint*)&sA[(mt * 16 + quad * 4 + r) * PADM + col];
            float2 ho = h2f2(*sp2);
            *sp2 = f2h2(ho.x + av, ho.y + bv);
        }
    __syncthreads();
    // phase H: coalesced store sA -> h
    for (int i = t; i < 1024; i += 256) {
        int row = i >> 4, c = i & 15;
        int n = n0b + row;
        if (n < N_HITS) ((uint4*)(hp + (size_t)n * HD))[c] = *(uint4*)&sA[row * PADM + c * 8];
    }
}

// ---------------- sp fused (M=64), 4-peel 3-plane gather ----------------
#define SCAP 576
__launch_bounds__(256, 6)
__global__ void sp_fused_kernel(const _Float16* __restrict__ h, const int* __restrict__ off,
                                const int* __restrict__ csr_s, const _Float16* __restrict__ WspP,
                                const float* __restrict__ b, _Float16* __restrict__ spf) {
    __shared__ _Float16 sA[64 * PADM];
    __shared__ int sOff[3][65];
    __shared__ int sIdx[SCAP];
    int t = threadIdx.x;
    int n0b = blockIdx.x * 64;
    int lane = t & 63, wave = t >> 6;
    int lcol = lane & 15, quad = lane >> 4;
    int nt0 = wave * 2;
    bool odd = (lcol & 1) != 0;

    if (t < 195) {
        int p = t / 65, i = t - p * 65;
        int idx = n0b + i; if (idx > N_SPS) idx = N_SPS;
        sOff[p][i] = off[(3 + p) * 30001 + idx];
    }
    __syncthreads();
    int base0 = sOff[0][0], len0 = sOff[0][64] - base0;
    int base1 = sOff[1][0], len1 = sOff[1][64] - base1;
    int base2 = sOff[2][0], len2 = sOff[2][64] - base2;
    int ofs1 = len0, ofs2 = len0 + len1;
    bool useL = (ofs2 + len2 <= SCAP);
    if (useL) {
        for (int i = t; i < len0; i += 256) sIdx[i] = csr_s[base0 + i];
        for (int i = t; i < len1; i += 256) sIdx[ofs1 + i] = csr_s[N_SPS + base1 + i];
        for (int i = t; i < len2; i += 256) sIdx[ofs2 + i] = csr_s[2 * N_SPS + base2 + i];
    }
    __syncthreads();

    for (int i = t; i < 1024; i += 256) {
        int row = i >> 4, c = i & 15;
        int s = n0b + row;
        f16x8 tv = (f16x8)(_Float16)0;
        if (s < N_SPS) {
#pragma unroll
            for (int p = 0; p < 3; ++p) {
                int beg = sOff[p][row], end = sOff[p][row + 1];
                int bb = (p == 0) ? base0 : (p == 1) ? base1 : base2;
                int oo = (p == 0) ? 0 : (p == 1) ? ofs1 : ofs2;
                const int* csr = csr_s + p * N_SPS;
                const _Float16* hb = h + (size_t)p * N_HITS * HD;
                f16x8 s0v = (f16x8)(_Float16)0, s1v = (f16x8)(_Float16)0;
                int k = beg;
                int rem = end - beg;
                if (rem > 0) {
                    int h0 = useL ? sIdx[oo + (k - bb)] : csr[k];
                    int h1 = (rem > 1) ? (useL ? sIdx[oo + (k + 1 - bb)] : csr[k + 1]) : h0;
                    f16x8 v0 = *(const f16x8*)&hb[(size_t)h0 * HD + c * 8];
                    f16x8 v1 = *(const f16x8*)&hb[(size_t)h1 * HD + c * 8];
                    s0v += v0;
                    if (rem > 1) s1v += v1;
                    k += (rem < 2) ? rem : 2;
                }
                for (; k + 2 <= end; k += 2) {
                    int h0 = useL ? sIdx[oo + (k - bb)] : csr[k];
                    int h1 = useL ? sIdx[oo + (k + 1 - bb)] : csr[k + 1];
                    f16x8 v0 = *(const f16x8*)&hb[(size_t)h0 * HD + c * 8];
                    f16x8 v1 = *(const f16x8*)&hb[(size_t)h1 * HD + c * 8];
                    s0v += v0; s1v += v1;
                }
                if (k < end) {
                    int h0 = useL ? sIdx[oo + (k - bb)] : csr[k];
                    s0v += *(const f16x8*)&hb[(size_t)h0 * HD + c * 8];
                }
                f16x8 sv = s0v + s1v;
                _Float16 iv = (_Float16)((end > beg) ? 1.f / (float)(end - beg) : 0.f);
                tv += sv * iv;
            }
        }
        *(f16x8*)&sA[row * PADM + c * 8] = tv;
    }
    __syncthreads();

    const f16x8* wp = (const f16x8*)WspP;
    f16x8 B[2][4];
#pragma unroll
    for (int nt = 0; nt < 2; ++nt)
#pragma unroll
        for (int ks = 0; ks < 4; ++ks)
            B[nt][ks] = wp[((nt0 + nt) * 4 + ks) * 64 + lane];

    floatx4 acc[4][2];
#pragma unroll
    for (int nt = 0; nt < 2; ++nt) {
        float bv = b[(nt0 + nt) * 16 + lcol];
#pragma unroll
        for (int mt = 0; mt < 4; ++mt) acc[mt][nt] = (floatx4){bv, bv, bv, bv};
    }
#pragma unroll
    for (int mt = 0; mt < 4; ++mt)
#pragma unroll
        for (int ks = 0; ks < 4; ++ks) {
            f16x8 a = *(const f16x8*)&sA[(mt * 16 + lcol) * PADM + ks * 32 + quad * 8];
            acc[mt][0] = __builtin_amdgcn_mfma_f32_16x16x32_f16(a, B[0][ks], acc[mt][0], 0, 0, 0);
            acc[mt][1] = __builtin_amdgcn_mfma_f32_16x16x32_f16(a, B[1][ks], acc[mt][1], 0, 0, 0);
        }
    __syncthreads();
#pragma unroll
    for (int mt = 0; mt < 4; ++mt)
#pragma unroll
        for (int r = 0; r < 4; ++r) {
            float v0 = fmaxf(acc[mt][0][r], 0.f), v1 = fmaxf(acc[mt][1][r], 0.f);
            float p0 = __shfl_xor(v0, 1), p1 = __shfl_xor(v1, 1);
            float av = odd ? p1 : v0, bv = odd ? v1 : p0;
            int col = nt0 * 16 + (odd ? 15 + lcol : lcol);
            *(uint*)&sA[(mt * 16 + quad * 4 + r) * PADM + col] = f2h2(av, bv);
        }
    __syncthreads();
    for (int i = t; i < 1024; i += 256) {
        int row = i >> 4, c = i & 15;
        int n = n0b + row;
        if (n < N_SPS) ((uint4*)(spf + (size_t)n * HD))[c] = *(uint4*)&sA[row * PADM + c * 8];
    }
}

// ---------------- nexus update (M=64); last iter: skip y GEMMs, fuse decoder ----------------
#define HCAP 320
__launch_bounds__(256, 4)
__global__ void update_y_kernel(_Float16* __restrict__ h, const _Float16* __restrict__ sp,
                                const int* __restrict__ off, const int* __restrict__ csr_h,
                                const _Float16* __restrict__ WP, const float* __restrict__ b,
                                const _Float16* __restrict__ W1dP, const _Float16* __restrict__ W1sP,
                                _Float16* __restrict__ y_d, _Float16* __restrict__ y_s,
                                const float* __restrict__ Wsem, const float* __restrict__ bsem,
                                float* __restrict__ out, int last) {
    int p = blockIdx.y;
    _Float16* hp = h + (size_t)p * N_HITS * HD;
    _Float16* ydp = y_d + (size_t)p * N_HITS * HD;
    _Float16* ysp = y_s + (size_t)p * N_HITS * HD;
    const int* o = off + (6 + p) * 30001;
    const int* csr = csr_h + p * N_SPS;

    __shared__ _Float16 sH[64 * PADM];
    __shared__ _Float16 sA[64 * PADM];
    __shared__ int sOff[65];
    __shared__ int sIdx[HCAP];
    int t = threadIdx.x;
    int n0b = blockIdx.x * 64;
    int lane = t & 63, wave = t >> 6;
    int lcol = lane & 15, quad = lane >> 4;
    int nt0 = wave * 2;
    bool odd = (lcol & 1) != 0;

    if (t < 65) {
        int idx = n0b + t; if (idx > N_HITS) idx = N_HITS;
        sOff[t] = o[idx];
    }
    for (int i = t; i < 1024; i += 256) {
        int row = i >> 4, c = i & 15;
        int n = n0b + row; if (n >= N_HITS) n = N_HITS - 1;
        *(uint4*)&sH[row * PADM + c * 8] = ((const uint4*)(hp + (size_t)n * HD))[c];
    }
    __syncthreads();
    int base = sOff[0];
    int total = sOff[64] - base;
    bool useL = (total <= HCAP);
    if (useL) for (int i = t; i < total; i += 256) sIdx[i] = csr[base + i];
    __syncthreads();

    // phase A: gather aux -> sA (4-peel + 2-way)
    for (int i = t; i < 1024; i += 256) {
        int row = i >> 4, c = i & 15;
        int hit = n0b + row;
        int beg = 0, end = 0;
        if (hit < N_HITS) { beg = sOff[row]; end = sOff[row + 1]; }
        f16x8 a0 = (f16x8)(_Float16)0, a1 = (f16x8)(_Float16)0;
        int k = beg;
        int rem = end - beg;
        if (rem > 0) {
            int s0 = useL ? sIdx[k - base] : csr[k];
            int s1 = (rem > 1) ? (useL ? sIdx[k + 1 - base] : csr[k + 1]) : s0;
            f16x8 v0 = *(const f16x8*)&sp[(size_t)s0 * HD + c * 8];
            f16x8 v1 = *(const f16x8*)&sp[(size_t)s1 * HD + c * 8];
            a0 += v0;
            if (rem > 1) a1 += v1;
            k += (rem < 2) ? rem : 2;
        }
        for (; k + 2 <= end; k += 2) {
            int s0 = useL ? sIdx[k - base] : csr[k];
            int s1 = useL ? sIdx[k + 1 - base] : csr[k + 1];
            f16x8 v0 = *(const f16x8*)&sp[(size_t)s0 * HD + c * 8];
            f16x8 v1 = *(const f16x8*)&sp[(size_t)s1 * HD + c * 8];
            a0 += v0; a1 += v1;
        }
        if (k < end) {
            int s0 = useL ? sIdx[k - base] : csr[k];
            a0 += *(const f16x8*)&sp[(size_t)s0 * HD + c * 8];
        }
        f16x8 av8 = a0 + a1;
        _Float16 iv = (_Float16)((end > beg) ? 1.f / (float)(end - beg) : 0.f);
        av8 *= iv;
        *(f16x8*)&sA[row * PADM + c * 8] = av8;
    }
    __syncthreads();
    // phase B: acc = b + sH@Wn[ks0..3] + sA@Wn[ks4..7]
    floatx4 acc[4][2];
    {
        const f16x8* wp = (const f16x8*)WP;
        f16x8 BH[2][4], BA[2][4];
#pragma unroll
        for (int nt = 0; nt < 2; ++nt)
#pragma unroll
            for (int ks = 0; ks < 4; ++ks) {
                BH[nt][ks] = wp[((nt0 + nt) * 8 + ks) * 64 + lane];
                BA[nt][ks] = wp[((nt0 + nt) * 8 + 4 + ks) * 64 + lane];
            }
#pragma unroll
        for (int nt = 0; nt < 2; ++nt) {
            float bv = b[(nt0 + nt) * 16 + lcol];
#pragma unroll
            for (int mt = 0; mt < 4; ++mt) acc[mt][nt] = (floatx4){bv, bv, bv, bv};
        }
#pragma unroll
        for (int mt = 0; mt < 4; ++mt)
#pragma unroll
            for (int ks = 0; ks < 4; ++ks) {
                f16x8 ah = *(const f16x8*)&sH[(mt * 16 + lcol) * PADM + ks * 32 + quad * 8];
                f16x8 aa = *(const f16x8*)&sA[(mt * 16 + lcol) * PADM + ks * 32 + quad * 8];
                acc[mt][0] = __builtin_amdgcn_mfma_f32_16x16x32_f16(ah, BH[0][ks], acc[mt][0], 0, 0, 0);
                acc[mt][1] = __builtin_amdgcn_mfma_f32_16x16x32_f16(ah, BH[1][ks], acc[mt][1], 0, 0, 0);
                acc[mt][0] = __builtin_amdgcn_mfma_f32_16x16x32_f16(aa, BA[0][ks], acc[mt][0], 0, 0, 0);
                acc[mt][1] = __builtin_amdgcn_mfma_f32_16x16x32_f16(aa, BA[1][ks], acc[mt][1], 0, 0, 0);
            }
    }
    __syncthreads();
    // phase C: h_new = sH + relu(acc) -> sH
#pragma unroll
    for (int mt = 0; mt < 4; ++mt)
#pragma unroll
        for (int r = 0; r < 4; ++r) {
            float v0 = fmaxf(acc[mt][0][r], 0.f), v1 = fmaxf(acc[mt][1][r], 0.f);
            float p0 = __shfl_xor(v0, 1), p1 = __shfl_xor(v1, 1);
            float av = odd ? p1 : v0, bv = odd ? v1 : p0;
            int col = nt0 * 16 + (odd ? 15 + lcol : lcol);
            uint* sp2 = (uint*)&sH[(mt * 16 + quad * 4 + r) * PADM + col];
            float2 ho = h2f2(*sp2);
            *sp2 = f2h2(ho.x + av, ho.y + bv);
        }
    __syncthreads();
    // phase D: coalesced h store
    for (int i = t; i < 1024; i += 256) {
        int row = i >> 4, c = i & 15;
        int n = n0b + row;
        if (n < N_HITS) ((uint4*)(hp + (size_t)n * HD))[c] = *(uint4*)&sH[row * PADM + c * 8];
    }
    if (last) {
        // fused decoder: out[n] = h_new @ Wsem + bsem; 4 threads/row, 32 cols each
        int row = t >> 2, part = t & 3;
        int n = n0b + row;
        float a0 = 0.f, a1 = 0.f, a2 = 0.f, a3 = 0.f, a4 = 0.f;
        const _Float16* hr = &sH[row * PADM + part * 32];
#pragma unroll
        for (int q = 0; q < 4; ++q) {
            f16x8 v = *(const f16x8*)(hr + q * 8);
#pragma unroll
            for (int j = 0; j < 8; ++j) {
                float x = (float)v[j];
                const float* w = Wsem + (part * 32 + q * 8 + j) * NCLS;
                a0 = fmaf(x, w[0], a0);
                a1 = fmaf(x, w[1], a1);
                a2 = fmaf(x, w[2], a2);
                a3 = fmaf(x, w[3], a3);
                a4 = fmaf(x, w[4], a4);
            }
        }
        a0 += __shfl_xor(a0, 1); a0 += __shfl_xor(a0, 2);
        a1 += __shfl_xor(a1, 1); a1 += __shfl_xor(a1, 2);
        a2 += __shfl_xor(a2, 1); a2 += __shfl_xor(a2, 2);
        a3 += __shfl_xor(a3, 1); a3 += __shfl_xor(a3, 2);
        a4 += __shfl_xor(a4, 1); a4 += __shfl_xor(a4, 2);
        if (part == 0 && n < N_HITS) {
            float* oo = out + ((size_t)p * N_HITS + n) * NCLS;
            oo[0] = a0 + bsem[0]; oo[1] = a1 + bsem[1]; oo[2] = a2 + bsem[2];
            oo[3] = a3 + bsem[3]; oo[4] = a4 + bsem[4];
        }
        return;
    }
    // phase E: y GEMMs from sH
    for (int half = 0; half < 2; ++half) {
        const f16x8* wyp = (const f16x8*)(half == 0 ? W1sP : W1dP);
        _Float16* outy = half == 0 ? ysp : ydp;
        f16x8 B[2][4];
#pragma unroll
        for (int nt = 0; nt < 2; ++nt)
#pragma unroll
            for (int ks = 0; ks < 4; ++ks)
                B[nt][ks] = wyp[((nt0 + nt) * 4 + ks) * 64 + lane];
        floatx4 yacc[4][2];
#pragma unroll
        for (int mt = 0; mt < 4; ++mt) { yacc[mt][0] = (floatx4){0,0,0,0}; yacc[mt][1] = (floatx4){0,0,0,0}; }
#pragma unroll
        for (int mt = 0; mt < 4; ++mt)
#pragma unroll
            for (int ks = 0; ks < 4; ++ks) {
                f16x8 a = *(const f16x8*)&sH[(mt * 16 + lcol) * PADM + ks * 32 + quad * 8];
                yacc[mt][0] = __builtin_amdgcn_mfma_f32_16x16x32_f16(a, B[0][ks], yacc[mt][0], 0, 0, 0);
                yacc[mt][1] = __builtin_amdgcn_mfma_f32_16x16x32_f16(a, B[1][ks], yacc[mt][1], 0, 0, 0);
            }
        __syncthreads();
#pragma unroll
        for (int mt = 0; mt < 4; ++mt)
#pragma unroll
            for (int r = 0; r < 4; ++r) {
                float v0 = yacc[mt][0][r], v1 = yacc[mt][1][r];
                float p0 = __shfl_xor(v0, 1), p1 = __shfl_xor(v1, 1);
                float av = odd ? p1 : v0, bv = odd ? v1 : p0;
                int col = nt0 * 16 + (odd ? 15 + lcol : lcol);
                *(uint*)&sA[(mt * 16 + quad * 4 + r) * PADM + col] = f2h2(av, bv);
            }
        __syncthreads();
        for (int i = t; i < 1024; i += 256) {
            int row = i >> 4, c = i & 15;
            int n = n0b + row;
            if (n < N_HITS) ((uint4*)(outy + (size_t)n * HD))[c] = *(uint4*)&sA[row * PADM + c * 8];
        }
    }
}

extern "C" void kernel_launch(void* const* d_in, const int* in_sizes, int n_in,
                              void* d_out, int out_size, void* d_ws, size_t ws_size,
                              hipStream_t stream) {
    const float* xu = (const float*)d_in[0];
    const int* eu = (const int*)d_in[1];
    const int* nu = (const int*)d_in[2];
    const float* xv = (const float*)d_in[3];
    const int* ev = (const int*)d_in[4];
    const int* nv = (const int*)d_in[5];
    const float* xy = (const float*)d_in[6];
    const int* ey = (const int*)d_in[7];
    const int* ny = (const int*)d_in[8];
    const float* W_enc = (const float*)d_in[9];
    const float* b_enc = (const float*)d_in[10];
    const float* W1 = (const float*)d_in[11];
    const float* b1 = (const float*)d_in[12];
    const float* W2 = (const float*)d_in[13];
    const float* b2 = (const float*)d_in[14];
    const float* W_upd = (const float*)d_in[15];
    const float* b_upd = (const float*)d_in[16];
    const float* W_sp = (const float*)d_in[17];
    const float* b_sp = (const float*)d_in[18];
    const float* W_nx = (const float*)d_in[19];
    const float* b_nx = (const float*)d_in[20];
    const float* W_sem = (const float*)d_in[21];
    const float* b_sem = (const float*)d_in[22];

    const size_t HN = (size_t)3 * N_HITS * HD;
    _Float16* h = (_Float16*)d_ws;                 // f16 [3][N_HITS][HD]
    _Float16* y_s = h + HN;                        // f16 [3][N_HITS][HD]
    _Float16* y_d = y_s + HN;                      // f16 [3][N_HITS][HD]
    _Float16* sp = y_d + HN;                       // f16 [N_SPS][HD]
    int* cnt = (int*)(sp + (size_t)N_SPS * HD);    // [270000]
    int* off = cnt + 270000;                       // [9*30001]
    int* cursor = off + 270009;                    // [270000]
    int* csr_e = cursor + 270000;                  // [3*90000]
    int* csr_s = csr_e + 270000;                   // [3*30000]
    int* csr_h = csr_s + 90000;                    // [3*30000]
    _Float16* packs = (_Float16*)(csr_h + 90000);  // [131072]
    _Float16* W1dP = packs;
    _Float16* W1sP = packs + 16384;
    _Float16* W2P = packs + 32768;
    _Float16* WuP = packs + 49152;
    _Float16* WnP = packs + 81920;
    _Float16* WspP = packs + 114688;

    wprep_kernel<<<512, 256, 0, stream>>>(W1, W2, W_upd, W_nx, W_sp, packs);
    (void)hipMemsetAsync(cnt, 0, 270000 * sizeof(int), stream);
    hist_all_kernel<<<(450000 + 255) / 256, 256, 0, stream>>>(eu, ev, ey, nu, nv, ny, cnt);
    scan_kernel<<<9, 1024, 0, stream>>>(cnt, off, cursor);
    fill_kernel<<<(450000 + 255) / 256, 256, 0, stream>>>(eu, ev, ey, nu, nv, ny,
                                                          cursor, csr_e, csr_s, csr_h);

    enc_y_kernel<<<(3 * N_HITS + 127) / 128, 256, 0, stream>>>(xu, xv, xy, W_enc, b_enc,
                                                               W1dP, W1sP, h, y_d, y_s);

    for (int it = 0; it < 3; ++it) {
        update_planar_kernel<<<dim3((N_HITS + 63) / 64, 3), 256, 0, stream>>>(
            h, y_d, y_s, off, csr_e, b1, W2P, b2, WuP, b_upd);
        sp_fused_kernel<<<(N_SPS + 63) / 64, 256, 0, stream>>>(h, off, csr_s, WspP, b_sp, sp);
        update_y_kernel<<<dim3((N_HITS + 63) / 64, 3), 256, 0, stream>>>(
            h, sp, off, csr_h, WnP, b_nx, W1dP, W1sP, y_d, y_s,
            W_sem, b_sem, (float*)d_out, it == 2 ? 1 : 0);
    }
}